// Round 1
// baseline (1110.030 us; speedup 1.0000x reference)
//
#include <hip/hip_runtime.h>
#include <hip/hip_bf16.h>

// ---------------------------------------------------------------------------
// QueryGuidedFusionNet forward on MI355X.
// Strategy: bf16 MFMA (16x16x32) for all matmuls, fp32 accum + fp32
// softmax/LN/residual epilogues. Round 0: direct-global-load GEMM, no LDS.
// ---------------------------------------------------------------------------

typedef __attribute__((ext_vector_type(8))) short short8;   // 8 bf16
typedef __attribute__((ext_vector_type(4))) float f32x4;

#define DEV static __device__ __forceinline__

DEV unsigned short f2bf(float f) {
    unsigned u = __float_as_uint(f);
    u += 0x7fffu + ((u >> 16) & 1u);          // RNE
    return (unsigned short)(u >> 16);
}

// ------------------------------ convert ------------------------------------
__global__ void k_cvt(const float* __restrict__ in, unsigned short* __restrict__ out, long n) {
    long i = ((long)blockIdx.x * blockDim.x + threadIdx.x) * 4;
    long stride = (long)gridDim.x * blockDim.x * 4;
    for (; i < n; i += stride) {
        if (i + 3 < n) {
            float4 v = *(const float4*)(in + i);
            ushort4 o;
            o.x = f2bf(v.x); o.y = f2bf(v.y); o.z = f2bf(v.z); o.w = f2bf(v.w);
            *(ushort4*)(out + i) = o;
        } else {
            for (long t = i; t < n; ++t) out[t] = f2bf(in[t]);
        }
    }
}

// ------------------------------ GEMM NT ------------------------------------
// C[m,n] = act( scale * sum_k A[m,k]*B[n,k] + bias[n] + res[m,n] )
// A bf16 [*,lda], B bf16 [N,ldb] row-major, batched via z -> (b = z/H, h = z%H)
template<bool GELU>
__global__ __launch_bounds__(256)
void k_gemm_nt(const unsigned short* __restrict__ A, const unsigned short* __restrict__ B,
               const float* __restrict__ bias, const float* __restrict__ res,
               float* __restrict__ outF, unsigned short* __restrict__ outB,
               int M, int N, int K, int lda, int ldb, int ldc,
               int H, long sAb, long sAh, long sBb, long sBh, long sCb, long sCh,
               float scale)
{
    int z = blockIdx.z;
    int b = z / H, h = z % H;
    const unsigned short* Ap = A + (long)b * sAb + (long)h * sAh;
    const unsigned short* Bp = B + (long)b * sBb + (long)h * sBh;
    long offC = (long)b * sCb + (long)h * sCh;

    int wid  = threadIdx.x >> 6;
    int lane = threadIdx.x & 63;
    int lrow = lane & 15;
    int kgrp = lane >> 4;

    int m_w = blockIdx.y * 128 + (wid >> 1) * 64;
    int n_w = blockIdx.x * 128 + (wid & 1) * 64;

    f32x4 acc[4][4] = {};

    for (int k0 = 0; k0 < K; k0 += 32) {
        int koff = k0 + kgrp * 8;
        short8 a[4], bb[4];
#pragma unroll
        for (int i = 0; i < 4; ++i) {
            int r = m_w + i * 16 + lrow; if (r > M - 1) r = M - 1;
            a[i] = *(const short8*)(Ap + (long)r * lda + koff);
        }
#pragma unroll
        for (int j = 0; j < 4; ++j) {
            int n = n_w + j * 16 + lrow; if (n > N - 1) n = N - 1;
            bb[j] = *(const short8*)(Bp + (long)n * ldb + koff);
        }
#pragma unroll
        for (int i = 0; i < 4; ++i)
#pragma unroll
            for (int j = 0; j < 4; ++j)
                acc[i][j] = __builtin_amdgcn_mfma_f32_16x16x32_bf16(a[i], bb[j], acc[i][j], 0, 0, 0);
    }

#pragma unroll
    for (int i = 0; i < 4; ++i) {
        int rbase = m_w + i * 16 + kgrp * 4;
#pragma unroll
        for (int j = 0; j < 4; ++j) {
            int c = n_w + j * 16 + lrow;
            if (c >= N) continue;
            float bv = bias ? bias[c] : 0.0f;
#pragma unroll
            for (int e = 0; e < 4; ++e) {
                int r = rbase + e;
                if (r >= M) continue;
                float v = acc[i][j][e] * scale + bv;
                long oidx = offC + (long)r * ldc + c;
                if (res) v += res[oidx];
                if (GELU) v = 0.5f * v * (1.0f + erff(v * 0.70710678118654752f));
                if (outF) outF[oidx] = v;
                if (outB) outB[oidx] = f2bf(v);
            }
        }
    }
}

// ------------------------------ GEMM NN ------------------------------------
// C[m,n] = sum_k A[m,k]*B[k,n].  A fp32 (probs), B bf16 row-major [K,ldb].
// M multiple of 64, N multiple of 64; K arbitrary (guarded).
__global__ __launch_bounds__(256)
void k_gemm_nn(const float* __restrict__ A, const unsigned short* __restrict__ B,
               float* __restrict__ outF, unsigned short* __restrict__ outB,
               int M, int N, int K, int lda, int ldb, int ldc,
               int H, long sAb, long sAh, long sBb, long sBh, long sCb, long sCh)
{
    int z = blockIdx.z;
    int b = z / H, h = z % H;
    const float* Ap = A + (long)b * sAb + (long)h * sAh;
    const unsigned short* Bp = B + (long)b * sBb + (long)h * sBh;
    long offC = (long)b * sCb + (long)h * sCh;

    int wid  = threadIdx.x >> 6;
    int lane = threadIdx.x & 63;
    int lrow = lane & 15;
    int kgrp = lane >> 4;

    int m_w = blockIdx.y * 64 + wid * 16;
    int n_w = blockIdx.x * 64;

    f32x4 acc[4] = {};

    for (int k0 = 0; k0 < K; k0 += 32) {
        int kbase = k0 + kgrp * 8;
        short8 a;
        const float* ap = Ap + (long)(m_w + lrow) * lda + kbase;
#pragma unroll
        for (int j = 0; j < 8; ++j) {
            float v = (kbase + j < K) ? ap[j] : 0.0f;
            a[j] = (short)f2bf(v);
        }
#pragma unroll
        for (int jn = 0; jn < 4; ++jn) {
            short8 bb;
            int n = n_w + jn * 16 + lrow;
#pragma unroll
            for (int j = 0; j < 8; ++j) {
                int k = kbase + j;
                bb[j] = (k < K) ? (short)Bp[(long)k * ldb + n] : (short)0;
            }
            acc[jn] = __builtin_amdgcn_mfma_f32_16x16x32_bf16(a, bb, acc[jn], 0, 0, 0);
        }
    }

#pragma unroll
    for (int jn = 0; jn < 4; ++jn) {
        int c = n_w + jn * 16 + lrow;
#pragma unroll
        for (int e = 0; e < 4; ++e) {
            int r = m_w + kgrp * 4 + e;
            long oidx = offC + (long)r * ldc + c;
            float v = acc[jn][e];
            if (outF) outF[oidx] = v;
            if (outB) outB[oidx] = f2bf(v);
        }
    }
}

// --------------------------- masked softmax --------------------------------
__global__ void k_softmax(float* __restrict__ sc, const int* __restrict__ mask,
                          int L, int rows_per_batch)
{
    int row = blockIdx.x;
    int b = row / rows_per_batch;
    float* p = sc + (long)row * L;
    const int* mrow = mask + (long)b * L;
    int t = threadIdx.x;
    __shared__ float red[256];

    float mx = -INFINITY;
    for (int j = t; j < L; j += 256) {
        float v = (mrow[j] != 0) ? p[j] : -INFINITY;
        mx = fmaxf(mx, v);
    }
    red[t] = mx; __syncthreads();
    for (int s = 128; s > 0; s >>= 1) { if (t < s) red[t] = fmaxf(red[t], red[t + s]); __syncthreads(); }
    mx = red[0]; __syncthreads();

    float sum = 0.f;
    for (int j = t; j < L; j += 256) {
        float v = (mrow[j] != 0) ? expf(p[j] - mx) : 0.0f;
        p[j] = v;
        sum += v;
    }
    red[t] = sum; __syncthreads();
    for (int s = 128; s > 0; s >>= 1) { if (t < s) red[t] += red[t + s]; __syncthreads(); }
    float inv = 1.0f / red[0];
    for (int j = t; j < L; j += 256) p[j] *= inv;
}

// ------------------------------ LayerNorm ----------------------------------
__global__ __launch_bounds__(256)
void k_ln(const float* __restrict__ x, const float* __restrict__ g, const float* __restrict__ bt,
          float* __restrict__ yf, unsigned short* __restrict__ yb)
{
    int row = blockIdx.x;
    const float* xr = x + (long)row * 1024;
    int t = threadIdx.x;
    float4 v = *(const float4*)(xr + t * 4);
    float s  = v.x + v.y + v.z + v.w;
    float ss = v.x * v.x + v.y * v.y + v.z * v.z + v.w * v.w;
    __shared__ float rs[256], rss[256];
    rs[t] = s; rss[t] = ss; __syncthreads();
    for (int d = 128; d > 0; d >>= 1) { if (t < d) { rs[t] += rs[t + d]; rss[t] += rss[t + d]; } __syncthreads(); }
    float mu  = rs[0]  * (1.0f / 1024.0f);
    float var = rss[0] * (1.0f / 1024.0f) - mu * mu;
    float inv = rsqrtf(var + 1e-5f);
    float xv[4] = { v.x, v.y, v.z, v.w };
#pragma unroll
    for (int e = 0; e < 4; ++e) {
        int c = t * 4 + e;
        float yv = (xv[e] - mu) * inv * g[c] + bt[c];
        yf[(long)row * 1024 + c] = yv;
        yb[(long)row * 1024 + c] = f2bf(yv);
    }
}

// ------------------------------ combine ------------------------------------
__global__ void k_combine(float* __restrict__ qf, unsigned short* __restrict__ qb,
                          const float* __restrict__ aggt, const float* __restrict__ aggr,
                          const float* __restrict__ alpha, long n)
{
    float a = *alpha;
    long i = (long)blockIdx.x * blockDim.x + threadIdx.x;
    long stride = (long)gridDim.x * blockDim.x;
    for (; i < n; i += stride) {
        float v = qf[i] + a * aggr[i] + (1.0f - a) * aggt[i];
        qf[i] = v;
        qb[i] = f2bf(v);
    }
}

// ---------------------------------------------------------------------------
extern "C" void kernel_launch(void* const* d_in, const int* in_sizes, int n_in,
                              void* d_out, int out_size, void* d_ws, size_t ws_size,
                              hipStream_t stream)
{
    const float* queries = (const float*)d_in[0];
    const float* text    = (const float*)d_in[1];
    const float* region  = (const float*)d_in[2];
    const int*   tmask   = (const int*)d_in[3];
    const int*   rmask   = (const int*)d_in[4];
    const float* w_qkv_t = (const float*)d_in[5];
    const float* b_qkv_t = (const float*)d_in[6];
    const float* w_o_t   = (const float*)d_in[7];
    const float* b_o_t   = (const float*)d_in[8];
    const float* w_qkv_r = (const float*)d_in[9];
    const float* b_qkv_r = (const float*)d_in[10];
    const float* w_o_r   = (const float*)d_in[11];
    const float* b_o_r   = (const float*)d_in[12];
    const float* ln_g    = (const float*)d_in[13];
    const float* ln_b    = (const float*)d_in[14];
    const float* w1      = (const float*)d_in[15];
    const float* b1      = (const float*)d_in[16];
    const float* w2      = (const float*)d_in[17];
    const float* b2      = (const float*)d_in[18];
    const float* alpha   = (const float*)d_in[19];

    const int Bn = 16, NQ = 128, LT = 512, LR = 196, D = 1024, H = 16;
    const int MQ = Bn * NQ;       // 2048
    const int MT = Bn * LT;       // 8192
    const int MR = Bn * LR;       // 3136

    // ---- workspace layout (bump allocator, 256B aligned) ----
    char* ws = (char*)d_ws;
    size_t off = 0;
    auto alloc = [&](size_t bytes) -> void* {
        void* p = ws + off;
        off = (off + bytes + 255) & ~(size_t)255;
        return p;
    };
    unsigned short* qb     = (unsigned short*)alloc((size_t)MQ * D * 2);
    unsigned short* tb     = (unsigned short*)alloc((size_t)MT * D * 2);
    unsigned short* rb     = (unsigned short*)alloc((size_t)MR * D * 2);
    unsigned short* wqkvtb = (unsigned short*)alloc((size_t)3 * D * D * 2);
    unsigned short* wotb   = (unsigned short*)alloc((size_t)D * D * 2);
    unsigned short* wqkvrb = (unsigned short*)alloc((size_t)3 * D * D * 2);
    unsigned short* worb   = (unsigned short*)alloc((size_t)D * D * 2);
    unsigned short* w1b    = (unsigned short*)alloc((size_t)4 * D * D * 2);
    unsigned short* w2b    = (unsigned short*)alloc((size_t)4 * D * D * 2);
    unsigned short* kt     = (unsigned short*)alloc((size_t)MT * D * 2);
    unsigned short* vt     = (unsigned short*)alloc((size_t)MT * D * 2);
    unsigned short* kr     = (unsigned short*)alloc((size_t)MR * D * 2);
    unsigned short* vr     = (unsigned short*)alloc((size_t)MR * D * 2);
    unsigned short* qp     = (unsigned short*)alloc((size_t)MQ * D * 2);
    unsigned short* ao     = (unsigned short*)alloc((size_t)MQ * D * 2);
    unsigned short* qlnb   = (unsigned short*)alloc((size_t)MQ * D * 2);
    float* xf   = (float*)alloc((size_t)MQ * D * 4);
    float* qlf  = (float*)alloc((size_t)MQ * D * 4);
    float* aggt = (float*)alloc((size_t)MQ * D * 4);
    float* aggr = (float*)alloc((size_t)MQ * D * 4);
    float* sc   = (float*)alloc((size_t)Bn * H * NQ * LT * 4);   // 67MB arena (reused)
    if (off > ws_size) return;   // insufficient scratch -> clean fail

    // arena views
    float* at  = sc;                                  // [B,NQ,LT] fp32
    float* ar  = sc + (size_t)Bn * NQ * LT;           // [B,NQ,LR] fp32
    unsigned short* hb = (unsigned short*)sc;         // FFN hidden bf16 (after attn)

    // ---- converts ----
    auto cvt = [&](const float* src, unsigned short* dst, long n) {
        int blocks = (int)((n / 4 + 255) / 256);
        if (blocks > 4096) blocks = 4096;
        k_cvt<<<blocks, 256, 0, stream>>>(src, dst, n);
    };
    cvt(queries, qb, (long)MQ * D);
    cvt(text,    tb, (long)MT * D);
    cvt(region,  rb, (long)MR * D);
    cvt(w_qkv_t, wqkvtb, (long)3 * D * D);
    cvt(w_o_t,   wotb,   (long)D * D);
    cvt(w_qkv_r, wqkvrb, (long)3 * D * D);
    cvt(w_o_r,   worb,   (long)D * D);
    cvt(w1,      w1b,    (long)4 * D * D);
    cvt(w2,      w2b,    (long)4 * D * D);

    auto NT = [&](const unsigned short* A, const unsigned short* Bm, const float* bias,
                  const float* res, float* oF, unsigned short* oB,
                  int M, int N, int K, int lda, int ldb, int ldc,
                  int Hh, long sAb, long sAh, long sBb, long sBh, long sCb, long sCh,
                  int batch, float scale, bool gelu) {
        dim3 g((N + 127) / 128, (M + 127) / 128, batch);
        if (gelu)
            k_gemm_nt<true><<<g, 256, 0, stream>>>(A, Bm, bias, res, oF, oB, M, N, K,
                lda, ldb, ldc, Hh, sAb, sAh, sBb, sBh, sCb, sCh, scale);
        else
            k_gemm_nt<false><<<g, 256, 0, stream>>>(A, Bm, bias, res, oF, oB, M, N, K,
                lda, ldb, ldc, Hh, sAb, sAh, sBb, sBh, sCb, sCh, scale);
    };
    auto NN = [&](const float* A, const unsigned short* Bm, float* oF, unsigned short* oB,
                  int M, int N, int K, int lda, int ldb, int ldc,
                  int Hh, long sAb, long sAh, long sBb, long sBh, long sCb, long sCh,
                  int batch) {
        dim3 g(N / 64, M / 64, batch);
        k_gemm_nn<<<g, 256, 0, stream>>>(A, Bm, oF, oB, M, N, K,
            lda, ldb, ldc, Hh, sAb, sAh, sBb, sBh, sCb, sCh);
    };

    // ---- K/V projections ----
    NT(tb, wqkvtb + (long)D * D,     b_qkv_t + D,     nullptr, nullptr, kt, MT, D, D, D, D, D, 1,0,0,0,0,0,0, 1, 1.0f, false);
    NT(tb, wqkvtb + (long)2 * D * D, b_qkv_t + 2 * D, nullptr, nullptr, vt, MT, D, D, D, D, D, 1,0,0,0,0,0,0, 1, 1.0f, false);
    NT(rb, wqkvrb + (long)D * D,     b_qkv_r + D,     nullptr, nullptr, kr, MR, D, D, D, D, D, 1,0,0,0,0,0,0, 1, 1.0f, false);
    NT(rb, wqkvrb + (long)2 * D * D, b_qkv_r + 2 * D, nullptr, nullptr, vr, MR, D, D, D, D, D, 1,0,0,0,0,0,0, 1, 1.0f, false);

    // ================= MHA 1 (text) =================
    NT(qb, wqkvtb, b_qkv_t, nullptr, nullptr, qp, MQ, D, D, D, D, D, 1,0,0,0,0,0,0, 1, 1.0f, false);
    // scores: per (b,h): qp[b,:,h*64:] . kt[b,:,h*64:]^T / 8
    NT(qp, kt, nullptr, nullptr, sc, nullptr, NQ, LT, 64, D, D, LT,
       H, (long)NQ * D, 64, (long)LT * D, 64, (long)H * NQ * LT, (long)NQ * LT,
       Bn * H, 0.125f, false);
    k_softmax<<<Bn * H * NQ, 256, 0, stream>>>(sc, tmask, LT, H * NQ);
    NN(sc, vt, nullptr, ao, NQ, 64, LT, LT, D, D,
       H, (long)H * NQ * LT, (long)NQ * LT, (long)LT * D, 64, (long)NQ * D, 64, Bn * H);
    NT(ao, wotb, b_o_t, queries, xf, nullptr, MQ, D, D, D, D, D, 1,0,0,0,0,0,0, 1, 1.0f, false);
    k_ln<<<MQ, 256, 0, stream>>>(xf, ln_g, ln_b, qlf, qlnb);

    // ================= MHA 2 (region) =================
    NT(qlnb, wqkvrb, b_qkv_r, nullptr, nullptr, qp, MQ, D, D, D, D, D, 1,0,0,0,0,0,0, 1, 1.0f, false);
    NT(qp, kr, nullptr, nullptr, sc, nullptr, NQ, LR, 64, D, D, LR,
       H, (long)NQ * D, 64, (long)LR * D, 64, (long)H * NQ * LR, (long)NQ * LR,
       Bn * H, 0.125f, false);
    k_softmax<<<Bn * H * NQ, 256, 0, stream>>>(sc, rmask, LR, H * NQ);
    NN(sc, vr, nullptr, ao, NQ, 64, LR, LR, D, D,
       H, (long)H * NQ * LR, (long)NQ * LR, (long)LR * D, 64, (long)NQ * D, 64, Bn * H);
    NT(ao, worb, b_o_r, qlf, xf, nullptr, MQ, D, D, D, D, D, 1,0,0,0,0,0,0, 1, 1.0f, false);
    k_ln<<<MQ, 256, 0, stream>>>(xf, ln_g, ln_b, qlf, qlnb);

    // ================= manual masked cross-attention =================
    // at = q . text^T / 32  (batched over b, H=1)
    NT(qlnb, tb, nullptr, nullptr, at, nullptr, NQ, LT, D, D, D, LT,
       1, (long)NQ * D, 0, (long)LT * D, 0, (long)NQ * LT, 0, Bn, 0.03125f, false);
    k_softmax<<<Bn * NQ, 256, 0, stream>>>(at, tmask, LT, NQ);
    NN(at, tb, aggt, nullptr, NQ, D, LT, LT, D, D,
       1, (long)NQ * LT, 0, (long)LT * D, 0, (long)NQ * D, 0, Bn);

    NT(qlnb, rb, nullptr, nullptr, ar, nullptr, NQ, LR, D, D, D, LR,
       1, (long)NQ * D, 0, (long)LR * D, 0, (long)NQ * LR, 0, Bn, 0.03125f, false);
    k_softmax<<<Bn * NQ, 256, 0, stream>>>(ar, rmask, LR, NQ);
    NN(ar, rb, aggr, nullptr, NQ, D, LR, LR, D, D,
       1, (long)NQ * LR, 0, (long)LR * D, 0, (long)NQ * D, 0, Bn);

    // q = q + alpha*agg_r + (1-alpha)*agg_t  (in place on qlf/qlnb)
    k_combine<<<2048, 256, 0, stream>>>(qlf, qlnb, aggt, aggr, alpha, (long)MQ * D);

    // ================= FFN =================
    NT(qlnb, w1b, b1, nullptr, nullptr, hb, MQ, 4 * D, D, D, D, 4 * D,
       1,0,0,0,0,0,0, 1, 1.0f, true);                       // GELU
    NT(hb, w2b, b2, qlf, (float*)d_out, nullptr, MQ, D, 4 * D, 4 * D, 4 * D, D,
       1,0,0,0,0,0,0, 1, 1.0f, false);
}

// Round 2
// 803.866 us; speedup vs baseline: 1.3809x; 1.3809x over previous
//
#include <hip/hip_runtime.h>
#include <hip/hip_bf16.h>

// ---------------------------------------------------------------------------
// QueryGuidedFusionNet forward on MI355X.
// Round 2: m97-structure LDS GEMM (128x128 tile, BK=64, global_load_lds w=16,
// XOR-swizzled LDS reads). All matmuls via bf16 MFMA NT path; NN GEMMs
// eliminated by transposing V/text/region; softmax writes bf16 P in-place.
// ---------------------------------------------------------------------------

typedef __attribute__((ext_vector_type(8))) short short8;   // 8 bf16
typedef __attribute__((ext_vector_type(4))) float f32x4;

#define DEV static __device__ __forceinline__

DEV unsigned short f2bf(float f) {
    unsigned u = __float_as_uint(f);
    u += 0x7fffu + ((u >> 16) & 1u);          // RNE
    return (unsigned short)(u >> 16);
}

// ------------------------------ convert ------------------------------------
__global__ void k_cvt(const float* __restrict__ in, unsigned short* __restrict__ out, long n) {
    long i = ((long)blockIdx.x * blockDim.x + threadIdx.x) * 4;
    long stride = (long)gridDim.x * blockDim.x * 4;
    for (; i < n; i += stride) {
        if (i + 3 < n) {
            float4 v = *(const float4*)(in + i);
            ushort4 o;
            o.x = f2bf(v.x); o.y = f2bf(v.y); o.z = f2bf(v.z); o.w = f2bf(v.w);
            *(ushort4*)(out + i) = o;
        } else {
            for (long t = i; t < n; ++t) out[t] = f2bf(in[t]);
        }
    }
}

// ------------------------------ GEMM NT (LDS) -------------------------------
// C[m,n] = act( scale * sum_k A[m,k]*B[n,k] + bias[n] + res[m,n] )
// A bf16 [*,lda], B bf16 [N,ldb], both k-contiguous. Batched via z=(b,h).
// 128x128 block tile, BK=64, 4 waves of 64x64. LDS: linear-dest
// global_load_lds staging with pre-swizzled source; ds_read with XOR swizzle
// byte ^= (row&7)<<4 (conflict-free for 128-B rows).
template<bool GELU>
__global__ __launch_bounds__(256)
void k_gemm_nt(const unsigned short* __restrict__ A, const unsigned short* __restrict__ B,
               const float* __restrict__ bias, const float* __restrict__ res,
               float* __restrict__ outF, unsigned short* __restrict__ outB,
               int M, int N, int K, int lda, int ldb, int ldc,
               int H, long sAb, long sAh, long sBb, long sBh, long sCb, long sCh,
               float scale)
{
    __shared__ unsigned short smem[2 * 128 * 64];   // A: 16KB, B: 16KB
    unsigned short* As = smem;
    unsigned short* Bs = smem + 128 * 64;

    int z = blockIdx.z;
    int b = z / H, h = z - b * H;
    const unsigned short* Ap = A + (long)b * sAb + (long)h * sAh;
    const unsigned short* Bp = B + (long)b * sBb + (long)h * sBh;
    long offC = (long)b * sCb + (long)h * sCh;

    int t    = threadIdx.x;
    int wid  = t >> 6;
    int lane = t & 63;
    int lrow = lane & 15;
    int kgrp = lane >> 4;

    int tm = blockIdx.y * 128;
    int tn = blockIdx.x * 128;
    int wm = (wid >> 1) * 64;
    int wn = (wid & 1) * 64;

    // staging geometry: per round r (0..3), this thread fills dest byte
    // d = r*4096 + t*16 of the operand tile; row = d>>7; source column is
    // the inverse swizzle of the within-row byte.
    int srow[4], scol[4];
#pragma unroll
    for (int r = 0; r < 4; ++r) {
        int d = r * 4096 + t * 16;
        int row = d >> 7;
        srow[r] = row;
        scol[r] = (((d & 127) ^ ((row & 7) << 4)) >> 1);
    }

    f32x4 acc[4][4] = {};
    const char* Ab = (const char*)As;
    const char* Bb = (const char*)Bs;

    for (int k0 = 0; k0 < K; k0 += 64) {
#pragma unroll
        for (int r = 0; r < 4; ++r) {
            int gr = tm + srow[r]; if (gr > M - 1) gr = M - 1;
            const unsigned short* srcA = Ap + (long)gr * lda + k0 + scol[r];
            unsigned short* dstA = As + (r * 2048 + wid * 512);
            __builtin_amdgcn_global_load_lds(
                (const __attribute__((address_space(1))) unsigned int*)srcA,
                (__attribute__((address_space(3))) unsigned int*)dstA, 16, 0, 0);
            int gn = tn + srow[r]; if (gn > N - 1) gn = N - 1;
            const unsigned short* srcB = Bp + (long)gn * ldb + k0 + scol[r];
            unsigned short* dstB = Bs + (r * 2048 + wid * 512);
            __builtin_amdgcn_global_load_lds(
                (const __attribute__((address_space(1))) unsigned int*)srcB,
                (__attribute__((address_space(3))) unsigned int*)dstB, 16, 0, 0);
        }
        __syncthreads();   // compiler emits vmcnt(0) drain before barrier

#pragma unroll
        for (int ks = 0; ks < 2; ++ks) {
            short8 a[4], bb[4];
#pragma unroll
            for (int i = 0; i < 4; ++i) {
                int row = wm + i * 16 + lrow;
                int kb = ks * 64 + kgrp * 16;
                a[i] = *(const short8*)(Ab + row * 128 + (kb ^ ((row & 7) << 4)));
            }
#pragma unroll
            for (int j = 0; j < 4; ++j) {
                int row = wn + j * 16 + lrow;
                int kb = ks * 64 + kgrp * 16;
                bb[j] = *(const short8*)(Bb + row * 128 + (kb ^ ((row & 7) << 4)));
            }
#pragma unroll
            for (int i = 0; i < 4; ++i)
#pragma unroll
                for (int j = 0; j < 4; ++j)
                    acc[i][j] = __builtin_amdgcn_mfma_f32_16x16x32_bf16(a[i], bb[j], acc[i][j], 0, 0, 0);
        }
        __syncthreads();
    }

#pragma unroll
    for (int i = 0; i < 4; ++i) {
        int rbase = tm + wm + i * 16 + kgrp * 4;
#pragma unroll
        for (int j = 0; j < 4; ++j) {
            int c = tn + wn + j * 16 + lrow;
            if (c >= N) continue;
            float bv = bias ? bias[c] : 0.0f;
#pragma unroll
            for (int e = 0; e < 4; ++e) {
                int r = rbase + e;
                if (r >= M) continue;
                float v = acc[i][j][e] * scale + bv;
                long oidx = offC + (long)r * ldc + c;
                if (res) v += res[oidx];
                if (GELU) v = 0.5f * v * (1.0f + erff(v * 0.70710678118654752f));
                if (outF) outF[oidx] = v;
                if (outB) outB[oidx] = f2bf(v);
            }
        }
    }
}

// ---------------------- tiled transpose (bf16) ------------------------------
// out[z][c][r] = (r < R) ? in[base(z) + r*ldin + c] : 0     (zero-pads rows)
// grid: (C/32, Rpad/32, Z), block 256.
__global__ __launch_bounds__(256)
void k_tr(const unsigned short* __restrict__ in, unsigned short* __restrict__ out,
          int R, int ldin, int ldout,
          int H, long sIb, long sIh, long sOz)
{
    __shared__ unsigned short tile[32][33];
    int z = blockIdx.z;
    int b = z / H, h = z - b * H;
    const unsigned short* ip = in + (long)b * sIb + (long)h * sIh;
    unsigned short* op = out + (long)z * sOz;
    int t = threadIdx.x;
    int cl = t & 31, rl = t >> 5;
    int c0 = blockIdx.x * 32, r0 = blockIdx.y * 32;
#pragma unroll
    for (int i = 0; i < 4; ++i) {
        int r = r0 + rl + i * 8;
        unsigned short v = 0;
        if (r < R) v = ip[(long)r * ldin + (c0 + cl)];
        tile[rl + i * 8][cl] = v;
    }
    __syncthreads();
#pragma unroll
    for (int i = 0; i < 4; ++i) {
        int orow = c0 + rl + i * 8;     // c-dim
        int ocol = r0 + cl;             // r-dim (padded)
        op[(long)orow * ldout + ocol] = tile[cl][rl + i * 8];
    }
}

// --------------------------- masked softmax ---------------------------------
// Reads fp32 scores row [L] (ld_sc), writes bf16 probabilities IN-PLACE over
// the same rows (ld_p elements), zero-filled out to Lpad. L <= 512.
__global__ __launch_bounds__(256)
void k_softmax_p(const float* __restrict__ sc, unsigned short* __restrict__ P,
                 const int* __restrict__ mask, int L, int Lpad,
                 int ld_sc, int ld_p, int rows_per_batch)
{
    int row = blockIdx.x;
    int b = row / rows_per_batch;
    const float* p = sc + (long)row * ld_sc;
    unsigned short* po = P + (long)row * ld_p;
    const int* mrow = mask + (long)b * L;
    int t = threadIdx.x;
    int lane = t & 63, wid = t >> 6;

    int j0 = t, j1 = t + 256;
    float v0 = -INFINITY, v1 = -INFINITY;
    if (j0 < L && mrow[j0] != 0) v0 = p[j0];
    if (j1 < L && mrow[j1] != 0) v1 = p[j1];

    float mx = fmaxf(v0, v1);
#pragma unroll
    for (int s = 32; s > 0; s >>= 1) mx = fmaxf(mx, __shfl_xor(mx, s, 64));
    __shared__ float wr[4], wsum[4];
    if (lane == 0) wr[wid] = mx;
    __syncthreads();
    mx = fmaxf(fmaxf(wr[0], wr[1]), fmaxf(wr[2], wr[3]));

    float e0 = (v0 == -INFINITY) ? 0.0f : __expf(v0 - mx);
    float e1 = (v1 == -INFINITY) ? 0.0f : __expf(v1 - mx);
    float sm = e0 + e1;
#pragma unroll
    for (int s = 32; s > 0; s >>= 1) sm += __shfl_xor(sm, s, 64);
    if (lane == 0) wsum[wid] = sm;
    __syncthreads();          // also orders: all score reads done before writes
    float inv = 1.0f / (wsum[0] + wsum[1] + wsum[2] + wsum[3]);

    if (j0 < Lpad) po[j0] = f2bf((j0 < L) ? e0 * inv : 0.0f);
    if (j1 < Lpad) po[j1] = f2bf((j1 < L) ? e1 * inv : 0.0f);
}

// ------------------------------ LayerNorm ----------------------------------
__global__ __launch_bounds__(256)
void k_ln(const float* __restrict__ x, const float* __restrict__ g, const float* __restrict__ bt,
          float* __restrict__ yf, unsigned short* __restrict__ yb)
{
    int row = blockIdx.x;
    const float* xr = x + (long)row * 1024;
    int t = threadIdx.x;
    int lane = t & 63, wid = t >> 6;
    float4 v = *(const float4*)(xr + t * 4);
    float s  = v.x + v.y + v.z + v.w;
    float ss = v.x * v.x + v.y * v.y + v.z * v.z + v.w * v.w;
#pragma unroll
    for (int d = 32; d > 0; d >>= 1) { s += __shfl_xor(s, d, 64); ss += __shfl_xor(ss, d, 64); }
    __shared__ float rs[4], rss[4];
    if (lane == 0) { rs[wid] = s; rss[wid] = ss; }
    __syncthreads();
    s  = rs[0] + rs[1] + rs[2] + rs[3];
    ss = rss[0] + rss[1] + rss[2] + rss[3];
    float mu  = s  * (1.0f / 1024.0f);
    float var = ss * (1.0f / 1024.0f) - mu * mu;
    float inv = rsqrtf(var + 1e-5f);
    float xv[4] = { v.x, v.y, v.z, v.w };
#pragma unroll
    for (int e = 0; e < 4; ++e) {
        int c = t * 4 + e;
        float yv = (xv[e] - mu) * inv * g[c] + bt[c];
        yf[(long)row * 1024 + c] = yv;
        yb[(long)row * 1024 + c] = f2bf(yv);
    }
}

// ------------------------------ combine ------------------------------------
__global__ void k_combine(float* __restrict__ qf, unsigned short* __restrict__ qb,
                          const float* __restrict__ aggt, const float* __restrict__ aggr,
                          const float* __restrict__ alpha, long n)
{
    float a = *alpha;
    long i = (long)blockIdx.x * blockDim.x + threadIdx.x;
    long stride = (long)gridDim.x * blockDim.x;
    for (; i < n; i += stride) {
        float v = qf[i] + a * aggr[i] + (1.0f - a) * aggt[i];
        qf[i] = v;
        qb[i] = f2bf(v);
    }
}

// ---------------------------------------------------------------------------
extern "C" void kernel_launch(void* const* d_in, const int* in_sizes, int n_in,
                              void* d_out, int out_size, void* d_ws, size_t ws_size,
                              hipStream_t stream)
{
    const float* queries = (const float*)d_in[0];
    const float* text    = (const float*)d_in[1];
    const float* region  = (const float*)d_in[2];
    const int*   tmask   = (const int*)d_in[3];
    const int*   rmask   = (const int*)d_in[4];
    const float* w_qkv_t = (const float*)d_in[5];
    const float* b_qkv_t = (const float*)d_in[6];
    const float* w_o_t   = (const float*)d_in[7];
    const float* b_o_t   = (const float*)d_in[8];
    const float* w_qkv_r = (const float*)d_in[9];
    const float* b_qkv_r = (const float*)d_in[10];
    const float* w_o_r   = (const float*)d_in[11];
    const float* b_o_r   = (const float*)d_in[12];
    const float* ln_g    = (const float*)d_in[13];
    const float* ln_b    = (const float*)d_in[14];
    const float* w1      = (const float*)d_in[15];
    const float* b1      = (const float*)d_in[16];
    const float* w2      = (const float*)d_in[17];
    const float* b2      = (const float*)d_in[18];
    const float* alpha   = (const float*)d_in[19];

    const int Bn = 16, NQ = 128, LT = 512, LR = 196, D = 1024, H = 16;
    const int LRp = 256;                 // region length padded to 64-multiple
    const int MQ = Bn * NQ;              // 2048
    const int MT = Bn * LT;              // 8192
    const int MR = Bn * LR;              // 3136

    char* ws = (char*)d_ws;
    size_t off = 0;
    auto alloc = [&](size_t bytes) -> void* {
        void* p = ws + off;
        off = (off + bytes + 255) & ~(size_t)255;
        return p;
    };
    unsigned short* qb     = (unsigned short*)alloc((size_t)MQ * D * 2);
    unsigned short* tb     = (unsigned short*)alloc((size_t)MT * D * 2);
    unsigned short* rb     = (unsigned short*)alloc((size_t)MR * D * 2);
    unsigned short* wqkvtb = (unsigned short*)alloc((size_t)3 * D * D * 2);
    unsigned short* wotb   = (unsigned short*)alloc((size_t)D * D * 2);
    unsigned short* wqkvrb = (unsigned short*)alloc((size_t)3 * D * D * 2);
    unsigned short* worb   = (unsigned short*)alloc((size_t)D * D * 2);
    unsigned short* w1b    = (unsigned short*)alloc((size_t)4 * D * D * 2);
    unsigned short* w2b    = (unsigned short*)alloc((size_t)4 * D * D * 2);
    unsigned short* kt     = (unsigned short*)alloc((size_t)MT * D * 2);  // reused as tbT
    unsigned short* vt     = (unsigned short*)alloc((size_t)MT * D * 2);  // reused as rbT
    unsigned short* kr     = (unsigned short*)alloc((size_t)MR * D * 2);
    unsigned short* vr     = (unsigned short*)alloc((size_t)MR * D * 2);
    unsigned short* vtT    = (unsigned short*)alloc((size_t)Bn * H * 64 * LT * 2);
    unsigned short* vrT    = (unsigned short*)alloc((size_t)Bn * H * 64 * LRp * 2);
    unsigned short* qp     = (unsigned short*)alloc((size_t)MQ * D * 2);
    unsigned short* ao     = (unsigned short*)alloc((size_t)MQ * D * 2);
    unsigned short* qlnb   = (unsigned short*)alloc((size_t)MQ * D * 2);
    float* xf   = (float*)alloc((size_t)MQ * D * 4);
    float* qlf  = (float*)alloc((size_t)MQ * D * 4);
    float* aggt = (float*)alloc((size_t)MQ * D * 4);
    float* aggr = (float*)alloc((size_t)MQ * D * 4);
    float* sc   = (float*)alloc((size_t)Bn * H * NQ * LT * 4);   // 67MB arena
    if (off > ws_size) return;

    unsigned short* tbT = kt;   // [B][1024][512]   (kt dead after MHA1 scores)
    unsigned short* rbT = vt;   // [B][1024][256p]  (vt dead after MHA1 PV)

    // arena views (phase-reused)
    float* sct = sc;                                   // MHA1 scores [z][128][512]
    float* scr = sc;                                   // MHA2 scores [z][128][256]
    float* at  = sc;                                   // manual text scores [b][128][512]
    float* ar  = sc + (size_t)Bn * NQ * LT;            // manual region scores [b][128][256]
    unsigned short* hb = (unsigned short*)sc;          // FFN hidden bf16

    auto cvt = [&](const float* src, unsigned short* dst, long n) {
        int blocks = (int)((n / 4 + 255) / 256);
        if (blocks > 4096) blocks = 4096;
        k_cvt<<<blocks, 256, 0, stream>>>(src, dst, n);
    };
    cvt(queries, qb, (long)MQ * D);
    cvt(text,    tb, (long)MT * D);
    cvt(region,  rb, (long)MR * D);
    cvt(w_qkv_t, wqkvtb, (long)3 * D * D);
    cvt(w_o_t,   wotb,   (long)D * D);
    cvt(w_qkv_r, wqkvrb, (long)3 * D * D);
    cvt(w_o_r,   worb,   (long)D * D);
    cvt(w1,      w1b,    (long)4 * D * D);
    cvt(w2,      w2b,    (long)4 * D * D);

    auto NT = [&](const unsigned short* A, const unsigned short* Bm, const float* bias,
                  const float* res, float* oF, unsigned short* oB,
                  int M, int N, int K, int lda, int ldb, int ldc,
                  int Hh, long sAb, long sAh, long sBb, long sBh, long sCb, long sCh,
                  int batch, float scale, bool gelu) {
        dim3 g((N + 127) / 128, (M + 127) / 128, batch);
        if (gelu)
            k_gemm_nt<true><<<g, 256, 0, stream>>>(A, Bm, bias, res, oF, oB, M, N, K,
                lda, ldb, ldc, Hh, sAb, sAh, sBb, sBh, sCb, sCh, scale);
        else
            k_gemm_nt<false><<<g, 256, 0, stream>>>(A, Bm, bias, res, oF, oB, M, N, K,
                lda, ldb, ldc, Hh, sAb, sAh, sBb, sBh, sCb, sCh, scale);
    };

    // ---- K/V projections ----
    NT(tb, wqkvtb + (long)D * D,     b_qkv_t + D,     nullptr, nullptr, kt, MT, D, D, D, D, D, 1,0,0,0,0,0,0, 1, 1.0f, false);
    NT(tb, wqkvtb + (long)2 * D * D, b_qkv_t + 2 * D, nullptr, nullptr, vt, MT, D, D, D, D, D, 1,0,0,0,0,0,0, 1, 1.0f, false);
    NT(rb, wqkvrb + (long)D * D,     b_qkv_r + D,     nullptr, nullptr, kr, MR, D, D, D, D, D, 1,0,0,0,0,0,0, 1, 1.0f, false);
    NT(rb, wqkvrb + (long)2 * D * D, b_qkv_r + 2 * D, nullptr, nullptr, vr, MR, D, D, D, D, D, 1,0,0,0,0,0,0, 1, 1.0f, false);

    // per-head V transposes: vtT[z][64][512], vrT[z][64][256p]
    {
        dim3 g1(64 / 32, LT / 32, Bn * H);
        k_tr<<<g1, 256, 0, stream>>>(vt, vtT, LT, D, LT, H, (long)LT * D, 64, (long)64 * LT);
        dim3 g2(64 / 32, LRp / 32, Bn * H);
        k_tr<<<g2, 256, 0, stream>>>(vr, vrT, LR, D, LRp, H, (long)LR * D, 64, (long)64 * LRp);
    }

    // ================= MHA 1 (text) =================
    NT(qb, wqkvtb, b_qkv_t, nullptr, nullptr, qp, MQ, D, D, D, D, D, 1,0,0,0,0,0,0, 1, 1.0f, false);
    NT(qp, kt, nullptr, nullptr, sct, nullptr, NQ, LT, 64, D, D, LT,
       H, (long)NQ * D, 64, (long)LT * D, 64, (long)H * NQ * LT, (long)NQ * LT,
       Bn * H, 0.125f, false);
    k_softmax_p<<<Bn * H * NQ, 256, 0, stream>>>(sct, (unsigned short*)sct, tmask,
                                                 LT, LT, LT, 2 * LT, H * NQ);
    // PV: A = P bf16 [z][128][512] (lda = 1024 elems over fp32 rows)
    NT((const unsigned short*)sct, vtT, nullptr, nullptr, nullptr, ao, NQ, 64, LT,
       2 * LT, LT, D,
       H, (long)H * NQ * 2 * LT, (long)NQ * 2 * LT, (long)64 * LT * H, (long)64 * LT,
       (long)NQ * D, 64, Bn * H, 1.0f, false);
    NT(ao, wotb, b_o_t, queries, xf, nullptr, MQ, D, D, D, D, D, 1,0,0,0,0,0,0, 1, 1.0f, false);
    k_ln<<<MQ, 256, 0, stream>>>(xf, ln_g, ln_b, qlf, qlnb);

    // ================= MHA 2 (region) =================
    NT(qlnb, wqkvrb, b_qkv_r, nullptr, nullptr, qp, MQ, D, D, D, D, D, 1,0,0,0,0,0,0, 1, 1.0f, false);
    NT(qp, kr, nullptr, nullptr, scr, nullptr, NQ, LR, 64, D, D, LRp,
       H, (long)NQ * D, 64, (long)LR * D, 64, (long)H * NQ * LRp, (long)NQ * LRp,
       Bn * H, 0.125f, false);
    k_softmax_p<<<Bn * H * NQ, 256, 0, stream>>>(scr, (unsigned short*)scr, rmask,
                                                 LR, LRp, LRp, 2 * LRp, H * NQ);
    NT((const unsigned short*)scr, vrT, nullptr, nullptr, nullptr, ao, NQ, 64, LRp,
       2 * LRp, LRp, D,
       H, (long)H * NQ * 2 * LRp, (long)NQ * 2 * LRp, (long)64 * LRp * H, (long)64 * LRp,
       (long)NQ * D, 64, Bn * H, 1.0f, false);
    NT(ao, worb, b_o_r, qlf, xf, nullptr, MQ, D, D, D, D, D, 1,0,0,0,0,0,0, 1, 1.0f, false);
    k_ln<<<MQ, 256, 0, stream>>>(xf, ln_g, ln_b, qlf, qlnb);

    // ================= manual masked cross-attention =================
    // feature transposes into now-dead buffers
    {
        dim3 g1(D / 32, LT / 32, Bn);
        k_tr<<<g1, 256, 0, stream>>>(tb, tbT, LT, D, LT, 1, (long)LT * D, 0, (long)D * LT);
        dim3 g2(D / 32, LRp / 32, Bn);
        k_tr<<<g2, 256, 0, stream>>>(rb, rbT, LR, D, LRp, 1, (long)LR * D, 0, (long)D * LRp);
    }
    // text branch
    NT(qlnb, tb, nullptr, nullptr, at, nullptr, NQ, LT, D, D, D, LT,
       1, (long)NQ * D, 0, (long)LT * D, 0, (long)NQ * LT, 0, Bn, 0.03125f, false);
    k_softmax_p<<<Bn * NQ, 256, 0, stream>>>(at, (unsigned short*)at, tmask,
                                             LT, LT, LT, 2 * LT, NQ);
    NT((const unsigned short*)at, tbT, nullptr, nullptr, aggt, nullptr, NQ, D, LT,
       2 * LT, LT, D,
       1, (long)NQ * 2 * LT, 0, (long)D * LT, 0, (long)NQ * D, 0, Bn, 1.0f, false);
    // region branch
    NT(qlnb, rb, nullptr, nullptr, ar, nullptr, NQ, LR, D, D, D, LRp,
       1, (long)NQ * D, 0, (long)LR * D, 0, (long)NQ * LRp, 0, Bn, 0.03125f, false);
    k_softmax_p<<<Bn * NQ, 256, 0, stream>>>(ar, (unsigned short*)ar, rmask,
                                             LR, LRp, LRp, 2 * LRp, NQ);
    NT((const unsigned short*)ar, rbT, nullptr, nullptr, aggr, nullptr, NQ, D, LRp,
       2 * LRp, LRp, D,
       1, (long)NQ * 2 * LRp, 0, (long)D * LRp, 0, (long)NQ * D, 0, Bn, 1.0f, false);

    k_combine<<<2048, 256, 0, stream>>>(qlf, qlnb, aggt, aggr, alpha, (long)MQ * D);

    // ================= FFN =================
    NT(qlnb, w1b, b1, nullptr, nullptr, hb, MQ, 4 * D, D, D, D, 4 * D,
       1,0,0,0,0,0,0, 1, 1.0f, true);
    NT(hb, w2b, b2, qlf, (float*)d_out, nullptr, MQ, D, 4 * D, 4 * D, 4 * D, D,
       1,0,0,0,0,0,0, 1, 1.0f, false);
}

// Round 3
// 682.730 us; speedup vs baseline: 1.6259x; 1.1774x over previous
//
#include <hip/hip_runtime.h>
#include <hip/hip_bf16.h>

// ---------------------------------------------------------------------------
// QueryGuidedFusionNet forward on MI355X.
// Round 3: double-buffered LDS GEMM (T3-minimum 2-phase pipeline: stage next
// tile BEFORE compute, one barrier per K-step), fused K+V projections.
// ---------------------------------------------------------------------------

typedef __attribute__((ext_vector_type(8))) short short8;   // 8 bf16
typedef __attribute__((ext_vector_type(4))) float f32x4;

#define DEV static __device__ __forceinline__

DEV unsigned short f2bf(float f) {
    unsigned u = __float_as_uint(f);
    u += 0x7fffu + ((u >> 16) & 1u);          // RNE
    return (unsigned short)(u >> 16);
}

// ------------------------------ convert ------------------------------------
__global__ void k_cvt(const float* __restrict__ in, unsigned short* __restrict__ out, long n) {
    long i = ((long)blockIdx.x * blockDim.x + threadIdx.x) * 4;
    long stride = (long)gridDim.x * blockDim.x * 4;
    for (; i < n; i += stride) {
        if (i + 3 < n) {
            float4 v = *(const float4*)(in + i);
            ushort4 o;
            o.x = f2bf(v.x); o.y = f2bf(v.y); o.z = f2bf(v.z); o.w = f2bf(v.w);
            *(ushort4*)(out + i) = o;
        } else {
            for (long t = i; t < n; ++t) out[t] = f2bf(in[t]);
        }
    }
}

// ------------------------------ GEMM NT (LDS, dbuf) -------------------------
// C[m,n] = act( scale * sum_k A[m,k]*B[n,k] + bias[n] + res[m,n] )
// A bf16 [*,lda], B bf16 [N,ldb], k-contiguous. Batched via z=(b,h).
// 128x128 tile, BK=64, 4 waves of 64x64. Double-buffered LDS; per K-step:
// issue next-tile global_load_lds, ds_read+MFMA current, one barrier.
template<bool GELU>
__global__ __launch_bounds__(256)
void k_gemm_nt(const unsigned short* __restrict__ A, const unsigned short* __restrict__ B,
               const float* __restrict__ bias, const float* __restrict__ res,
               float* __restrict__ outF, unsigned short* __restrict__ outB,
               int M, int N, int K, int lda, int ldb, int ldc,
               int H, long sAb, long sAh, long sBb, long sBh, long sCb, long sCh,
               float scale)
{
    __shared__ unsigned short smem[2 * 2 * 128 * 64];   // [buf][A|B][128][64] = 64KB

    int z = blockIdx.z;
    int b = z / H, h = z - b * H;
    const unsigned short* Ap = A + (long)b * sAb + (long)h * sAh;
    const unsigned short* Bp = B + (long)b * sBb + (long)h * sBh;
    long offC = (long)b * sCb + (long)h * sCh;

    int t    = threadIdx.x;
    int wid  = t >> 6;
    int lane = t & 63;
    int lrow = lane & 15;
    int kgrp = lane >> 4;

    int tm = blockIdx.y * 128;
    int tn = blockIdx.x * 128;
    int wm = (wid >> 1) * 64;
    int wn = (wid & 1) * 64;

    // staging geometry: round r fills tile dest byte d = r*4096 + t*16;
    // row = d>>7; source col = inverse-swizzle of within-row byte.
    int srow[4], scol[4];
#pragma unroll
    for (int r = 0; r < 4; ++r) {
        int d = r * 4096 + t * 16;
        int row = d >> 7;
        srow[r] = row;
        scol[r] = (((d & 127) ^ ((row & 7) << 4)) >> 1);
    }

    auto stage = [&](int buf, int k0) {
#pragma unroll
        for (int r = 0; r < 4; ++r) {
            int gr = tm + srow[r]; if (gr > M - 1) gr = M - 1;
            const unsigned short* srcA = Ap + (long)gr * lda + k0 + scol[r];
            unsigned short* dstA = smem + buf * 16384 + (r * 2048 + wid * 512);
            __builtin_amdgcn_global_load_lds(
                (const __attribute__((address_space(1))) unsigned int*)srcA,
                (__attribute__((address_space(3))) unsigned int*)dstA, 16, 0, 0);
            int gn = tn + srow[r]; if (gn > N - 1) gn = N - 1;
            const unsigned short* srcB = Bp + (long)gn * ldb + k0 + scol[r];
            unsigned short* dstB = smem + buf * 16384 + 8192 + (r * 2048 + wid * 512);
            __builtin_amdgcn_global_load_lds(
                (const __attribute__((address_space(1))) unsigned int*)srcB,
                (__attribute__((address_space(3))) unsigned int*)dstB, 16, 0, 0);
        }
    };

    f32x4 acc[4][4] = {};
    int nt = K >> 6;

    stage(0, 0);
    __syncthreads();                       // drain prologue loads

    for (int ti = 0; ti < nt; ++ti) {
        int cur = ti & 1;
        if (ti + 1 < nt) stage(cur ^ 1, (ti + 1) << 6);   // issue-early prefetch

        const char* Ab = (const char*)(smem + cur * 16384);
        const char* Bb = Ab + 16384;
#pragma unroll
        for (int ks = 0; ks < 2; ++ks) {
            short8 a[4], bb[4];
            int kb = ks * 64 + kgrp * 16;
#pragma unroll
            for (int i = 0; i < 4; ++i) {
                int row = wm + i * 16 + lrow;
                a[i] = *(const short8*)(Ab + row * 128 + (kb ^ ((row & 7) << 4)));
            }
#pragma unroll
            for (int j = 0; j < 4; ++j) {
                int row = wn + j * 16 + lrow;
                bb[j] = *(const short8*)(Bb + row * 128 + (kb ^ ((row & 7) << 4)));
            }
#pragma unroll
            for (int i = 0; i < 4; ++i)
#pragma unroll
                for (int j = 0; j < 4; ++j)
                    acc[i][j] = __builtin_amdgcn_mfma_f32_16x16x32_bf16(a[i], bb[j], acc[i][j], 0, 0, 0);
        }
        __syncthreads();    // drains this iter's prefetch (overlapped w/ MFMA)
    }

#pragma unroll
    for (int i = 0; i < 4; ++i) {
        int rbase = tm + wm + i * 16 + kgrp * 4;
#pragma unroll
        for (int j = 0; j < 4; ++j) {
            int c = tn + wn + j * 16 + lrow;
            if (c >= N) continue;
            float bv = bias ? bias[c] : 0.0f;
#pragma unroll
            for (int e = 0; e < 4; ++e) {
                int r = rbase + e;
                if (r >= M) continue;
                float v = acc[i][j][e] * scale + bv;
                long oidx = offC + (long)r * ldc + c;
                if (res) v += res[oidx];
                if (GELU) v = 0.5f * v * (1.0f + erff(v * 0.70710678118654752f));
                if (outF) outF[oidx] = v;
                if (outB) outB[oidx] = f2bf(v);
            }
        }
    }
}

// ---------------------- tiled transpose (bf16) ------------------------------
__global__ __launch_bounds__(256)
void k_tr(const unsigned short* __restrict__ in, unsigned short* __restrict__ out,
          int R, int ldin, int ldout,
          int H, long sIb, long sIh, long sOz)
{
    __shared__ unsigned short tile[32][33];
    int z = blockIdx.z;
    int b = z / H, h = z - b * H;
    const unsigned short* ip = in + (long)b * sIb + (long)h * sIh;
    unsigned short* op = out + (long)z * sOz;
    int t = threadIdx.x;
    int cl = t & 31, rl = t >> 5;
    int c0 = blockIdx.x * 32, r0 = blockIdx.y * 32;
#pragma unroll
    for (int i = 0; i < 4; ++i) {
        int r = r0 + rl + i * 8;
        unsigned short v = 0;
        if (r < R) v = ip[(long)r * ldin + (c0 + cl)];
        tile[rl + i * 8][cl] = v;
    }
    __syncthreads();
#pragma unroll
    for (int i = 0; i < 4; ++i) {
        int orow = c0 + rl + i * 8;
        int ocol = r0 + cl;
        op[(long)orow * ldout + ocol] = tile[cl][rl + i * 8];
    }
}

// --------------------------- masked softmax ---------------------------------
__global__ __launch_bounds__(256)
void k_softmax_p(const float* __restrict__ sc, unsigned short* __restrict__ P,
                 const int* __restrict__ mask, int L, int Lpad,
                 int ld_sc, int ld_p, int rows_per_batch)
{
    int row = blockIdx.x;
    int b = row / rows_per_batch;
    const float* p = sc + (long)row * ld_sc;
    unsigned short* po = P + (long)row * ld_p;
    const int* mrow = mask + (long)b * L;
    int t = threadIdx.x;
    int lane = t & 63, wid = t >> 6;

    int j0 = t, j1 = t + 256;
    float v0 = -INFINITY, v1 = -INFINITY;
    if (j0 < L && mrow[j0] != 0) v0 = p[j0];
    if (j1 < L && mrow[j1] != 0) v1 = p[j1];

    float mx = fmaxf(v0, v1);
#pragma unroll
    for (int s = 32; s > 0; s >>= 1) mx = fmaxf(mx, __shfl_xor(mx, s, 64));
    __shared__ float wr[4], wsum[4];
    if (lane == 0) wr[wid] = mx;
    __syncthreads();
    mx = fmaxf(fmaxf(wr[0], wr[1]), fmaxf(wr[2], wr[3]));

    float e0 = (v0 == -INFINITY) ? 0.0f : __expf(v0 - mx);
    float e1 = (v1 == -INFINITY) ? 0.0f : __expf(v1 - mx);
    float sm = e0 + e1;
#pragma unroll
    for (int s = 32; s > 0; s >>= 1) sm += __shfl_xor(sm, s, 64);
    if (lane == 0) wsum[wid] = sm;
    __syncthreads();          // also orders: score reads done before P writes
    float inv = 1.0f / (wsum[0] + wsum[1] + wsum[2] + wsum[3]);

    if (j0 < Lpad) po[j0] = f2bf((j0 < L) ? e0 * inv : 0.0f);
    if (j1 < Lpad) po[j1] = f2bf((j1 < L) ? e1 * inv : 0.0f);
}

// ------------------------------ LayerNorm ----------------------------------
__global__ __launch_bounds__(256)
void k_ln(const float* __restrict__ x, const float* __restrict__ g, const float* __restrict__ bt,
          float* __restrict__ yf, unsigned short* __restrict__ yb)
{
    int row = blockIdx.x;
    const float* xr = x + (long)row * 1024;
    int t = threadIdx.x;
    int lane = t & 63, wid = t >> 6;
    float4 v = *(const float4*)(xr + t * 4);
    float s  = v.x + v.y + v.z + v.w;
    float ss = v.x * v.x + v.y * v.y + v.z * v.z + v.w * v.w;
#pragma unroll
    for (int d = 32; d > 0; d >>= 1) { s += __shfl_xor(s, d, 64); ss += __shfl_xor(ss, d, 64); }
    __shared__ float rs[4], rss[4];
    if (lane == 0) { rs[wid] = s; rss[wid] = ss; }
    __syncthreads();
    s  = rs[0] + rs[1] + rs[2] + rs[3];
    ss = rss[0] + rss[1] + rss[2] + rss[3];
    float mu  = s  * (1.0f / 1024.0f);
    float var = ss * (1.0f / 1024.0f) - mu * mu;
    float inv = rsqrtf(var + 1e-5f);
    float xv[4] = { v.x, v.y, v.z, v.w };
#pragma unroll
    for (int e = 0; e < 4; ++e) {
        int c = t * 4 + e;
        float yv = (xv[e] - mu) * inv * g[c] + bt[c];
        yf[(long)row * 1024 + c] = yv;
        yb[(long)row * 1024 + c] = f2bf(yv);
    }
}

// ------------------------------ combine ------------------------------------
__global__ void k_combine(float* __restrict__ qf, unsigned short* __restrict__ qb,
                          const float* __restrict__ aggt, const float* __restrict__ aggr,
                          const float* __restrict__ alpha, long n)
{
    float a = *alpha;
    long i = (long)blockIdx.x * blockDim.x + threadIdx.x;
    long stride = (long)gridDim.x * blockDim.x;
    for (; i < n; i += stride) {
        float v = qf[i] + a * aggr[i] + (1.0f - a) * aggt[i];
        qf[i] = v;
        qb[i] = f2bf(v);
    }
}

// ---------------------------------------------------------------------------
extern "C" void kernel_launch(void* const* d_in, const int* in_sizes, int n_in,
                              void* d_out, int out_size, void* d_ws, size_t ws_size,
                              hipStream_t stream)
{
    const float* queries = (const float*)d_in[0];
    const float* text    = (const float*)d_in[1];
    const float* region  = (const float*)d_in[2];
    const int*   tmask   = (const int*)d_in[3];
    const int*   rmask   = (const int*)d_in[4];
    const float* w_qkv_t = (const float*)d_in[5];
    const float* b_qkv_t = (const float*)d_in[6];
    const float* w_o_t   = (const float*)d_in[7];
    const float* b_o_t   = (const float*)d_in[8];
    const float* w_qkv_r = (const float*)d_in[9];
    const float* b_qkv_r = (const float*)d_in[10];
    const float* w_o_r   = (const float*)d_in[11];
    const float* b_o_r   = (const float*)d_in[12];
    const float* ln_g    = (const float*)d_in[13];
    const float* ln_b    = (const float*)d_in[14];
    const float* w1      = (const float*)d_in[15];
    const float* b1      = (const float*)d_in[16];
    const float* w2      = (const float*)d_in[17];
    const float* b2      = (const float*)d_in[18];
    const float* alpha   = (const float*)d_in[19];

    const int Bn = 16, NQ = 128, LT = 512, LR = 196, D = 1024, H = 16;
    const int LRp = 256;
    const int MQ = Bn * NQ;              // 2048
    const int MT = Bn * LT;              // 8192
    const int MR = Bn * LR;              // 3136

    char* ws = (char*)d_ws;
    size_t off = 0;
    auto alloc = [&](size_t bytes) -> void* {
        void* p = ws + off;
        off = (off + bytes + 255) & ~(size_t)255;
        return p;
    };
    unsigned short* qb     = (unsigned short*)alloc((size_t)MQ * D * 2);
    unsigned short* tb     = (unsigned short*)alloc((size_t)MT * D * 2);
    unsigned short* rb     = (unsigned short*)alloc((size_t)MR * D * 2);
    unsigned short* wqkvtb = (unsigned short*)alloc((size_t)3 * D * D * 2);
    unsigned short* wotb   = (unsigned short*)alloc((size_t)D * D * 2);
    unsigned short* wqkvrb = (unsigned short*)alloc((size_t)3 * D * D * 2);
    unsigned short* worb   = (unsigned short*)alloc((size_t)D * D * 2);
    unsigned short* w1b    = (unsigned short*)alloc((size_t)4 * D * D * 2);
    unsigned short* w2b    = (unsigned short*)alloc((size_t)4 * D * D * 2);
    unsigned short* ktv    = (unsigned short*)alloc((size_t)MT * 2 * D * 2);  // [MT][2048]
    unsigned short* krv    = (unsigned short*)alloc((size_t)MR * 2 * D * 2);  // [MR][2048]
    unsigned short* vtT    = (unsigned short*)alloc((size_t)Bn * H * 64 * LT * 2);
    unsigned short* vrT    = (unsigned short*)alloc((size_t)Bn * H * 64 * LRp * 2);
    unsigned short* qp     = (unsigned short*)alloc((size_t)MQ * D * 2);
    unsigned short* ao     = (unsigned short*)alloc((size_t)MQ * D * 2);
    unsigned short* qlnb   = (unsigned short*)alloc((size_t)MQ * D * 2);
    float* xf   = (float*)alloc((size_t)MQ * D * 4);
    float* qlf  = (float*)alloc((size_t)MQ * D * 4);
    float* aggt = (float*)alloc((size_t)MQ * D * 4);
    float* aggr = (float*)alloc((size_t)MQ * D * 4);
    float* sc   = (float*)alloc((size_t)Bn * H * NQ * LT * 4);   // 67MB arena
    if (off > ws_size) return;

    // ktv(text) is dead after MHA1 scores + V-transpose -> reuse for tbT/rbT
    unsigned short* tbT = ktv;                               // [B][1024][512]
    unsigned short* rbT = ktv + (size_t)Bn * D * LT;         // [B][1024][256p]

    float* sct = sc;
    float* scr = sc;
    float* at  = sc;
    float* ar  = sc + (size_t)Bn * NQ * LT;
    unsigned short* hb = (unsigned short*)sc;

    auto cvt = [&](const float* src, unsigned short* dst, long n) {
        int blocks = (int)((n / 4 + 255) / 256);
        if (blocks > 4096) blocks = 4096;
        k_cvt<<<blocks, 256, 0, stream>>>(src, dst, n);
    };
    cvt(queries, qb, (long)MQ * D);
    cvt(text,    tb, (long)MT * D);
    cvt(region,  rb, (long)MR * D);
    cvt(w_qkv_t, wqkvtb, (long)3 * D * D);
    cvt(w_o_t,   wotb,   (long)D * D);
    cvt(w_qkv_r, wqkvrb, (long)3 * D * D);
    cvt(w_o_r,   worb,   (long)D * D);
    cvt(w1,      w1b,    (long)4 * D * D);
    cvt(w2,      w2b,    (long)4 * D * D);

    auto NT = [&](const unsigned short* A, const unsigned short* Bm, const float* bias,
                  const float* res, float* oF, unsigned short* oB,
                  int M, int N, int K, int lda, int ldb, int ldc,
                  int Hh, long sAb, long sAh, long sBb, long sBh, long sCb, long sCh,
                  int batch, float scale, bool gelu) {
        dim3 g((N + 127) / 128, (M + 127) / 128, batch);
        if (gelu)
            k_gemm_nt<true><<<g, 256, 0, stream>>>(A, Bm, bias, res, oF, oB, M, N, K,
                lda, ldb, ldc, Hh, sAb, sAh, sBb, sBh, sCb, sCh, scale);
        else
            k_gemm_nt<false><<<g, 256, 0, stream>>>(A, Bm, bias, res, oF, oB, M, N, K,
                lda, ldb, ldc, Hh, sAb, sAh, sBb, sBh, sCb, sCh, scale);
    };

    // ---- fused K+V projections: ktv[MT][2048], krv[MR][2048] ----
    NT(tb, wqkvtb + (long)D * D, b_qkv_t + D, nullptr, nullptr, ktv,
       MT, 2 * D, D, D, D, 2 * D, 1,0,0,0,0,0,0, 1, 1.0f, false);
    NT(rb, wqkvrb + (long)D * D, b_qkv_r + D, nullptr, nullptr, krv,
       MR, 2 * D, D, D, D, 2 * D, 1,0,0,0,0,0,0, 1, 1.0f, false);

    // per-head V transposes: vtT[z][64][512], vrT[z][64][256p]
    {
        dim3 g1(64 / 32, LT / 32, Bn * H);
        k_tr<<<g1, 256, 0, stream>>>(ktv + D, vtT, LT, 2 * D, LT,
                                     H, (long)LT * 2 * D, 64, (long)64 * LT);
        dim3 g2(64 / 32, LRp / 32, Bn * H);
        k_tr<<<g2, 256, 0, stream>>>(krv + D, vrT, LR, 2 * D, LRp,
                                     H, (long)LR * 2 * D, 64, (long)64 * LRp);
    }

    // ================= MHA 1 (text) =================
    NT(qb, wqkvtb, b_qkv_t, nullptr, nullptr, qp, MQ, D, D, D, D, D, 1,0,0,0,0,0,0, 1, 1.0f, false);
    NT(qp, ktv, nullptr, nullptr, sct, nullptr, NQ, LT, 64, D, 2 * D, LT,
       H, (long)NQ * D, 64, (long)LT * 2 * D, 64, (long)H * NQ * LT, (long)NQ * LT,
       Bn * H, 0.125f, false);
    k_softmax_p<<<Bn * H * NQ, 256, 0, stream>>>(sct, (unsigned short*)sct, tmask,
                                                 LT, LT, LT, 2 * LT, H * NQ);
    NT((const unsigned short*)sct, vtT, nullptr, nullptr, nullptr, ao, NQ, 64, LT,
       2 * LT, LT, D,
       H, (long)H * NQ * 2 * LT, (long)NQ * 2 * LT, (long)64 * LT * H, (long)64 * LT,
       (long)NQ * D, 64, Bn * H, 1.0f, false);
    NT(ao, wotb, b_o_t, queries, xf, nullptr, MQ, D, D, D, D, D, 1,0,0,0,0,0,0, 1, 1.0f, false);
    k_ln<<<MQ, 256, 0, stream>>>(xf, ln_g, ln_b, qlf, qlnb);

    // ================= MHA 2 (region) =================
    NT(qlnb, wqkvrb, b_qkv_r, nullptr, nullptr, qp, MQ, D, D, D, D, D, 1,0,0,0,0,0,0, 1, 1.0f, false);
    NT(qp, krv, nullptr, nullptr, scr, nullptr, NQ, LR, 64, D, 2 * D, LRp,
       H, (long)NQ * D, 64, (long)LR * 2 * D, 64, (long)H * NQ * LRp, (long)NQ * LRp,
       Bn * H, 0.125f, false);
    k_softmax_p<<<Bn * H * NQ, 256, 0, stream>>>(scr, (unsigned short*)scr, rmask,
                                                 LR, LRp, LRp, 2 * LRp, H * NQ);
    NT((const unsigned short*)scr, vrT, nullptr, nullptr, nullptr, ao, NQ, 64, LRp,
       2 * LRp, LRp, D,
       H, (long)H * NQ * 2 * LRp, (long)NQ * 2 * LRp, (long)64 * LRp * H, (long)64 * LRp,
       (long)NQ * D, 64, Bn * H, 1.0f, false);
    NT(ao, worb, b_o_r, qlf, xf, nullptr, MQ, D, D, D, D, D, 1,0,0,0,0,0,0, 1, 1.0f, false);
    k_ln<<<MQ, 256, 0, stream>>>(xf, ln_g, ln_b, qlf, qlnb);

    // ================= manual masked cross-attention =================
    {
        dim3 g1(D / 32, LT / 32, Bn);
        k_tr<<<g1, 256, 0, stream>>>(tb, tbT, LT, D, LT, 1, (long)LT * D, 0, (long)D * LT);
        dim3 g2(D / 32, LRp / 32, Bn);
        k_tr<<<g2, 256, 0, stream>>>(rb, rbT, LR, D, LRp, 1, (long)LR * D, 0, (long)D * LRp);
    }
    NT(qlnb, tb, nullptr, nullptr, at, nullptr, NQ, LT, D, D, D, LT,
       1, (long)NQ * D, 0, (long)LT * D, 0, (long)NQ * LT, 0, Bn, 0.03125f, false);
    k_softmax_p<<<Bn * NQ, 256, 0, stream>>>(at, (unsigned short*)at, tmask,
                                             LT, LT, LT, 2 * LT, NQ);
    NT((const unsigned short*)at, tbT, nullptr, nullptr, aggt, nullptr, NQ, D, LT,
       2 * LT, LT, D,
       1, (long)NQ * 2 * LT, 0, (long)D * LT, 0, (long)NQ * D, 0, Bn, 1.0f, false);

    NT(qlnb, rb, nullptr, nullptr, ar, nullptr, NQ, LR, D, D, D, LRp,
       1, (long)NQ * D, 0, (long)LR * D, 0, (long)NQ * LRp, 0, Bn, 0.03125f, false);
    k_softmax_p<<<Bn * NQ, 256, 0, stream>>>(ar, (unsigned short*)ar, rmask,
                                             LR, LRp, LRp, 2 * LRp, NQ);
    NT((const unsigned short*)ar, rbT, nullptr, nullptr, aggr, nullptr, NQ, D, LRp,
       2 * LRp, LRp, D,
       1, (long)NQ * 2 * LRp, 0, (long)D * LRp, 0, (long)NQ * D, 0, Bn, 1.0f, false);

    k_combine<<<2048, 256, 0, stream>>>(qlf, qlnb, aggt, aggr, alpha, (long)MQ * D);

    // ================= FFN =================
    NT(qlnb, w1b, b1, nullptr, nullptr, hb, MQ, 4 * D, D, D, D, 4 * D,
       1,0,0,0,0,0,0, 1, 1.0f, true);
    NT(hb, w2b, b2, qlf, (float*)d_out, nullptr, MQ, D, 4 * D, 4 * D, 4 * D, D,
       1,0,0,0,0,0,0, 1, 1.0f, false);
}

// Round 4
// 680.184 us; speedup vs baseline: 1.6320x; 1.0037x over previous
//
#include <hip/hip_runtime.h>
#include <hip/hip_bf16.h>

// ---------------------------------------------------------------------------
// QueryGuidedFusionNet forward on MI355X.
// Round 4: 5-buffer BK=32 counted-vmcnt pipeline (T3+T4), deterministic
// split-K + redux for skinny M=2048 GEMMs, XCD-chunked block swizzle (T1).
// ---------------------------------------------------------------------------

typedef __attribute__((ext_vector_type(8))) short short8;   // 8 bf16
typedef __attribute__((ext_vector_type(4))) float f32x4;

#define DEV static __device__ __forceinline__

DEV unsigned short f2bf(float f) {
    unsigned u = __float_as_uint(f);
    u += 0x7fffu + ((u >> 16) & 1u);          // RNE
    return (unsigned short)(u >> 16);
}

// ------------------------------ convert ------------------------------------
__global__ void k_cvt(const float* __restrict__ in, unsigned short* __restrict__ out, long n) {
    long i = ((long)blockIdx.x * blockDim.x + threadIdx.x) * 4;
    long stride = (long)gridDim.x * blockDim.x * 4;
    for (; i < n; i += stride) {
        if (i + 3 < n) {
            float4 v = *(const float4*)(in + i);
            ushort4 o;
            o.x = f2bf(v.x); o.y = f2bf(v.y); o.z = f2bf(v.z); o.w = f2bf(v.w);
            *(ushort4*)(out + i) = o;
        } else {
            for (long t = i; t < n; ++t) out[t] = f2bf(in[t]);
        }
    }
}

// ------------------------------ GEMM NT (pipelined) -------------------------
// C[m,n] = act( scale * sum_k A[m,k]*B[n,k] + bias[n] + res[m,n] )
// A bf16 [*,lda], B bf16 [N,ldb], k-contiguous. z decodes (batch,head,ksplit).
// 128x128 tile, BK=32, 4 waves of 64x64. 5 LDS buffers, prefetch depth 3,
// counted vmcnt (never drains to 0 in steady state), raw s_barrier.
// When S>1: K = chunk length, writes fp32 partial at outF + s*sPart (no
// bias/res/outB -- host passes null).
template<bool GELU>
__global__ __launch_bounds__(256)
void k_gemm_nt(const unsigned short* __restrict__ A, const unsigned short* __restrict__ B,
               const float* __restrict__ bias, const float* __restrict__ res,
               float* __restrict__ outF, unsigned short* __restrict__ outB,
               int M, int N, int K, int lda, int ldb, int ldc,
               int H, long sAb, long sAh, long sBb, long sBh, long sCb, long sCh,
               float scale, int S, long sPart)
{
    __shared__ unsigned short smem[5 * 8192];   // 5 bufs x (A 8KB + B 8KB) = 80KB

    // ---- XCD-chunked bijective swizzle (all grids are multiples of 8) ----
    unsigned gx = gridDim.x, gy = gridDim.y, gz = gridDim.z;
    unsigned nwg = gx * gy * gz;
    unsigned lin = (blockIdx.z * gy + blockIdx.y) * gx + blockIdx.x;
    unsigned bx = blockIdx.x, by = blockIdx.y, bz = blockIdx.z;
    if ((nwg & 7u) == 0u) {
        unsigned cpx = nwg >> 3;
        unsigned s = (lin & 7u) * cpx + (lin >> 3);
        bx = s % gx; unsigned r2 = s / gx;
        by = r2 % gy; bz = r2 / gy;
    }

    int zz = (int)bz;
    int s_k = 0;
    if (S > 1) { s_k = zz % S; zz /= S; }
    int b = zz / H, h = zz - b * H;
    const unsigned short* Ap = A + (long)b * sAb + (long)h * sAh + (long)s_k * K;
    const unsigned short* Bp = B + (long)b * sBb + (long)h * sBh + (long)s_k * K;
    float* outFp = outF;
    if (outFp && S > 1) outFp += (long)s_k * sPart;
    long offC = (long)b * sCb + (long)h * sCh;

    int t    = threadIdx.x;
    int wid  = t >> 6;
    int lane = t & 63;
    int lrow = lane & 15;
    int kgrp = lane >> 4;

    int tm = by * 128;
    int tn = bx * 128;
    int wm = (wid >> 1) * 64;
    int wn = (wid & 1) * 64;

    // stage: one BK=32 tile pair (A 8KB + B 8KB). 2 rounds x 2 loads per lane.
    // LDS dest linear; global source column pre-inverse-swizzled
    // (byte ^ ((row&3)<<4) within the 64B k-window).
    auto stage = [&](int buf, int k0) {
#pragma unroll
        for (int r = 0; r < 2; ++r) {
            int d = r * 4096 + t * 16;                 // byte in 8KB operand tile
            int row = d >> 6;
            int colb = (d & 63) ^ ((row & 3) << 4);    // source byte in k-window
            int gr = tm + row; if (gr > M - 1) gr = M - 1;
            const unsigned short* srcA = Ap + (long)gr * lda + k0 + (colb >> 1);
            unsigned short* dstA = smem + ((buf * 16384 + r * 4096 + wid * 1024) >> 1);
            __builtin_amdgcn_global_load_lds(
                (const __attribute__((address_space(1))) unsigned int*)srcA,
                (__attribute__((address_space(3))) unsigned int*)dstA, 16, 0, 0);
            int gn = tn + row; if (gn > N - 1) gn = N - 1;
            const unsigned short* srcB = Bp + (long)gn * ldb + k0 + (colb >> 1);
            unsigned short* dstB = smem + ((buf * 16384 + 8192 + r * 4096 + wid * 1024) >> 1);
            __builtin_amdgcn_global_load_lds(
                (const __attribute__((address_space(1))) unsigned int*)srcB,
                (__attribute__((address_space(3))) unsigned int*)dstB, 16, 0, 0);
        }
    };

    f32x4 acc[4][4] = {};
    int nt = K >> 5;

    for (int p = 0; p < 4 && p < nt; ++p) stage(p, p << 5);

    for (int ti = 0; ti < nt; ++ti) {
        int cur = ti % 5;
        int rem = nt - 1 - ti;     // stages allowed to stay outstanding
        if (rem >= 3)      asm volatile("s_waitcnt vmcnt(12)" ::: "memory");
        else if (rem == 2) asm volatile("s_waitcnt vmcnt(8)"  ::: "memory");
        else if (rem == 1) asm volatile("s_waitcnt vmcnt(4)"  ::: "memory");
        else               asm volatile("s_waitcnt vmcnt(0)"  ::: "memory");
        __builtin_amdgcn_sched_barrier(0);
        __builtin_amdgcn_s_barrier();
        __builtin_amdgcn_sched_barrier(0);

        if (ti + 4 < nt) stage((ti + 4) % 5, (ti + 4) << 5);

        const char* Ab = (const char*)smem + cur * 16384;
        const char* Bb = Ab + 8192;
        short8 a[4], bb[4];
#pragma unroll
        for (int i = 0; i < 4; ++i) {
            int row = wm + i * 16 + lrow;
            a[i] = *(const short8*)(Ab + row * 64 + ((kgrp * 16) ^ ((row & 3) << 4)));
        }
#pragma unroll
        for (int j = 0; j < 4; ++j) {
            int row = wn + j * 16 + lrow;
            bb[j] = *(const short8*)(Bb + row * 64 + ((kgrp * 16) ^ ((row & 3) << 4)));
        }
#pragma unroll
        for (int i = 0; i < 4; ++i)
#pragma unroll
            for (int j = 0; j < 4; ++j)
                acc[i][j] = __builtin_amdgcn_mfma_f32_16x16x32_bf16(a[i], bb[j], acc[i][j], 0, 0, 0);
    }

#pragma unroll
    for (int i = 0; i < 4; ++i) {
        int rbase = tm + wm + i * 16 + kgrp * 4;
#pragma unroll
        for (int j = 0; j < 4; ++j) {
            int c = tn + wn + j * 16 + lrow;
            if (c >= N) continue;
            float bv = bias ? bias[c] : 0.0f;
#pragma unroll
            for (int e = 0; e < 4; ++e) {
                int r = rbase + e;
                if (r >= M) continue;
                float v = acc[i][j][e] * scale + bv;
                long oidx = offC + (long)r * ldc + c;
                if (res) v += res[oidx];
                if (GELU) v = 0.5f * v * (1.0f + erff(v * 0.70710678118654752f));
                if (outFp) outFp[oidx] = v;
                if (outB) outB[oidx] = f2bf(v);
            }
        }
    }
}

// ------------------------------ split-K reduce -------------------------------
// out = act( sum_s part[s] + bias[c] + res ), vectorized x4.
__global__ __launch_bounds__(256)
void k_redux(const float* __restrict__ part, long sPart4, int S,
             const float* __restrict__ bias, const float* __restrict__ res,
             float* __restrict__ outF, unsigned short* __restrict__ outB,
             long n4, int ldc4, int gelu)
{
    const float4* p4 = (const float4*)part;
    long i = (long)blockIdx.x * blockDim.x + threadIdx.x;
    long stride = (long)gridDim.x * blockDim.x;
    for (; i < n4; i += stride) {
        int c = (int)(i % ldc4);
        float4 v = p4[i];
        for (int s = 1; s < S; ++s) {
            float4 w = p4[i + (long)s * sPart4];
            v.x += w.x; v.y += w.y; v.z += w.z; v.w += w.w;
        }
        if (bias) {
            float4 bv = ((const float4*)bias)[c];
            v.x += bv.x; v.y += bv.y; v.z += bv.z; v.w += bv.w;
        }
        if (res) {
            float4 rv = ((const float4*)res)[i];
            v.x += rv.x; v.y += rv.y; v.z += rv.z; v.w += rv.w;
        }
        if (gelu) {
            v.x = 0.5f * v.x * (1.0f + erff(v.x * 0.70710678118654752f));
            v.y = 0.5f * v.y * (1.0f + erff(v.y * 0.70710678118654752f));
            v.z = 0.5f * v.z * (1.0f + erff(v.z * 0.70710678118654752f));
            v.w = 0.5f * v.w * (1.0f + erff(v.w * 0.70710678118654752f));
        }
        if (outF) ((float4*)outF)[i] = v;
        if (outB) {
            ushort4 o;
            o.x = f2bf(v.x); o.y = f2bf(v.y); o.z = f2bf(v.z); o.w = f2bf(v.w);
            ((ushort4*)outB)[i] = o;
        }
    }
}

// ---------------------- tiled transpose (bf16) ------------------------------
__global__ __launch_bounds__(256)
void k_tr(const unsigned short* __restrict__ in, unsigned short* __restrict__ out,
          int R, int ldin, int ldout,
          int H, long sIb, long sIh, long sOz)
{
    __shared__ unsigned short tile[32][33];
    int z = blockIdx.z;
    int b = z / H, h = z - b * H;
    const unsigned short* ip = in + (long)b * sIb + (long)h * sIh;
    unsigned short* op = out + (long)z * sOz;
    int t = threadIdx.x;
    int cl = t & 31, rl = t >> 5;
    int c0 = blockIdx.x * 32, r0 = blockIdx.y * 32;
#pragma unroll
    for (int i = 0; i < 4; ++i) {
        int r = r0 + rl + i * 8;
        unsigned short v = 0;
        if (r < R) v = ip[(long)r * ldin + (c0 + cl)];
        tile[rl + i * 8][cl] = v;
    }
    __syncthreads();
#pragma unroll
    for (int i = 0; i < 4; ++i) {
        int orow = c0 + rl + i * 8;
        int ocol = r0 + cl;
        op[(long)orow * ldout + ocol] = tile[cl][rl + i * 8];
    }
}

// --------------------------- masked softmax ---------------------------------
__global__ __launch_bounds__(256)
void k_softmax_p(const float* __restrict__ sc, unsigned short* __restrict__ P,
                 const int* __restrict__ mask, int L, int Lpad,
                 int ld_sc, int ld_p, int rows_per_batch)
{
    int row = blockIdx.x;
    int b = row / rows_per_batch;
    const float* p = sc + (long)row * ld_sc;
    unsigned short* po = P + (long)row * ld_p;
    const int* mrow = mask + (long)b * L;
    int t = threadIdx.x;
    int lane = t & 63, wid = t >> 6;

    int j0 = t, j1 = t + 256;
    float v0 = -INFINITY, v1 = -INFINITY;
    if (j0 < L && mrow[j0] != 0) v0 = p[j0];
    if (j1 < L && mrow[j1] != 0) v1 = p[j1];

    float mx = fmaxf(v0, v1);
#pragma unroll
    for (int s = 32; s > 0; s >>= 1) mx = fmaxf(mx, __shfl_xor(mx, s, 64));
    __shared__ float wr[4], wsum[4];
    if (lane == 0) wr[wid] = mx;
    __syncthreads();
    mx = fmaxf(fmaxf(wr[0], wr[1]), fmaxf(wr[2], wr[3]));

    float e0 = (v0 == -INFINITY) ? 0.0f : __expf(v0 - mx);
    float e1 = (v1 == -INFINITY) ? 0.0f : __expf(v1 - mx);
    float sm = e0 + e1;
#pragma unroll
    for (int s = 32; s > 0; s >>= 1) sm += __shfl_xor(sm, s, 64);
    if (lane == 0) wsum[wid] = sm;
    __syncthreads();          // also orders: score reads done before P writes
    float inv = 1.0f / (wsum[0] + wsum[1] + wsum[2] + wsum[3]);

    if (j0 < Lpad) po[j0] = f2bf((j0 < L) ? e0 * inv : 0.0f);
    if (j1 < Lpad) po[j1] = f2bf((j1 < L) ? e1 * inv : 0.0f);
}

// ------------------------------ LayerNorm ----------------------------------
__global__ __launch_bounds__(256)
void k_ln(const float* __restrict__ x, const float* __restrict__ g, const float* __restrict__ bt,
          float* __restrict__ yf, unsigned short* __restrict__ yb)
{
    int row = blockIdx.x;
    const float* xr = x + (long)row * 1024;
    int t = threadIdx.x;
    int lane = t & 63, wid = t >> 6;
    float4 v = *(const float4*)(xr + t * 4);
    float s  = v.x + v.y + v.z + v.w;
    float ss = v.x * v.x + v.y * v.y + v.z * v.z + v.w * v.w;
#pragma unroll
    for (int d = 32; d > 0; d >>= 1) { s += __shfl_xor(s, d, 64); ss += __shfl_xor(ss, d, 64); }
    __shared__ float rs[4], rss[4];
    if (lane == 0) { rs[wid] = s; rss[wid] = ss; }
    __syncthreads();
    s  = rs[0] + rs[1] + rs[2] + rs[3];
    ss = rss[0] + rss[1] + rss[2] + rss[3];
    float mu  = s  * (1.0f / 1024.0f);
    float var = ss * (1.0f / 1024.0f) - mu * mu;
    float inv = rsqrtf(var + 1e-5f);
    float xv[4] = { v.x, v.y, v.z, v.w };
#pragma unroll
    for (int e = 0; e < 4; ++e) {
        int c = t * 4 + e;
        float yv = (xv[e] - mu) * inv * g[c] + bt[c];
        yf[(long)row * 1024 + c] = yv;
        yb[(long)row * 1024 + c] = f2bf(yv);
    }
}

// ------------------------------ combine ------------------------------------
__global__ void k_combine(float* __restrict__ qf, unsigned short* __restrict__ qb,
                          const float* __restrict__ aggt, const float* __restrict__ aggr,
                          const float* __restrict__ alpha, long n)
{
    float a = *alpha;
    long i = (long)blockIdx.x * blockDim.x + threadIdx.x;
    long stride = (long)gridDim.x * blockDim.x;
    for (; i < n; i += stride) {
        float v = qf[i] + a * aggr[i] + (1.0f - a) * aggt[i];
        qf[i] = v;
        qb[i] = f2bf(v);
    }
}

// ---------------------------------------------------------------------------
extern "C" void kernel_launch(void* const* d_in, const int* in_sizes, int n_in,
                              void* d_out, int out_size, void* d_ws, size_t ws_size,
                              hipStream_t stream)
{
    const float* queries = (const float*)d_in[0];
    const float* text    = (const float*)d_in[1];
    const float* region  = (const float*)d_in[2];
    const int*   tmask   = (const int*)d_in[3];
    const int*   rmask   = (const int*)d_in[4];
    const float* w_qkv_t = (const float*)d_in[5];
    const float* b_qkv_t = (const float*)d_in[6];
    const float* w_o_t   = (const float*)d_in[7];
    const float* b_o_t   = (const float*)d_in[8];
    const float* w_qkv_r = (const float*)d_in[9];
    const float* b_qkv_r = (const float*)d_in[10];
    const float* w_o_r   = (const float*)d_in[11];
    const float* b_o_r   = (const float*)d_in[12];
    const float* ln_g    = (const float*)d_in[13];
    const float* ln_b    = (const float*)d_in[14];
    const float* w1      = (const float*)d_in[15];
    const float* b1      = (const float*)d_in[16];
    const float* w2      = (const float*)d_in[17];
    const float* b2      = (const float*)d_in[18];
    const float* alpha   = (const float*)d_in[19];

    const int Bn = 16, NQ = 128, LT = 512, LR = 196, D = 1024, H = 16;
    const int LRp = 256;
    const int MQ = Bn * NQ;              // 2048
    const int MT = Bn * LT;              // 8192
    const int MR = Bn * LR;              // 3136

    char* ws = (char*)d_ws;
    size_t off = 0;
    auto alloc = [&](size_t bytes) -> void* {
        void* p = ws + off;
        off = (off + bytes + 255) & ~(size_t)255;
        return p;
    };
    unsigned short* qb     = (unsigned short*)alloc((size_t)MQ * D * 2);
    unsigned short* tb     = (unsigned short*)alloc((size_t)MT * D * 2);
    unsigned short* rb     = (unsigned short*)alloc((size_t)MR * D * 2);
    unsigned short* wqkvtb = (unsigned short*)alloc((size_t)3 * D * D * 2);
    unsigned short* wotb   = (unsigned short*)alloc((size_t)D * D * 2);
    unsigned short* wqkvrb = (unsigned short*)alloc((size_t)3 * D * D * 2);
    unsigned short* worb   = (unsigned short*)alloc((size_t)D * D * 2);
    unsigned short* w1b    = (unsigned short*)alloc((size_t)4 * D * D * 2);
    unsigned short* w2b    = (unsigned short*)alloc((size_t)4 * D * D * 2);
    unsigned short* ktv    = (unsigned short*)alloc((size_t)MT * 2 * D * 2);  // 64MB
    unsigned short* krv    = (unsigned short*)alloc((size_t)MR * 2 * D * 2);
    unsigned short* vtT    = (unsigned short*)alloc((size_t)Bn * H * 64 * LT * 2);
    unsigned short* vrT    = (unsigned short*)alloc((size_t)Bn * H * 64 * LRp * 2);
    unsigned short* qp     = (unsigned short*)alloc((size_t)MQ * D * 2);
    unsigned short* ao     = (unsigned short*)alloc((size_t)MQ * D * 2);
    unsigned short* qlnb   = (unsigned short*)alloc((size_t)MQ * D * 2);
    float* xf   = (float*)alloc((size_t)MQ * D * 4);
    float* qlf  = (float*)alloc((size_t)MQ * D * 4);
    float* aggt = (float*)alloc((size_t)MQ * D * 4);
    float* aggr = (float*)alloc((size_t)MQ * D * 4);
    float* sc   = (float*)alloc((size_t)Bn * H * NQ * LT * 4);   // 67MB arena
    if (off > ws_size) return;

    // phase-reused views
    unsigned short* tbT = ktv;                               // [B][1024][512]
    unsigned short* rbT = ktv + (size_t)Bn * D * LT;         // [B][1024][256p]
    float* sct = sc;
    float* scr = sc;
    float* at  = sc;
    float* ar  = sc + (size_t)Bn * NQ * LT;
    unsigned short* hb = (unsigned short*)sc;                // FFN hidden bf16 [0,16MB)
    float* part_q  = sc;                                     // 32MB: Q/O-proj partials
    float* part_f1 = (float*)ktv;                            // 64MB: FFN1 partials
    float* part_f2 = (float*)((char*)sc + (size_t)16 * 1024 * 1024);  // 32MB @ [16,48)

    const long PQ = (long)MQ * D;        // 2048*1024 partial slice

    auto cvt = [&](const float* src, unsigned short* dst, long n) {
        int blocks = (int)((n / 4 + 255) / 256);
        if (blocks > 4096) blocks = 4096;
        k_cvt<<<blocks, 256, 0, stream>>>(src, dst, n);
    };
    cvt(queries, qb, (long)MQ * D);
    cvt(text,    tb, (long)MT * D);
    cvt(region,  rb, (long)MR * D);
    cvt(w_qkv_t, wqkvtb, (long)3 * D * D);
    cvt(w_o_t,   wotb,   (long)D * D);
    cvt(w_qkv_r, wqkvrb, (long)3 * D * D);
    cvt(w_o_r,   worb,   (long)D * D);
    cvt(w1,      w1b,    (long)4 * D * D);
    cvt(w2,      w2b,    (long)4 * D * D);

    auto NT = [&](const unsigned short* A, const unsigned short* Bm, const float* bias,
                  const float* res, float* oF, unsigned short* oB,
                  int M, int N, int K, int lda, int ldb, int ldc,
                  int Hh, long sAb, long sAh, long sBb, long sBh, long sCb, long sCh,
                  int batch, float scale, bool gelu, int S = 1, long sPart = 0) {
        dim3 g((N + 127) / 128, (M + 127) / 128, batch * S);
        if (gelu)
            k_gemm_nt<true><<<g, 256, 0, stream>>>(A, Bm, bias, res, oF, oB, M, N, K,
                lda, ldb, ldc, Hh, sAb, sAh, sBb, sBh, sCb, sCh, scale, S, sPart);
        else
            k_gemm_nt<false><<<g, 256, 0, stream>>>(A, Bm, bias, res, oF, oB, M, N, K,
                lda, ldb, ldc, Hh, sAb, sAh, sBb, sBh, sCb, sCh, scale, S, sPart);
    };
    auto REDUX = [&](const float* part, long sPart, int S, const float* bias,
                     const float* res, float* oF, unsigned short* oB,
                     long total, int ldc, int gelu) {
        long n4 = total / 4;
        int blocks = (int)((n4 + 255) / 256);
        if (blocks > 2048) blocks = 2048;
        k_redux<<<blocks, 256, 0, stream>>>(part, sPart / 4, S, bias, res, oF, oB,
                                            n4, ldc / 4, gelu);
    };

    // ---- fused K+V projections: ktv[MT][2048], krv[MR][2048] ----
    NT(tb, wqkvtb + (long)D * D, b_qkv_t + D, nullptr, nullptr, ktv,
       MT, 2 * D, D, D, D, 2 * D, 1,0,0,0,0,0,0, 1, 1.0f, false);
    NT(rb, wqkvrb + (long)D * D, b_qkv_r + D, nullptr, nullptr, krv,
       MR, 2 * D, D, D, D, 2 * D, 1,0,0,0,0,0,0, 1, 1.0f, false);

    // per-head V transposes: vtT[z][64][512], vrT[z][64][256p]
    {
        dim3 g1(64 / 32, LT / 32, Bn * H);
        k_tr<<<g1, 256, 0, stream>>>(ktv + D, vtT, LT, 2 * D, LT,
                                     H, (long)LT * 2 * D, 64, (long)64 * LT);
        dim3 g2(64 / 32, LRp / 32, Bn * H);
        k_tr<<<g2, 256, 0, stream>>>(krv + D, vrT, LR, 2 * D, LRp,
                                     H, (long)LR * 2 * D, 64, (long)64 * LRp);
    }

    // ================= MHA 1 (text) =================
    // Q-proj split-K=4 (sc arena free until scores)
    NT(qb, wqkvtb, nullptr, nullptr, part_q, nullptr, MQ, D, 256, D, D, D,
       1,0,0,0,0,0,0, 1, 1.0f, false, 4, PQ);
    REDUX(part_q, PQ, 4, b_qkv_t, nullptr, nullptr, qp, PQ, D, 0);
    NT(qp, ktv, nullptr, nullptr, sct, nullptr, NQ, LT, 64, D, 2 * D, LT,
       H, (long)NQ * D, 64, (long)LT * 2 * D, 64, (long)H * NQ * LT, (long)NQ * LT,
       Bn * H, 0.125f, false);
    k_softmax_p<<<Bn * H * NQ, 256, 0, stream>>>(sct, (unsigned short*)sct, tmask,
                                                 LT, LT, LT, 2 * LT, H * NQ);
    NT((const unsigned short*)sct, vtT, nullptr, nullptr, nullptr, ao, NQ, 64, LT,
       2 * LT, LT, D,
       H, (long)H * NQ * 2 * LT, (long)NQ * 2 * LT, (long)64 * LT * H, (long)64 * LT,
       (long)NQ * D, 64, Bn * H, 1.0f, false);
    // O-proj split-K=4 (P-text dead after PV)
    NT(ao, wotb, nullptr, nullptr, part_q, nullptr, MQ, D, 256, D, D, D,
       1,0,0,0,0,0,0, 1, 1.0f, false, 4, PQ);
    REDUX(part_q, PQ, 4, b_o_t, queries, xf, nullptr, PQ, D, 0);
    k_ln<<<MQ, 256, 0, stream>>>(xf, ln_g, ln_b, qlf, qlnb);

    // ================= MHA 2 (region) =================
    NT(qlnb, wqkvrb, nullptr, nullptr, part_q, nullptr, MQ, D, 256, D, D, D,
       1,0,0,0,0,0,0, 1, 1.0f, false, 4, PQ);
    REDUX(part_q, PQ, 4, b_qkv_r, nullptr, nullptr, qp, PQ, D, 0);
    NT(qp, krv, nullptr, nullptr, scr, nullptr, NQ, LR, 64, D, 2 * D, LRp,
       H, (long)NQ * D, 64, (long)LR * 2 * D, 64, (long)H * NQ * LRp, (long)NQ * LRp,
       Bn * H, 0.125f, false);
    k_softmax_p<<<Bn * H * NQ, 256, 0, stream>>>(scr, (unsigned short*)scr, rmask,
                                                 LR, LRp, LRp, 2 * LRp, H * NQ);
    NT((const unsigned short*)scr, vrT, nullptr, nullptr, nullptr, ao, NQ, 64, LRp,
       2 * LRp, LRp, D,
       H, (long)H * NQ * 2 * LRp, (long)NQ * 2 * LRp, (long)64 * LRp * H, (long)64 * LRp,
       (long)NQ * D, 64, Bn * H, 1.0f, false);
    NT(ao, worb, nullptr, nullptr, part_q, nullptr, MQ, D, 256, D, D, D,
       1,0,0,0,0,0,0, 1, 1.0f, false, 4, PQ);
    REDUX(part_q, PQ, 4, b_o_r, qlf, xf, nullptr, PQ, D, 0);
    k_ln<<<MQ, 256, 0, stream>>>(xf, ln_g, ln_b, qlf, qlnb);

    // ================= manual masked cross-attention =================
    {
        dim3 g1(D / 32, LT / 32, Bn);
        k_tr<<<g1, 256, 0, stream>>>(tb, tbT, LT, D, LT, 1, (long)LT * D, 0, (long)D * LT);
        dim3 g2(D / 32, LRp / 32, Bn);
        k_tr<<<g2, 256, 0, stream>>>(rb, rbT, LR, D, LRp, 1, (long)LR * D, 0, (long)D * LRp);
    }
    NT(qlnb, tb, nullptr, nullptr, at, nullptr, NQ, LT, D, D, D, LT,
       1, (long)NQ * D, 0, (long)LT * D, 0, (long)NQ * LT, 0, Bn, 0.03125f, false);
    k_softmax_p<<<Bn * NQ, 256, 0, stream>>>(at, (unsigned short*)at, tmask,
                                             LT, LT, LT, 2 * LT, NQ);
    NT((const unsigned short*)at, tbT, nullptr, nullptr, aggt, nullptr, NQ, D, LT,
       2 * LT, LT, D,
       1, (long)NQ * 2 * LT, 0, (long)D * LT, 0, (long)NQ * D, 0, Bn, 1.0f, false);

    NT(qlnb, rb, nullptr, nullptr, ar, nullptr, NQ, LR, D, D, D, LRp,
       1, (long)NQ * D, 0, (long)LR * D, 0, (long)NQ * LRp, 0, Bn, 0.03125f, false);
    k_softmax_p<<<Bn * NQ, 256, 0, stream>>>(ar, (unsigned short*)ar, rmask,
                                             LR, LRp, LRp, 2 * LRp, NQ);
    NT((const unsigned short*)ar, rbT, nullptr, nullptr, aggr, nullptr, NQ, D, LRp,
       2 * LRp, LRp, D,
       1, (long)NQ * 2 * LRp, 0, (long)D * LRp, 0, (long)NQ * D, 0, Bn, 1.0f, false);

    k_combine<<<2048, 256, 0, stream>>>(qlf, qlnb, aggt, aggr, alpha, (long)MQ * D);

    // ================= FFN =================
    // FFN1 split-K=2, partials in ktv (tbT/rbT dead); GELU in redux -> hb
    NT(qlnb, w1b, nullptr, nullptr, part_f1, nullptr, MQ, 4 * D, 512, D, D, 4 * D,
       1,0,0,0,0,0,0, 1, 1.0f, false, 2, (long)MQ * 4 * D);
    REDUX(part_f1, (long)MQ * 4 * D, 2, b1, nullptr, nullptr, hb,
          (long)MQ * 4 * D, 4 * D, 1);
    // FFN2 split-K=4 (chunks of 1024), partials at sc+16MB (hb at sc[0,16MB))
    NT(hb, w2b, nullptr, nullptr, part_f2, nullptr, MQ, D, 1024, 4 * D, 4 * D, D,
       1,0,0,0,0,0,0, 1, 1.0f, false, 4, PQ);
    REDUX(part_f2, PQ, 4, b2, qlf, (float*)d_out, nullptr, PQ, D, 0);
}

// Round 5
// 661.328 us; speedup vs baseline: 1.6785x; 1.0285x over previous
//
#include <hip/hip_runtime.h>
#include <hip/hip_bf16.h>

// ---------------------------------------------------------------------------
// QueryGuidedFusionNet forward on MI355X.
// Round 5: fix LDS swizzle for 64B rows (swz=((row>>1)&3)<<4 -> 2-way=free),
// fuse all fp32->bf16 converts into one multi-tensor kernel.
// ---------------------------------------------------------------------------

typedef __attribute__((ext_vector_type(8))) short short8;   // 8 bf16
typedef __attribute__((ext_vector_type(4))) float f32x4;

#define DEV static __device__ __forceinline__

DEV unsigned short f2bf(float f) {
    unsigned u = __float_as_uint(f);
    u += 0x7fffu + ((u >> 16) & 1u);          // RNE
    return (unsigned short)(u >> 16);
}

// ------------------------- multi-tensor convert -----------------------------
struct CvtPack {
    const float* src[9];
    unsigned short* dst[9];
    long n[9];          // element counts, all multiples of 4
};

__global__ __launch_bounds__(256)
void k_cvt_multi(CvtPack p) {
    int ti = blockIdx.y;
    const float* in = p.src[ti];
    unsigned short* out = p.dst[ti];
    long n = p.n[ti];
    long i = ((long)blockIdx.x * blockDim.x + threadIdx.x) * 4;
    long stride = (long)gridDim.x * blockDim.x * 4;
    for (; i < n; i += stride) {
        float4 v = *(const float4*)(in + i);
        ushort4 o;
        o.x = f2bf(v.x); o.y = f2bf(v.y); o.z = f2bf(v.z); o.w = f2bf(v.w);
        *(ushort4*)(out + i) = o;
    }
}

// ------------------------------ GEMM NT (pipelined) -------------------------
// C[m,n] = act( scale * sum_k A[m,k]*B[n,k] + bias[n] + res[m,n] )
// A bf16 [*,lda], B bf16 [N,ldb], k-contiguous. z decodes (batch,head,ksplit).
// 128x128 tile, BK=32, 4 waves of 64x64. 5 LDS buffers, prefetch depth 3,
// counted vmcnt, raw s_barrier. LDS rows 64B; XOR swizzle ((row>>1)&3)<<4
// puts rows 0..7 in 8 distinct 16B bank-slots (2 lanes/bank = free).
template<bool GELU>
__global__ __launch_bounds__(256)
void k_gemm_nt(const unsigned short* __restrict__ A, const unsigned short* __restrict__ B,
               const float* __restrict__ bias, const float* __restrict__ res,
               float* __restrict__ outF, unsigned short* __restrict__ outB,
               int M, int N, int K, int lda, int ldb, int ldc,
               int H, long sAb, long sAh, long sBb, long sBh, long sCb, long sCh,
               float scale, int S, long sPart)
{
    __shared__ unsigned short smem[5 * 8192];   // 5 bufs x (A 8KB + B 8KB) = 80KB

    // ---- XCD-chunked bijective swizzle (all grids are multiples of 8) ----
    unsigned gx = gridDim.x, gy = gridDim.y, gz = gridDim.z;
    unsigned nwg = gx * gy * gz;
    unsigned lin = (blockIdx.z * gy + blockIdx.y) * gx + blockIdx.x;
    unsigned bx = blockIdx.x, by = blockIdx.y, bz = blockIdx.z;
    if ((nwg & 7u) == 0u) {
        unsigned cpx = nwg >> 3;
        unsigned s = (lin & 7u) * cpx + (lin >> 3);
        bx = s % gx; unsigned r2 = s / gx;
        by = r2 % gy; bz = r2 / gy;
    }

    int zz = (int)bz;
    int s_k = 0;
    if (S > 1) { s_k = zz % S; zz /= S; }
    int b = zz / H, h = zz - b * H;
    const unsigned short* Ap = A + (long)b * sAb + (long)h * sAh + (long)s_k * K;
    const unsigned short* Bp = B + (long)b * sBb + (long)h * sBh + (long)s_k * K;
    float* outFp = outF;
    if (outFp && S > 1) outFp += (long)s_k * sPart;
    long offC = (long)b * sCb + (long)h * sCh;

    int t    = threadIdx.x;
    int wid  = t >> 6;
    int lane = t & 63;
    int lrow = lane & 15;
    int kgrp = lane >> 4;

    int tm = by * 128;
    int tn = bx * 128;
    int wm = (wid >> 1) * 64;
    int wn = (wid & 1) * 64;

    // stage one BK=32 tile pair (A 8KB + B 8KB); LDS dest linear, global
    // source column pre-inverse-swizzled.
    auto stage = [&](int buf, int k0) {
#pragma unroll
        for (int r = 0; r < 2; ++r) {
            int d = r * 4096 + t * 16;                       // byte in 8KB tile
            int row = d >> 6;
            int colb = (d & 63) ^ (((row >> 1) & 3) << 4);   // src byte in k-window
            int gr = tm + row; if (gr > M - 1) gr = M - 1;
            const unsigned short* srcA = Ap + (long)gr * lda + k0 + (colb >> 1);
            unsigned short* dstA = smem + ((buf * 16384 + r * 4096 + wid * 1024) >> 1);
            __builtin_amdgcn_global_load_lds(
                (const __attribute__((address_space(1))) unsigned int*)srcA,
                (__attribute__((address_space(3))) unsigned int*)dstA, 16, 0, 0);
            int gn = tn + row; if (gn > N - 1) gn = N - 1;
            const unsigned short* srcB = Bp + (long)gn * ldb + k0 + (colb >> 1);
            unsigned short* dstB = smem + ((buf * 16384 + 8192 + r * 4096 + wid * 1024) >> 1);
            __builtin_amdgcn_global_load_lds(
                (const __attribute__((address_space(1))) unsigned int*)srcB,
                (__attribute__((address_space(3))) unsigned int*)dstB, 16, 0, 0);
        }
    };

    f32x4 acc[4][4] = {};
    int nt = K >> 5;

    for (int p = 0; p < 4 && p < nt; ++p) stage(p, p << 5);

    for (int ti = 0; ti < nt; ++ti) {
        int cur = ti % 5;
        int rem = nt - 1 - ti;     // stages allowed to stay outstanding
        if (rem >= 3)      asm volatile("s_waitcnt vmcnt(12)" ::: "memory");
        else if (rem == 2) asm volatile("s_waitcnt vmcnt(8)"  ::: "memory");
        else if (rem == 1) asm volatile("s_waitcnt vmcnt(4)"  ::: "memory");
        else               asm volatile("s_waitcnt vmcnt(0)"  ::: "memory");
        __builtin_amdgcn_sched_barrier(0);
        __builtin_amdgcn_s_barrier();
        __builtin_amdgcn_sched_barrier(0);

        if (ti + 4 < nt) stage((ti + 4) % 5, (ti + 4) << 5);

        const char* Ab = (const char*)smem + cur * 16384;
        const char* Bb = Ab + 8192;
        short8 a[4], bb[4];
#pragma unroll
        for (int i = 0; i < 4; ++i) {
            int row = wm + i * 16 + lrow;
            a[i] = *(const short8*)(Ab + row * 64 + ((kgrp * 16) ^ (((row >> 1) & 3) << 4)));
        }
#pragma unroll
        for (int j = 0; j < 4; ++j) {
            int row = wn + j * 16 + lrow;
            bb[j] = *(const short8*)(Bb + row * 64 + ((kgrp * 16) ^ (((row >> 1) & 3) << 4)));
        }
#pragma unroll
        for (int i = 0; i < 4; ++i)
#pragma unroll
            for (int j = 0; j < 4; ++j)
                acc[i][j] = __builtin_amdgcn_mfma_f32_16x16x32_bf16(a[i], bb[j], acc[i][j], 0, 0, 0);
    }

#pragma unroll
    for (int i = 0; i < 4; ++i) {
        int rbase = tm + wm + i * 16 + kgrp * 4;
#pragma unroll
        for (int j = 0; j < 4; ++j) {
            int c = tn + wn + j * 16 + lrow;
            if (c >= N) continue;
            float bv = bias ? bias[c] : 0.0f;
#pragma unroll
            for (int e = 0; e < 4; ++e) {
                int r = rbase + e;
                if (r >= M) continue;
                float v = acc[i][j][e] * scale + bv;
                long oidx = offC + (long)r * ldc + c;
                if (res) v += res[oidx];
                if (GELU) v = 0.5f * v * (1.0f + erff(v * 0.70710678118654752f));
                if (outFp) outFp[oidx] = v;
                if (outB) outB[oidx] = f2bf(v);
            }
        }
    }
}

// ------------------------------ split-K reduce -------------------------------
__global__ __launch_bounds__(256)
void k_redux(const float* __restrict__ part, long sPart4, int S,
             const float* __restrict__ bias, const float* __restrict__ res,
             float* __restrict__ outF, unsigned short* __restrict__ outB,
             long n4, int ldc4, int gelu)
{
    const float4* p4 = (const float4*)part;
    long i = (long)blockIdx.x * blockDim.x + threadIdx.x;
    long stride = (long)gridDim.x * blockDim.x;
    for (; i < n4; i += stride) {
        int c = (int)(i % ldc4);
        float4 v = p4[i];
        for (int s = 1; s < S; ++s) {
            float4 w = p4[i + (long)s * sPart4];
            v.x += w.x; v.y += w.y; v.z += w.z; v.w += w.w;
        }
        if (bias) {
            float4 bv = ((const float4*)bias)[c];
            v.x += bv.x; v.y += bv.y; v.z += bv.z; v.w += bv.w;
        }
        if (res) {
            float4 rv = ((const float4*)res)[i];
            v.x += rv.x; v.y += rv.y; v.z += rv.z; v.w += rv.w;
        }
        if (gelu) {
            v.x = 0.5f * v.x * (1.0f + erff(v.x * 0.70710678118654752f));
            v.y = 0.5f * v.y * (1.0f + erff(v.y * 0.70710678118654752f));
            v.z = 0.5f * v.z * (1.0f + erff(v.z * 0.70710678118654752f));
            v.w = 0.5f * v.w * (1.0f + erff(v.w * 0.70710678118654752f));
        }
        if (outF) ((float4*)outF)[i] = v;
        if (outB) {
            ushort4 o;
            o.x = f2bf(v.x); o.y = f2bf(v.y); o.z = f2bf(v.z); o.w = f2bf(v.w);
            ((ushort4*)outB)[i] = o;
        }
    }
}

// ---------------------- tiled transpose (bf16) ------------------------------
__global__ __launch_bounds__(256)
void k_tr(const unsigned short* __restrict__ in, unsigned short* __restrict__ out,
          int R, int ldin, int ldout,
          int H, long sIb, long sIh, long sOz)
{
    __shared__ unsigned short tile[32][33];
    int z = blockIdx.z;
    int b = z / H, h = z - b * H;
    const unsigned short* ip = in + (long)b * sIb + (long)h * sIh;
    unsigned short* op = out + (long)z * sOz;
    int t = threadIdx.x;
    int cl = t & 31, rl = t >> 5;
    int c0 = blockIdx.x * 32, r0 = blockIdx.y * 32;
#pragma unroll
    for (int i = 0; i < 4; ++i) {
        int r = r0 + rl + i * 8;
        unsigned short v = 0;
        if (r < R) v = ip[(long)r * ldin + (c0 + cl)];
        tile[rl + i * 8][cl] = v;
    }
    __syncthreads();
#pragma unroll
    for (int i = 0; i < 4; ++i) {
        int orow = c0 + rl + i * 8;
        int ocol = r0 + cl;
        op[(long)orow * ldout + ocol] = tile[cl][rl + i * 8];
    }
}

// --------------------------- masked softmax ---------------------------------
__global__ __launch_bounds__(256)
void k_softmax_p(const float* __restrict__ sc, unsigned short* __restrict__ P,
                 const int* __restrict__ mask, int L, int Lpad,
                 int ld_sc, int ld_p, int rows_per_batch)
{
    int row = blockIdx.x;
    int b = row / rows_per_batch;
    const float* p = sc + (long)row * ld_sc;
    unsigned short* po = P + (long)row * ld_p;
    const int* mrow = mask + (long)b * L;
    int t = threadIdx.x;
    int lane = t & 63, wid = t >> 6;

    int j0 = t, j1 = t + 256;
    float v0 = -INFINITY, v1 = -INFINITY;
    if (j0 < L && mrow[j0] != 0) v0 = p[j0];
    if (j1 < L && mrow[j1] != 0) v1 = p[j1];

    float mx = fmaxf(v0, v1);
#pragma unroll
    for (int s = 32; s > 0; s >>= 1) mx = fmaxf(mx, __shfl_xor(mx, s, 64));
    __shared__ float wr[4], wsum[4];
    if (lane == 0) wr[wid] = mx;
    __syncthreads();
    mx = fmaxf(fmaxf(wr[0], wr[1]), fmaxf(wr[2], wr[3]));

    float e0 = (v0 == -INFINITY) ? 0.0f : __expf(v0 - mx);
    float e1 = (v1 == -INFINITY) ? 0.0f : __expf(v1 - mx);
    float sm = e0 + e1;
#pragma unroll
    for (int s = 32; s > 0; s >>= 1) sm += __shfl_xor(sm, s, 64);
    if (lane == 0) wsum[wid] = sm;
    __syncthreads();          // also orders: score reads done before P writes
    float inv = 1.0f / (wsum[0] + wsum[1] + wsum[2] + wsum[3]);

    if (j0 < Lpad) po[j0] = f2bf((j0 < L) ? e0 * inv : 0.0f);
    if (j1 < Lpad) po[j1] = f2bf((j1 < L) ? e1 * inv : 0.0f);
}

// ------------------------------ LayerNorm ----------------------------------
__global__ __launch_bounds__(256)
void k_ln(const float* __restrict__ x, const float* __restrict__ g, const float* __restrict__ bt,
          float* __restrict__ yf, unsigned short* __restrict__ yb)
{
    int row = blockIdx.x;
    const float* xr = x + (long)row * 1024;
    int t = threadIdx.x;
    int lane = t & 63, wid = t >> 6;
    float4 v = *(const float4*)(xr + t * 4);
    float s  = v.x + v.y + v.z + v.w;
    float ss = v.x * v.x + v.y * v.y + v.z * v.z + v.w * v.w;
#pragma unroll
    for (int d = 32; d > 0; d >>= 1) { s += __shfl_xor(s, d, 64); ss += __shfl_xor(ss, d, 64); }
    __shared__ float rs[4], rss[4];
    if (lane == 0) { rs[wid] = s; rss[wid] = ss; }
    __syncthreads();
    s  = rs[0] + rs[1] + rs[2] + rs[3];
    ss = rss[0] + rss[1] + rss[2] + rss[3];
    float mu  = s  * (1.0f / 1024.0f);
    float var = ss * (1.0f / 1024.0f) - mu * mu;
    float inv = rsqrtf(var + 1e-5f);
    float xv[4] = { v.x, v.y, v.z, v.w };
#pragma unroll
    for (int e = 0; e < 4; ++e) {
        int c = t * 4 + e;
        float yv = (xv[e] - mu) * inv * g[c] + bt[c];
        yf[(long)row * 1024 + c] = yv;
        yb[(long)row * 1024 + c] = f2bf(yv);
    }
}

// ------------------------------ combine ------------------------------------
__global__ void k_combine(float* __restrict__ qf, unsigned short* __restrict__ qb,
                          const float* __restrict__ aggt, const float* __restrict__ aggr,
                          const float* __restrict__ alpha, long n)
{
    float a = *alpha;
    long i = (long)blockIdx.x * blockDim.x + threadIdx.x;
    long stride = (long)gridDim.x * blockDim.x;
    for (; i < n; i += stride) {
        float v = qf[i] + a * aggr[i] + (1.0f - a) * aggt[i];
        qf[i] = v;
        qb[i] = f2bf(v);
    }
}

// ---------------------------------------------------------------------------
extern "C" void kernel_launch(void* const* d_in, const int* in_sizes, int n_in,
                              void* d_out, int out_size, void* d_ws, size_t ws_size,
                              hipStream_t stream)
{
    const float* queries = (const float*)d_in[0];
    const float* text    = (const float*)d_in[1];
    const float* region  = (const float*)d_in[2];
    const int*   tmask   = (const int*)d_in[3];
    const int*   rmask   = (const int*)d_in[4];
    const float* w_qkv_t = (const float*)d_in[5];
    const float* b_qkv_t = (const float*)d_in[6];
    const float* w_o_t   = (const float*)d_in[7];
    const float* b_o_t   = (const float*)d_in[8];
    const float* w_qkv_r = (const float*)d_in[9];
    const float* b_qkv_r = (const float*)d_in[10];
    const float* w_o_r   = (const float*)d_in[11];
    const float* b_o_r   = (const float*)d_in[12];
    const float* ln_g    = (const float*)d_in[13];
    const float* ln_b    = (const float*)d_in[14];
    const float* w1      = (const float*)d_in[15];
    const float* b1      = (const float*)d_in[16];
    const float* w2      = (const float*)d_in[17];
    const float* b2      = (const float*)d_in[18];
    const float* alpha   = (const float*)d_in[19];

    const int Bn = 16, NQ = 128, LT = 512, LR = 196, D = 1024, H = 16;
    const int LRp = 256;
    const int MQ = Bn * NQ;              // 2048
    const int MT = Bn * LT;              // 8192
    const int MR = Bn * LR;              // 3136

    char* ws = (char*)d_ws;
    size_t off = 0;
    auto alloc = [&](size_t bytes) -> void* {
        void* p = ws + off;
        off = (off + bytes + 255) & ~(size_t)255;
        return p;
    };
    unsigned short* qb     = (unsigned short*)alloc((size_t)MQ * D * 2);
    unsigned short* tb     = (unsigned short*)alloc((size_t)MT * D * 2);
    unsigned short* rb     = (unsigned short*)alloc((size_t)MR * D * 2);
    unsigned short* wqkvtb = (unsigned short*)alloc((size_t)3 * D * D * 2);
    unsigned short* wotb   = (unsigned short*)alloc((size_t)D * D * 2);
    unsigned short* wqkvrb = (unsigned short*)alloc((size_t)3 * D * D * 2);
    unsigned short* worb   = (unsigned short*)alloc((size_t)D * D * 2);
    unsigned short* w1b    = (unsigned short*)alloc((size_t)4 * D * D * 2);
    unsigned short* w2b    = (unsigned short*)alloc((size_t)4 * D * D * 2);
    unsigned short* ktv    = (unsigned short*)alloc((size_t)MT * 2 * D * 2);  // 64MB
    unsigned short* krv    = (unsigned short*)alloc((size_t)MR * 2 * D * 2);
    unsigned short* vtT    = (unsigned short*)alloc((size_t)Bn * H * 64 * LT * 2);
    unsigned short* vrT    = (unsigned short*)alloc((size_t)Bn * H * 64 * LRp * 2);
    unsigned short* qp     = (unsigned short*)alloc((size_t)MQ * D * 2);
    unsigned short* ao     = (unsigned short*)alloc((size_t)MQ * D * 2);
    unsigned short* qlnb   = (unsigned short*)alloc((size_t)MQ * D * 2);
    float* xf   = (float*)alloc((size_t)MQ * D * 4);
    float* qlf  = (float*)alloc((size_t)MQ * D * 4);
    float* aggt = (float*)alloc((size_t)MQ * D * 4);
    float* aggr = (float*)alloc((size_t)MQ * D * 4);
    float* sc   = (float*)alloc((size_t)Bn * H * NQ * LT * 4);   // 67MB arena
    if (off > ws_size) return;

    // phase-reused views
    unsigned short* tbT = ktv;                               // [B][1024][512]
    unsigned short* rbT = ktv + (size_t)Bn * D * LT;         // [B][1024][256p]
    float* sct = sc;
    float* scr = sc;
    float* at  = sc;
    float* ar  = sc + (size_t)Bn * NQ * LT;
    unsigned short* hb = (unsigned short*)sc;                // FFN hidden bf16 [0,16MB)
    float* part_q  = sc;                                     // 32MB: Q/O-proj partials
    float* part_f1 = (float*)ktv;                            // 64MB: FFN1 partials
    float* part_f2 = (float*)((char*)sc + (size_t)16 * 1024 * 1024);  // 32MB @ [16,48)

    const long PQ = (long)MQ * D;        // 2048*1024 partial slice

    // ---- all converts in one launch ----
    {
        CvtPack pk;
        pk.src[0] = queries; pk.dst[0] = qb;     pk.n[0] = (long)MQ * D;
        pk.src[1] = text;    pk.dst[1] = tb;     pk.n[1] = (long)MT * D;
        pk.src[2] = region;  pk.dst[2] = rb;     pk.n[2] = (long)MR * D;
        pk.src[3] = w_qkv_t; pk.dst[3] = wqkvtb; pk.n[3] = (long)3 * D * D;
        pk.src[4] = w_o_t;   pk.dst[4] = wotb;   pk.n[4] = (long)D * D;
        pk.src[5] = w_qkv_r; pk.dst[5] = wqkvrb; pk.n[5] = (long)3 * D * D;
        pk.src[6] = w_o_r;   pk.dst[6] = worb;   pk.n[6] = (long)D * D;
        pk.src[7] = w1;      pk.dst[7] = w1b;    pk.n[7] = (long)4 * D * D;
        pk.src[8] = w2;      pk.dst[8] = w2b;    pk.n[8] = (long)4 * D * D;
        k_cvt_multi<<<dim3(256, 9, 1), 256, 0, stream>>>(pk);
    }

    auto NT = [&](const unsigned short* A, const unsigned short* Bm, const float* bias,
                  const float* res, float* oF, unsigned short* oB,
                  int M, int N, int K, int lda, int ldb, int ldc,
                  int Hh, long sAb, long sAh, long sBb, long sBh, long sCb, long sCh,
                  int batch, float scale, bool gelu, int S = 1, long sPart = 0) {
        dim3 g((N + 127) / 128, (M + 127) / 128, batch * S);
        if (gelu)
            k_gemm_nt<true><<<g, 256, 0, stream>>>(A, Bm, bias, res, oF, oB, M, N, K,
                lda, ldb, ldc, Hh, sAb, sAh, sBb, sBh, sCb, sCh, scale, S, sPart);
        else
            k_gemm_nt<false><<<g, 256, 0, stream>>>(A, Bm, bias, res, oF, oB, M, N, K,
                lda, ldb, ldc, Hh, sAb, sAh, sBb, sBh, sCb, sCh, scale, S, sPart);
    };
    auto REDUX = [&](const float* part, long sPart, int S, const float* bias,
                     const float* res, float* oF, unsigned short* oB,
                     long total, int ldc, int gelu) {
        long n4 = total / 4;
        int blocks = (int)((n4 + 255) / 256);
        if (blocks > 2048) blocks = 2048;
        k_redux<<<blocks, 256, 0, stream>>>(part, sPart / 4, S, bias, res, oF, oB,
                                            n4, ldc / 4, gelu);
    };

    // ---- fused K+V projections: ktv[MT][2048], krv[MR][2048] ----
    NT(tb, wqkvtb + (long)D * D, b_qkv_t + D, nullptr, nullptr, ktv,
       MT, 2 * D, D, D, D, 2 * D, 1,0,0,0,0,0,0, 1, 1.0f, false);
    NT(rb, wqkvrb + (long)D * D, b_qkv_r + D, nullptr, nullptr, krv,
       MR, 2 * D, D, D, D, 2 * D, 1,0,0,0,0,0,0, 1, 1.0f, false);

    // per-head V transposes: vtT[z][64][512], vrT[z][64][256p]
    {
        dim3 g1(64 / 32, LT / 32, Bn * H);
        k_tr<<<g1, 256, 0, stream>>>(ktv + D, vtT, LT, 2 * D, LT,
                                     H, (long)LT * 2 * D, 64, (long)64 * LT);
        dim3 g2(64 / 32, LRp / 32, Bn * H);
        k_tr<<<g2, 256, 0, stream>>>(krv + D, vrT, LR, 2 * D, LRp,
                                     H, (long)LR * 2 * D, 64, (long)64 * LRp);
    }

    // ================= MHA 1 (text) =================
    NT(qb, wqkvtb, nullptr, nullptr, part_q, nullptr, MQ, D, 256, D, D, D,
       1,0,0,0,0,0,0, 1, 1.0f, false, 4, PQ);
    REDUX(part_q, PQ, 4, b_qkv_t, nullptr, nullptr, qp, PQ, D, 0);
    NT(qp, ktv, nullptr, nullptr, sct, nullptr, NQ, LT, 64, D, 2 * D, LT,
       H, (long)NQ * D, 64, (long)LT * 2 * D, 64, (long)H * NQ * LT, (long)NQ * LT,
       Bn * H, 0.125f, false);
    k_softmax_p<<<Bn * H * NQ, 256, 0, stream>>>(sct, (unsigned short*)sct, tmask,
                                                 LT, LT, LT, 2 * LT, H * NQ);
    NT((const unsigned short*)sct, vtT, nullptr, nullptr, nullptr, ao, NQ, 64, LT,
       2 * LT, LT, D,
       H, (long)H * NQ * 2 * LT, (long)NQ * 2 * LT, (long)64 * LT * H, (long)64 * LT,
       (long)NQ * D, 64, Bn * H, 1.0f, false);
    NT(ao, wotb, nullptr, nullptr, part_q, nullptr, MQ, D, 256, D, D, D,
       1,0,0,0,0,0,0, 1, 1.0f, false, 4, PQ);
    REDUX(part_q, PQ, 4, b_o_t, queries, xf, nullptr, PQ, D, 0);
    k_ln<<<MQ, 256, 0, stream>>>(xf, ln_g, ln_b, qlf, qlnb);

    // ================= MHA 2 (region) =================
    NT(qlnb, wqkvrb, nullptr, nullptr, part_q, nullptr, MQ, D, 256, D, D, D,
       1,0,0,0,0,0,0, 1, 1.0f, false, 4, PQ);
    REDUX(part_q, PQ, 4, b_qkv_r, nullptr, nullptr, qp, PQ, D, 0);
    NT(qp, krv, nullptr, nullptr, scr, nullptr, NQ, LR, 64, D, 2 * D, LRp,
       H, (long)NQ * D, 64, (long)LR * 2 * D, 64, (long)H * NQ * LRp, (long)NQ * LRp,
       Bn * H, 0.125f, false);
    k_softmax_p<<<Bn * H * NQ, 256, 0, stream>>>(scr, (unsigned short*)scr, rmask,
                                                 LR, LRp, LRp, 2 * LRp, H * NQ);
    NT((const unsigned short*)scr, vrT, nullptr, nullptr, nullptr, ao, NQ, 64, LRp,
       2 * LRp, LRp, D,
       H, (long)H * NQ * 2 * LRp, (long)NQ * 2 * LRp, (long)64 * LRp * H, (long)64 * LRp,
       (long)NQ * D, 64, Bn * H, 1.0f, false);
    NT(ao, worb, nullptr, nullptr, part_q, nullptr, MQ, D, 256, D, D, D,
       1,0,0,0,0,0,0, 1, 1.0f, false, 4, PQ);
    REDUX(part_q, PQ, 4, b_o_r, qlf, xf, nullptr, PQ, D, 0);
    k_ln<<<MQ, 256, 0, stream>>>(xf, ln_g, ln_b, qlf, qlnb);

    // ================= manual masked cross-attention =================
    {
        dim3 g1(D / 32, LT / 32, Bn);
        k_tr<<<g1, 256, 0, stream>>>(tb, tbT, LT, D, LT, 1, (long)LT * D, 0, (long)D * LT);
        dim3 g2(D / 32, LRp / 32, Bn);
        k_tr<<<g2, 256, 0, stream>>>(rb, rbT, LR, D, LRp, 1, (long)LR * D, 0, (long)D * LRp);
    }
    NT(qlnb, tb, nullptr, nullptr, at, nullptr, NQ, LT, D, D, D, LT,
       1, (long)NQ * D, 0, (long)LT * D, 0, (long)NQ * LT, 0, Bn, 0.03125f, false);
    k_softmax_p<<<Bn * NQ, 256, 0, stream>>>(at, (unsigned short*)at, tmask,
                                             LT, LT, LT, 2 * LT, NQ);
    NT((const unsigned short*)at, tbT, nullptr, nullptr, aggt, nullptr, NQ, D, LT,
       2 * LT, LT, D,
       1, (long)NQ * 2 * LT, 0, (long)D * LT, 0, (long)NQ * D, 0, Bn, 1.0f, false);

    NT(qlnb, rb, nullptr, nullptr, ar, nullptr, NQ, LR, D, D, D, LRp,
       1, (long)NQ * D, 0, (long)LR * D, 0, (long)NQ * LRp, 0, Bn, 0.03125f, false);
    k_softmax_p<<<Bn * NQ, 256, 0, stream>>>(ar, (unsigned short*)ar, rmask,
                                             LR, LRp, LRp, 2 * LRp, NQ);
    NT((const unsigned short*)ar, rbT, nullptr, nullptr, aggr, nullptr, NQ, D, LRp,
       2 * LRp, LRp, D,
       1, (long)NQ * 2 * LRp, 0, (long)D * LRp, 0, (long)NQ * D, 0, Bn, 1.0f, false);

    k_combine<<<2048, 256, 0, stream>>>(qlf, qlnb, aggt, aggr, alpha, (long)MQ * D);

    // ================= FFN =================
    NT(qlnb, w1b, nullptr, nullptr, part_f1, nullptr, MQ, 4 * D, 512, D, D, 4 * D,
       1,0,0,0,0,0,0, 1, 1.0f, false, 2, (long)MQ * 4 * D);
    REDUX(part_f1, (long)MQ * 4 * D, 2, b1, nullptr, nullptr, hb,
          (long)MQ * 4 * D, 4 * D, 1);
    NT(hb, w2b, nullptr, nullptr, part_f2, nullptr, MQ, D, 1024, 4 * D, 4 * D, D,
       1,0,0,0,0,0,0, 1, 1.0f, false, 4, PQ);
    REDUX(part_f2, PQ, 4, b2, qlf, (float*)d_out, nullptr, PQ, D, 0);
}

// Round 6
// 628.731 us; speedup vs baseline: 1.7655x; 1.0518x over previous
//
#include <hip/hip_runtime.h>
#include <hip/hip_bf16.h>

// ---------------------------------------------------------------------------
// QueryGuidedFusionNet forward on MI355X.
// Round 6: 256x256-tile GEMM (16 waves, BK=32, dbuf LDS) for the cache-
// traffic-bound GEMMs (KV-text, FFN1, FFN2) -- halves bytes/FLOP vs 128².
// ---------------------------------------------------------------------------

typedef __attribute__((ext_vector_type(8))) short short8;   // 8 bf16
typedef __attribute__((ext_vector_type(4))) float f32x4;

#define DEV static __device__ __forceinline__

DEV unsigned short f2bf(float f) {
    unsigned u = __float_as_uint(f);
    u += 0x7fffu + ((u >> 16) & 1u);          // RNE
    return (unsigned short)(u >> 16);
}

// ------------------------- multi-tensor convert -----------------------------
struct CvtPack {
    const float* src[9];
    unsigned short* dst[9];
    long n[9];          // element counts, all multiples of 4
};

__global__ __launch_bounds__(256)
void k_cvt_multi(CvtPack p) {
    int ti = blockIdx.y;
    const float* in = p.src[ti];
    unsigned short* out = p.dst[ti];
    long n = p.n[ti];
    long i = ((long)blockIdx.x * blockDim.x + threadIdx.x) * 4;
    long stride = (long)gridDim.x * blockDim.x * 4;
    for (; i < n; i += stride) {
        float4 v = *(const float4*)(in + i);
        ushort4 o;
        o.x = f2bf(v.x); o.y = f2bf(v.y); o.z = f2bf(v.z); o.w = f2bf(v.w);
        *(ushort4*)(out + i) = o;
    }
}

// --------------------- GEMM NT 256x256 (16 waves) ---------------------------
// C[m,n] = sum_k A[m,k]*B[n,k] (+bias) ; batch=1; z = split-K index.
// 1024 threads = 16 waves of 64x64. BK=32. 2 LDS buffers (64KB total).
// T3-minimum pipeline: stage(next) issued BEFORE compute, one barrier/iter.
// LDS rows 64B, XOR swizzle ((row>>1)&3)<<4 (verified conflict-free r5).
__global__ __launch_bounds__(1024, 4)
void k_gemm_nt256(const unsigned short* __restrict__ A, const unsigned short* __restrict__ B,
                  const float* __restrict__ bias,
                  float* __restrict__ outF, unsigned short* __restrict__ outB,
                  int M, int N, int K, int lda, int ldb, int ldc,
                  long sPart)
{
    __shared__ unsigned short smem[2 * 16384];   // 2 bufs x (A16KB + B16KB)

    unsigned gx = gridDim.x, gy = gridDim.y;
    unsigned nwg = gx * gy * gridDim.z;
    unsigned lin = (blockIdx.z * gy + blockIdx.y) * gx + blockIdx.x;
    unsigned bx = blockIdx.x, by = blockIdx.y, bz = blockIdx.z;
    if ((nwg & 7u) == 0u) {
        unsigned cpx = nwg >> 3;
        unsigned s = (lin & 7u) * cpx + (lin >> 3);
        bx = s % gx; unsigned r2 = s / gx;
        by = r2 % gy; bz = r2 / gy;
    }
    int s_k = (int)bz;                       // split-K slice (gridDim.z = S)
    const unsigned short* Ap = A + (long)s_k * K;
    const unsigned short* Bp = B + (long)s_k * K;
    float* outFp = outF ? outF + (long)s_k * sPart : nullptr;

    int t = threadIdx.x;
    int wid = t >> 6, lane = t & 63;
    int lrow = lane & 15, kgrp = lane >> 4;
    int tm = by * 256, tn = bx * 256;
    int wm = (wid >> 2) * 64, wn = (wid & 3) * 64;

    // stage one BK=32 tile pair: A 16KB (1 round of 1024x16B) + B 16KB.
    auto stage = [&](int buf, int k0) {
        int d = t * 16;                                   // byte in 16KB tile
        int row = d >> 6;
        int colb = (d & 63) ^ (((row >> 1) & 3) << 4);    // inverse swizzle
        int gr = tm + row; if (gr > M - 1) gr = M - 1;
        const unsigned short* srcA = Ap + (long)gr * lda + k0 + (colb >> 1);
        unsigned short* dstA = smem + ((buf * 32768 + d) >> 1);
        __builtin_amdgcn_global_load_lds(
            (const __attribute__((address_space(1))) unsigned int*)srcA,
            (__attribute__((address_space(3))) unsigned int*)dstA, 16, 0, 0);
        int gn = tn + row; if (gn > N - 1) gn = N - 1;
        const unsigned short* srcB = Bp + (long)gn * ldb + k0 + (colb >> 1);
        unsigned short* dstB = smem + ((buf * 32768 + 16384 + d) >> 1);
        __builtin_amdgcn_global_load_lds(
            (const __attribute__((address_space(1))) unsigned int*)srcB,
            (__attribute__((address_space(3))) unsigned int*)dstB, 16, 0, 0);
    };

    f32x4 acc[4][4] = {};
    int nt = K >> 5;

    stage(0, 0);
    __syncthreads();

    for (int ti = 0; ti < nt; ++ti) {
        int cur = ti & 1;
        if (ti + 1 < nt) stage(cur ^ 1, (ti + 1) << 5);   // overlaps compute

        const char* Ab = (const char*)smem + cur * 32768;
        const char* Bb = Ab + 16384;
        short8 a[4], bb[4];
#pragma unroll
        for (int i = 0; i < 4; ++i) {
            int row = wm + i * 16 + lrow;
            a[i] = *(const short8*)(Ab + row * 64 + ((kgrp * 16) ^ (((row >> 1) & 3) << 4)));
        }
#pragma unroll
        for (int j = 0; j < 4; ++j) {
            int row = wn + j * 16 + lrow;
            bb[j] = *(const short8*)(Bb + row * 64 + ((kgrp * 16) ^ (((row >> 1) & 3) << 4)));
        }
#pragma unroll
        for (int i = 0; i < 4; ++i)
#pragma unroll
            for (int j = 0; j < 4; ++j)
                acc[i][j] = __builtin_amdgcn_mfma_f32_16x16x32_bf16(a[i], bb[j], acc[i][j], 0, 0, 0);
        __syncthreads();   // drains next-tile loads (overlapped) + reuse guard
    }

#pragma unroll
    for (int i = 0; i < 4; ++i) {
        int rbase = tm + wm + i * 16 + kgrp * 4;
#pragma unroll
        for (int j = 0; j < 4; ++j) {
            int c = tn + wn + j * 16 + lrow;
            if (c >= N) continue;
            float bv = bias ? bias[c] : 0.0f;
#pragma unroll
            for (int e = 0; e < 4; ++e) {
                int r = rbase + e;
                if (r >= M) continue;
                float v = acc[i][j][e] + bv;
                long oidx = (long)r * ldc + c;
                if (outFp) outFp[oidx] = v;
                if (outB) outB[oidx] = f2bf(v);
            }
        }
    }
}

// ------------------------------ GEMM NT (pipelined 128²) --------------------
template<bool GELU>
__global__ __launch_bounds__(256)
void k_gemm_nt(const unsigned short* __restrict__ A, const unsigned short* __restrict__ B,
               const float* __restrict__ bias, const float* __restrict__ res,
               float* __restrict__ outF, unsigned short* __restrict__ outB,
               int M, int N, int K, int lda, int ldb, int ldc,
               int H, long sAb, long sAh, long sBb, long sBh, long sCb, long sCh,
               float scale, int S, long sPart)
{
    __shared__ unsigned short smem[5 * 8192];   // 5 bufs x (A 8KB + B 8KB) = 80KB

    unsigned gx = gridDim.x, gy = gridDim.y, gz = gridDim.z;
    unsigned nwg = gx * gy * gz;
    unsigned lin = (blockIdx.z * gy + blockIdx.y) * gx + blockIdx.x;
    unsigned bx = blockIdx.x, by = blockIdx.y, bz = blockIdx.z;
    if ((nwg & 7u) == 0u) {
        unsigned cpx = nwg >> 3;
        unsigned s = (lin & 7u) * cpx + (lin >> 3);
        bx = s % gx; unsigned r2 = s / gx;
        by = r2 % gy; bz = r2 / gy;
    }

    int zz = (int)bz;
    int s_k = 0;
    if (S > 1) { s_k = zz % S; zz /= S; }
    int b = zz / H, h = zz - b * H;
    const unsigned short* Ap = A + (long)b * sAb + (long)h * sAh + (long)s_k * K;
    const unsigned short* Bp = B + (long)b * sBb + (long)h * sBh + (long)s_k * K;
    float* outFp = outF;
    if (outFp && S > 1) outFp += (long)s_k * sPart;
    long offC = (long)b * sCb + (long)h * sCh;

    int t    = threadIdx.x;
    int wid  = t >> 6;
    int lane = t & 63;
    int lrow = lane & 15;
    int kgrp = lane >> 4;

    int tm = by * 128;
    int tn = bx * 128;
    int wm = (wid >> 1) * 64;
    int wn = (wid & 1) * 64;

    auto stage = [&](int buf, int k0) {
#pragma unroll
        for (int r = 0; r < 2; ++r) {
            int d = r * 4096 + t * 16;
            int row = d >> 6;
            int colb = (d & 63) ^ (((row >> 1) & 3) << 4);
            int gr = tm + row; if (gr > M - 1) gr = M - 1;
            const unsigned short* srcA = Ap + (long)gr * lda + k0 + (colb >> 1);
            unsigned short* dstA = smem + ((buf * 16384 + r * 4096 + wid * 1024) >> 1);
            __builtin_amdgcn_global_load_lds(
                (const __attribute__((address_space(1))) unsigned int*)srcA,
                (__attribute__((address_space(3))) unsigned int*)dstA, 16, 0, 0);
            int gn = tn + row; if (gn > N - 1) gn = N - 1;
            const unsigned short* srcB = Bp + (long)gn * ldb + k0 + (colb >> 1);
            unsigned short* dstB = smem + ((buf * 16384 + 8192 + r * 4096 + wid * 1024) >> 1);
            __builtin_amdgcn_global_load_lds(
                (const __attribute__((address_space(1))) unsigned int*)srcB,
                (__attribute__((address_space(3))) unsigned int*)dstB, 16, 0, 0);
        }
    };

    f32x4 acc[4][4] = {};
    int nt = K >> 5;

    for (int p = 0; p < 4 && p < nt; ++p) stage(p, p << 5);

    for (int ti = 0; ti < nt; ++ti) {
        int cur = ti % 5;
        int rem = nt - 1 - ti;
        if (rem >= 3)      asm volatile("s_waitcnt vmcnt(12)" ::: "memory");
        else if (rem == 2) asm volatile("s_waitcnt vmcnt(8)"  ::: "memory");
        else if (rem == 1) asm volatile("s_waitcnt vmcnt(4)"  ::: "memory");
        else               asm volatile("s_waitcnt vmcnt(0)"  ::: "memory");
        __builtin_amdgcn_sched_barrier(0);
        __builtin_amdgcn_s_barrier();
        __builtin_amdgcn_sched_barrier(0);

        if (ti + 4 < nt) stage((ti + 4) % 5, (ti + 4) << 5);

        const char* Ab = (const char*)smem + cur * 16384;
        const char* Bb = Ab + 8192;
        short8 a[4], bb[4];
#pragma unroll
        for (int i = 0; i < 4; ++i) {
            int row = wm + i * 16 + lrow;
            a[i] = *(const short8*)(Ab + row * 64 + ((kgrp * 16) ^ (((row >> 1) & 3) << 4)));
        }
#pragma unroll
        for (int j = 0; j < 4; ++j) {
            int row = wn + j * 16 + lrow;
            bb[j] = *(const short8*)(Bb + row * 64 + ((kgrp * 16) ^ (((row >> 1) & 3) << 4)));
        }
#pragma unroll
        for (int i = 0; i < 4; ++i)
#pragma unroll
            for (int j = 0; j < 4; ++j)
                acc[i][j] = __builtin_amdgcn_mfma_f32_16x16x32_bf16(a[i], bb[j], acc[i][j], 0, 0, 0);
    }

#pragma unroll
    for (int i = 0; i < 4; ++i) {
        int rbase = tm + wm + i * 16 + kgrp * 4;
#pragma unroll
        for (int j = 0; j < 4; ++j) {
            int c = tn + wn + j * 16 + lrow;
            if (c >= N) continue;
            float bv = bias ? bias[c] : 0.0f;
#pragma unroll
            for (int e = 0; e < 4; ++e) {
                int r = rbase + e;
                if (r >= M) continue;
                float v = acc[i][j][e] * scale + bv;
                long oidx = offC + (long)r * ldc + c;
                if (res) v += res[oidx];
                if (GELU) v = 0.5f * v * (1.0f + erff(v * 0.70710678118654752f));
                if (outFp) outFp[oidx] = v;
                if (outB) outB[oidx] = f2bf(v);
            }
        }
    }
}

// ------------------------------ split-K reduce -------------------------------
__global__ __launch_bounds__(256)
void k_redux(const float* __restrict__ part, long sPart4, int S,
             const float* __restrict__ bias, const float* __restrict__ res,
             float* __restrict__ outF, unsigned short* __restrict__ outB,
             long n4, int ldc4, int gelu)
{
    const float4* p4 = (const float4*)part;
    long i = (long)blockIdx.x * blockDim.x + threadIdx.x;
    long stride = (long)gridDim.x * blockDim.x;
    for (; i < n4; i += stride) {
        int c = (int)(i % ldc4);
        float4 v = p4[i];
        for (int s = 1; s < S; ++s) {
            float4 w = p4[i + (long)s * sPart4];
            v.x += w.x; v.y += w.y; v.z += w.z; v.w += w.w;
        }
        if (bias) {
            float4 bv = ((const float4*)bias)[c];
            v.x += bv.x; v.y += bv.y; v.z += bv.z; v.w += bv.w;
        }
        if (res) {
            float4 rv = ((const float4*)res)[i];
            v.x += rv.x; v.y += rv.y; v.z += rv.z; v.w += rv.w;
        }
        if (gelu) {
            v.x = 0.5f * v.x * (1.0f + erff(v.x * 0.70710678118654752f));
            v.y = 0.5f * v.y * (1.0f + erff(v.y * 0.70710678118654752f));
            v.z = 0.5f * v.z * (1.0f + erff(v.z * 0.70710678118654752f));
            v.w = 0.5f * v.w * (1.0f + erff(v.w * 0.70710678118654752f));
        }
        if (outF) ((float4*)outF)[i] = v;
        if (outB) {
            ushort4 o;
            o.x = f2bf(v.x); o.y = f2bf(v.y); o.z = f2bf(v.z); o.w = f2bf(v.w);
            ((ushort4*)outB)[i] = o;
        }
    }
}

// ---------------------- tiled transpose (bf16) ------------------------------
__global__ __launch_bounds__(256)
void k_tr(const unsigned short* __restrict__ in, unsigned short* __restrict__ out,
          int R, int ldin, int ldout,
          int H, long sIb, long sIh, long sOz)
{
    __shared__ unsigned short tile[32][33];
    int z = blockIdx.z;
    int b = z / H, h = z - b * H;
    const unsigned short* ip = in + (long)b * sIb + (long)h * sIh;
    unsigned short* op = out + (long)z * sOz;
    int t = threadIdx.x;
    int cl = t & 31, rl = t >> 5;
    int c0 = blockIdx.x * 32, r0 = blockIdx.y * 32;
#pragma unroll
    for (int i = 0; i < 4; ++i) {
        int r = r0 + rl + i * 8;
        unsigned short v = 0;
        if (r < R) v = ip[(long)r * ldin + (c0 + cl)];
        tile[rl + i * 8][cl] = v;
    }
    __syncthreads();
#pragma unroll
    for (int i = 0; i < 4; ++i) {
        int orow = c0 + rl + i * 8;
        int ocol = r0 + cl;
        op[(long)orow * ldout + ocol] = tile[cl][rl + i * 8];
    }
}

// --------------------------- masked softmax ---------------------------------
__global__ __launch_bounds__(256)
void k_softmax_p(const float* __restrict__ sc, unsigned short* __restrict__ P,
                 const int* __restrict__ mask, int L, int Lpad,
                 int ld_sc, int ld_p, int rows_per_batch)
{
    int row = blockIdx.x;
    int b = row / rows_per_batch;
    const float* p = sc + (long)row * ld_sc;
    unsigned short* po = P + (long)row * ld_p;
    const int* mrow = mask + (long)b * L;
    int t = threadIdx.x;
    int lane = t & 63, wid = t >> 6;

    int j0 = t, j1 = t + 256;
    float v0 = -INFINITY, v1 = -INFINITY;
    if (j0 < L && mrow[j0] != 0) v0 = p[j0];
    if (j1 < L && mrow[j1] != 0) v1 = p[j1];

    float mx = fmaxf(v0, v1);
#pragma unroll
    for (int s = 32; s > 0; s >>= 1) mx = fmaxf(mx, __shfl_xor(mx, s, 64));
    __shared__ float wr[4], wsum[4];
    if (lane == 0) wr[wid] = mx;
    __syncthreads();
    mx = fmaxf(fmaxf(wr[0], wr[1]), fmaxf(wr[2], wr[3]));

    float e0 = (v0 == -INFINITY) ? 0.0f : __expf(v0 - mx);
    float e1 = (v1 == -INFINITY) ? 0.0f : __expf(v1 - mx);
    float sm = e0 + e1;
#pragma unroll
    for (int s = 32; s > 0; s >>= 1) sm += __shfl_xor(sm, s, 64);
    if (lane == 0) wsum[wid] = sm;
    __syncthreads();          // also orders: score reads done before P writes
    float inv = 1.0f / (wsum[0] + wsum[1] + wsum[2] + wsum[3]);

    if (j0 < Lpad) po[j0] = f2bf((j0 < L) ? e0 * inv : 0.0f);
    if (j1 < Lpad) po[j1] = f2bf((j1 < L) ? e1 * inv : 0.0f);
}

// ------------------------------ LayerNorm ----------------------------------
__global__ __launch_bounds__(256)
void k_ln(const float* __restrict__ x, const float* __restrict__ g, const float* __restrict__ bt,
          float* __restrict__ yf, unsigned short* __restrict__ yb)
{
    int row = blockIdx.x;
    const float* xr = x + (long)row * 1024;
    int t = threadIdx.x;
    int lane = t & 63, wid = t >> 6;
    float4 v = *(const float4*)(xr + t * 4);
    float s  = v.x + v.y + v.z + v.w;
    float ss = v.x * v.x + v.y * v.y + v.z * v.z + v.w * v.w;
#pragma unroll
    for (int d = 32; d > 0; d >>= 1) { s += __shfl_xor(s, d, 64); ss += __shfl_xor(ss, d, 64); }
    __shared__ float rs[4], rss[4];
    if (lane == 0) { rs[wid] = s; rss[wid] = ss; }
    __syncthreads();
    s  = rs[0] + rs[1] + rs[2] + rs[3];
    ss = rss[0] + rss[1] + rss[2] + rss[3];
    float mu  = s  * (1.0f / 1024.0f);
    float var = ss * (1.0f / 1024.0f) - mu * mu;
    float inv = rsqrtf(var + 1e-5f);
    float xv[4] = { v.x, v.y, v.z, v.w };
#pragma unroll
    for (int e = 0; e < 4; ++e) {
        int c = t * 4 + e;
        float yv = (xv[e] - mu) * inv * g[c] + bt[c];
        yf[(long)row * 1024 + c] = yv;
        yb[(long)row * 1024 + c] = f2bf(yv);
    }
}

// ------------------------------ combine ------------------------------------
__global__ void k_combine(float* __restrict__ qf, unsigned short* __restrict__ qb,
                          const float* __restrict__ aggt, const float* __restrict__ aggr,
                          const float* __restrict__ alpha, long n)
{
    float a = *alpha;
    long i = (long)blockIdx.x * blockDim.x + threadIdx.x;
    long stride = (long)gridDim.x * blockDim.x;
    for (; i < n; i += stride) {
        float v = qf[i] + a * aggr[i] + (1.0f - a) * aggt[i];
        qf[i] = v;
        qb[i] = f2bf(v);
    }
}

// ---------------------------------------------------------------------------
extern "C" void kernel_launch(void* const* d_in, const int* in_sizes, int n_in,
                              void* d_out, int out_size, void* d_ws, size_t ws_size,
                              hipStream_t stream)
{
    const float* queries = (const float*)d_in[0];
    const float* text    = (const float*)d_in[1];
    const float* region  = (const float*)d_in[2];
    const int*   tmask   = (const int*)d_in[3];
    const int*   rmask   = (const int*)d_in[4];
    const float* w_qkv_t = (const float*)d_in[5];
    const float* b_qkv_t = (const float*)d_in[6];
    const float* w_o_t   = (const float*)d_in[7];
    const float* b_o_t   = (const float*)d_in[8];
    const float* w_qkv_r = (const float*)d_in[9];
    const float* b_qkv_r = (const float*)d_in[10];
    const float* w_o_r   = (const float*)d_in[11];
    const float* b_o_r   = (const float*)d_in[12];
    const float* ln_g    = (const float*)d_in[13];
    const float* ln_b    = (const float*)d_in[14];
    const float* w1      = (const float*)d_in[15];
    const float* b1      = (const float*)d_in[16];
    const float* w2      = (const float*)d_in[17];
    const float* b2      = (const float*)d_in[18];
    const float* alpha   = (const float*)d_in[19];

    const int Bn = 16, NQ = 128, LT = 512, LR = 196, D = 1024, H = 16;
    const int LRp = 256;
    const int MQ = Bn * NQ;              // 2048
    const int MT = Bn * LT;              // 8192
    const int MR = Bn * LR;              // 3136

    char* ws = (char*)d_ws;
    size_t off = 0;
    auto alloc = [&](size_t bytes) -> void* {
        void* p = ws + off;
        off = (off + bytes + 255) & ~(size_t)255;
        return p;
    };
    unsigned short* qb     = (unsigned short*)alloc((size_t)MQ * D * 2);
    unsigned short* tb     = (unsigned short*)alloc((size_t)MT * D * 2);
    unsigned short* rb     = (unsigned short*)alloc((size_t)MR * D * 2);
    unsigned short* wqkvtb = (unsigned short*)alloc((size_t)3 * D * D * 2);
    unsigned short* wotb   = (unsigned short*)alloc((size_t)D * D * 2);
    unsigned short* wqkvrb = (unsigned short*)alloc((size_t)3 * D * D * 2);
    unsigned short* worb   = (unsigned short*)alloc((size_t)D * D * 2);
    unsigned short* w1b    = (unsigned short*)alloc((size_t)4 * D * D * 2);
    unsigned short* w2b    = (unsigned short*)alloc((size_t)4 * D * D * 2);
    unsigned short* ktv    = (unsigned short*)alloc((size_t)MT * 2 * D * 2);  // 64MB
    unsigned short* krv    = (unsigned short*)alloc((size_t)MR * 2 * D * 2);
    unsigned short* vtT    = (unsigned short*)alloc((size_t)Bn * H * 64 * LT * 2);
    unsigned short* vrT    = (unsigned short*)alloc((size_t)Bn * H * 64 * LRp * 2);
    unsigned short* qp     = (unsigned short*)alloc((size_t)MQ * D * 2);
    unsigned short* ao     = (unsigned short*)alloc((size_t)MQ * D * 2);
    unsigned short* qlnb   = (unsigned short*)alloc((size_t)MQ * D * 2);
    float* xf   = (float*)alloc((size_t)MQ * D * 4);
    float* qlf  = (float*)alloc((size_t)MQ * D * 4);
    float* aggt = (float*)alloc((size_t)MQ * D * 4);
    float* aggr = (float*)alloc((size_t)MQ * D * 4);
    float* sc   = (float*)alloc((size_t)Bn * H * NQ * LT * 4);   // 67MB arena
    if (off > ws_size) return;

    // phase-reused views
    unsigned short* tbT = ktv;                               // [B][1024][512]
    unsigned short* rbT = ktv + (size_t)Bn * D * LT;         // [B][1024][256p]
    float* sct = sc;
    float* scr = sc;
    float* at  = sc;
    float* ar  = sc + (size_t)Bn * NQ * LT;
    unsigned short* hb = (unsigned short*)sc;                // FFN hidden bf16 [0,16MB)
    float* part_q  = sc;                                     // 32MB: Q/O-proj partials
    float* part_f1 = (float*)ktv;                            // 64MB: FFN1 partials
    float* part_f2 = (float*)ktv;                            // 64MB: FFN2 partials (after f1 redux)

    const long PQ = (long)MQ * D;        // 2048*1024 partial slice

    // ---- all converts in one launch ----
    {
        CvtPack pk;
        pk.src[0] = queries; pk.dst[0] = qb;     pk.n[0] = (long)MQ * D;
        pk.src[1] = text;    pk.dst[1] = tb;     pk.n[1] = (long)MT * D;
        pk.src[2] = region;  pk.dst[2] = rb;     pk.n[2] = (long)MR * D;
        pk.src[3] = w_qkv_t; pk.dst[3] = wqkvtb; pk.n[3] = (long)3 * D * D;
        pk.src[4] = w_o_t;   pk.dst[4] = wotb;   pk.n[4] = (long)D * D;
        pk.src[5] = w_qkv_r; pk.dst[5] = wqkvrb; pk.n[5] = (long)3 * D * D;
        pk.src[6] = w_o_r;   pk.dst[6] = worb;   pk.n[6] = (long)D * D;
        pk.src[7] = w1;      pk.dst[7] = w1b;    pk.n[7] = (long)4 * D * D;
        pk.src[8] = w2;      pk.dst[8] = w2b;    pk.n[8] = (long)4 * D * D;
        k_cvt_multi<<<dim3(256, 9, 1), 256, 0, stream>>>(pk);
    }

    auto NT = [&](const unsigned short* A, const unsigned short* Bm, const float* bias,
                  const float* res, float* oF, unsigned short* oB,
                  int M, int N, int K, int lda, int ldb, int ldc,
                  int Hh, long sAb, long sAh, long sBb, long sBh, long sCb, long sCh,
                  int batch, float scale, bool gelu, int S = 1, long sPart = 0) {
        dim3 g((N + 127) / 128, (M + 127) / 128, batch * S);
        if (gelu)
            k_gemm_nt<true><<<g, 256, 0, stream>>>(A, Bm, bias, res, oF, oB, M, N, K,
                lda, ldb, ldc, Hh, sAb, sAh, sBb, sBh, sCb, sCh, scale, S, sPart);
        else
            k_gemm_nt<false><<<g, 256, 0, stream>>>(A, Bm, bias, res, oF, oB, M, N, K,
                lda, ldb, ldc, Hh, sAb, sAh, sBb, sBh, sCb, sCh, scale, S, sPart);
    };
    auto NT256 = [&](const unsigned short* A, const unsigned short* Bm, const float* bias,
                     float* oF, unsigned short* oB, int M, int N, int Kc,
                     int lda, int ldb, int ldc, int S, long sPart) {
        dim3 g((N + 255) / 256, (M + 255) / 256, S);
        k_gemm_nt256<<<g, 1024, 0, stream>>>(A, Bm, bias, oF, oB, M, N, Kc,
                                             lda, ldb, ldc, sPart);
    };
    auto REDUX = [&](const float* part, long sPart, int S, const float* bias,
                     const float* res, float* oF, unsigned short* oB,
                     long total, int ldc, int gelu) {
        long n4 = total / 4;
        int blocks = (int)((n4 + 255) / 256);
        if (blocks > 2048) blocks = 2048;
        k_redux<<<blocks, 256, 0, stream>>>(part, sPart / 4, S, bias, res, oF, oB,
                                            n4, ldc / 4, gelu);
    };

    // ---- fused K+V projections: ktv[MT][2048] via 256² tile, krv on 128² ----
    NT256(tb, wqkvtb + (long)D * D, b_qkv_t + D, nullptr, ktv,
          MT, 2 * D, D, D, D, 2 * D, 1, 0);                       // grid 8x32 = 256
    NT(rb, wqkvrb + (long)D * D, b_qkv_r + D, nullptr, nullptr, krv,
       MR, 2 * D, D, D, D, 2 * D, 1,0,0,0,0,0,0, 1, 1.0f, false);

    // per-head V transposes: vtT[z][64][512], vrT[z][64][256p]
    {
        dim3 g1(64 / 32, LT / 32, Bn * H);
        k_tr<<<g1, 256, 0, stream>>>(ktv + D, vtT, LT, 2 * D, LT,
                                     H, (long)LT * 2 * D, 64, (long)64 * LT);
        dim3 g2(64 / 32, LRp / 32, Bn * H);
        k_tr<<<g2, 256, 0, stream>>>(krv + D, vrT, LR, 2 * D, LRp,
                                     H, (long)LR * 2 * D, 64, (long)64 * LRp);
    }

    // ================= MHA 1 (text) =================
    NT(qb, wqkvtb, nullptr, nullptr, part_q, nullptr, MQ, D, 256, D, D, D,
       1,0,0,0,0,0,0, 1, 1.0f, false, 4, PQ);
    REDUX(part_q, PQ, 4, b_qkv_t, nullptr, nullptr, qp, PQ, D, 0);
    NT(qp, ktv, nullptr, nullptr, sct, nullptr, NQ, LT, 64, D, 2 * D, LT,
       H, (long)NQ * D, 64, (long)LT * 2 * D, 64, (long)H * NQ * LT, (long)NQ * LT,
       Bn * H, 0.125f, false);
    k_softmax_p<<<Bn * H * NQ, 256, 0, stream>>>(sct, (unsigned short*)sct, tmask,
                                                 LT, LT, LT, 2 * LT, H * NQ);
    NT((const unsigned short*)sct, vtT, nullptr, nullptr, nullptr, ao, NQ, 64, LT,
       2 * LT, LT, D,
       H, (long)H * NQ * 2 * LT, (long)NQ * 2 * LT, (long)64 * LT * H, (long)64 * LT,
       (long)NQ * D, 64, Bn * H, 1.0f, false);
    NT(ao, wotb, nullptr, nullptr, part_q, nullptr, MQ, D, 256, D, D, D,
       1,0,0,0,0,0,0, 1, 1.0f, false, 4, PQ);
    REDUX(part_q, PQ, 4, b_o_t, queries, xf, nullptr, PQ, D, 0);
    k_ln<<<MQ, 256, 0, stream>>>(xf, ln_g, ln_b, qlf, qlnb);

    // ================= MHA 2 (region) =================
    NT(qlnb, wqkvrb, nullptr, nullptr, part_q, nullptr, MQ, D, 256, D, D, D,
       1,0,0,0,0,0,0, 1, 1.0f, false, 4, PQ);
    REDUX(part_q, PQ, 4, b_qkv_r, nullptr, nullptr, qp, PQ, D, 0);
    NT(qp, krv, nullptr, nullptr, scr, nullptr, NQ, LR, 64, D, 2 * D, LRp,
       H, (long)NQ * D, 64, (long)LR * 2 * D, 64, (long)H * NQ * LRp, (long)NQ * LRp,
       Bn * H, 0.125f, false);
    k_softmax_p<<<Bn * H * NQ, 256, 0, stream>>>(scr, (unsigned short*)scr, rmask,
                                                 LR, LRp, LRp, 2 * LRp, H * NQ);
    NT((const unsigned short*)scr, vrT, nullptr, nullptr, nullptr, ao, NQ, 64, LRp,
       2 * LRp, LRp, D,
       H, (long)H * NQ * 2 * LRp, (long)NQ * 2 * LRp, (long)64 * LRp * H, (long)64 * LRp,
       (long)NQ * D, 64, Bn * H, 1.0f, false);
    NT(ao, worb, nullptr, nullptr, part_q, nullptr, MQ, D, 256, D, D, D,
       1,0,0,0,0,0,0, 1, 1.0f, false, 4, PQ);
    REDUX(part_q, PQ, 4, b_o_r, qlf, xf, nullptr, PQ, D, 0);
    k_ln<<<MQ, 256, 0, stream>>>(xf, ln_g, ln_b, qlf, qlnb);

    // ================= manual masked cross-attention =================
    {
        dim3 g1(D / 32, LT / 32, Bn);
        k_tr<<<g1, 256, 0, stream>>>(tb, tbT, LT, D, LT, 1, (long)LT * D, 0, (long)D * LT);
        dim3 g2(D / 32, LRp / 32, Bn);
        k_tr<<<g2, 256, 0, stream>>>(rb, rbT, LR, D, LRp, 1, (long)LR * D, 0, (long)D * LRp);
    }
    NT(qlnb, tb, nullptr, nullptr, at, nullptr, NQ, LT, D, D, D, LT,
       1, (long)NQ * D, 0, (long)LT * D, 0, (long)NQ * LT, 0, Bn, 0.03125f, false);
    k_softmax_p<<<Bn * NQ, 256, 0, stream>>>(at, (unsigned short*)at, tmask,
                                             LT, LT, LT, 2 * LT, NQ);
    NT((const unsigned short*)at, tbT, nullptr, nullptr, aggt, nullptr, NQ, D, LT,
       2 * LT, LT, D,
       1, (long)NQ * 2 * LT, 0, (long)D * LT, 0, (long)NQ * D, 0, Bn, 1.0f, false);

    NT(qlnb, rb, nullptr, nullptr, ar, nullptr, NQ, LR, D, D, D, LRp,
       1, (long)NQ * D, 0, (long)LR * D, 0, (long)NQ * LRp, 0, Bn, 0.03125f, false);
    k_softmax_p<<<Bn * NQ, 256, 0, stream>>>(ar, (unsigned short*)ar, rmask,
                                             LR, LRp, LRp, 2 * LRp, NQ);
    NT((const unsigned short*)ar, rbT, nullptr, nullptr, aggr, nullptr, NQ, D, LRp,
       2 * LRp, LRp, D,
       1, (long)NQ * 2 * LRp, 0, (long)D * LRp, 0, (long)NQ * D, 0, Bn, 1.0f, false);

    k_combine<<<2048, 256, 0, stream>>>(qlf, qlnb, aggt, aggr, alpha, (long)MQ * D);

    // ================= FFN =================
    // FFN1: 256² tile, S=2 (Kc=512) -> grid 16x8x2 = 256 blocks; partials in ktv
    NT256(qlnb, w1b, nullptr, part_f1, nullptr, MQ, 4 * D, 512,
          D, D, 4 * D, 2, (long)MQ * 4 * D);
    REDUX(part_f1, (long)MQ * 4 * D, 2, b1, nullptr, nullptr, hb,
          (long)MQ * 4 * D, 4 * D, 1);
    // FFN2: 256² tile, S=8 (Kc=512) -> grid 4x8x8 = 256 blocks; partials in ktv
    NT256(hb, w2b, nullptr, part_f2, nullptr, MQ, D, 512,
          4 * D, 4 * D, D, 8, PQ);
    REDUX(part_f2, PQ, 8, b2, qlf, (float*)d_out, nullptr, PQ, D, 0);
}

// Round 7
// 618.282 us; speedup vs baseline: 1.7953x; 1.0169x over previous
//
#include <hip/hip_runtime.h>
#include <hip/hip_bf16.h>

// ---------------------------------------------------------------------------
// QueryGuidedFusionNet forward on MI355X.
// Round 7: balanced multi-tensor convert (flat grid + prefix table),
// NT256 3-buffer counted-vmcnt pipeline, split-K manual scores with
// redux fused into softmax, split-K agg with redux fused into combine.
// ---------------------------------------------------------------------------

typedef __attribute__((ext_vector_type(8))) short short8;   // 8 bf16
typedef __attribute__((ext_vector_type(4))) float f32x4;

#define DEV static __device__ __forceinline__

DEV unsigned short f2bf(float f) {
    unsigned u = __float_as_uint(f);
    u += 0x7fffu + ((u >> 16) & 1u);          // RNE
    return (unsigned short)(u >> 16);
}

// ------------------------- multi-tensor convert (balanced) ------------------
struct CvtPack {
    const float* src[9];
    unsigned short* dst[9];
    long start4[10];        // prefix sums in float4 units
};

__global__ __launch_bounds__(256)
void k_cvt_multi(CvtPack p, long total4) {
    long i = (long)blockIdx.x * blockDim.x + threadIdx.x;
    long stride = (long)gridDim.x * blockDim.x;
    for (; i < total4; i += stride) {
        int t = 0;
#pragma unroll
        for (int k = 1; k < 9; ++k) t += (i >= p.start4[k]) ? 1 : 0;
        long off = i - p.start4[t];
        float4 v = ((const float4*)p.src[t])[off];
        ushort4 o;
        o.x = f2bf(v.x); o.y = f2bf(v.y); o.z = f2bf(v.z); o.w = f2bf(v.w);
        ((ushort4*)p.dst[t])[off] = o;
    }
}

// --------------------- GEMM NT 256x256 (16 waves) ---------------------------
// C[m,n] = sum_k A[m,k]*B[n,k] (+bias) ; z = split-K index.
// 1024 threads = 16 waves of 64x64. BK=32. 3 LDS buffers (96KB), counted
// vmcnt(2) steady-state (mirrors verified 128-tile pattern). XOR swizzle
// ((row>>1)&3)<<4 (verified conflict-free r5).
__global__ __launch_bounds__(1024)
void k_gemm_nt256(const unsigned short* __restrict__ A, const unsigned short* __restrict__ B,
                  const float* __restrict__ bias,
                  float* __restrict__ outF, unsigned short* __restrict__ outB,
                  int M, int N, int K, int lda, int ldb, int ldc,
                  long sPart)
{
    __shared__ unsigned short smem[3 * 16384];   // 3 bufs x (A16KB + B16KB)

    unsigned gx = gridDim.x, gy = gridDim.y;
    unsigned nwg = gx * gy * gridDim.z;
    unsigned lin = (blockIdx.z * gy + blockIdx.y) * gx + blockIdx.x;
    unsigned bx = blockIdx.x, by = blockIdx.y, bz = blockIdx.z;
    if ((nwg & 7u) == 0u) {
        unsigned cpx = nwg >> 3;
        unsigned s = (lin & 7u) * cpx + (lin >> 3);
        bx = s % gx; unsigned r2 = s / gx;
        by = r2 % gy; bz = r2 / gy;
    }
    int s_k = (int)bz;                       // split-K slice (gridDim.z = S)
    const unsigned short* Ap = A + (long)s_k * K;
    const unsigned short* Bp = B + (long)s_k * K;
    float* outFp = outF ? outF + (long)s_k * sPart : nullptr;

    int t = threadIdx.x;
    int wid = t >> 6, lane = t & 63;
    int lrow = lane & 15, kgrp = lane >> 4;
    int tm = by * 256, tn = bx * 256;
    int wm = (wid >> 2) * 64, wn = (wid & 3) * 64;

    // stage one BK=32 tile pair: A 16KB + B 16KB (2 gload_lds per thread).
    auto stage = [&](int buf, int k0) {
        int d = t * 16;                                   // byte in 16KB tile
        int row = d >> 6;
        int colb = (d & 63) ^ (((row >> 1) & 3) << 4);    // inverse swizzle
        int gr = tm + row; if (gr > M - 1) gr = M - 1;
        const unsigned short* srcA = Ap + (long)gr * lda + k0 + (colb >> 1);
        unsigned short* dstA = smem + ((buf * 32768 + d) >> 1);
        __builtin_amdgcn_global_load_lds(
            (const __attribute__((address_space(1))) unsigned int*)srcA,
            (__attribute__((address_space(3))) unsigned int*)dstA, 16, 0, 0);
        int gn = tn + row; if (gn > N - 1) gn = N - 1;
        const unsigned short* srcB = Bp + (long)gn * ldb + k0 + (colb >> 1);
        unsigned short* dstB = smem + ((buf * 32768 + 16384 + d) >> 1);
        __builtin_amdgcn_global_load_lds(
            (const __attribute__((address_space(1))) unsigned int*)srcB,
            (__attribute__((address_space(3))) unsigned int*)dstB, 16, 0, 0);
    };

    f32x4 acc[4][4] = {};
    int nt = K >> 5;

    stage(0, 0);
    if (nt > 1) stage(1, 32);

    for (int ti = 0; ti < nt; ++ti) {
        int cur = ti % 3;
        if (ti + 1 < nt) asm volatile("s_waitcnt vmcnt(2)" ::: "memory");
        else             asm volatile("s_waitcnt vmcnt(0)" ::: "memory");
        __builtin_amdgcn_sched_barrier(0);
        __builtin_amdgcn_s_barrier();
        __builtin_amdgcn_sched_barrier(0);

        if (ti + 2 < nt) stage((ti + 2) % 3, (ti + 2) << 5);

        const char* Ab = (const char*)smem + cur * 32768;
        const char* Bb = Ab + 16384;
        short8 a[4], bb[4];
#pragma unroll
        for (int i = 0; i < 4; ++i) {
            int row = wm + i * 16 + lrow;
            a[i] = *(const short8*)(Ab + row * 64 + ((kgrp * 16) ^ (((row >> 1) & 3) << 4)));
        }
#pragma unroll
        for (int j = 0; j < 4; ++j) {
            int row = wn + j * 16 + lrow;
            bb[j] = *(const short8*)(Bb + row * 64 + ((kgrp * 16) ^ (((row >> 1) & 3) << 4)));
        }
#pragma unroll
        for (int i = 0; i < 4; ++i)
#pragma unroll
            for (int j = 0; j < 4; ++j)
                acc[i][j] = __builtin_amdgcn_mfma_f32_16x16x32_bf16(a[i], bb[j], acc[i][j], 0, 0, 0);
    }

#pragma unroll
    for (int i = 0; i < 4; ++i) {
        int rbase = tm + wm + i * 16 + kgrp * 4;
#pragma unroll
        for (int j = 0; j < 4; ++j) {
            int c = tn + wn + j * 16 + lrow;
            if (c >= N) continue;
            float bv = bias ? bias[c] : 0.0f;
#pragma unroll
            for (int e = 0; e < 4; ++e) {
                int r = rbase + e;
                if (r >= M) continue;
                float v = acc[i][j][e] + bv;
                long oidx = (long)r * ldc + c;
                if (outFp) outFp[oidx] = v;
                if (outB) outB[oidx] = f2bf(v);
            }
        }
    }
}

// ------------------------------ GEMM NT (pipelined 128²) --------------------
template<bool GELU>
__global__ __launch_bounds__(256)
void k_gemm_nt(const unsigned short* __restrict__ A, const unsigned short* __restrict__ B,
               const float* __restrict__ bias, const float* __restrict__ res,
               float* __restrict__ outF, unsigned short* __restrict__ outB,
               int M, int N, int K, int lda, int ldb, int ldc,
               int H, long sAb, long sAh, long sBb, long sBh, long sCb, long sCh,
               float scale, int S, long sPart)
{
    __shared__ unsigned short smem[5 * 8192];   // 5 bufs x (A 8KB + B 8KB) = 80KB

    unsigned gx = gridDim.x, gy = gridDim.y, gz = gridDim.z;
    unsigned nwg = gx * gy * gz;
    unsigned lin = (blockIdx.z * gy + blockIdx.y) * gx + blockIdx.x;
    unsigned bx = blockIdx.x, by = blockIdx.y, bz = blockIdx.z;
    if ((nwg & 7u) == 0u) {
        unsigned cpx = nwg >> 3;
        unsigned s = (lin & 7u) * cpx + (lin >> 3);
        bx = s % gx; unsigned r2 = s / gx;
        by = r2 % gy; bz = r2 / gy;
    }

    int zz = (int)bz;
    int s_k = 0;
    if (S > 1) { s_k = zz % S; zz /= S; }
    int b = zz / H, h = zz - b * H;
    const unsigned short* Ap = A + (long)b * sAb + (long)h * sAh + (long)s_k * K;
    const unsigned short* Bp = B + (long)b * sBb + (long)h * sBh + (long)s_k * K;
    float* outFp = outF;
    if (outFp && S > 1) outFp += (long)s_k * sPart;
    long offC = (long)b * sCb + (long)h * sCh;

    int t    = threadIdx.x;
    int wid  = t >> 6;
    int lane = t & 63;
    int lrow = lane & 15;
    int kgrp = lane >> 4;

    int tm = by * 128;
    int tn = bx * 128;
    int wm = (wid >> 1) * 64;
    int wn = (wid & 1) * 64;

    auto stage = [&](int buf, int k0) {
#pragma unroll
        for (int r = 0; r < 2; ++r) {
            int d = r * 4096 + t * 16;
            int row = d >> 6;
            int colb = (d & 63) ^ (((row >> 1) & 3) << 4);
            int gr = tm + row; if (gr > M - 1) gr = M - 1;
            const unsigned short* srcA = Ap + (long)gr * lda + k0 + (colb >> 1);
            unsigned short* dstA = smem + ((buf * 16384 + r * 4096 + wid * 1024) >> 1);
            __builtin_amdgcn_global_load_lds(
                (const __attribute__((address_space(1))) unsigned int*)srcA,
                (__attribute__((address_space(3))) unsigned int*)dstA, 16, 0, 0);
            int gn = tn + row; if (gn > N - 1) gn = N - 1;
            const unsigned short* srcB = Bp + (long)gn * ldb + k0 + (colb >> 1);
            unsigned short* dstB = smem + ((buf * 16384 + 8192 + r * 4096 + wid * 1024) >> 1);
            __builtin_amdgcn_global_load_lds(
                (const __attribute__((address_space(1))) unsigned int*)srcB,
                (__attribute__((address_space(3))) unsigned int*)dstB, 16, 0, 0);
        }
    };

    f32x4 acc[4][4] = {};
    int nt = K >> 5;

    for (int p = 0; p < 4 && p < nt; ++p) stage(p, p << 5);

    for (int ti = 0; ti < nt; ++ti) {
        int cur = ti % 5;
        int rem = nt - 1 - ti;
        if (rem >= 3)      asm volatile("s_waitcnt vmcnt(12)" ::: "memory");
        else if (rem == 2) asm volatile("s_waitcnt vmcnt(8)"  ::: "memory");
        else if (rem == 1) asm volatile("s_waitcnt vmcnt(4)"  ::: "memory");
        else               asm volatile("s_waitcnt vmcnt(0)"  ::: "memory");
        __builtin_amdgcn_sched_barrier(0);
        __builtin_amdgcn_s_barrier();
        __builtin_amdgcn_sched_barrier(0);

        if (ti + 4 < nt) stage((ti + 4) % 5, (ti + 4) << 5);

        const char* Ab = (const char*)smem + cur * 16384;
        const char* Bb = Ab + 8192;
        short8 a[4], bb[4];
#pragma unroll
        for (int i = 0; i < 4; ++i) {
            int row = wm + i * 16 + lrow;
            a[i] = *(const short8*)(Ab + row * 64 + ((kgrp * 16) ^ (((row >> 1) & 3) << 4)));
        }
#pragma unroll
        for (int j = 0; j < 4; ++j) {
            int row = wn + j * 16 + lrow;
            bb[j] = *(const short8*)(Bb + row * 64 + ((kgrp * 16) ^ (((row >> 1) & 3) << 4)));
        }
#pragma unroll
        for (int i = 0; i < 4; ++i)
#pragma unroll
            for (int j = 0; j < 4; ++j)
                acc[i][j] = __builtin_amdgcn_mfma_f32_16x16x32_bf16(a[i], bb[j], acc[i][j], 0, 0, 0);
    }

#pragma unroll
    for (int i = 0; i < 4; ++i) {
        int rbase = tm + wm + i * 16 + kgrp * 4;
#pragma unroll
        for (int j = 0; j < 4; ++j) {
            int c = tn + wn + j * 16 + lrow;
            if (c >= N) continue;
            float bv = bias ? bias[c] : 0.0f;
#pragma unroll
            for (int e = 0; e < 4; ++e) {
                int r = rbase + e;
                if (r >= M) continue;
                float v = acc[i][j][e] * scale + bv;
                long oidx = offC + (long)r * ldc + c;
                if (res) v += res[oidx];
                if (GELU) v = 0.5f * v * (1.0f + erff(v * 0.70710678118654752f));
                if (outFp) outFp[oidx] = v;
                if (outB) outB[oidx] = f2bf(v);
            }
        }
    }
}

// ------------------------------ split-K reduce -------------------------------
__global__ __launch_bounds__(256)
void k_redux(const float* __restrict__ part, long sPart4, int S,
             const float* __restrict__ bias, const float* __restrict__ res,
             float* __restrict__ outF, unsigned short* __restrict__ outB,
             long n4, int ldc4, int gelu)
{
    const float4* p4 = (const float4*)part;
    long i = (long)blockIdx.x * blockDim.x + threadIdx.x;
    long stride = (long)gridDim.x * blockDim.x;
    for (; i < n4; i += stride) {
        int c = (int)(i % ldc4);
        float4 v = p4[i];
        for (int s = 1; s < S; ++s) {
            float4 w = p4[i + (long)s * sPart4];
            v.x += w.x; v.y += w.y; v.z += w.z; v.w += w.w;
        }
        if (bias) {
            float4 bv = ((const float4*)bias)[c];
            v.x += bv.x; v.y += bv.y; v.z += bv.z; v.w += bv.w;
        }
        if (res) {
            float4 rv = ((const float4*)res)[i];
            v.x += rv.x; v.y += rv.y; v.z += rv.z; v.w += rv.w;
        }
        if (gelu) {
            v.x = 0.5f * v.x * (1.0f + erff(v.x * 0.70710678118654752f));
            v.y = 0.5f * v.y * (1.0f + erff(v.y * 0.70710678118654752f));
            v.z = 0.5f * v.z * (1.0f + erff(v.z * 0.70710678118654752f));
            v.w = 0.5f * v.w * (1.0f + erff(v.w * 0.70710678118654752f));
        }
        if (outF) ((float4*)outF)[i] = v;
        if (outB) {
            ushort4 o;
            o.x = f2bf(v.x); o.y = f2bf(v.y); o.z = f2bf(v.z); o.w = f2bf(v.w);
            ((ushort4*)outB)[i] = o;
        }
    }
}

// ---------------------- tiled transpose (bf16) ------------------------------
__global__ __launch_bounds__(256)
void k_tr(const unsigned short* __restrict__ in, unsigned short* __restrict__ out,
          int R, int ldin, int ldout,
          int H, long sIb, long sIh, long sOz)
{
    __shared__ unsigned short tile[32][33];
    int z = blockIdx.z;
    int b = z / H, h = z - b * H;
    const unsigned short* ip = in + (long)b * sIb + (long)h * sIh;
    unsigned short* op = out + (long)z * sOz;
    int t = threadIdx.x;
    int cl = t & 31, rl = t >> 5;
    int c0 = blockIdx.x * 32, r0 = blockIdx.y * 32;
#pragma unroll
    for (int i = 0; i < 4; ++i) {
        int r = r0 + rl + i * 8;
        unsigned short v = 0;
        if (r < R) v = ip[(long)r * ldin + (c0 + cl)];
        tile[rl + i * 8][cl] = v;
    }
    __syncthreads();
#pragma unroll
    for (int i = 0; i < 4; ++i) {
        int orow = c0 + rl + i * 8;
        int ocol = r0 + cl;
        op[(long)orow * ldout + ocol] = tile[cl][rl + i * 8];
    }
}

// --------------------------- masked softmax (w/ partial-sum) ----------------
// Reads S fp32 partial score slices (stride sPart elems), sums, masks,
// softmaxes, writes bf16 P rows (ld_p shorts), zero-padded to Lpad.
__global__ __launch_bounds__(256)
void k_softmax_p(const float* __restrict__ sc, long sPart, int S,
                 unsigned short* __restrict__ P,
                 const int* __restrict__ mask, int L, int Lpad,
                 int ld_sc, int ld_p, int rows_per_batch)
{
    int row = blockIdx.x;
    int b = row / rows_per_batch;
    const float* p = sc + (long)row * ld_sc;
    unsigned short* po = P + (long)row * ld_p;
    const int* mrow = mask + (long)b * L;
    int t = threadIdx.x;
    int lane = t & 63, wid = t >> 6;

    int j0 = t, j1 = t + 256;
    float v0 = -INFINITY, v1 = -INFINITY;
    if (j0 < L) {
        float x = 0.f;
        for (int s = 0; s < S; ++s) x += p[j0 + (long)s * sPart];
        if (mrow[j0] != 0) v0 = x;
    }
    if (j1 < L) {
        float x = 0.f;
        for (int s = 0; s < S; ++s) x += p[j1 + (long)s * sPart];
        if (mrow[j1] != 0) v1 = x;
    }

    float mx = fmaxf(v0, v1);
#pragma unroll
    for (int s = 32; s > 0; s >>= 1) mx = fmaxf(mx, __shfl_xor(mx, s, 64));
    __shared__ float wr[4], wsum[4];
    if (lane == 0) wr[wid] = mx;
    __syncthreads();
    mx = fmaxf(fmaxf(wr[0], wr[1]), fmaxf(wr[2], wr[3]));

    float e0 = (v0 == -INFINITY) ? 0.0f : __expf(v0 - mx);
    float e1 = (v1 == -INFINITY) ? 0.0f : __expf(v1 - mx);
    float sm = e0 + e1;
#pragma unroll
    for (int s = 32; s > 0; s >>= 1) sm += __shfl_xor(sm, s, 64);
    if (lane == 0) wsum[wid] = sm;
    __syncthreads();          // orders: score reads done before P writes
    float inv = 1.0f / (wsum[0] + wsum[1] + wsum[2] + wsum[3]);

    if (j0 < Lpad) po[j0] = f2bf((j0 < L) ? e0 * inv : 0.0f);
    if (j1 < Lpad) po[j1] = f2bf((j1 < L) ? e1 * inv : 0.0f);
}

// ------------------------------ LayerNorm ----------------------------------
__global__ __launch_bounds__(256)
void k_ln(const float* __restrict__ x, const float* __restrict__ g, const float* __restrict__ bt,
          float* __restrict__ yf, unsigned short* __restrict__ yb)
{
    int row = blockIdx.x;
    const float* xr = x + (long)row * 1024;
    int t = threadIdx.x;
    int lane = t & 63, wid = t >> 6;
    float4 v = *(const float4*)(xr + t * 4);
    float s  = v.x + v.y + v.z + v.w;
    float ss = v.x * v.x + v.y * v.y + v.z * v.z + v.w * v.w;
#pragma unroll
    for (int d = 32; d > 0; d >>= 1) { s += __shfl_xor(s, d, 64); ss += __shfl_xor(ss, d, 64); }
    __shared__ float rs[4], rss[4];
    if (lane == 0) { rs[wid] = s; rss[wid] = ss; }
    __syncthreads();
    s  = rs[0] + rs[1] + rs[2] + rs[3];
    ss = rss[0] + rss[1] + rss[2] + rss[3];
    float mu  = s  * (1.0f / 1024.0f);
    float var = ss * (1.0f / 1024.0f) - mu * mu;
    float inv = rsqrtf(var + 1e-5f);
    float xv[4] = { v.x, v.y, v.z, v.w };
#pragma unroll
    for (int e = 0; e < 4; ++e) {
        int c = t * 4 + e;
        float yv = (xv[e] - mu) * inv * g[c] + bt[c];
        yf[(long)row * 1024 + c] = yv;
        yb[(long)row * 1024 + c] = f2bf(yv);
    }
}

// ------------------------- combine (w/ partial-sum) -------------------------
__global__ void k_combine(float* __restrict__ qf, unsigned short* __restrict__ qb,
                          const float* __restrict__ aggtp, const float* __restrict__ aggrp,
                          const float* __restrict__ alpha, long n, long sPart, int S)
{
    float a = *alpha;
    long i = (long)blockIdx.x * blockDim.x + threadIdx.x;
    long stride = (long)gridDim.x * blockDim.x;
    for (; i < n; i += stride) {
        float st = 0.f, sr = 0.f;
        for (int s = 0; s < S; ++s) {
            st += aggtp[i + (long)s * sPart];
            sr += aggrp[i + (long)s * sPart];
        }
        float v = qf[i] + a * sr + (1.0f - a) * st;
        qf[i] = v;
        qb[i] = f2bf(v);
    }
}

// ---------------------------------------------------------------------------
extern "C" void kernel_launch(void* const* d_in, const int* in_sizes, int n_in,
                              void* d_out, int out_size, void* d_ws, size_t ws_size,
                              hipStream_t stream)
{
    const float* queries = (const float*)d_in[0];
    const float* text    = (const float*)d_in[1];
    const float* region  = (const float*)d_in[2];
    const int*   tmask   = (const int*)d_in[3];
    const int*   rmask   = (const int*)d_in[4];
    const float* w_qkv_t = (const float*)d_in[5];
    const float* b_qkv_t = (const float*)d_in[6];
    const float* w_o_t   = (const float*)d_in[7];
    const float* b_o_t   = (const float*)d_in[8];
    const float* w_qkv_r = (const float*)d_in[9];
    const float* b_qkv_r = (const float*)d_in[10];
    const float* w_o_r   = (const float*)d_in[11];
    const float* b_o_r   = (const float*)d_in[12];
    const float* ln_g    = (const float*)d_in[13];
    const float* ln_b    = (const float*)d_in[14];
    const float* w1      = (const float*)d_in[15];
    const float* b1      = (const float*)d_in[16];
    const float* w2      = (const float*)d_in[17];
    const float* b2      = (const float*)d_in[18];
    const float* alpha   = (const float*)d_in[19];

    const int Bn = 16, NQ = 128, LT = 512, LR = 196, D = 1024, H = 16;
    const int LRp = 256;
    const int MQ = Bn * NQ;              // 2048
    const int MT = Bn * LT;              // 8192
    const int MR = Bn * LR;              // 3136

    char* ws = (char*)d_ws;
    size_t off = 0;
    auto alloc = [&](size_t bytes) -> void* {
        void* p = ws + off;
        off = (off + bytes + 255) & ~(size_t)255;
        return p;
    };
    unsigned short* qb     = (unsigned short*)alloc((size_t)MQ * D * 2);
    unsigned short* tb     = (unsigned short*)alloc((size_t)MT * D * 2);
    unsigned short* rb     = (unsigned short*)alloc((size_t)MR * D * 2);
    unsigned short* wqkvtb = (unsigned short*)alloc((size_t)3 * D * D * 2);
    unsigned short* wotb   = (unsigned short*)alloc((size_t)D * D * 2);
    unsigned short* wqkvrb = (unsigned short*)alloc((size_t)3 * D * D * 2);
    unsigned short* worb   = (unsigned short*)alloc((size_t)D * D * 2);
    unsigned short* w1b    = (unsigned short*)alloc((size_t)4 * D * D * 2);
    unsigned short* w2b    = (unsigned short*)alloc((size_t)4 * D * D * 2);
    unsigned short* ktv    = (unsigned short*)alloc((size_t)MT * 2 * D * 2);
    unsigned short* krv    = (unsigned short*)alloc((size_t)MR * 2 * D * 2);
    unsigned short* vtT    = (unsigned short*)alloc((size_t)Bn * H * 64 * LT * 2);
    unsigned short* vrT    = (unsigned short*)alloc((size_t)Bn * H * 64 * LRp * 2);
    unsigned short* qp     = (unsigned short*)alloc((size_t)MQ * D * 2);
    unsigned short* ao     = (unsigned short*)alloc((size_t)MQ * D * 2);
    unsigned short* qlnb   = (unsigned short*)alloc((size_t)MQ * D * 2);
    float* xf   = (float*)alloc((size_t)MQ * D * 4);
    float* qlf  = (float*)alloc((size_t)MQ * D * 4);
    float* sc   = (float*)alloc((size_t)Bn * H * NQ * LT * 4);   // 67MB arena
    if (off > ws_size) return;

    // phase-reused views
    unsigned short* tbT = ktv;                               // [B][1024][512]
    unsigned short* rbT = ktv + (size_t)Bn * D * LT;         // [B][1024][256p]
    float* sct = sc;                                         // MHA scores (fp32, whole arena)
    float* scr = sc;
    // manual-phase layout inside sc (floats):
    unsigned short* Pt = (unsigned short*)sc;                          // [0, .52M) fl
    unsigned short* Pr = (unsigned short*)(sc + 1 * 1048576);          // [1.0M,1.3M)
    float* atp   = sc + 2 * 1048576;       // 4 x 1,048,576   [2M, 6.3M)
    float* arp   = sc + 6 * 1048576;       // 4 x   524,288   [6.3M, 8.4M)
    float* aggtp = sc + 8 * 1048576;       // 2 x 2,097,152   [8.4M, 12.6M)
    float* aggrp = sc + 12 * 1048576;      // 2 x 2,097,152   [12.6M, 16.8M)
    unsigned short* hb = (unsigned short*)sc;                // FFN hidden bf16 [0,16MB)
    float* part_q  = sc;                                     // Q/O-proj partials
    float* part_f1 = (float*)ktv;                            // FFN1 partials (spills into dead krv/vtT/vrT/qp)
    float* part_f2 = (float*)ktv;                            // FFN2 partials

    const long PQ = (long)MQ * D;        // 2048*1024 partial slice

    // ---- all converts in one balanced launch ----
    {
        CvtPack pk;
        const float* srcs[9] = { queries, text, region, w_qkv_t, w_o_t, w_qkv_r, w_o_r, w1, w2 };
        unsigned short* dsts[9] = { qb, tb, rb, wqkvtb, wotb, wqkvrb, worb, w1b, w2b };
        long ns[9] = { (long)MQ * D, (long)MT * D, (long)MR * D, (long)3 * D * D,
                       (long)D * D, (long)3 * D * D, (long)D * D, (long)4 * D * D,
                       (long)4 * D * D };
        long acc4 = 0;
        pk.start4[0] = 0;
        for (int i = 0; i < 9; ++i) {
            pk.src[i] = srcs[i]; pk.dst[i] = dsts[i];
            acc4 += ns[i] / 4;
            pk.start4[i + 1] = acc4;
        }
        k_cvt_multi<<<2048, 256, 0, stream>>>(pk, acc4);
    }

    auto NT = [&](const unsigned short* A, const unsigned short* Bm, const float* bias,
                  const float* res, float* oF, unsigned short* oB,
                  int M, int N, int K, int lda, int ldb, int ldc,
                  int Hh, long sAb, long sAh, long sBb, long sBh, long sCb, long sCh,
                  int batch, float scale, bool gelu, int S = 1, long sPart = 0) {
        dim3 g((N + 127) / 128, (M + 127) / 128, batch * S);
        if (gelu)
            k_gemm_nt<true><<<g, 256, 0, stream>>>(A, Bm, bias, res, oF, oB, M, N, K,
                lda, ldb, ldc, Hh, sAb, sAh, sBb, sBh, sCb, sCh, scale, S, sPart);
        else
            k_gemm_nt<false><<<g, 256, 0, stream>>>(A, Bm, bias, res, oF, oB, M, N, K,
                lda, ldb, ldc, Hh, sAb, sAh, sBb, sBh, sCb, sCh, scale, S, sPart);
    };
    auto NT256 = [&](const unsigned short* A, const unsigned short* Bm, const float* bias,
                     float* oF, unsigned short* oB, int M, int N, int Kc,
                     int lda, int ldb, int ldc, int S, long sPart) {
        dim3 g((N + 255) / 256, (M + 255) / 256, S);
        k_gemm_nt256<<<g, 1024, 0, stream>>>(A, Bm, bias, oF, oB, M, N, Kc,
                                             lda, ldb, ldc, sPart);
    };
    auto REDUX = [&](const float* part, long sPart, int S, const float* bias,
                     const float* res, float* oF, unsigned short* oB,
                     long total, int ldc, int gelu) {
        long n4 = total / 4;
        int blocks = (int)((n4 + 255) / 256);
        if (blocks > 2048) blocks = 2048;
        k_redux<<<blocks, 256, 0, stream>>>(part, sPart / 4, S, bias, res, oF, oB,
                                            n4, ldc / 4, gelu);
    };

    // ---- fused K+V projections ----
    NT256(tb, wqkvtb + (long)D * D, b_qkv_t + D, nullptr, ktv,
          MT, 2 * D, D, D, D, 2 * D, 1, 0);
    NT(rb, wqkvrb + (long)D * D, b_qkv_r + D, nullptr, nullptr, krv,
       MR, 2 * D, D, D, D, 2 * D, 1,0,0,0,0,0,0, 1, 1.0f, false);

    // per-head V transposes
    {
        dim3 g1(64 / 32, LT / 32, Bn * H);
        k_tr<<<g1, 256, 0, stream>>>(ktv + D, vtT, LT, 2 * D, LT,
                                     H, (long)LT * 2 * D, 64, (long)64 * LT);
        dim3 g2(64 / 32, LRp / 32, Bn * H);
        k_tr<<<g2, 256, 0, stream>>>(krv + D, vrT, LR, 2 * D, LRp,
                                     H, (long)LR * 2 * D, 64, (long)64 * LRp);
    }

    // ================= MHA 1 (text) =================
    NT(qb, wqkvtb, nullptr, nullptr, part_q, nullptr, MQ, D, 256, D, D, D,
       1,0,0,0,0,0,0, 1, 1.0f, false, 4, PQ);
    REDUX(part_q, PQ, 4, b_qkv_t, nullptr, nullptr, qp, PQ, D, 0);
    NT(qp, ktv, nullptr, nullptr, sct, nullptr, NQ, LT, 64, D, 2 * D, LT,
       H, (long)NQ * D, 64, (long)LT * 2 * D, 64, (long)H * NQ * LT, (long)NQ * LT,
       Bn * H, 0.125f, false);
    k_softmax_p<<<Bn * H * NQ, 256, 0, stream>>>(sct, 0, 1, (unsigned short*)sct, tmask,
                                                 LT, LT, LT, 2 * LT, H * NQ);
    NT((const unsigned short*)sct, vtT, nullptr, nullptr, nullptr, ao, NQ, 64, LT,
       2 * LT, LT, D,
       H, (long)H * NQ * 2 * LT, (long)NQ * 2 * LT, (long)64 * LT * H, (long)64 * LT,
       (long)NQ * D, 64, Bn * H, 1.0f, false);
    NT(ao, wotb, nullptr, nullptr, part_q, nullptr, MQ, D, 256, D, D, D,
       1,0,0,0,0,0,0, 1, 1.0f, false, 4, PQ);
    REDUX(part_q, PQ, 4, b_o_t, queries, xf, nullptr, PQ, D, 0);
    k_ln<<<MQ, 256, 0, stream>>>(xf, ln_g, ln_b, qlf, qlnb);

    // ================= MHA 2 (region) =================
    NT(qlnb, wqkvrb, nullptr, nullptr, part_q, nullptr, MQ, D, 256, D, D, D,
       1,0,0,0,0,0,0, 1, 1.0f, false, 4, PQ);
    REDUX(part_q, PQ, 4, b_qkv_r, nullptr, nullptr, qp, PQ, D, 0);
    NT(qp, krv, nullptr, nullptr, scr, nullptr, NQ, LR, 64, D, 2 * D, LRp,
       H, (long)NQ * D, 64, (long)LR * 2 * D, 64, (long)H * NQ * LRp, (long)NQ * LRp,
       Bn * H, 0.125f, false);
    k_softmax_p<<<Bn * H * NQ, 256, 0, stream>>>(scr, 0, 1, (unsigned short*)scr, rmask,
                                                 LR, LRp, LRp, 2 * LRp, H * NQ);
    NT((const unsigned short*)scr, vrT, nullptr, nullptr, nullptr, ao, NQ, 64, LRp,
       2 * LRp, LRp, D,
       H, (long)H * NQ * 2 * LRp, (long)NQ * 2 * LRp, (long)64 * LRp * H, (long)64 * LRp,
       (long)NQ * D, 64, Bn * H, 1.0f, false);
    NT(ao, worb, nullptr, nullptr, part_q, nullptr, MQ, D, 256, D, D, D,
       1,0,0,0,0,0,0, 1, 1.0f, false, 4, PQ);
    REDUX(part_q, PQ, 4, b_o_r, qlf, xf, nullptr, PQ, D, 0);
    k_ln<<<MQ, 256, 0, stream>>>(xf, ln_g, ln_b, qlf, qlnb);

    // ================= manual masked cross-attention =================
    {
        dim3 g1(D / 32, LT / 32, Bn);
        k_tr<<<g1, 256, 0, stream>>>(tb, tbT, LT, D, LT, 1, (long)LT * D, 0, (long)D * LT);
        dim3 g2(D / 32, LRp / 32, Bn);
        k_tr<<<g2, 256, 0, stream>>>(rb, rbT, LR, D, LRp, 1, (long)LR * D, 0, (long)D * LRp);
    }
    // text scores: split-K=4 into atp, redux fused into softmax -> Pt (compact ld=LT)
    NT(qlnb, tb, nullptr, nullptr, atp, nullptr, NQ, LT, 256, D, D, LT,
       1, (long)NQ * D, 0, (long)LT * D, 0, (long)NQ * LT, 0, Bn, 0.03125f, false,
       4, (long)Bn * NQ * LT);
    k_softmax_p<<<Bn * NQ, 256, 0, stream>>>(atp, (long)Bn * NQ * LT, 4, Pt, tmask,
                                             LT, LT, LT, LT, NQ);
    NT(Pt, tbT, nullptr, nullptr, aggtp, nullptr, NQ, D, 256, LT, LT, D,
       1, (long)NQ * LT, 0, (long)D * LT, 0, (long)NQ * D, 0, Bn, 1.0f, false,
       2, PQ);
    // region scores: split-K=4 into arp -> Pr (compact ld=LRp)
    NT(qlnb, rb, nullptr, nullptr, arp, nullptr, NQ, LR, 256, D, D, LRp,
       1, (long)NQ * D, 0, (long)LR * D, 0, (long)NQ * LRp, 0, Bn, 0.03125f, false,
       4, (long)Bn * NQ * LRp);
    k_softmax_p<<<Bn * NQ, 256, 0, stream>>>(arp, (long)Bn * NQ * LRp, 4, Pr, rmask,
                                             LR, LRp, LRp, LRp, NQ);
    NT(Pr, rbT, nullptr, nullptr, aggrp, nullptr, NQ, D, 128, LRp, LRp, D,
       1, (long)NQ * LRp, 0, (long)D * LRp, 0, (long)NQ * D, 0, Bn, 1.0f, false,
       2, PQ);

    k_combine<<<2048, 256, 0, stream>>>(qlf, qlnb, aggtp, aggrp, alpha,
                                        (long)MQ * D, PQ, 2);

    // ================= FFN =================
    NT256(qlnb, w1b, nullptr, part_f1, nullptr, MQ, 4 * D, 512,
          D, D, 4 * D, 2, (long)MQ * 4 * D);
    REDUX(part_f1, (long)MQ * 4 * D, 2, b1, nullptr, nullptr, hb,
          (long)MQ * 4 * D, 4 * D, 1);
    NT256(hb, w2b, nullptr, part_f2, nullptr, MQ, D, 512,
          4 * D, 4 * D, D, 8, PQ);
    REDUX(part_f2, PQ, 8, b2, qlf, (float*)d_out, nullptr, PQ, D, 0);
}

// Round 8
// 570.051 us; speedup vs baseline: 1.9472x; 1.0846x over previous
//
#include <hip/hip_runtime.h>
#include <hip/hip_bf16.h>

// ---------------------------------------------------------------------------
// QueryGuidedFusionNet forward on MI355X.
// Round 8: wave-per-row softmax (no barriers/LDS, 4 rows/block) and
// ushort8-store convert. GEMM structure unchanged from round 7.
// ---------------------------------------------------------------------------

typedef __attribute__((ext_vector_type(8))) short short8;   // 8 bf16
typedef __attribute__((ext_vector_type(4))) float f32x4;

#define DEV static __device__ __forceinline__

DEV unsigned short f2bf(float f) {
    unsigned u = __float_as_uint(f);
    u += 0x7fffu + ((u >> 16) & 1u);          // RNE
    return (unsigned short)(u >> 16);
}

// ------------------------- multi-tensor convert (balanced) ------------------
struct CvtPack {
    const float* src[9];
    unsigned short* dst[9];
    long start8[10];        // prefix sums in 8-element units
};

__global__ __launch_bounds__(256)
void k_cvt_multi(CvtPack p, long total8) {
    long i = (long)blockIdx.x * blockDim.x + threadIdx.x;
    long stride = (long)gridDim.x * blockDim.x;
    for (; i < total8; i += stride) {
        int t = 0;
#pragma unroll
        for (int k = 1; k < 9; ++k) t += (i >= p.start8[k]) ? 1 : 0;
        long off = i - p.start8[t];
        const float4* s = (const float4*)p.src[t] + off * 2;
        float4 a = s[0], b = s[1];
        short8 o;
        o[0] = (short)f2bf(a.x); o[1] = (short)f2bf(a.y);
        o[2] = (short)f2bf(a.z); o[3] = (short)f2bf(a.w);
        o[4] = (short)f2bf(b.x); o[5] = (short)f2bf(b.y);
        o[6] = (short)f2bf(b.z); o[7] = (short)f2bf(b.w);
        ((short8*)p.dst[t])[off] = o;       // 16B store
    }
}

// --------------------- GEMM NT 256x256 (16 waves) ---------------------------
// C[m,n] = sum_k A[m,k]*B[n,k] (+bias) ; z = split-K index.
// 1024 threads = 16 waves of 64x64. BK=32. 3 LDS buffers, counted vmcnt(2).
__global__ __launch_bounds__(1024)
void k_gemm_nt256(const unsigned short* __restrict__ A, const unsigned short* __restrict__ B,
                  const float* __restrict__ bias,
                  float* __restrict__ outF, unsigned short* __restrict__ outB,
                  int M, int N, int K, int lda, int ldb, int ldc,
                  long sPart)
{
    __shared__ unsigned short smem[3 * 16384];   // 3 bufs x (A16KB + B16KB)

    unsigned gx = gridDim.x, gy = gridDim.y;
    unsigned nwg = gx * gy * gridDim.z;
    unsigned lin = (blockIdx.z * gy + blockIdx.y) * gx + blockIdx.x;
    unsigned bx = blockIdx.x, by = blockIdx.y, bz = blockIdx.z;
    if ((nwg & 7u) == 0u) {
        unsigned cpx = nwg >> 3;
        unsigned s = (lin & 7u) * cpx + (lin >> 3);
        bx = s % gx; unsigned r2 = s / gx;
        by = r2 % gy; bz = r2 / gy;
    }
    int s_k = (int)bz;
    const unsigned short* Ap = A + (long)s_k * K;
    const unsigned short* Bp = B + (long)s_k * K;
    float* outFp = outF ? outF + (long)s_k * sPart : nullptr;

    int t = threadIdx.x;
    int wid = t >> 6, lane = t & 63;
    int lrow = lane & 15, kgrp = lane >> 4;
    int tm = by * 256, tn = bx * 256;
    int wm = (wid >> 2) * 64, wn = (wid & 3) * 64;

    auto stage = [&](int buf, int k0) {
        int d = t * 16;
        int row = d >> 6;
        int colb = (d & 63) ^ (((row >> 1) & 3) << 4);
        int gr = tm + row; if (gr > M - 1) gr = M - 1;
        const unsigned short* srcA = Ap + (long)gr * lda + k0 + (colb >> 1);
        unsigned short* dstA = smem + ((buf * 32768 + d) >> 1);
        __builtin_amdgcn_global_load_lds(
            (const __attribute__((address_space(1))) unsigned int*)srcA,
            (__attribute__((address_space(3))) unsigned int*)dstA, 16, 0, 0);
        int gn = tn + row; if (gn > N - 1) gn = N - 1;
        const unsigned short* srcB = Bp + (long)gn * ldb + k0 + (colb >> 1);
        unsigned short* dstB = smem + ((buf * 32768 + 16384 + d) >> 1);
        __builtin_amdgcn_global_load_lds(
            (const __attribute__((address_space(1))) unsigned int*)srcB,
            (__attribute__((address_space(3))) unsigned int*)dstB, 16, 0, 0);
    };

    f32x4 acc[4][4] = {};
    int nt = K >> 5;

    stage(0, 0);
    if (nt > 1) stage(1, 32);

    for (int ti = 0; ti < nt; ++ti) {
        int cur = ti % 3;
        if (ti + 1 < nt) asm volatile("s_waitcnt vmcnt(2)" ::: "memory");
        else             asm volatile("s_waitcnt vmcnt(0)" ::: "memory");
        __builtin_amdgcn_sched_barrier(0);
        __builtin_amdgcn_s_barrier();
        __builtin_amdgcn_sched_barrier(0);

        if (ti + 2 < nt) stage((ti + 2) % 3, (ti + 2) << 5);

        const char* Ab = (const char*)smem + cur * 32768;
        const char* Bb = Ab + 16384;
        short8 a[4], bb[4];
#pragma unroll
        for (int i = 0; i < 4; ++i) {
            int row = wm + i * 16 + lrow;
            a[i] = *(const short8*)(Ab + row * 64 + ((kgrp * 16) ^ (((row >> 1) & 3) << 4)));
        }
#pragma unroll
        for (int j = 0; j < 4; ++j) {
            int row = wn + j * 16 + lrow;
            bb[j] = *(const short8*)(Bb + row * 64 + ((kgrp * 16) ^ (((row >> 1) & 3) << 4)));
        }
#pragma unroll
        for (int i = 0; i < 4; ++i)
#pragma unroll
            for (int j = 0; j < 4; ++j)
                acc[i][j] = __builtin_amdgcn_mfma_f32_16x16x32_bf16(a[i], bb[j], acc[i][j], 0, 0, 0);
    }

#pragma unroll
    for (int i = 0; i < 4; ++i) {
        int rbase = tm + wm + i * 16 + kgrp * 4;
#pragma unroll
        for (int j = 0; j < 4; ++j) {
            int c = tn + wn + j * 16 + lrow;
            if (c >= N) continue;
            float bv = bias ? bias[c] : 0.0f;
#pragma unroll
            for (int e = 0; e < 4; ++e) {
                int r = rbase + e;
                if (r >= M) continue;
                float v = acc[i][j][e] + bv;
                long oidx = (long)r * ldc + c;
                if (outFp) outFp[oidx] = v;
                if (outB) outB[oidx] = f2bf(v);
            }
        }
    }
}

// ------------------------------ GEMM NT (pipelined 128²) --------------------
template<bool GELU>
__global__ __launch_bounds__(256)
void k_gemm_nt(const unsigned short* __restrict__ A, const unsigned short* __restrict__ B,
               const float* __restrict__ bias, const float* __restrict__ res,
               float* __restrict__ outF, unsigned short* __restrict__ outB,
               int M, int N, int K, int lda, int ldb, int ldc,
               int H, long sAb, long sAh, long sBb, long sBh, long sCb, long sCh,
               float scale, int S, long sPart)
{
    __shared__ unsigned short smem[5 * 8192];

    unsigned gx = gridDim.x, gy = gridDim.y, gz = gridDim.z;
    unsigned nwg = gx * gy * gz;
    unsigned lin = (blockIdx.z * gy + blockIdx.y) * gx + blockIdx.x;
    unsigned bx = blockIdx.x, by = blockIdx.y, bz = blockIdx.z;
    if ((nwg & 7u) == 0u) {
        unsigned cpx = nwg >> 3;
        unsigned s = (lin & 7u) * cpx + (lin >> 3);
        bx = s % gx; unsigned r2 = s / gx;
        by = r2 % gy; bz = r2 / gy;
    }

    int zz = (int)bz;
    int s_k = 0;
    if (S > 1) { s_k = zz % S; zz /= S; }
    int b = zz / H, h = zz - b * H;
    const unsigned short* Ap = A + (long)b * sAb + (long)h * sAh + (long)s_k * K;
    const unsigned short* Bp = B + (long)b * sBb + (long)h * sBh + (long)s_k * K;
    float* outFp = outF;
    if (outFp && S > 1) outFp += (long)s_k * sPart;
    long offC = (long)b * sCb + (long)h * sCh;

    int t    = threadIdx.x;
    int wid  = t >> 6;
    int lane = t & 63;
    int lrow = lane & 15;
    int kgrp = lane >> 4;

    int tm = by * 128;
    int tn = bx * 128;
    int wm = (wid >> 1) * 64;
    int wn = (wid & 1) * 64;

    auto stage = [&](int buf, int k0) {
#pragma unroll
        for (int r = 0; r < 2; ++r) {
            int d = r * 4096 + t * 16;
            int row = d >> 6;
            int colb = (d & 63) ^ (((row >> 1) & 3) << 4);
            int gr = tm + row; if (gr > M - 1) gr = M - 1;
            const unsigned short* srcA = Ap + (long)gr * lda + k0 + (colb >> 1);
            unsigned short* dstA = smem + ((buf * 16384 + r * 4096 + wid * 1024) >> 1);
            __builtin_amdgcn_global_load_lds(
                (const __attribute__((address_space(1))) unsigned int*)srcA,
                (__attribute__((address_space(3))) unsigned int*)dstA, 16, 0, 0);
            int gn = tn + row; if (gn > N - 1) gn = N - 1;
            const unsigned short* srcB = Bp + (long)gn * ldb + k0 + (colb >> 1);
            unsigned short* dstB = smem + ((buf * 16384 + 8192 + r * 4096 + wid * 1024) >> 1);
            __builtin_amdgcn_global_load_lds(
                (const __attribute__((address_space(1))) unsigned int*)srcB,
                (__attribute__((address_space(3))) unsigned int*)dstB, 16, 0, 0);
        }
    };

    f32x4 acc[4][4] = {};
    int nt = K >> 5;

    for (int p = 0; p < 4 && p < nt; ++p) stage(p, p << 5);

    for (int ti = 0; ti < nt; ++ti) {
        int cur = ti % 5;
        int rem = nt - 1 - ti;
        if (rem >= 3)      asm volatile("s_waitcnt vmcnt(12)" ::: "memory");
        else if (rem == 2) asm volatile("s_waitcnt vmcnt(8)"  ::: "memory");
        else if (rem == 1) asm volatile("s_waitcnt vmcnt(4)"  ::: "memory");
        else               asm volatile("s_waitcnt vmcnt(0)"  ::: "memory");
        __builtin_amdgcn_sched_barrier(0);
        __builtin_amdgcn_s_barrier();
        __builtin_amdgcn_sched_barrier(0);

        if (ti + 4 < nt) stage((ti + 4) % 5, (ti + 4) << 5);

        const char* Ab = (const char*)smem + cur * 16384;
        const char* Bb = Ab + 8192;
        short8 a[4], bb[4];
#pragma unroll
        for (int i = 0; i < 4; ++i) {
            int row = wm + i * 16 + lrow;
            a[i] = *(const short8*)(Ab + row * 64 + ((kgrp * 16) ^ (((row >> 1) & 3) << 4)));
        }
#pragma unroll
        for (int j = 0; j < 4; ++j) {
            int row = wn + j * 16 + lrow;
            bb[j] = *(const short8*)(Bb + row * 64 + ((kgrp * 16) ^ (((row >> 1) & 3) << 4)));
        }
#pragma unroll
        for (int i = 0; i < 4; ++i)
#pragma unroll
            for (int j = 0; j < 4; ++j)
                acc[i][j] = __builtin_amdgcn_mfma_f32_16x16x32_bf16(a[i], bb[j], acc[i][j], 0, 0, 0);
    }

#pragma unroll
    for (int i = 0; i < 4; ++i) {
        int rbase = tm + wm + i * 16 + kgrp * 4;
#pragma unroll
        for (int j = 0; j < 4; ++j) {
            int c = tn + wn + j * 16 + lrow;
            if (c >= N) continue;
            float bv = bias ? bias[c] : 0.0f;
#pragma unroll
            for (int e = 0; e < 4; ++e) {
                int r = rbase + e;
                if (r >= M) continue;
                float v = acc[i][j][e] * scale + bv;
                long oidx = offC + (long)r * ldc + c;
                if (res) v += res[oidx];
                if (GELU) v = 0.5f * v * (1.0f + erff(v * 0.70710678118654752f));
                if (outFp) outFp[oidx] = v;
                if (outB) outB[oidx] = f2bf(v);
            }
        }
    }
}

// ------------------------------ split-K reduce -------------------------------
__global__ __launch_bounds__(256)
void k_redux(const float* __restrict__ part, long sPart4, int S,
             const float* __restrict__ bias, const float* __restrict__ res,
             float* __restrict__ outF, unsigned short* __restrict__ outB,
             long n4, int ldc4, int gelu)
{
    const float4* p4 = (const float4*)part;
    long i = (long)blockIdx.x * blockDim.x + threadIdx.x;
    long stride = (long)gridDim.x * blockDim.x;
    for (; i < n4; i += stride) {
        int c = (int)(i % ldc4);
        float4 v = p4[i];
        for (int s = 1; s < S; ++s) {
            float4 w = p4[i + (long)s * sPart4];
            v.x += w.x; v.y += w.y; v.z += w.z; v.w += w.w;
        }
        if (bias) {
            float4 bv = ((const float4*)bias)[c];
            v.x += bv.x; v.y += bv.y; v.z += bv.z; v.w += bv.w;
        }
        if (res) {
            float4 rv = ((const float4*)res)[i];
            v.x += rv.x; v.y += rv.y; v.z += rv.z; v.w += rv.w;
        }
        if (gelu) {
            v.x = 0.5f * v.x * (1.0f + erff(v.x * 0.70710678118654752f));
            v.y = 0.5f * v.y * (1.0f + erff(v.y * 0.70710678118654752f));
            v.z = 0.5f * v.z * (1.0f + erff(v.z * 0.70710678118654752f));
            v.w = 0.5f * v.w * (1.0f + erff(v.w * 0.70710678118654752f));
        }
        if (outF) ((float4*)outF)[i] = v;
        if (outB) {
            ushort4 o;
            o.x = f2bf(v.x); o.y = f2bf(v.y); o.z = f2bf(v.z); o.w = f2bf(v.w);
            ((ushort4*)outB)[i] = o;
        }
    }
}

// ---------------------- tiled transpose (bf16) ------------------------------
__global__ __launch_bounds__(256)
void k_tr(const unsigned short* __restrict__ in, unsigned short* __restrict__ out,
          int R, int ldin, int ldout,
          int H, long sIb, long sIh, long sOz)
{
    __shared__ unsigned short tile[32][33];
    int z = blockIdx.z;
    int b = z / H, h = z - b * H;
    const unsigned short* ip = in + (long)b * sIb + (long)h * sIh;
    unsigned short* op = out + (long)z * sOz;
    int t = threadIdx.x;
    int cl = t & 31, rl = t >> 5;
    int c0 = blockIdx.x * 32, r0 = blockIdx.y * 32;
#pragma unroll
    for (int i = 0; i < 4; ++i) {
        int r = r0 + rl + i * 8;
        unsigned short v = 0;
        if (r < R) v = ip[(long)r * ldin + (c0 + cl)];
        tile[rl + i * 8][cl] = v;
    }
    __syncthreads();
#pragma unroll
    for (int i = 0; i < 4; ++i) {
        int orow = c0 + rl + i * 8;
        int ocol = r0 + cl;
        op[(long)orow * ldout + ocol] = tile[cl][rl + i * 8];
    }
}

// --------------------- wave-per-row masked softmax ---------------------------
// One 64-lane wave per row; lane holds 4 elems per 256-elem chunk (max 2
// chunks, L<=512). No barriers, no LDS. Sums S fp32 partial slices, masks,
// softmaxes, writes bf16 P rows (ld_p shorts) zero-padded to Lpad.
__global__ __launch_bounds__(256)
void k_softmax_w(const float* __restrict__ sc, long sPart, int S,
                 unsigned short* __restrict__ P,
                 const int* __restrict__ mask, int L, int Lpad,
                 int ld_sc, int ld_p, int rows_per_batch, int nrows)
{
    int gw = (int)((blockIdx.x * 256 + threadIdx.x) >> 6);
    if (gw >= nrows) return;
    int lane = threadIdx.x & 63;
    int b = gw / rows_per_batch;
    const float* p = sc + (long)gw * ld_sc;
    unsigned short* po = P + (long)gw * ld_p;
    const int* mrow = mask + (long)b * L;

    int nch = (Lpad + 255) >> 8;     // 1 or 2
    float v[2][4];
    float mx = -INFINITY;
#pragma unroll
    for (int c = 0; c < 2; ++c) {
        if (c >= nch) { v[c][0]=v[c][1]=v[c][2]=v[c][3] = -INFINITY; continue; }
        int j = c * 256 + lane * 4;
        if (j < L) {
            float4 x = *(const float4*)(p + j);
            for (int s = 1; s < S; ++s) {
                float4 y = *(const float4*)(p + j + (long)s * sPart);
                x.x += y.x; x.y += y.y; x.z += y.z; x.w += y.w;
            }
            int4 m = *(const int4*)(mrow + j);
            v[c][0] = m.x ? x.x : -INFINITY;
            v[c][1] = m.y ? x.y : -INFINITY;
            v[c][2] = m.z ? x.z : -INFINITY;
            v[c][3] = m.w ? x.w : -INFINITY;
        } else {
            v[c][0]=v[c][1]=v[c][2]=v[c][3] = -INFINITY;
        }
        mx = fmaxf(mx, fmaxf(fmaxf(v[c][0], v[c][1]), fmaxf(v[c][2], v[c][3])));
    }
#pragma unroll
    for (int d = 32; d > 0; d >>= 1) mx = fmaxf(mx, __shfl_xor(mx, d, 64));

    float sum = 0.f;
#pragma unroll
    for (int c = 0; c < 2; ++c)
#pragma unroll
        for (int k = 0; k < 4; ++k) {
            float e = (v[c][k] == -INFINITY) ? 0.0f : __expf(v[c][k] - mx);
            v[c][k] = e;
            sum += e;
        }
#pragma unroll
    for (int d = 32; d > 0; d >>= 1) sum += __shfl_xor(sum, d, 64);
    float inv = 1.0f / sum;

#pragma unroll
    for (int c = 0; c < 2; ++c) {
        if (c >= nch) continue;
        int j = c * 256 + lane * 4;
        if (j < Lpad) {
            ushort4 o;
            o.x = f2bf(v[c][0] * inv);
            o.y = f2bf(v[c][1] * inv);
            o.z = f2bf(v[c][2] * inv);
            o.w = f2bf(v[c][3] * inv);
            *(ushort4*)(po + j) = o;
        }
    }
}

// ------------------------------ LayerNorm ----------------------------------
__global__ __launch_bounds__(256)
void k_ln(const float* __restrict__ x, const float* __restrict__ g, const float* __restrict__ bt,
          float* __restrict__ yf, unsigned short* __restrict__ yb)
{
    int row = blockIdx.x;
    const float* xr = x + (long)row * 1024;
    int t = threadIdx.x;
    int lane = t & 63, wid = t >> 6;
    float4 v = *(const float4*)(xr + t * 4);
    float s  = v.x + v.y + v.z + v.w;
    float ss = v.x * v.x + v.y * v.y + v.z * v.z + v.w * v.w;
#pragma unroll
    for (int d = 32; d > 0; d >>= 1) { s += __shfl_xor(s, d, 64); ss += __shfl_xor(ss, d, 64); }
    __shared__ float rs[4], rss[4];
    if (lane == 0) { rs[wid] = s; rss[wid] = ss; }
    __syncthreads();
    s  = rs[0] + rs[1] + rs[2] + rs[3];
    ss = rss[0] + rss[1] + rss[2] + rss[3];
    float mu  = s  * (1.0f / 1024.0f);
    float var = ss * (1.0f / 1024.0f) - mu * mu;
    float inv = rsqrtf(var + 1e-5f);
    float xv[4] = { v.x, v.y, v.z, v.w };
#pragma unroll
    for (int e = 0; e < 4; ++e) {
        int c = t * 4 + e;
        float yv = (xv[e] - mu) * inv * g[c] + bt[c];
        yf[(long)row * 1024 + c] = yv;
        yb[(long)row * 1024 + c] = f2bf(yv);
    }
}

// ------------------------- combine (w/ partial-sum) -------------------------
__global__ void k_combine(float* __restrict__ qf, unsigned short* __restrict__ qb,
                          const float* __restrict__ aggtp, const float* __restrict__ aggrp,
                          const float* __restrict__ alpha, long n, long sPart, int S)
{
    float a = *alpha;
    long i = (long)blockIdx.x * blockDim.x + threadIdx.x;
    long stride = (long)gridDim.x * blockDim.x;
    for (; i < n; i += stride) {
        float st = 0.f, sr = 0.f;
        for (int s = 0; s < S; ++s) {
            st += aggtp[i + (long)s * sPart];
            sr += aggrp[i + (long)s * sPart];
        }
        float v = qf[i] + a * sr + (1.0f - a) * st;
        qf[i] = v;
        qb[i] = f2bf(v);
    }
}

// ---------------------------------------------------------------------------
extern "C" void kernel_launch(void* const* d_in, const int* in_sizes, int n_in,
                              void* d_out, int out_size, void* d_ws, size_t ws_size,
                              hipStream_t stream)
{
    const float* queries = (const float*)d_in[0];
    const float* text    = (const float*)d_in[1];
    const float* region  = (const float*)d_in[2];
    const int*   tmask   = (const int*)d_in[3];
    const int*   rmask   = (const int*)d_in[4];
    const float* w_qkv_t = (const float*)d_in[5];
    const float* b_qkv_t = (const float*)d_in[6];
    const float* w_o_t   = (const float*)d_in[7];
    const float* b_o_t   = (const float*)d_in[8];
    const float* w_qkv_r = (const float*)d_in[9];
    const float* b_qkv_r = (const float*)d_in[10];
    const float* w_o_r   = (const float*)d_in[11];
    const float* b_o_r   = (const float*)d_in[12];
    const float* ln_g    = (const float*)d_in[13];
    const float* ln_b    = (const float*)d_in[14];
    const float* w1      = (const float*)d_in[15];
    const float* b1      = (const float*)d_in[16];
    const float* w2      = (const float*)d_in[17];
    const float* b2      = (const float*)d_in[18];
    const float* alpha   = (const float*)d_in[19];

    const int Bn = 16, NQ = 128, LT = 512, LR = 196, D = 1024, H = 16;
    const int LRp = 256;
    const int MQ = Bn * NQ;              // 2048
    const int MT = Bn * LT;              // 8192
    const int MR = Bn * LR;              // 3136

    char* ws = (char*)d_ws;
    size_t off = 0;
    auto alloc = [&](size_t bytes) -> void* {
        void* p = ws + off;
        off = (off + bytes + 255) & ~(size_t)255;
        return p;
    };
    unsigned short* qb     = (unsigned short*)alloc((size_t)MQ * D * 2);
    unsigned short* tb     = (unsigned short*)alloc((size_t)MT * D * 2);
    unsigned short* rb     = (unsigned short*)alloc((size_t)MR * D * 2);
    unsigned short* wqkvtb = (unsigned short*)alloc((size_t)3 * D * D * 2);
    unsigned short* wotb   = (unsigned short*)alloc((size_t)D * D * 2);
    unsigned short* wqkvrb = (unsigned short*)alloc((size_t)3 * D * D * 2);
    unsigned short* worb   = (unsigned short*)alloc((size_t)D * D * 2);
    unsigned short* w1b    = (unsigned short*)alloc((size_t)4 * D * D * 2);
    unsigned short* w2b    = (unsigned short*)alloc((size_t)4 * D * D * 2);
    unsigned short* ktv    = (unsigned short*)alloc((size_t)MT * 2 * D * 2);
    unsigned short* krv    = (unsigned short*)alloc((size_t)MR * 2 * D * 2);
    unsigned short* vtT    = (unsigned short*)alloc((size_t)Bn * H * 64 * LT * 2);
    unsigned short* vrT    = (unsigned short*)alloc((size_t)Bn * H * 64 * LRp * 2);
    unsigned short* qp     = (unsigned short*)alloc((size_t)MQ * D * 2);
    unsigned short* ao     = (unsigned short*)alloc((size_t)MQ * D * 2);
    unsigned short* qlnb   = (unsigned short*)alloc((size_t)MQ * D * 2);
    float* xf   = (float*)alloc((size_t)MQ * D * 4);
    float* qlf  = (float*)alloc((size_t)MQ * D * 4);
    float* sc   = (float*)alloc((size_t)Bn * H * NQ * LT * 4);   // 67MB arena
    if (off > ws_size) return;

    // phase-reused views
    unsigned short* tbT = ktv;                               // [B][1024][512]
    unsigned short* rbT = ktv + (size_t)Bn * D * LT;         // [B][1024][256p]
    float* sct = sc;
    float* scr = sc;
    unsigned short* Pt = (unsigned short*)sc;                          // manual P-text
    unsigned short* Pr = (unsigned short*)(sc + 1 * 1048576);          // manual P-region
    float* atp   = sc + 2 * 1048576;
    float* arp   = sc + 6 * 1048576;
    float* aggtp = sc + 8 * 1048576;
    float* aggrp = sc + 12 * 1048576;
    unsigned short* hb = (unsigned short*)sc;                // FFN hidden bf16
    float* part_q  = sc;
    float* part_f1 = (float*)ktv;
    float* part_f2 = (float*)ktv;

    const long PQ = (long)MQ * D;

    // ---- all converts in one balanced launch ----
    {
        CvtPack pk;
        const float* srcs[9] = { queries, text, region, w_qkv_t, w_o_t, w_qkv_r, w_o_r, w1, w2 };
        unsigned short* dsts[9] = { qb, tb, rb, wqkvtb, wotb, wqkvrb, worb, w1b, w2b };
        long ns[9] = { (long)MQ * D, (long)MT * D, (long)MR * D, (long)3 * D * D,
                       (long)D * D, (long)3 * D * D, (long)D * D, (long)4 * D * D,
                       (long)4 * D * D };
        long acc8 = 0;
        pk.start8[0] = 0;
        for (int i = 0; i < 9; ++i) {
            pk.src[i] = srcs[i]; pk.dst[i] = dsts[i];
            acc8 += ns[i] / 8;
            pk.start8[i + 1] = acc8;
        }
        k_cvt_multi<<<2048, 256, 0, stream>>>(pk, acc8);
    }

    auto NT = [&](const unsigned short* A, const unsigned short* Bm, const float* bias,
                  const float* res, float* oF, unsigned short* oB,
                  int M, int N, int K, int lda, int ldb, int ldc,
                  int Hh, long sAb, long sAh, long sBb, long sBh, long sCb, long sCh,
                  int batch, float scale, bool gelu, int S = 1, long sPart = 0) {
        dim3 g((N + 127) / 128, (M + 127) / 128, batch * S);
        if (gelu)
            k_gemm_nt<true><<<g, 256, 0, stream>>>(A, Bm, bias, res, oF, oB, M, N, K,
                lda, ldb, ldc, Hh, sAb, sAh, sBb, sBh, sCb, sCh, scale, S, sPart);
        else
            k_gemm_nt<false><<<g, 256, 0, stream>>>(A, Bm, bias, res, oF, oB, M, N, K,
                lda, ldb, ldc, Hh, sAb, sAh, sBb, sBh, sCb, sCh, scale, S, sPart);
    };
    auto NT256 = [&](const unsigned short* A, const unsigned short* Bm, const float* bias,
                     float* oF, unsigned short* oB, int M, int N, int Kc,
                     int lda, int ldb, int ldc, int S, long sPart) {
        dim3 g((N + 255) / 256, (M + 255) / 256, S);
        k_gemm_nt256<<<g, 1024, 0, stream>>>(A, Bm, bias, oF, oB, M, N, Kc,
                                             lda, ldb, ldc, sPart);
    };
    auto REDUX = [&](const float* part, long sPart, int S, const float* bias,
                     const float* res, float* oF, unsigned short* oB,
                     long total, int ldc, int gelu) {
        long n4 = total / 4;
        int blocks = (int)((n4 + 255) / 256);
        if (blocks > 2048) blocks = 2048;
        k_redux<<<blocks, 256, 0, stream>>>(part, sPart / 4, S, bias, res, oF, oB,
                                            n4, ldc / 4, gelu);
    };
    auto SMAX = [&](const float* scp, long sPart, int S, unsigned short* P,
                    const int* mask, int L, int Lpad, int ld_sc, int ld_p,
                    int rpb, int nrows) {
        int blocks = (nrows + 3) / 4;
        k_softmax_w<<<blocks, 256, 0, stream>>>(scp, sPart, S, P, mask, L, Lpad,
                                                ld_sc, ld_p, rpb, nrows);
    };

    // ---- fused K+V projections ----
    NT256(tb, wqkvtb + (long)D * D, b_qkv_t + D, nullptr, ktv,
          MT, 2 * D, D, D, D, 2 * D, 1, 0);
    NT(rb, wqkvrb + (long)D * D, b_qkv_r + D, nullptr, nullptr, krv,
       MR, 2 * D, D, D, D, 2 * D, 1,0,0,0,0,0,0, 1, 1.0f, false);

    // per-head V transposes
    {
        dim3 g1(64 / 32, LT / 32, Bn * H);
        k_tr<<<g1, 256, 0, stream>>>(ktv + D, vtT, LT, 2 * D, LT,
                                     H, (long)LT * 2 * D, 64, (long)64 * LT);
        dim3 g2(64 / 32, LRp / 32, Bn * H);
        k_tr<<<g2, 256, 0, stream>>>(krv + D, vrT, LR, 2 * D, LRp,
                                     H, (long)LR * 2 * D, 64, (long)64 * LRp);
    }

    // ================= MHA 1 (text) =================
    NT(qb, wqkvtb, nullptr, nullptr, part_q, nullptr, MQ, D, 256, D, D, D,
       1,0,0,0,0,0,0, 1, 1.0f, false, 4, PQ);
    REDUX(part_q, PQ, 4, b_qkv_t, nullptr, nullptr, qp, PQ, D, 0);
    NT(qp, ktv, nullptr, nullptr, sct, nullptr, NQ, LT, 64, D, 2 * D, LT,
       H, (long)NQ * D, 64, (long)LT * 2 * D, 64, (long)H * NQ * LT, (long)NQ * LT,
       Bn * H, 0.125f, false);
    SMAX(sct, 0, 1, (unsigned short*)sct, tmask, LT, LT, LT, 2 * LT,
         H * NQ, Bn * H * NQ);
    NT((const unsigned short*)sct, vtT, nullptr, nullptr, nullptr, ao, NQ, 64, LT,
       2 * LT, LT, D,
       H, (long)H * NQ * 2 * LT, (long)NQ * 2 * LT, (long)64 * LT * H, (long)64 * LT,
       (long)NQ * D, 64, Bn * H, 1.0f, false);
    NT(ao, wotb, nullptr, nullptr, part_q, nullptr, MQ, D, 256, D, D, D,
       1,0,0,0,0,0,0, 1, 1.0f, false, 4, PQ);
    REDUX(part_q, PQ, 4, b_o_t, queries, xf, nullptr, PQ, D, 0);
    k_ln<<<MQ, 256, 0, stream>>>(xf, ln_g, ln_b, qlf, qlnb);

    // ================= MHA 2 (region) =================
    NT(qlnb, wqkvrb, nullptr, nullptr, part_q, nullptr, MQ, D, 256, D, D, D,
       1,0,0,0,0,0,0, 1, 1.0f, false, 4, PQ);
    REDUX(part_q, PQ, 4, b_qkv_r, nullptr, nullptr, qp, PQ, D, 0);
    NT(qp, krv, nullptr, nullptr, scr, nullptr, NQ, LR, 64, D, 2 * D, LRp,
       H, (long)NQ * D, 64, (long)LR * 2 * D, 64, (long)H * NQ * LRp, (long)NQ * LRp,
       Bn * H, 0.125f, false);
    SMAX(scr, 0, 1, (unsigned short*)scr, rmask, LR, LRp, LRp, 2 * LRp,
         H * NQ, Bn * H * NQ);
    NT((const unsigned short*)scr, vrT, nullptr, nullptr, nullptr, ao, NQ, 64, LRp,
       2 * LRp, LRp, D,
       H, (long)H * NQ * 2 * LRp, (long)NQ * 2 * LRp, (long)64 * LRp * H, (long)64 * LRp,
       (long)NQ * D, 64, Bn * H, 1.0f, false);
    NT(ao, worb, nullptr, nullptr, part_q, nullptr, MQ, D, 256, D, D, D,
       1,0,0,0,0,0,0, 1, 1.0f, false, 4, PQ);
    REDUX(part_q, PQ, 4, b_o_r, qlf, xf, nullptr, PQ, D, 0);
    k_ln<<<MQ, 256, 0, stream>>>(xf, ln_g, ln_b, qlf, qlnb);

    // ================= manual masked cross-attention =================
    {
        dim3 g1(D / 32, LT / 32, Bn);
        k_tr<<<g1, 256, 0, stream>>>(tb, tbT, LT, D, LT, 1, (long)LT * D, 0, (long)D * LT);
        dim3 g2(D / 32, LRp / 32, Bn);
        k_tr<<<g2, 256, 0, stream>>>(rb, rbT, LR, D, LRp, 1, (long)LR * D, 0, (long)D * LRp);
    }
    NT(qlnb, tb, nullptr, nullptr, atp, nullptr, NQ, LT, 256, D, D, LT,
       1, (long)NQ * D, 0, (long)LT * D, 0, (long)NQ * LT, 0, Bn, 0.03125f, false,
       4, (long)Bn * NQ * LT);
    SMAX(atp, (long)Bn * NQ * LT, 4, Pt, tmask, LT, LT, LT, LT, NQ, Bn * NQ);
    NT(Pt, tbT, nullptr, nullptr, aggtp, nullptr, NQ, D, 256, LT, LT, D,
       1, (long)NQ * LT, 0, (long)D * LT, 0, (long)NQ * D, 0, Bn, 1.0f, false,
       2, PQ);
    NT(qlnb, rb, nullptr, nullptr, arp, nullptr, NQ, LR, 256, D, D, LRp,
       1, (long)NQ * D, 0, (long)LR * D, 0, (long)NQ * LRp, 0, Bn, 0.03125f, false,
       4, (long)Bn * NQ * LRp);
    SMAX(arp, (long)Bn * NQ * LRp, 4, Pr, rmask, LR, LRp, LRp, LRp, NQ, Bn * NQ);
    NT(Pr, rbT, nullptr, nullptr, aggrp, nullptr, NQ, D, 128, LRp, LRp, D,
       1, (long)NQ * LRp, 0, (long)D * LRp, 0, (long)NQ * D, 0, Bn, 1.0f, false,
       2, PQ);

    k_combine<<<2048, 256, 0, stream>>>(qlf, qlnb, aggtp, aggrp, alpha,
                                        (long)MQ * D, PQ, 2);

    // ================= FFN =================
    NT256(qlnb, w1b, nullptr, part_f1, nullptr, MQ, 4 * D, 512,
          D, D, 4 * D, 2, (long)MQ * 4 * D);
    REDUX(part_f1, (long)MQ * 4 * D, 2, b1, nullptr, nullptr, hb,
          (long)MQ * 4 * D, 4 * D, 1);
    NT256(hb, w2b, nullptr, part_f2, nullptr, MQ, D, 512,
          4 * D, 4 * D, D, 8, PQ);
    REDUX(part_f2, PQ, 8, b2, qlf, (float*)d_out, nullptr, PQ, D, 0);
}

// Round 9
// 557.497 us; speedup vs baseline: 1.9911x; 1.0225x over previous
//
#include <hip/hip_runtime.h>
#include <hip/hip_bf16.h>

// ---------------------------------------------------------------------------
// QueryGuidedFusionNet forward on MI355X.
// Round 9: fused split-K-reduce+LayerNorm (kills xf round-trip + k_ln),
// S=4->2 on Q/O-proj split-K, 16-elem/iter convert.
// ---------------------------------------------------------------------------

typedef __attribute__((ext_vector_type(8))) short short8;   // 8 bf16
typedef __attribute__((ext_vector_type(4))) float f32x4;

#define DEV static __device__ __forceinline__

DEV unsigned short f2bf(float f) {
    unsigned u = __float_as_uint(f);
    u += 0x7fffu + ((u >> 16) & 1u);          // RNE
    return (unsigned short)(u >> 16);
}

// ------------------------- multi-tensor convert (balanced) ------------------
struct CvtPack {
    const float* src[9];
    unsigned short* dst[9];
    long start16[10];       // prefix sums in 16-element units
};

__global__ __launch_bounds__(256)
void k_cvt_multi(CvtPack p, long total16) {
    long i = (long)blockIdx.x * blockDim.x + threadIdx.x;
    long stride = (long)gridDim.x * blockDim.x;
    for (; i < total16; i += stride) {
        int t = 0;
#pragma unroll
        for (int k = 1; k < 9; ++k) t += (i >= p.start16[k]) ? 1 : 0;
        long off = i - p.start16[t];
        const float4* s = (const float4*)p.src[t] + off * 4;
        float4 a = s[0], b = s[1], c = s[2], d = s[3];
        short8 o0, o1;
        o0[0] = (short)f2bf(a.x); o0[1] = (short)f2bf(a.y);
        o0[2] = (short)f2bf(a.z); o0[3] = (short)f2bf(a.w);
        o0[4] = (short)f2bf(b.x); o0[5] = (short)f2bf(b.y);
        o0[6] = (short)f2bf(b.z); o0[7] = (short)f2bf(b.w);
        o1[0] = (short)f2bf(c.x); o1[1] = (short)f2bf(c.y);
        o1[2] = (short)f2bf(c.z); o1[3] = (short)f2bf(c.w);
        o1[4] = (short)f2bf(d.x); o1[5] = (short)f2bf(d.y);
        o1[6] = (short)f2bf(d.z); o1[7] = (short)f2bf(d.w);
        short8* dp = (short8*)p.dst[t] + off * 2;
        dp[0] = o0;
        dp[1] = o1;
    }
}

// --------------------- GEMM NT 256x256 (16 waves) ---------------------------
__global__ __launch_bounds__(1024)
void k_gemm_nt256(const unsigned short* __restrict__ A, const unsigned short* __restrict__ B,
                  const float* __restrict__ bias,
                  float* __restrict__ outF, unsigned short* __restrict__ outB,
                  int M, int N, int K, int lda, int ldb, int ldc,
                  long sPart)
{
    __shared__ unsigned short smem[3 * 16384];   // 3 bufs x (A16KB + B16KB)

    unsigned gx = gridDim.x, gy = gridDim.y;
    unsigned nwg = gx * gy * gridDim.z;
    unsigned lin = (blockIdx.z * gy + blockIdx.y) * gx + blockIdx.x;
    unsigned bx = blockIdx.x, by = blockIdx.y, bz = blockIdx.z;
    if ((nwg & 7u) == 0u) {
        unsigned cpx = nwg >> 3;
        unsigned s = (lin & 7u) * cpx + (lin >> 3);
        bx = s % gx; unsigned r2 = s / gx;
        by = r2 % gy; bz = r2 / gy;
    }
    int s_k = (int)bz;
    const unsigned short* Ap = A + (long)s_k * K;
    const unsigned short* Bp = B + (long)s_k * K;
    float* outFp = outF ? outF + (long)s_k * sPart : nullptr;

    int t = threadIdx.x;
    int wid = t >> 6, lane = t & 63;
    int lrow = lane & 15, kgrp = lane >> 4;
    int tm = by * 256, tn = bx * 256;
    int wm = (wid >> 2) * 64, wn = (wid & 3) * 64;

    auto stage = [&](int buf, int k0) {
        int d = t * 16;
        int row = d >> 6;
        int colb = (d & 63) ^ (((row >> 1) & 3) << 4);
        int gr = tm + row; if (gr > M - 1) gr = M - 1;
        const unsigned short* srcA = Ap + (long)gr * lda + k0 + (colb >> 1);
        unsigned short* dstA = smem + ((buf * 32768 + d) >> 1);
        __builtin_amdgcn_global_load_lds(
            (const __attribute__((address_space(1))) unsigned int*)srcA,
            (__attribute__((address_space(3))) unsigned int*)dstA, 16, 0, 0);
        int gn = tn + row; if (gn > N - 1) gn = N - 1;
        const unsigned short* srcB = Bp + (long)gn * ldb + k0 + (colb >> 1);
        unsigned short* dstB = smem + ((buf * 32768 + 16384 + d) >> 1);
        __builtin_amdgcn_global_load_lds(
            (const __attribute__((address_space(1))) unsigned int*)srcB,
            (__attribute__((address_space(3))) unsigned int*)dstB, 16, 0, 0);
    };

    f32x4 acc[4][4] = {};
    int nt = K >> 5;

    stage(0, 0);
    if (nt > 1) stage(1, 32);

    for (int ti = 0; ti < nt; ++ti) {
        int cur = ti % 3;
        if (ti + 1 < nt) asm volatile("s_waitcnt vmcnt(2)" ::: "memory");
        else             asm volatile("s_waitcnt vmcnt(0)" ::: "memory");
        __builtin_amdgcn_sched_barrier(0);
        __builtin_amdgcn_s_barrier();
        __builtin_amdgcn_sched_barrier(0);

        if (ti + 2 < nt) stage((ti + 2) % 3, (ti + 2) << 5);

        const char* Ab = (const char*)smem + cur * 32768;
        const char* Bb = Ab + 16384;
        short8 a[4], bb[4];
#pragma unroll
        for (int i = 0; i < 4; ++i) {
            int row = wm + i * 16 + lrow;
            a[i] = *(const short8*)(Ab + row * 64 + ((kgrp * 16) ^ (((row >> 1) & 3) << 4)));
        }
#pragma unroll
        for (int j = 0; j < 4; ++j) {
            int row = wn + j * 16 + lrow;
            bb[j] = *(const short8*)(Bb + row * 64 + ((kgrp * 16) ^ (((row >> 1) & 3) << 4)));
        }
#pragma unroll
        for (int i = 0; i < 4; ++i)
#pragma unroll
            for (int j = 0; j < 4; ++j)
                acc[i][j] = __builtin_amdgcn_mfma_f32_16x16x32_bf16(a[i], bb[j], acc[i][j], 0, 0, 0);
    }

#pragma unroll
    for (int i = 0; i < 4; ++i) {
        int rbase = tm + wm + i * 16 + kgrp * 4;
#pragma unroll
        for (int j = 0; j < 4; ++j) {
            int c = tn + wn + j * 16 + lrow;
            if (c >= N) continue;
            float bv = bias ? bias[c] : 0.0f;
#pragma unroll
            for (int e = 0; e < 4; ++e) {
                int r = rbase + e;
                if (r >= M) continue;
                float v = acc[i][j][e] + bv;
                long oidx = (long)r * ldc + c;
                if (outFp) outFp[oidx] = v;
                if (outB) outB[oidx] = f2bf(v);
            }
        }
    }
}

// ------------------------------ GEMM NT (pipelined 128²) --------------------
template<bool GELU>
__global__ __launch_bounds__(256)
void k_gemm_nt(const unsigned short* __restrict__ A, const unsigned short* __restrict__ B,
               const float* __restrict__ bias, const float* __restrict__ res,
               float* __restrict__ outF, unsigned short* __restrict__ outB,
               int M, int N, int K, int lda, int ldb, int ldc,
               int H, long sAb, long sAh, long sBb, long sBh, long sCb, long sCh,
               float scale, int S, long sPart)
{
    __shared__ unsigned short smem[5 * 8192];

    unsigned gx = gridDim.x, gy = gridDim.y, gz = gridDim.z;
    unsigned nwg = gx * gy * gz;
    unsigned lin = (blockIdx.z * gy + blockIdx.y) * gx + blockIdx.x;
    unsigned bx = blockIdx.x, by = blockIdx.y, bz = blockIdx.z;
    if ((nwg & 7u) == 0u) {
        unsigned cpx = nwg >> 3;
        unsigned s = (lin & 7u) * cpx + (lin >> 3);
        bx = s % gx; unsigned r2 = s / gx;
        by = r2 % gy; bz = r2 / gy;
    }

    int zz = (int)bz;
    int s_k = 0;
    if (S > 1) { s_k = zz % S; zz /= S; }
    int b = zz / H, h = zz - b * H;
    const unsigned short* Ap = A + (long)b * sAb + (long)h * sAh + (long)s_k * K;
    const unsigned short* Bp = B + (long)b * sBb + (long)h * sBh + (long)s_k * K;
    float* outFp = outF;
    if (outFp && S > 1) outFp += (long)s_k * sPart;
    long offC = (long)b * sCb + (long)h * sCh;

    int t    = threadIdx.x;
    int wid  = t >> 6;
    int lane = t & 63;
    int lrow = lane & 15;
    int kgrp = lane >> 4;

    int tm = by * 128;
    int tn = bx * 128;
    int wm = (wid >> 1) * 64;
    int wn = (wid & 1) * 64;

    auto stage = [&](int buf, int k0) {
#pragma unroll
        for (int r = 0; r < 2; ++r) {
            int d = r * 4096 + t * 16;
            int row = d >> 6;
            int colb = (d & 63) ^ (((row >> 1) & 3) << 4);
            int gr = tm + row; if (gr > M - 1) gr = M - 1;
            const unsigned short* srcA = Ap + (long)gr * lda + k0 + (colb >> 1);
            unsigned short* dstA = smem + ((buf * 16384 + r * 4096 + wid * 1024) >> 1);
            __builtin_amdgcn_global_load_lds(
                (const __attribute__((address_space(1))) unsigned int*)srcA,
                (__attribute__((address_space(3))) unsigned int*)dstA, 16, 0, 0);
            int gn = tn + row; if (gn > N - 1) gn = N - 1;
            const unsigned short* srcB = Bp + (long)gn * ldb + k0 + (colb >> 1);
            unsigned short* dstB = smem + ((buf * 16384 + 8192 + r * 4096 + wid * 1024) >> 1);
            __builtin_amdgcn_global_load_lds(
                (const __attribute__((address_space(1))) unsigned int*)srcB,
                (__attribute__((address_space(3))) unsigned int*)dstB, 16, 0, 0);
        }
    };

    f32x4 acc[4][4] = {};
    int nt = K >> 5;

    for (int p = 0; p < 4 && p < nt; ++p) stage(p, p << 5);

    for (int ti = 0; ti < nt; ++ti) {
        int cur = ti % 5;
        int rem = nt - 1 - ti;
        if (rem >= 3)      asm volatile("s_waitcnt vmcnt(12)" ::: "memory");
        else if (rem == 2) asm volatile("s_waitcnt vmcnt(8)"  ::: "memory");
        else if (rem == 1) asm volatile("s_waitcnt vmcnt(4)"  ::: "memory");
        else               asm volatile("s_waitcnt vmcnt(0)"  ::: "memory");
        __builtin_amdgcn_sched_barrier(0);
        __builtin_amdgcn_s_barrier();
        __builtin_amdgcn_sched_barrier(0);

        if (ti + 4 < nt) stage((ti + 4) % 5, (ti + 4) << 5);

        const char* Ab = (const char*)smem + cur * 16384;
        const char* Bb = Ab + 8192;
        short8 a[4], bb[4];
#pragma unroll
        for (int i = 0; i < 4; ++i) {
            int row = wm + i * 16 + lrow;
            a[i] = *(const short8*)(Ab + row * 64 + ((kgrp * 16) ^ (((row >> 1) & 3) << 4)));
        }
#pragma unroll
        for (int j = 0; j < 4; ++j) {
            int row = wn + j * 16 + lrow;
            bb[j] = *(const short8*)(Bb + row * 64 + ((kgrp * 16) ^ (((row >> 1) & 3) << 4)));
        }
#pragma unroll
        for (int i = 0; i < 4; ++i)
#pragma unroll
            for (int j = 0; j < 4; ++j)
                acc[i][j] = __builtin_amdgcn_mfma_f32_16x16x32_bf16(a[i], bb[j], acc[i][j], 0, 0, 0);
    }

#pragma unroll
    for (int i = 0; i < 4; ++i) {
        int rbase = tm + wm + i * 16 + kgrp * 4;
#pragma unroll
        for (int j = 0; j < 4; ++j) {
            int c = tn + wn + j * 16 + lrow;
            if (c >= N) continue;
            float bv = bias ? bias[c] : 0.0f;
#pragma unroll
            for (int e = 0; e < 4; ++e) {
                int r = rbase + e;
                if (r >= M) continue;
                float v = acc[i][j][e] * scale + bv;
                long oidx = offC + (long)r * ldc + c;
                if (res) v += res[oidx];
                if (GELU) v = 0.5f * v * (1.0f + erff(v * 0.70710678118654752f));
                if (outFp) outFp[oidx] = v;
                if (outB) outB[oidx] = f2bf(v);
            }
        }
    }
}

// ------------------------------ split-K reduce -------------------------------
__global__ __launch_bounds__(256)
void k_redux(const float* __restrict__ part, long sPart4, int S,
             const float* __restrict__ bias, const float* __restrict__ res,
             float* __restrict__ outF, unsigned short* __restrict__ outB,
             long n4, int ldc4, int gelu)
{
    const float4* p4 = (const float4*)part;
    long i = (long)blockIdx.x * blockDim.x + threadIdx.x;
    long stride = (long)gridDim.x * blockDim.x;
    for (; i < n4; i += stride) {
        int c = (int)(i % ldc4);
        float4 v = p4[i];
        for (int s = 1; s < S; ++s) {
            float4 w = p4[i + (long)s * sPart4];
            v.x += w.x; v.y += w.y; v.z += w.z; v.w += w.w;
        }
        if (bias) {
            float4 bv = ((const float4*)bias)[c];
            v.x += bv.x; v.y += bv.y; v.z += bv.z; v.w += bv.w;
        }
        if (res) {
            float4 rv = ((const float4*)res)[i];
            v.x += rv.x; v.y += rv.y; v.z += rv.z; v.w += rv.w;
        }
        if (gelu) {
            v.x = 0.5f * v.x * (1.0f + erff(v.x * 0.70710678118654752f));
            v.y = 0.5f * v.y * (1.0f + erff(v.y * 0.70710678118654752f));
            v.z = 0.5f * v.z * (1.0f + erff(v.z * 0.70710678118654752f));
            v.w = 0.5f * v.w * (1.0f + erff(v.w * 0.70710678118654752f));
        }
        if (outF) ((float4*)outF)[i] = v;
        if (outB) {
            ushort4 o;
            o.x = f2bf(v.x); o.y = f2bf(v.y); o.z = f2bf(v.z); o.w = f2bf(v.w);
            ((ushort4*)outB)[i] = o;
        }
    }
}

// ---------------- fused split-K reduce + bias + residual + LayerNorm --------
// One row (1024 elems) per block. x = sum_s part[s] + bias + res; then
// y = LN(x)*g + b -> yf (fp32) and yb (bf16). Safe when res aliases yf.
__global__ __launch_bounds__(256)
void k_redux_ln(const float* __restrict__ part, long sPart, int S,
                const float* __restrict__ bias, const float* __restrict__ res,
                const float* __restrict__ g, const float* __restrict__ bt,
                float* __restrict__ yf, unsigned short* __restrict__ yb)
{
    int row = blockIdx.x;
    int t = threadIdx.x;
    int lane = t & 63, wid = t >> 6;
    long base = (long)row * 1024 + t * 4;

    float4 v = *(const float4*)(part + base);
    for (int s = 1; s < S; ++s) {
        float4 w = *(const float4*)(part + base + (long)s * sPart);
        v.x += w.x; v.y += w.y; v.z += w.z; v.w += w.w;
    }
    float4 bv = *(const float4*)(bias + t * 4);
    v.x += bv.x; v.y += bv.y; v.z += bv.z; v.w += bv.w;
    float4 rv = *(const float4*)(res + base);
    v.x += rv.x; v.y += rv.y; v.z += rv.z; v.w += rv.w;

    float s1 = v.x + v.y + v.z + v.w;
    float s2 = v.x * v.x + v.y * v.y + v.z * v.z + v.w * v.w;
#pragma unroll
    for (int d = 32; d > 0; d >>= 1) { s1 += __shfl_xor(s1, d, 64); s2 += __shfl_xor(s2, d, 64); }
    __shared__ float rs[4], rss[4];
    if (lane == 0) { rs[wid] = s1; rss[wid] = s2; }
    __syncthreads();
    s1 = rs[0] + rs[1] + rs[2] + rs[3];
    s2 = rss[0] + rss[1] + rss[2] + rss[3];
    float mu  = s1 * (1.0f / 1024.0f);
    float var = s2 * (1.0f / 1024.0f) - mu * mu;
    float inv = rsqrtf(var + 1e-5f);

    float xv[4] = { v.x, v.y, v.z, v.w };
    float4 gv = *(const float4*)(g + t * 4);
    float4 btv = *(const float4*)(bt + t * 4);
    float gvx[4] = { gv.x, gv.y, gv.z, gv.w };
    float btx[4] = { btv.x, btv.y, btv.z, btv.w };
    float4 of;
    ushort4 ob;
    float o0 = (xv[0] - mu) * inv * gvx[0] + btx[0];
    float o1 = (xv[1] - mu) * inv * gvx[1] + btx[1];
    float o2 = (xv[2] - mu) * inv * gvx[2] + btx[2];
    float o3 = (xv[3] - mu) * inv * gvx[3] + btx[3];
    of.x = o0; of.y = o1; of.z = o2; of.w = o3;
    ob.x = f2bf(o0); ob.y = f2bf(o1); ob.z = f2bf(o2); ob.w = f2bf(o3);
    *(float4*)(yf + base) = of;
    *(ushort4*)(yb + base) = ob;
}

// ---------------------- tiled transpose (bf16) ------------------------------
__global__ __launch_bounds__(256)
void k_tr(const unsigned short* __restrict__ in, unsigned short* __restrict__ out,
          int R, int ldin, int ldout,
          int H, long sIb, long sIh, long sOz)
{
    __shared__ unsigned short tile[32][33];
    int z = blockIdx.z;
    int b = z / H, h = z - b * H;
    const unsigned short* ip = in + (long)b * sIb + (long)h * sIh;
    unsigned short* op = out + (long)z * sOz;
    int t = threadIdx.x;
    int cl = t & 31, rl = t >> 5;
    int c0 = blockIdx.x * 32, r0 = blockIdx.y * 32;
#pragma unroll
    for (int i = 0; i < 4; ++i) {
        int r = r0 + rl + i * 8;
        unsigned short v = 0;
        if (r < R) v = ip[(long)r * ldin + (c0 + cl)];
        tile[rl + i * 8][cl] = v;
    }
    __syncthreads();
#pragma unroll
    for (int i = 0; i < 4; ++i) {
        int orow = c0 + rl + i * 8;
        int ocol = r0 + cl;
        op[(long)orow * ldout + ocol] = tile[cl][rl + i * 8];
    }
}

// --------------------- wave-per-row masked softmax ---------------------------
__global__ __launch_bounds__(256)
void k_softmax_w(const float* __restrict__ sc, long sPart, int S,
                 unsigned short* __restrict__ P,
                 const int* __restrict__ mask, int L, int Lpad,
                 int ld_sc, int ld_p, int rows_per_batch, int nrows)
{
    int gw = (int)((blockIdx.x * 256 + threadIdx.x) >> 6);
    if (gw >= nrows) return;
    int lane = threadIdx.x & 63;
    int b = gw / rows_per_batch;
    const float* p = sc + (long)gw * ld_sc;
    unsigned short* po = P + (long)gw * ld_p;
    const int* mrow = mask + (long)b * L;

    int nch = (Lpad + 255) >> 8;     // 1 or 2
    float v[2][4];
    float mx = -INFINITY;
#pragma unroll
    for (int c = 0; c < 2; ++c) {
        if (c >= nch) { v[c][0]=v[c][1]=v[c][2]=v[c][3] = -INFINITY; continue; }
        int j = c * 256 + lane * 4;
        if (j < L) {
            float4 x = *(const float4*)(p + j);
            for (int s = 1; s < S; ++s) {
                float4 y = *(const float4*)(p + j + (long)s * sPart);
                x.x += y.x; x.y += y.y; x.z += y.z; x.w += y.w;
            }
            int4 m = *(const int4*)(mrow + j);
            v[c][0] = m.x ? x.x : -INFINITY;
            v[c][1] = m.y ? x.y : -INFINITY;
            v[c][2] = m.z ? x.z : -INFINITY;
            v[c][3] = m.w ? x.w : -INFINITY;
        } else {
            v[c][0]=v[c][1]=v[c][2]=v[c][3] = -INFINITY;
        }
        mx = fmaxf(mx, fmaxf(fmaxf(v[c][0], v[c][1]), fmaxf(v[c][2], v[c][3])));
    }
#pragma unroll
    for (int d = 32; d > 0; d >>= 1) mx = fmaxf(mx, __shfl_xor(mx, d, 64));

    float sum = 0.f;
#pragma unroll
    for (int c = 0; c < 2; ++c)
#pragma unroll
        for (int k = 0; k < 4; ++k) {
            float e = (v[c][k] == -INFINITY) ? 0.0f : __expf(v[c][k] - mx);
            v[c][k] = e;
            sum += e;
        }
#pragma unroll
    for (int d = 32; d > 0; d >>= 1) sum += __shfl_xor(sum, d, 64);
    float inv = 1.0f / sum;

#pragma unroll
    for (int c = 0; c < 2; ++c) {
        if (c >= nch) continue;
        int j = c * 256 + lane * 4;
        if (j < Lpad) {
            ushort4 o;
            o.x = f2bf(v[c][0] * inv);
            o.y = f2bf(v[c][1] * inv);
            o.z = f2bf(v[c][2] * inv);
            o.w = f2bf(v[c][3] * inv);
            *(ushort4*)(po + j) = o;
        }
    }
}

// ------------------------- combine (w/ partial-sum) -------------------------
__global__ void k_combine(float* __restrict__ qf, unsigned short* __restrict__ qb,
                          const float* __restrict__ aggtp, const float* __restrict__ aggrp,
                          const float* __restrict__ alpha, long n, long sPart, int S)
{
    float a = *alpha;
    long i = (long)blockIdx.x * blockDim.x + threadIdx.x;
    long stride = (long)gridDim.x * blockDim.x;
    for (; i < n; i += stride) {
        float st = 0.f, sr = 0.f;
        for (int s = 0; s < S; ++s) {
            st += aggtp[i + (long)s * sPart];
            sr += aggrp[i + (long)s * sPart];
        }
        float v = qf[i] + a * sr + (1.0f - a) * st;
        qf[i] = v;
        qb[i] = f2bf(v);
    }
}

// ---------------------------------------------------------------------------
extern "C" void kernel_launch(void* const* d_in, const int* in_sizes, int n_in,
                              void* d_out, int out_size, void* d_ws, size_t ws_size,
                              hipStream_t stream)
{
    const float* queries = (const float*)d_in[0];
    const float* text    = (const float*)d_in[1];
    const float* region  = (const float*)d_in[2];
    const int*   tmask   = (const int*)d_in[3];
    const int*   rmask   = (const int*)d_in[4];
    const float* w_qkv_t = (const float*)d_in[5];
    const float* b_qkv_t = (const float*)d_in[6];
    const float* w_o_t   = (const float*)d_in[7];
    const float* b_o_t   = (const float*)d_in[8];
    const float* w_qkv_r = (const float*)d_in[9];
    const float* b_qkv_r = (const float*)d_in[10];
    const float* w_o_r   = (const float*)d_in[11];
    const float* b_o_r   = (const float*)d_in[12];
    const float* ln_g    = (const float*)d_in[13];
    const float* ln_b    = (const float*)d_in[14];
    const float* w1      = (const float*)d_in[15];
    const float* b1      = (const float*)d_in[16];
    const float* w2      = (const float*)d_in[17];
    const float* b2      = (const float*)d_in[18];
    const float* alpha   = (const float*)d_in[19];

    const int Bn = 16, NQ = 128, LT = 512, LR = 196, D = 1024, H = 16;
    const int LRp = 256;
    const int MQ = Bn * NQ;              // 2048
    const int MT = Bn * LT;              // 8192
    const int MR = Bn * LR;              // 3136

    char* ws = (char*)d_ws;
    size_t off = 0;
    auto alloc = [&](size_t bytes) -> void* {
        void* p = ws + off;
        off = (off + bytes + 255) & ~(size_t)255;
        return p;
    };
    unsigned short* qb     = (unsigned short*)alloc((size_t)MQ * D * 2);
    unsigned short* tb     = (unsigned short*)alloc((size_t)MT * D * 2);
    unsigned short* rb     = (unsigned short*)alloc((size_t)MR * D * 2);
    unsigned short* wqkvtb = (unsigned short*)alloc((size_t)3 * D * D * 2);
    unsigned short* wotb   = (unsigned short*)alloc((size_t)D * D * 2);
    unsigned short* wqkvrb = (unsigned short*)alloc((size_t)3 * D * D * 2);
    unsigned short* worb   = (unsigned short*)alloc((size_t)D * D * 2);
    unsigned short* w1b    = (unsigned short*)alloc((size_t)4 * D * D * 2);
    unsigned short* w2b    = (unsigned short*)alloc((size_t)4 * D * D * 2);
    unsigned short* ktv    = (unsigned short*)alloc((size_t)MT * 2 * D * 2);
    unsigned short* krv    = (unsigned short*)alloc((size_t)MR * 2 * D * 2);
    unsigned short* vtT    = (unsigned short*)alloc((size_t)Bn * H * 64 * LT * 2);
    unsigned short* vrT    = (unsigned short*)alloc((size_t)Bn * H * 64 * LRp * 2);
    unsigned short* qp     = (unsigned short*)alloc((size_t)MQ * D * 2);
    unsigned short* ao     = (unsigned short*)alloc((size_t)MQ * D * 2);
    unsigned short* qlnb   = (unsigned short*)alloc((size_t)MQ * D * 2);
    float* qlf  = (float*)alloc((size_t)MQ * D * 4);
    float* sc   = (float*)alloc((size_t)Bn * H * NQ * LT * 4);   // 67MB arena
    if (off > ws_size) return;

    // phase-reused views
    unsigned short* tbT = ktv;                               // [B][1024][512]
    unsigned short* rbT = ktv + (size_t)Bn * D * LT;         // [B][1024][256p]
    float* sct = sc;
    float* scr = sc;
    unsigned short* Pt = (unsigned short*)sc;                          // manual P-text
    unsigned short* Pr = (unsigned short*)(sc + 1 * 1048576);          // manual P-region
    float* atp   = sc + 2 * 1048576;
    float* arp   = sc + 6 * 1048576;
    float* aggtp = sc + 8 * 1048576;
    float* aggrp = sc + 12 * 1048576;
    unsigned short* hb = (unsigned short*)sc;                // FFN hidden bf16
    float* part_q  = sc;
    float* part_f1 = (float*)ktv;
    float* part_f2 = (float*)ktv;

    const long PQ = (long)MQ * D;

    // ---- all converts in one balanced launch ----
    {
        CvtPack pk;
        const float* srcs[9] = { queries, text, region, w_qkv_t, w_o_t, w_qkv_r, w_o_r, w1, w2 };
        unsigned short* dsts[9] = { qb, tb, rb, wqkvtb, wotb, wqkvrb, worb, w1b, w2b };
        long ns[9] = { (long)MQ * D, (long)MT * D, (long)MR * D, (long)3 * D * D,
                       (long)D * D, (long)3 * D * D, (long)D * D, (long)4 * D * D,
                       (long)4 * D * D };
        long acc16 = 0;
        pk.start16[0] = 0;
        for (int i = 0; i < 9; ++i) {
            pk.src[i] = srcs[i]; pk.dst[i] = dsts[i];
            acc16 += ns[i] / 16;
            pk.start16[i + 1] = acc16;
        }
        k_cvt_multi<<<2048, 256, 0, stream>>>(pk, acc16);
    }

    auto NT = [&](const unsigned short* A, const unsigned short* Bm, const float* bias,
                  const float* res, float* oF, unsigned short* oB,
                  int M, int N, int K, int lda, int ldb, int ldc,
                  int Hh, long sAb, long sAh, long sBb, long sBh, long sCb, long sCh,
                  int batch, float scale, bool gelu, int S = 1, long sPart = 0) {
        dim3 g((N + 127) / 128, (M + 127) / 128, batch * S);
        if (gelu)
            k_gemm_nt<true><<<g, 256, 0, stream>>>(A, Bm, bias, res, oF, oB, M, N, K,
                lda, ldb, ldc, Hh, sAb, sAh, sBb, sBh, sCb, sCh, scale, S, sPart);
        else
            k_gemm_nt<false><<<g, 256, 0, stream>>>(A, Bm, bias, res, oF, oB, M, N, K,
                lda, ldb, ldc, Hh, sAb, sAh, sBb, sBh, sCb, sCh, scale, S, sPart);
    };
    auto NT256 = [&](const unsigned short* A, const unsigned short* Bm, const float* bias,
                     float* oF, unsigned short* oB, int M, int N, int Kc,
                     int lda, int ldb, int ldc, int S, long sPart) {
        dim3 g((N + 255) / 256, (M + 255) / 256, S);
        k_gemm_nt256<<<g, 1024, 0, stream>>>(A, Bm, bias, oF, oB, M, N, Kc,
                                             lda, ldb, ldc, sPart);
    };
    auto REDUX = [&](const float* part, long sPart, int S, const float* bias,
                     const float* res, float* oF, unsigned short* oB,
                     long total, int ldc, int gelu) {
        long n4 = total / 4;
        int blocks = (int)((n4 + 255) / 256);
        if (blocks > 2048) blocks = 2048;
        k_redux<<<blocks, 256, 0, stream>>>(part, sPart / 4, S, bias, res, oF, oB,
                                            n4, ldc / 4, gelu);
    };
    auto SMAX = [&](const float* scp, long sPart, int S, unsigned short* P,
                    const int* mask, int L, int Lpad, int ld_sc, int ld_p,
                    int rpb, int nrows) {
        int blocks = (nrows + 3) / 4;
        k_softmax_w<<<blocks, 256, 0, stream>>>(scp, sPart, S, P, mask, L, Lpad,
                                                ld_sc, ld_p, rpb, nrows);
    };

    // ---- fused K+V projections ----
    NT256(tb, wqkvtb + (long)D * D, b_qkv_t + D, nullptr, ktv,
          MT, 2 * D, D, D, D, 2 * D, 1, 0);
    NT(rb, wqkvrb + (long)D * D, b_qkv_r + D, nullptr, nullptr, krv,
       MR, 2 * D, D, D, D, 2 * D, 1,0,0,0,0,0,0, 1, 1.0f, false);

    // per-head V transposes
    {
        dim3 g1(64 / 32, LT / 32, Bn * H);
        k_tr<<<g1, 256, 0, stream>>>(ktv + D, vtT, LT, 2 * D, LT,
                                     H, (long)LT * 2 * D, 64, (long)64 * LT);
        dim3 g2(64 / 32, LRp / 32, Bn * H);
        k_tr<<<g2, 256, 0, stream>>>(krv + D, vrT, LR, 2 * D, LRp,
                                     H, (long)LR * 2 * D, 64, (long)64 * LRp);
    }

    // ================= MHA 1 (text) =================
    NT(qb, wqkvtb, nullptr, nullptr, part_q, nullptr, MQ, D, 512, D, D, D,
       1,0,0,0,0,0,0, 1, 1.0f, false, 2, PQ);
    REDUX(part_q, PQ, 2, b_qkv_t, nullptr, nullptr, qp, PQ, D, 0);
    NT(qp, ktv, nullptr, nullptr, sct, nullptr, NQ, LT, 64, D, 2 * D, LT,
       H, (long)NQ * D, 64, (long)LT * 2 * D, 64, (long)H * NQ * LT, (long)NQ * LT,
       Bn * H, 0.125f, false);
    SMAX(sct, 0, 1, (unsigned short*)sct, tmask, LT, LT, LT, 2 * LT,
         H * NQ, Bn * H * NQ);
    NT((const unsigned short*)sct, vtT, nullptr, nullptr, nullptr, ao, NQ, 64, LT,
       2 * LT, LT, D,
       H, (long)H * NQ * 2 * LT, (long)NQ * 2 * LT, (long)64 * LT * H, (long)64 * LT,
       (long)NQ * D, 64, Bn * H, 1.0f, false);
    NT(ao, wotb, nullptr, nullptr, part_q, nullptr, MQ, D, 512, D, D, D,
       1,0,0,0,0,0,0, 1, 1.0f, false, 2, PQ);
    k_redux_ln<<<MQ, 256, 0, stream>>>(part_q, PQ, 2, b_o_t, queries,
                                       ln_g, ln_b, qlf, qlnb);

    // ================= MHA 2 (region) =================
    NT(qlnb, wqkvrb, nullptr, nullptr, part_q, nullptr, MQ, D, 512, D, D, D,
       1,0,0,0,0,0,0, 1, 1.0f, false, 2, PQ);
    REDUX(part_q, PQ, 2, b_qkv_r, nullptr, nullptr, qp, PQ, D, 0);
    NT(qp, krv, nullptr, nullptr, scr, nullptr, NQ, LR, 64, D, 2 * D, LRp,
       H, (long)NQ * D, 64, (long)LR * 2 * D, 64, (long)H * NQ * LRp, (long)NQ * LRp,
       Bn * H, 0.125f, false);
    SMAX(scr, 0, 1, (unsigned short*)scr, rmask, LR, LRp, LRp, 2 * LRp,
         H * NQ, Bn * H * NQ);
    NT((const unsigned short*)scr, vrT, nullptr, nullptr, nullptr, ao, NQ, 64, LRp,
       2 * LRp, LRp, D,
       H, (long)H * NQ * 2 * LRp, (long)NQ * 2 * LRp, (long)64 * LRp * H, (long)64 * LRp,
       (long)NQ * D, 64, Bn * H, 1.0f, false);
    NT(ao, worb, nullptr, nullptr, part_q, nullptr, MQ, D, 512, D, D, D,
       1,0,0,0,0,0,0, 1, 1.0f, false, 2, PQ);
    k_redux_ln<<<MQ, 256, 0, stream>>>(part_q, PQ, 2, b_o_r, qlf,
                                       ln_g, ln_b, qlf, qlnb);

    // ================= manual masked cross-attention =================
    {
        dim3 g1(D / 32, LT / 32, Bn);
        k_tr<<<g1, 256, 0, stream>>>(tb, tbT, LT, D, LT, 1, (long)LT * D, 0, (long)D * LT);
        dim3 g2(D / 32, LRp / 32, Bn);
        k_tr<<<g2, 256, 0, stream>>>(rb, rbT, LR, D, LRp, 1, (long)LR * D, 0, (long)D * LRp);
    }
    NT(qlnb, tb, nullptr, nullptr, atp, nullptr, NQ, LT, 256, D, D, LT,
       1, (long)NQ * D, 0, (long)LT * D, 0, (long)NQ * LT, 0, Bn, 0.03125f, false,
       4, (long)Bn * NQ * LT);
    SMAX(atp, (long)Bn * NQ * LT, 4, Pt, tmask, LT, LT, LT, LT, NQ, Bn * NQ);
    NT(Pt, tbT, nullptr, nullptr, aggtp, nullptr, NQ, D, 256, LT, LT, D,
       1, (long)NQ * LT, 0, (long)D * LT, 0, (long)NQ * D, 0, Bn, 1.0f, false,
       2, PQ);
    NT(qlnb, rb, nullptr, nullptr, arp, nullptr, NQ, LR, 256, D, D, LRp,
       1, (long)NQ * D, 0, (long)LR * D, 0, (long)NQ * LRp, 0, Bn, 0.03125f, false,
       4, (long)Bn * NQ * LRp);
    SMAX(arp, (long)Bn * NQ * LRp, 4, Pr, rmask, LR, LRp, LRp, LRp, NQ, Bn * NQ);
    NT(Pr, rbT, nullptr, nullptr, aggrp, nullptr, NQ, D, 128, LRp, LRp, D,
       1, (long)NQ * LRp, 0, (long)D * LRp, 0, (long)NQ * D, 0, Bn, 1.0f, false,
       2, PQ);

    k_combine<<<2048, 256, 0, stream>>>(qlf, qlnb, aggtp, aggrp, alpha,
                                        (long)MQ * D, PQ, 2);

    // ================= FFN =================
    NT256(qlnb, w1b, nullptr, part_f1, nullptr, MQ, 4 * D, 512,
          D, D, 4 * D, 2, (long)MQ * 4 * D);
    REDUX(part_f1, (long)MQ * 4 * D, 2, b1, nullptr, nullptr, hb,
          (long)MQ * 4 * D, 4 * D, 1);
    NT256(hb, w2b, nullptr, part_f2, nullptr, MQ, D, 512,
          4 * D, 4 * D, D, 8, PQ);
    REDUX(part_f2, PQ, 8, b2, qlf, (float*)d_out, nullptr, PQ, D, 0);
}

// Round 10
// 539.241 us; speedup vs baseline: 2.0585x; 1.0339x over previous
//
#include <hip/hip_runtime.h>
#include <hip/hip_bf16.h>

// ---------------------------------------------------------------------------
// QueryGuidedFusionNet forward on MI355X.
// Round 10: bf16 split-K partials (halves redux traffic) via outB-offset in
// GEMMs + bf16-reading redux/redux_ln/combine. GEMM cores unchanged.
// ---------------------------------------------------------------------------

typedef __attribute__((ext_vector_type(8))) short short8;   // 8 bf16
typedef __attribute__((ext_vector_type(4))) float f32x4;

#define DEV static __device__ __forceinline__

DEV unsigned short f2bf(float f) {
    unsigned u = __float_as_uint(f);
    u += 0x7fffu + ((u >> 16) & 1u);          // RNE
    return (unsigned short)(u >> 16);
}
DEV float bf2f(unsigned short u) {
    return __uint_as_float(((unsigned)u) << 16);
}

// ------------------------- multi-tensor convert (balanced) ------------------
struct CvtPack {
    const float* src[9];
    unsigned short* dst[9];
    long start16[10];       // prefix sums in 16-element units
};

__global__ __launch_bounds__(256)
void k_cvt_multi(CvtPack p, long total16) {
    long i = (long)blockIdx.x * blockDim.x + threadIdx.x;
    long stride = (long)gridDim.x * blockDim.x;
    for (; i < total16; i += stride) {
        int t = 0;
#pragma unroll
        for (int k = 1; k < 9; ++k) t += (i >= p.start16[k]) ? 1 : 0;
        long off = i - p.start16[t];
        const float4* s = (const float4*)p.src[t] + off * 4;
        float4 a = s[0], b = s[1], c = s[2], d = s[3];
        short8 o0, o1;
        o0[0] = (short)f2bf(a.x); o0[1] = (short)f2bf(a.y);
        o0[2] = (short)f2bf(a.z); o0[3] = (short)f2bf(a.w);
        o0[4] = (short)f2bf(b.x); o0[5] = (short)f2bf(b.y);
        o0[6] = (short)f2bf(b.z); o0[7] = (short)f2bf(b.w);
        o1[0] = (short)f2bf(c.x); o1[1] = (short)f2bf(c.y);
        o1[2] = (short)f2bf(c.z); o1[3] = (short)f2bf(c.w);
        o1[4] = (short)f2bf(d.x); o1[5] = (short)f2bf(d.y);
        o1[6] = (short)f2bf(d.z); o1[7] = (short)f2bf(d.w);
        short8* dp = (short8*)p.dst[t] + off * 2;
        dp[0] = o0;
        dp[1] = o1;
    }
}

// --------------------- GEMM NT 256x256 (16 waves) ---------------------------
__global__ __launch_bounds__(1024)
void k_gemm_nt256(const unsigned short* __restrict__ A, const unsigned short* __restrict__ B,
                  const float* __restrict__ bias,
                  float* __restrict__ outF, unsigned short* __restrict__ outB,
                  int M, int N, int K, int lda, int ldb, int ldc,
                  long sPart)
{
    __shared__ unsigned short smem[3 * 16384];   // 3 bufs x (A16KB + B16KB)

    unsigned gx = gridDim.x, gy = gridDim.y;
    unsigned nwg = gx * gy * gridDim.z;
    unsigned lin = (blockIdx.z * gy + blockIdx.y) * gx + blockIdx.x;
    unsigned bx = blockIdx.x, by = blockIdx.y, bz = blockIdx.z;
    if ((nwg & 7u) == 0u) {
        unsigned cpx = nwg >> 3;
        unsigned s = (lin & 7u) * cpx + (lin >> 3);
        bx = s % gx; unsigned r2 = s / gx;
        by = r2 % gy; bz = r2 / gy;
    }
    int s_k = (int)bz;
    const unsigned short* Ap = A + (long)s_k * K;
    const unsigned short* Bp = B + (long)s_k * K;
    float* outFp = outF ? outF + (long)s_k * sPart : nullptr;
    unsigned short* outBp = outB ? outB + (long)s_k * sPart : nullptr;

    int t = threadIdx.x;
    int wid = t >> 6, lane = t & 63;
    int lrow = lane & 15, kgrp = lane >> 4;
    int tm = by * 256, tn = bx * 256;
    int wm = (wid >> 2) * 64, wn = (wid & 3) * 64;

    auto stage = [&](int buf, int k0) {
        int d = t * 16;
        int row = d >> 6;
        int colb = (d & 63) ^ (((row >> 1) & 3) << 4);
        int gr = tm + row; if (gr > M - 1) gr = M - 1;
        const unsigned short* srcA = Ap + (long)gr * lda + k0 + (colb >> 1);
        unsigned short* dstA = smem + ((buf * 32768 + d) >> 1);
        __builtin_amdgcn_global_load_lds(
            (const __attribute__((address_space(1))) unsigned int*)srcA,
            (__attribute__((address_space(3))) unsigned int*)dstA, 16, 0, 0);
        int gn = tn + row; if (gn > N - 1) gn = N - 1;
        const unsigned short* srcB = Bp + (long)gn * ldb + k0 + (colb >> 1);
        unsigned short* dstB = smem + ((buf * 32768 + 16384 + d) >> 1);
        __builtin_amdgcn_global_load_lds(
            (const __attribute__((address_space(1))) unsigned int*)srcB,
            (__attribute__((address_space(3))) unsigned int*)dstB, 16, 0, 0);
    };

    f32x4 acc[4][4] = {};
    int nt = K >> 5;

    stage(0, 0);
    if (nt > 1) stage(1, 32);

    for (int ti = 0; ti < nt; ++ti) {
        int cur = ti % 3;
        if (ti + 1 < nt) asm volatile("s_waitcnt vmcnt(2)" ::: "memory");
        else             asm volatile("s_waitcnt vmcnt(0)" ::: "memory");
        __builtin_amdgcn_sched_barrier(0);
        __builtin_amdgcn_s_barrier();
        __builtin_amdgcn_sched_barrier(0);

        if (ti + 2 < nt) stage((ti + 2) % 3, (ti + 2) << 5);

        const char* Ab = (const char*)smem + cur * 32768;
        const char* Bb = Ab + 16384;
        short8 a[4], bb[4];
#pragma unroll
        for (int i = 0; i < 4; ++i) {
            int row = wm + i * 16 + lrow;
            a[i] = *(const short8*)(Ab + row * 64 + ((kgrp * 16) ^ (((row >> 1) & 3) << 4)));
        }
#pragma unroll
        for (int j = 0; j < 4; ++j) {
            int row = wn + j * 16 + lrow;
            bb[j] = *(const short8*)(Bb + row * 64 + ((kgrp * 16) ^ (((row >> 1) & 3) << 4)));
        }
#pragma unroll
        for (int i = 0; i < 4; ++i)
#pragma unroll
            for (int j = 0; j < 4; ++j)
                acc[i][j] = __builtin_amdgcn_mfma_f32_16x16x32_bf16(a[i], bb[j], acc[i][j], 0, 0, 0);
    }

#pragma unroll
    for (int i = 0; i < 4; ++i) {
        int rbase = tm + wm + i * 16 + kgrp * 4;
#pragma unroll
        for (int j = 0; j < 4; ++j) {
            int c = tn + wn + j * 16 + lrow;
            if (c >= N) continue;
            float bv = bias ? bias[c] : 0.0f;
#pragma unroll
            for (int e = 0; e < 4; ++e) {
                int r = rbase + e;
                if (r >= M) continue;
                float v = acc[i][j][e] + bv;
                long oidx = (long)r * ldc + c;
                if (outFp) outFp[oidx] = v;
                if (outBp) outBp[oidx] = f2bf(v);
            }
        }
    }
}

// ------------------------------ GEMM NT (pipelined 128²) --------------------
template<bool GELU>
__global__ __launch_bounds__(256)
void k_gemm_nt(const unsigned short* __restrict__ A, const unsigned short* __restrict__ B,
               const float* __restrict__ bias, const float* __restrict__ res,
               float* __restrict__ outF, unsigned short* __restrict__ outB,
               int M, int N, int K, int lda, int ldb, int ldc,
               int H, long sAb, long sAh, long sBb, long sBh, long sCb, long sCh,
               float scale, int S, long sPart)
{
    __shared__ unsigned short smem[5 * 8192];

    unsigned gx = gridDim.x, gy = gridDim.y, gz = gridDim.z;
    unsigned nwg = gx * gy * gz;
    unsigned lin = (blockIdx.z * gy + blockIdx.y) * gx + blockIdx.x;
    unsigned bx = blockIdx.x, by = blockIdx.y, bz = blockIdx.z;
    if ((nwg & 7u) == 0u) {
        unsigned cpx = nwg >> 3;
        unsigned s = (lin & 7u) * cpx + (lin >> 3);
        bx = s % gx; unsigned r2 = s / gx;
        by = r2 % gy; bz = r2 / gy;
    }

    int zz = (int)bz;
    int s_k = 0;
    if (S > 1) { s_k = zz % S; zz /= S; }
    int b = zz / H, h = zz - b * H;
    const unsigned short* Ap = A + (long)b * sAb + (long)h * sAh + (long)s_k * K;
    const unsigned short* Bp = B + (long)b * sBb + (long)h * sBh + (long)s_k * K;
    float* outFp = outF;
    if (outFp && S > 1) outFp += (long)s_k * sPart;
    unsigned short* outBp = outB;
    if (outBp && S > 1) outBp += (long)s_k * sPart;
    long offC = (long)b * sCb + (long)h * sCh;

    int t    = threadIdx.x;
    int wid  = t >> 6;
    int lane = t & 63;
    int lrow = lane & 15;
    int kgrp = lane >> 4;

    int tm = by * 128;
    int tn = bx * 128;
    int wm = (wid >> 1) * 64;
    int wn = (wid & 1) * 64;

    auto stage = [&](int buf, int k0) {
#pragma unroll
        for (int r = 0; r < 2; ++r) {
            int d = r * 4096 + t * 16;
            int row = d >> 6;
            int colb = (d & 63) ^ (((row >> 1) & 3) << 4);
            int gr = tm + row; if (gr > M - 1) gr = M - 1;
            const unsigned short* srcA = Ap + (long)gr * lda + k0 + (colb >> 1);
            unsigned short* dstA = smem + ((buf * 16384 + r * 4096 + wid * 1024) >> 1);
            __builtin_amdgcn_global_load_lds(
                (const __attribute__((address_space(1))) unsigned int*)srcA,
                (__attribute__((address_space(3))) unsigned int*)dstA, 16, 0, 0);
            int gn = tn + row; if (gn > N - 1) gn = N - 1;
            const unsigned short* srcB = Bp + (long)gn * ldb + k0 + (colb >> 1);
            unsigned short* dstB = smem + ((buf * 16384 + 8192 + r * 4096 + wid * 1024) >> 1);
            __builtin_amdgcn_global_load_lds(
                (const __attribute__((address_space(1))) unsigned int*)srcB,
                (__attribute__((address_space(3))) unsigned int*)dstB, 16, 0, 0);
        }
    };

    f32x4 acc[4][4] = {};
    int nt = K >> 5;

    for (int p = 0; p < 4 && p < nt; ++p) stage(p, p << 5);

    for (int ti = 0; ti < nt; ++ti) {
        int cur = ti % 5;
        int rem = nt - 1 - ti;
        if (rem >= 3)      asm volatile("s_waitcnt vmcnt(12)" ::: "memory");
        else if (rem == 2) asm volatile("s_waitcnt vmcnt(8)"  ::: "memory");
        else if (rem == 1) asm volatile("s_waitcnt vmcnt(4)"  ::: "memory");
        else               asm volatile("s_waitcnt vmcnt(0)"  ::: "memory");
        __builtin_amdgcn_sched_barrier(0);
        __builtin_amdgcn_s_barrier();
        __builtin_amdgcn_sched_barrier(0);

        if (ti + 4 < nt) stage((ti + 4) % 5, (ti + 4) << 5);

        const char* Ab = (const char*)smem + cur * 16384;
        const char* Bb = Ab + 8192;
        short8 a[4], bb[4];
#pragma unroll
        for (int i = 0; i < 4; ++i) {
            int row = wm + i * 16 + lrow;
            a[i] = *(const short8*)(Ab + row * 64 + ((kgrp * 16) ^ (((row >> 1) & 3) << 4)));
        }
#pragma unroll
        for (int j = 0; j < 4; ++j) {
            int row = wn + j * 16 + lrow;
            bb[j] = *(const short8*)(Bb + row * 64 + ((kgrp * 16) ^ (((row >> 1) & 3) << 4)));
        }
#pragma unroll
        for (int i = 0; i < 4; ++i)
#pragma unroll
            for (int j = 0; j < 4; ++j)
                acc[i][j] = __builtin_amdgcn_mfma_f32_16x16x32_bf16(a[i], bb[j], acc[i][j], 0, 0, 0);
    }

#pragma unroll
    for (int i = 0; i < 4; ++i) {
        int rbase = tm + wm + i * 16 + kgrp * 4;
#pragma unroll
        for (int j = 0; j < 4; ++j) {
            int c = tn + wn + j * 16 + lrow;
            if (c >= N) continue;
            float bv = bias ? bias[c] : 0.0f;
#pragma unroll
            for (int e = 0; e < 4; ++e) {
                int r = rbase + e;
                if (r >= M) continue;
                float v = acc[i][j][e] * scale + bv;
                long oidx = offC + (long)r * ldc + c;
                if (res) v += res[oidx];
                if (GELU) v = 0.5f * v * (1.0f + erff(v * 0.70710678118654752f));
                if (outFp) outFp[oidx] = v;
                if (outBp) outBp[oidx] = f2bf(v);
            }
        }
    }
}

// -------------------- split-K reduce (bf16 partials) -------------------------
__global__ __launch_bounds__(256)
void k_redux_b(const unsigned short* __restrict__ part, long sPart, int S,
               const float* __restrict__ bias, const float* __restrict__ res,
               float* __restrict__ outF, unsigned short* __restrict__ outB,
               long n8, int ldc8, int gelu)
{
    long i = (long)blockIdx.x * blockDim.x + threadIdx.x;
    long stride = (long)gridDim.x * blockDim.x;
    for (; i < n8; i += stride) {
        long e0 = i * 8;
        float v[8];
        short8 p0 = *(const short8*)(part + e0);
#pragma unroll
        for (int k = 0; k < 8; ++k) v[k] = bf2f((unsigned short)p0[k]);
        for (int s = 1; s < S; ++s) {
            short8 ps = *(const short8*)(part + e0 + (long)s * sPart);
#pragma unroll
            for (int k = 0; k < 8; ++k) v[k] += bf2f((unsigned short)ps[k]);
        }
        if (bias) {
            int c = (int)(i % ldc8) * 8;
            float4 b0 = *(const float4*)(bias + c);
            float4 b1 = *(const float4*)(bias + c + 4);
            v[0] += b0.x; v[1] += b0.y; v[2] += b0.z; v[3] += b0.w;
            v[4] += b1.x; v[5] += b1.y; v[6] += b1.z; v[7] += b1.w;
        }
        if (res) {
            float4 r0 = *(const float4*)(res + e0);
            float4 r1 = *(const float4*)(res + e0 + 4);
            v[0] += r0.x; v[1] += r0.y; v[2] += r0.z; v[3] += r0.w;
            v[4] += r1.x; v[5] += r1.y; v[6] += r1.z; v[7] += r1.w;
        }
        if (gelu) {
#pragma unroll
            for (int k = 0; k < 8; ++k)
                v[k] = 0.5f * v[k] * (1.0f + erff(v[k] * 0.70710678118654752f));
        }
        if (outF) {
            float4 o0 = { v[0], v[1], v[2], v[3] };
            float4 o1 = { v[4], v[5], v[6], v[7] };
            *(float4*)(outF + e0) = o0;
            *(float4*)(outF + e0 + 4) = o1;
        }
        if (outB) {
            short8 o;
#pragma unroll
            for (int k = 0; k < 8; ++k) o[k] = (short)f2bf(v[k]);
            *(short8*)(outB + e0) = o;
        }
    }
}

// ---- fused split-K(bf16) reduce + bias + residual + LayerNorm --------------
__global__ __launch_bounds__(256)
void k_redux_ln_b(const unsigned short* __restrict__ part, long sPart, int S,
                  const float* __restrict__ bias, const float* __restrict__ res,
                  const float* __restrict__ g, const float* __restrict__ bt,
                  float* __restrict__ yf, unsigned short* __restrict__ yb)
{
    int row = blockIdx.x;
    int t = threadIdx.x;
    int lane = t & 63, wid = t >> 6;
    long base = (long)row * 1024 + t * 4;

    ushort4 p0 = *(const ushort4*)(part + base);
    float v0 = bf2f(p0.x), v1 = bf2f(p0.y), v2 = bf2f(p0.z), v3 = bf2f(p0.w);
    for (int s = 1; s < S; ++s) {
        ushort4 ps = *(const ushort4*)(part + base + (long)s * sPart);
        v0 += bf2f(ps.x); v1 += bf2f(ps.y); v2 += bf2f(ps.z); v3 += bf2f(ps.w);
    }
    float4 bv = *(const float4*)(bias + t * 4);
    v0 += bv.x; v1 += bv.y; v2 += bv.z; v3 += bv.w;
    float4 rv = *(const float4*)(res + base);
    v0 += rv.x; v1 += rv.y; v2 += rv.z; v3 += rv.w;

    float s1 = v0 + v1 + v2 + v3;
    float s2 = v0 * v0 + v1 * v1 + v2 * v2 + v3 * v3;
#pragma unroll
    for (int d = 32; d > 0; d >>= 1) { s1 += __shfl_xor(s1, d, 64); s2 += __shfl_xor(s2, d, 64); }
    __shared__ float rs[4], rss[4];
    if (lane == 0) { rs[wid] = s1; rss[wid] = s2; }
    __syncthreads();
    s1 = rs[0] + rs[1] + rs[2] + rs[3];
    s2 = rss[0] + rss[1] + rss[2] + rss[3];
    float mu  = s1 * (1.0f / 1024.0f);
    float var = s2 * (1.0f / 1024.0f) - mu * mu;
    float inv = rsqrtf(var + 1e-5f);

    float4 gv = *(const float4*)(g + t * 4);
    float4 btv = *(const float4*)(bt + t * 4);
    float o0 = (v0 - mu) * inv * gv.x + btv.x;
    float o1 = (v1 - mu) * inv * gv.y + btv.y;
    float o2 = (v2 - mu) * inv * gv.z + btv.z;
    float o3 = (v3 - mu) * inv * gv.w + btv.w;
    float4 of = { o0, o1, o2, o3 };
    ushort4 ob = { f2bf(o0), f2bf(o1), f2bf(o2), f2bf(o3) };
    *(float4*)(yf + base) = of;
    *(ushort4*)(yb + base) = ob;
}

// ---------------------- tiled transpose (bf16) ------------------------------
__global__ __launch_bounds__(256)
void k_tr(const unsigned short* __restrict__ in, unsigned short* __restrict__ out,
          int R, int ldin, int ldout,
          int H, long sIb, long sIh, long sOz)
{
    __shared__ unsigned short tile[32][33];
    int z = blockIdx.z;
    int b = z / H, h = z - b * H;
    const unsigned short* ip = in + (long)b * sIb + (long)h * sIh;
    unsigned short* op = out + (long)z * sOz;
    int t = threadIdx.x;
    int cl = t & 31, rl = t >> 5;
    int c0 = blockIdx.x * 32, r0 = blockIdx.y * 32;
#pragma unroll
    for (int i = 0; i < 4; ++i) {
        int r = r0 + rl + i * 8;
        unsigned short v = 0;
        if (r < R) v = ip[(long)r * ldin + (c0 + cl)];
        tile[rl + i * 8][cl] = v;
    }
    __syncthreads();
#pragma unroll
    for (int i = 0; i < 4; ++i) {
        int orow = c0 + rl + i * 8;
        int ocol = r0 + cl;
        op[(long)orow * ldout + ocol] = tile[cl][rl + i * 8];
    }
}

// --------------------- wave-per-row masked softmax ---------------------------
__global__ __launch_bounds__(256)
void k_softmax_w(const float* __restrict__ sc, long sPart, int S,
                 unsigned short* __restrict__ P,
                 const int* __restrict__ mask, int L, int Lpad,
                 int ld_sc, int ld_p, int rows_per_batch, int nrows)
{
    int gw = (int)((blockIdx.x * 256 + threadIdx.x) >> 6);
    if (gw >= nrows) return;
    int lane = threadIdx.x & 63;
    int b = gw / rows_per_batch;
    const float* p = sc + (long)gw * ld_sc;
    unsigned short* po = P + (long)gw * ld_p;
    const int* mrow = mask + (long)b * L;

    int nch = (Lpad + 255) >> 8;     // 1 or 2
    float v[2][4];
    float mx = -INFINITY;
#pragma unroll
    for (int c = 0; c < 2; ++c) {
        if (c >= nch) { v[c][0]=v[c][1]=v[c][2]=v[c][3] = -INFINITY; continue; }
        int j = c * 256 + lane * 4;
        if (j < L) {
            float4 x = *(const float4*)(p + j);
            for (int s = 1; s < S; ++s) {
                float4 y = *(const float4*)(p + j + (long)s * sPart);
                x.x += y.x; x.y += y.y; x.z += y.z; x.w += y.w;
            }
            int4 m = *(const int4*)(mrow + j);
            v[c][0] = m.x ? x.x : -INFINITY;
            v[c][1] = m.y ? x.y : -INFINITY;
            v[c][2] = m.z ? x.z : -INFINITY;
            v[c][3] = m.w ? x.w : -INFINITY;
        } else {
            v[c][0]=v[c][1]=v[c][2]=v[c][3] = -INFINITY;
        }
        mx = fmaxf(mx, fmaxf(fmaxf(v[c][0], v[c][1]), fmaxf(v[c][2], v[c][3])));
    }
#pragma unroll
    for (int d = 32; d > 0; d >>= 1) mx = fmaxf(mx, __shfl_xor(mx, d, 64));

    float sum = 0.f;
#pragma unroll
    for (int c = 0; c < 2; ++c)
#pragma unroll
        for (int k = 0; k < 4; ++k) {
            float e = (v[c][k] == -INFINITY) ? 0.0f : __expf(v[c][k] - mx);
            v[c][k] = e;
            sum += e;
        }
#pragma unroll
    for (int d = 32; d > 0; d >>= 1) sum += __shfl_xor(sum, d, 64);
    float inv = 1.0f / sum;

#pragma unroll
    for (int c = 0; c < 2; ++c) {
        if (c >= nch) continue;
        int j = c * 256 + lane * 4;
        if (j < Lpad) {
            ushort4 o;
            o.x = f2bf(v[c][0] * inv);
            o.y = f2bf(v[c][1] * inv);
            o.z = f2bf(v[c][2] * inv);
            o.w = f2bf(v[c][3] * inv);
            *(ushort4*)(po + j) = o;
        }
    }
}

// ---------------- combine (bf16 partial aggs) -------------------------------
__global__ void k_combine_b(float* __restrict__ qf, unsigned short* __restrict__ qb,
                            const unsigned short* __restrict__ aggtp,
                            const unsigned short* __restrict__ aggrp,
                            const float* __restrict__ alpha, long n4, long sPart, int S)
{
    float a = *alpha;
    long i = (long)blockIdx.x * blockDim.x + threadIdx.x;
    long stride = (long)gridDim.x * blockDim.x;
    for (; i < n4; i += stride) {
        long e0 = i * 4;
        float st[4] = {0.f, 0.f, 0.f, 0.f}, sr[4] = {0.f, 0.f, 0.f, 0.f};
        for (int s = 0; s < S; ++s) {
            ushort4 pt = *(const ushort4*)(aggtp + e0 + (long)s * sPart);
            ushort4 pr = *(const ushort4*)(aggrp + e0 + (long)s * sPart);
            st[0] += bf2f(pt.x); st[1] += bf2f(pt.y); st[2] += bf2f(pt.z); st[3] += bf2f(pt.w);
            sr[0] += bf2f(pr.x); sr[1] += bf2f(pr.y); sr[2] += bf2f(pr.z); sr[3] += bf2f(pr.w);
        }
        float4 q = *(const float4*)(qf + e0);
        float v0 = q.x + a * sr[0] + (1.0f - a) * st[0];
        float v1 = q.y + a * sr[1] + (1.0f - a) * st[1];
        float v2 = q.z + a * sr[2] + (1.0f - a) * st[2];
        float v3 = q.w + a * sr[3] + (1.0f - a) * st[3];
        float4 of = { v0, v1, v2, v3 };
        ushort4 ob = { f2bf(v0), f2bf(v1), f2bf(v2), f2bf(v3) };
        *(float4*)(qf + e0) = of;
        *(ushort4*)(qb + e0) = ob;
    }
}

// ---------------------------------------------------------------------------
extern "C" void kernel_launch(void* const* d_in, const int* in_sizes, int n_in,
                              void* d_out, int out_size, void* d_ws, size_t ws_size,
                              hipStream_t stream)
{
    const float* queries = (const float*)d_in[0];
    const float* text    = (const float*)d_in[1];
    const float* region  = (const float*)d_in[2];
    const int*   tmask   = (const int*)d_in[3];
    const int*   rmask   = (const int*)d_in[4];
    const float* w_qkv_t = (const float*)d_in[5];
    const float* b_qkv_t = (const float*)d_in[6];
    const float* w_o_t   = (const float*)d_in[7];
    const float* b_o_t   = (const float*)d_in[8];
    const float* w_qkv_r = (const float*)d_in[9];
    const float* b_qkv_r = (const float*)d_in[10];
    const float* w_o_r   = (const float*)d_in[11];
    const float* b_o_r   = (const float*)d_in[12];
    const float* ln_g    = (const float*)d_in[13];
    const float* ln_b    = (const float*)d_in[14];
    const float* w1      = (const float*)d_in[15];
    const float* b1      = (const float*)d_in[16];
    const float* w2      = (const float*)d_in[17];
    const float* b2      = (const float*)d_in[18];
    const float* alpha   = (const float*)d_in[19];

    const int Bn = 16, NQ = 128, LT = 512, LR = 196, D = 1024, H = 16;
    const int LRp = 256;
    const int MQ = Bn * NQ;              // 2048
    const int MT = Bn * LT;              // 8192
    const int MR = Bn * LR;              // 3136

    char* ws = (char*)d_ws;
    size_t off = 0;
    auto alloc = [&](size_t bytes) -> void* {
        void* p = ws + off;
        off = (off + bytes + 255) & ~(size_t)255;
        return p;
    };
    unsigned short* qb     = (unsigned short*)alloc((size_t)MQ * D * 2);
    unsigned short* tb     = (unsigned short*)alloc((size_t)MT * D * 2);
    unsigned short* rb     = (unsigned short*)alloc((size_t)MR * D * 2);
    unsigned short* wqkvtb = (unsigned short*)alloc((size_t)3 * D * D * 2);
    unsigned short* wotb   = (unsigned short*)alloc((size_t)D * D * 2);
    unsigned short* wqkvrb = (unsigned short*)alloc((size_t)3 * D * D * 2);
    unsigned short* worb   = (unsigned short*)alloc((size_t)D * D * 2);
    unsigned short* w1b    = (unsigned short*)alloc((size_t)4 * D * D * 2);
    unsigned short* w2b    = (unsigned short*)alloc((size_t)4 * D * D * 2);
    unsigned short* ktv    = (unsigned short*)alloc((size_t)MT * 2 * D * 2);
    unsigned short* krv    = (unsigned short*)alloc((size_t)MR * 2 * D * 2);
    unsigned short* vtT    = (unsigned short*)alloc((size_t)Bn * H * 64 * LT * 2);
    unsigned short* vrT    = (unsigned short*)alloc((size_t)Bn * H * 64 * LRp * 2);
    unsigned short* qp     = (unsigned short*)alloc((size_t)MQ * D * 2);
    unsigned short* ao     = (unsigned short*)alloc((size_t)MQ * D * 2);
    unsigned short* qlnb   = (unsigned short*)alloc((size_t)MQ * D * 2);
    float* qlf  = (float*)alloc((size_t)MQ * D * 4);
    float* sc   = (float*)alloc((size_t)Bn * H * NQ * LT * 4);   // 67MB arena
    if (off > ws_size) return;

    // phase-reused views
    unsigned short* tbT = ktv;                               // [B][1024][512]
    unsigned short* rbT = ktv + (size_t)Bn * D * LT;         // [B][1024][256p]
    float* sct = sc;
    float* scr = sc;
    unsigned short* Pt = (unsigned short*)sc;                          // [0, 2.1MB)
    unsigned short* Pr = (unsigned short*)(sc + 1 * 1048576);          // [4, 5.1MB)
    float* atp   = sc + 2 * 1048576;                         // fp32 [8, 24MB)
    float* arp   = sc + 6 * 1048576;                         // fp32 [24, 32MB)
    unsigned short* aggtp_b = (unsigned short*)((char*)sc + (size_t)32 * 1048576);  // bf16 [32, 40.4)
    unsigned short* aggrp_b = (unsigned short*)((char*)sc + (size_t)48 * 1048576);  // bf16 [48, 56.4)
    unsigned short* hb = (unsigned short*)sc;                // FFN hidden bf16 [0, 16.8MB)
    unsigned short* part_qb  = (unsigned short*)sc;          // bf16 Q/O-proj partials [0, 8.4MB)
    unsigned short* part_f1b = ktv;                          // bf16 FFN1 partials (33.5MB)
    unsigned short* part_f2b = ktv;                          // bf16 FFN2 partials (33.5MB)

    const long PQ = (long)MQ * D;

    // ---- all converts in one balanced launch ----
    {
        CvtPack pk;
        const float* srcs[9] = { queries, text, region, w_qkv_t, w_o_t, w_qkv_r, w_o_r, w1, w2 };
        unsigned short* dsts[9] = { qb, tb, rb, wqkvtb, wotb, wqkvrb, worb, w1b, w2b };
        long ns[9] = { (long)MQ * D, (long)MT * D, (long)MR * D, (long)3 * D * D,
                       (long)D * D, (long)3 * D * D, (long)D * D, (long)4 * D * D,
                       (long)4 * D * D };
        long acc16 = 0;
        pk.start16[0] = 0;
        for (int i = 0; i < 9; ++i) {
            pk.src[i] = srcs[i]; pk.dst[i] = dsts[i];
            acc16 += ns[i] / 16;
            pk.start16[i + 1] = acc16;
        }
        k_cvt_multi<<<2048, 256, 0, stream>>>(pk, acc16);
    }

    auto NT = [&](const unsigned short* A, const unsigned short* Bm, const float* bias,
                  const float* res, float* oF, unsigned short* oB,
                  int M, int N, int K, int lda, int ldb, int ldc,
                  int Hh, long sAb, long sAh, long sBb, long sBh, long sCb, long sCh,
                  int batch, float scale, bool gelu, int S = 1, long sPart = 0) {
        dim3 g((N + 127) / 128, (M + 127) / 128, batch * S);
        if (gelu)
            k_gemm_nt<true><<<g, 256, 0, stream>>>(A, Bm, bias, res, oF, oB, M, N, K,
                lda, ldb, ldc, Hh, sAb, sAh, sBb, sBh, sCb, sCh, scale, S, sPart);
        else
            k_gemm_nt<false><<<g, 256, 0, stream>>>(A, Bm, bias, res, oF, oB, M, N, K,
                lda, ldb, ldc, Hh, sAb, sAh, sBb, sBh, sCb, sCh, scale, S, sPart);
    };
    auto NT256 = [&](const unsigned short* A, const unsigned short* Bm, const float* bias,
                     float* oF, unsigned short* oB, int M, int N, int Kc,
                     int lda, int ldb, int ldc, int S, long sPart) {
        dim3 g((N + 255) / 256, (M + 255) / 256, S);
        k_gemm_nt256<<<g, 1024, 0, stream>>>(A, Bm, bias, oF, oB, M, N, Kc,
                                             lda, ldb, ldc, sPart);
    };
    auto REDUXB = [&](const unsigned short* part, long sPart, int S, const float* bias,
                      const float* res, float* oF, unsigned short* oB,
                      long total, int ldc, int gelu) {
        long n8 = total / 8;
        int blocks = (int)((n8 + 255) / 256);
        if (blocks > 2048) blocks = 2048;
        k_redux_b<<<blocks, 256, 0, stream>>>(part, sPart, S, bias, res, oF, oB,
                                              n8, ldc / 8, gelu);
    };
    auto SMAX = [&](const float* scp, long sPart, int S, unsigned short* P,
                    const int* mask, int L, int Lpad, int ld_sc, int ld_p,
                    int rpb, int nrows) {
        int blocks = (nrows + 3) / 4;
        k_softmax_w<<<blocks, 256, 0, stream>>>(scp, sPart, S, P, mask, L, Lpad,
                                                ld_sc, ld_p, rpb, nrows);
    };

    // ---- fused K+V projections ----
    NT256(tb, wqkvtb + (long)D * D, b_qkv_t + D, nullptr, ktv,
          MT, 2 * D, D, D, D, 2 * D, 1, 0);
    NT(rb, wqkvrb + (long)D * D, b_qkv_r + D, nullptr, nullptr, krv,
       MR, 2 * D, D, D, D, 2 * D, 1,0,0,0,0,0,0, 1, 1.0f, false);

    // per-head V transposes
    {
        dim3 g1(64 / 32, LT / 32, Bn * H);
        k_tr<<<g1, 256, 0, stream>>>(ktv + D, vtT, LT, 2 * D, LT,
                                     H, (long)LT * 2 * D, 64, (long)64 * LT);
        dim3 g2(64 / 32, LRp / 32, Bn * H);
        k_tr<<<g2, 256, 0, stream>>>(krv + D, vrT, LR, 2 * D, LRp,
                                     H, (long)LR * 2 * D, 64, (long)64 * LRp);
    }

    // ================= MHA 1 (text) =================
    NT(qb, wqkvtb, nullptr, nullptr, nullptr, part_qb, MQ, D, 512, D, D, D,
       1,0,0,0,0,0,0, 1, 1.0f, false, 2, PQ);
    REDUXB(part_qb, PQ, 2, b_qkv_t, nullptr, nullptr, qp, PQ, D, 0);
    NT(qp, ktv, nullptr, nullptr, sct, nullptr, NQ, LT, 64, D, 2 * D, LT,
       H, (long)NQ * D, 64, (long)LT * 2 * D, 64, (long)H * NQ * LT, (long)NQ * LT,
       Bn * H, 0.125f, false);
    SMAX(sct, 0, 1, (unsigned short*)sct, tmask, LT, LT, LT, 2 * LT,
         H * NQ, Bn * H * NQ);
    NT((const unsigned short*)sct, vtT, nullptr, nullptr, nullptr, ao, NQ, 64, LT,
       2 * LT, LT, D,
       H, (long)H * NQ * 2 * LT, (long)NQ * 2 * LT, (long)64 * LT * H, (long)64 * LT,
       (long)NQ * D, 64, Bn * H, 1.0f, false);
    NT(ao, wotb, nullptr, nullptr, nullptr, part_qb, MQ, D, 512, D, D, D,
       1,0,0,0,0,0,0, 1, 1.0f, false, 2, PQ);
    k_redux_ln_b<<<MQ, 256, 0, stream>>>(part_qb, PQ, 2, b_o_t, queries,
                                         ln_g, ln_b, qlf, qlnb);

    // ================= MHA 2 (region) =================
    NT(qlnb, wqkvrb, nullptr, nullptr, nullptr, part_qb, MQ, D, 512, D, D, D,
       1,0,0,0,0,0,0, 1, 1.0f, false, 2, PQ);
    REDUXB(part_qb, PQ, 2, b_qkv_r, nullptr, nullptr, qp, PQ, D, 0);
    NT(qp, krv, nullptr, nullptr, scr, nullptr, NQ, LR, 64, D, 2 * D, LRp,
       H, (long)NQ * D, 64, (long)LR * 2 * D, 64, (long)H * NQ * LRp, (long)NQ * LRp,
       Bn * H, 0.125f, false);
    SMAX(scr, 0, 1, (unsigned short*)scr, rmask, LR, LRp, LRp, 2 * LRp,
         H * NQ, Bn * H * NQ);
    NT((const unsigned short*)scr, vrT, nullptr, nullptr, nullptr, ao, NQ, 64, LRp,
       2 * LRp, LRp, D,
       H, (long)H * NQ * 2 * LRp, (long)NQ * 2 * LRp, (long)64 * LRp * H, (long)64 * LRp,
       (long)NQ * D, 64, Bn * H, 1.0f, false);
    NT(ao, worb, nullptr, nullptr, nullptr, part_qb, MQ, D, 512, D, D, D,
       1,0,0,0,0,0,0, 1, 1.0f, false, 2, PQ);
    k_redux_ln_b<<<MQ, 256, 0, stream>>>(part_qb, PQ, 2, b_o_r, qlf,
                                         ln_g, ln_b, qlf, qlnb);

    // ================= manual masked cross-attention =================
    {
        dim3 g1(D / 32, LT / 32, Bn);
        k_tr<<<g1, 256, 0, stream>>>(tb, tbT, LT, D, LT, 1, (long)LT * D, 0, (long)D * LT);
        dim3 g2(D / 32, LRp / 32, Bn);
        k_tr<<<g2, 256, 0, stream>>>(rb, rbT, LR, D, LRp, 1, (long)LR * D, 0, (long)D * LRp);
    }
    NT(qlnb, tb, nullptr, nullptr, atp, nullptr, NQ, LT, 256, D, D, LT,
       1, (long)NQ * D, 0, (long)LT * D, 0, (long)NQ * LT, 0, Bn, 0.03125f, false,
       4, (long)Bn * NQ * LT);
    SMAX(atp, (long)Bn * NQ * LT, 4, Pt, tmask, LT, LT, LT, LT, NQ, Bn * NQ);
    NT(Pt, tbT, nullptr, nullptr, nullptr, aggtp_b, NQ, D, 256, LT, LT, D,
       1, (long)NQ * LT, 0, (long)D * LT, 0, (long)NQ * D, 0, Bn, 1.0f, false,
       2, PQ);
    NT(qlnb, rb, nullptr, nullptr, arp, nullptr, NQ, LR, 256, D, D, LRp,
       1, (long)NQ * D, 0, (long)LR * D, 0, (long)NQ * LRp, 0, Bn, 0.03125f, false,
       4, (long)Bn * NQ * LRp);
    SMAX(arp, (long)Bn * NQ * LRp, 4, Pr, rmask, LR, LRp, LRp, LRp, NQ, Bn * NQ);
    NT(Pr, rbT, nullptr, nullptr, nullptr, aggrp_b, NQ, D, 128, LRp, LRp, D,
       1, (long)NQ * LRp, 0, (long)D * LRp, 0, (long)NQ * D, 0, Bn, 1.0f, false,
       2, PQ);

    k_combine_b<<<2048, 256, 0, stream>>>(qlf, qlnb, aggtp_b, aggrp_b, alpha,
                                          (long)MQ * D / 4, PQ, 2);

    // ================= FFN =================
    NT256(qlnb, w1b, nullptr, nullptr, part_f1b, MQ, 4 * D, 512,
          D, D, 4 * D, 2, (long)MQ * 4 * D);
    REDUXB(part_f1b, (long)MQ * 4 * D, 2, b1, nullptr, nullptr, hb,
           (long)MQ * 4 * D, 4 * D, 1);
    NT256(hb, w2b, nullptr, nullptr, part_f2b, MQ, D, 512,
          4 * D, 4 * D, D, 8, PQ);
    REDUXB(part_f2b, PQ, 8, b2, qlf, (float*)d_out, nullptr, PQ, D, 0);
}

// Round 11
// 520.742 us; speedup vs baseline: 2.1316x; 1.0355x over previous
//
#include <hip/hip_runtime.h>
#include <hip/hip_bf16.h>

// ---------------------------------------------------------------------------
// QueryGuidedFusionNet forward on MI355X.
// Round 11: V-transpose fused into KV-projection GEMM epilogues (kills the
// two k_tr V dispatches); NT256 deepened to 4-buffer depth-2 prefetch.
// ---------------------------------------------------------------------------

typedef __attribute__((ext_vector_type(8))) short short8;   // 8 bf16
typedef __attribute__((ext_vector_type(4))) float f32x4;

#define DEV static __device__ __forceinline__

DEV unsigned short f2bf(float f) {
    unsigned u = __float_as_uint(f);
    u += 0x7fffu + ((u >> 16) & 1u);          // RNE
    return (unsigned short)(u >> 16);
}
DEV float bf2f(unsigned short u) {
    return __uint_as_float(((unsigned)u) << 16);
}

// ------------------------- multi-tensor convert (balanced) ------------------
struct CvtPack {
    const float* src[9];
    unsigned short* dst[9];
    long start16[10];       // prefix sums in 16-element units
};

__global__ __launch_bounds__(256)
void k_cvt_multi(CvtPack p, long total16) {
    long i = (long)blockIdx.x * blockDim.x + threadIdx.x;
    long stride = (long)gridDim.x * blockDim.x;
    for (; i < total16; i += stride) {
        int t = 0;
#pragma unroll
        for (int k = 1; k < 9; ++k) t += (i >= p.start16[k]) ? 1 : 0;
        long off = i - p.start16[t];
        const float4* s = (const float4*)p.src[t] + off * 4;
        float4 a = s[0], b = s[1], c = s[2], d = s[3];
        short8 o0, o1;
        o0[0] = (short)f2bf(a.x); o0[1] = (short)f2bf(a.y);
        o0[2] = (short)f2bf(a.z); o0[3] = (short)f2bf(a.w);
        o0[4] = (short)f2bf(b.x); o0[5] = (short)f2bf(b.y);
        o0[6] = (short)f2bf(b.z); o0[7] = (short)f2bf(b.w);
        o1[0] = (short)f2bf(c.x); o1[1] = (short)f2bf(c.y);
        o1[2] = (short)f2bf(c.z); o1[3] = (short)f2bf(c.w);
        o1[4] = (short)f2bf(d.x); o1[5] = (short)f2bf(d.y);
        o1[6] = (short)f2bf(d.z); o1[7] = (short)f2bf(d.w);
        short8* dp = (short8*)p.dst[t] + off * 2;
        dp[0] = o0;
        dp[1] = o1;
    }
}

// --------------------- GEMM NT 256x256 (16 waves) ---------------------------
// 4 LDS buffers (128KB), depth-2 prefetch, counted vmcnt(4/2/0).
// Optional fused V-transpose: cols c>=vColOff write ONLY to
// vT[(b*16+hh)][dd][l] (rows are 512/batch -> ushort4 contiguous stores).
__global__ __launch_bounds__(1024)
void k_gemm_nt256(const unsigned short* __restrict__ A, const unsigned short* __restrict__ B,
                  const float* __restrict__ bias,
                  float* __restrict__ outF, unsigned short* __restrict__ outB,
                  int M, int N, int K, int lda, int ldb, int ldc,
                  long sPart,
                  unsigned short* __restrict__ vT, int vColOff, long sVz, int vLd)
{
    __shared__ unsigned short smem[4 * 16384];   // 4 bufs x (A16KB + B16KB)

    unsigned gx = gridDim.x, gy = gridDim.y;
    unsigned nwg = gx * gy * gridDim.z;
    unsigned lin = (blockIdx.z * gy + blockIdx.y) * gx + blockIdx.x;
    unsigned bx = blockIdx.x, by = blockIdx.y, bz = blockIdx.z;
    if ((nwg & 7u) == 0u) {
        unsigned cpx = nwg >> 3;
        unsigned s = (lin & 7u) * cpx + (lin >> 3);
        bx = s % gx; unsigned r2 = s / gx;
        by = r2 % gy; bz = r2 / gy;
    }
    int s_k = (int)bz;
    const unsigned short* Ap = A + (long)s_k * K;
    const unsigned short* Bp = B + (long)s_k * K;
    float* outFp = outF ? outF + (long)s_k * sPart : nullptr;
    unsigned short* outBp = outB ? outB + (long)s_k * sPart : nullptr;

    int t = threadIdx.x;
    int wid = t >> 6, lane = t & 63;
    int lrow = lane & 15, kgrp = lane >> 4;
    int tm = by * 256, tn = bx * 256;
    int wm = (wid >> 2) * 64, wn = (wid & 3) * 64;

    auto stage = [&](int buf, int k0) {
        int d = t * 16;
        int row = d >> 6;
        int colb = (d & 63) ^ (((row >> 1) & 3) << 4);
        int gr = tm + row; if (gr > M - 1) gr = M - 1;
        const unsigned short* srcA = Ap + (long)gr * lda + k0 + (colb >> 1);
        unsigned short* dstA = smem + ((buf * 32768 + d) >> 1);
        __builtin_amdgcn_global_load_lds(
            (const __attribute__((address_space(1))) unsigned int*)srcA,
            (__attribute__((address_space(3))) unsigned int*)dstA, 16, 0, 0);
        int gn = tn + row; if (gn > N - 1) gn = N - 1;
        const unsigned short* srcB = Bp + (long)gn * ldb + k0 + (colb >> 1);
        unsigned short* dstB = smem + ((buf * 32768 + 16384 + d) >> 1);
        __builtin_amdgcn_global_load_lds(
            (const __attribute__((address_space(1))) unsigned int*)srcB,
            (__attribute__((address_space(3))) unsigned int*)dstB, 16, 0, 0);
    };

    f32x4 acc[4][4] = {};
    int nt = K >> 5;

    stage(0, 0);
    if (nt > 1) stage(1, 32);
    if (nt > 2) stage(2, 64);

    for (int ti = 0; ti < nt; ++ti) {
        int cur = ti & 3;
        int rem = nt - 1 - ti;
        if (rem >= 2)      asm volatile("s_waitcnt vmcnt(4)" ::: "memory");
        else if (rem == 1) asm volatile("s_waitcnt vmcnt(2)" ::: "memory");
        else               asm volatile("s_waitcnt vmcnt(0)" ::: "memory");
        __builtin_amdgcn_sched_barrier(0);
        __builtin_amdgcn_s_barrier();
        __builtin_amdgcn_sched_barrier(0);

        if (ti + 3 < nt) stage((ti + 3) & 3, (ti + 3) << 5);

        const char* Ab = (const char*)smem + cur * 32768;
        const char* Bb = Ab + 16384;
        short8 a[4], bb[4];
#pragma unroll
        for (int i = 0; i < 4; ++i) {
            int row = wm + i * 16 + lrow;
            a[i] = *(const short8*)(Ab + row * 64 + ((kgrp * 16) ^ (((row >> 1) & 3) << 4)));
        }
#pragma unroll
        for (int j = 0; j < 4; ++j) {
            int row = wn + j * 16 + lrow;
            bb[j] = *(const short8*)(Bb + row * 64 + ((kgrp * 16) ^ (((row >> 1) & 3) << 4)));
        }
#pragma unroll
        for (int i = 0; i < 4; ++i)
#pragma unroll
            for (int j = 0; j < 4; ++j)
                acc[i][j] = __builtin_amdgcn_mfma_f32_16x16x32_bf16(a[i], bb[j], acc[i][j], 0, 0, 0);
    }

#pragma unroll
    for (int i = 0; i < 4; ++i) {
        int rbase = tm + wm + i * 16 + kgrp * 4;
#pragma unroll
        for (int j = 0; j < 4; ++j) {
            int c = tn + wn + j * 16 + lrow;
            if (c >= N) continue;
            float bv = bias ? bias[c] : 0.0f;
            float v[4];
#pragma unroll
            for (int e = 0; e < 4; ++e) v[e] = acc[i][j][e] + bv;
            if (vT && c >= vColOff) {
                // rowsPerBatch = 512 (text); 4-run never crosses a batch.
                if (rbase + 3 < M) {
                    int hh = (c - vColOff) >> 6, dd = (c - vColOff) & 63;
                    int bb2 = rbase >> 9, l = rbase & 511;
                    ushort4 o = { f2bf(v[0]), f2bf(v[1]), f2bf(v[2]), f2bf(v[3]) };
                    *(ushort4*)(vT + (long)(bb2 * 16 + hh) * sVz + (long)dd * vLd + l) = o;
                }
            } else {
#pragma unroll
                for (int e = 0; e < 4; ++e) {
                    int r = rbase + e;
                    if (r >= M) continue;
                    long oidx = (long)r * ldc + c;
                    if (outFp) outFp[oidx] = v[e];
                    if (outBp) outBp[oidx] = f2bf(v[e]);
                }
            }
        }
    }
}

// ------------------------------ GEMM NT (pipelined 128²) --------------------
// Optional fused V-transpose for region KV (rowsPerBatch=196, scalar stores).
template<bool GELU>
__global__ __launch_bounds__(256)
void k_gemm_nt(const unsigned short* __restrict__ A, const unsigned short* __restrict__ B,
               const float* __restrict__ bias, const float* __restrict__ res,
               float* __restrict__ outF, unsigned short* __restrict__ outB,
               int M, int N, int K, int lda, int ldb, int ldc,
               int H, long sAb, long sAh, long sBb, long sBh, long sCb, long sCh,
               float scale, int S, long sPart,
               unsigned short* __restrict__ vT, int vColOff, long sVz, int vLd, int rpb)
{
    __shared__ unsigned short smem[5 * 8192];

    unsigned gx = gridDim.x, gy = gridDim.y, gz = gridDim.z;
    unsigned nwg = gx * gy * gz;
    unsigned lin = (blockIdx.z * gy + blockIdx.y) * gx + blockIdx.x;
    unsigned bx = blockIdx.x, by = blockIdx.y, bz = blockIdx.z;
    if ((nwg & 7u) == 0u) {
        unsigned cpx = nwg >> 3;
        unsigned s = (lin & 7u) * cpx + (lin >> 3);
        bx = s % gx; unsigned r2 = s / gx;
        by = r2 % gy; bz = r2 / gy;
    }

    int zz = (int)bz;
    int s_k = 0;
    if (S > 1) { s_k = zz % S; zz /= S; }
    int b = zz / H, h = zz - b * H;
    const unsigned short* Ap = A + (long)b * sAb + (long)h * sAh + (long)s_k * K;
    const unsigned short* Bp = B + (long)b * sBb + (long)h * sBh + (long)s_k * K;
    float* outFp = outF;
    if (outFp && S > 1) outFp += (long)s_k * sPart;
    unsigned short* outBp = outB;
    if (outBp && S > 1) outBp += (long)s_k * sPart;
    long offC = (long)b * sCb + (long)h * sCh;

    int t    = threadIdx.x;
    int wid  = t >> 6;
    int lane = t & 63;
    int lrow = lane & 15;
    int kgrp = lane >> 4;

    int tm = by * 128;
    int tn = bx * 128;
    int wm = (wid >> 1) * 64;
    int wn = (wid & 1) * 64;

    auto stage = [&](int buf, int k0) {
#pragma unroll
        for (int r = 0; r < 2; ++r) {
            int d = r * 4096 + t * 16;
            int row = d >> 6;
            int colb = (d & 63) ^ (((row >> 1) & 3) << 4);
            int gr = tm + row; if (gr > M - 1) gr = M - 1;
            const unsigned short* srcA = Ap + (long)gr * lda + k0 + (colb >> 1);
            unsigned short* dstA = smem + ((buf * 16384 + r * 4096 + wid * 1024) >> 1);
            __builtin_amdgcn_global_load_lds(
                (const __attribute__((address_space(1))) unsigned int*)srcA,
                (__attribute__((address_space(3))) unsigned int*)dstA, 16, 0, 0);
            int gn = tn + row; if (gn > N - 1) gn = N - 1;
            const unsigned short* srcB = Bp + (long)gn * ldb + k0 + (colb >> 1);
            unsigned short* dstB = smem + ((buf * 16384 + 8192 + r * 4096 + wid * 1024) >> 1);
            __builtin_amdgcn_global_load_lds(
                (const __attribute__((address_space(1))) unsigned int*)srcB,
                (__attribute__((address_space(3))) unsigned int*)dstB, 16, 0, 0);
        }
    };

    f32x4 acc[4][4] = {};
    int nt = K >> 5;

    for (int p = 0; p < 4 && p < nt; ++p) stage(p, p << 5);

    for (int ti = 0; ti < nt; ++ti) {
        int cur = ti % 5;
        int rem = nt - 1 - ti;
        if (rem >= 3)      asm volatile("s_waitcnt vmcnt(12)" ::: "memory");
        else if (rem == 2) asm volatile("s_waitcnt vmcnt(8)"  ::: "memory");
        else if (rem == 1) asm volatile("s_waitcnt vmcnt(4)"  ::: "memory");
        else               asm volatile("s_waitcnt vmcnt(0)"  ::: "memory");
        __builtin_amdgcn_sched_barrier(0);
        __builtin_amdgcn_s_barrier();
        __builtin_amdgcn_sched_barrier(0);

        if (ti + 4 < nt) stage((ti + 4) % 5, (ti + 4) << 5);

        const char* Ab = (const char*)smem + cur * 16384;
        const char* Bb = Ab + 8192;
        short8 a[4], bb[4];
#pragma unroll
        for (int i = 0; i < 4; ++i) {
            int row = wm + i * 16 + lrow;
            a[i] = *(const short8*)(Ab + row * 64 + ((kgrp * 16) ^ (((row >> 1) & 3) << 4)));
        }
#pragma unroll
        for (int j = 0; j < 4; ++j) {
            int row = wn + j * 16 + lrow;
            bb[j] = *(const short8*)(Bb + row * 64 + ((kgrp * 16) ^ (((row >> 1) & 3) << 4)));
        }
#pragma unroll
        for (int i = 0; i < 4; ++i)
#pragma unroll
            for (int j = 0; j < 4; ++j)
                acc[i][j] = __builtin_amdgcn_mfma_f32_16x16x32_bf16(a[i], bb[j], acc[i][j], 0, 0, 0);
    }

#pragma unroll
    for (int i = 0; i < 4; ++i) {
        int rbase = tm + wm + i * 16 + kgrp * 4;
#pragma unroll
        for (int j = 0; j < 4; ++j) {
            int c = tn + wn + j * 16 + lrow;
            if (c >= N) continue;
            float bv = bias ? bias[c] : 0.0f;
            if (vT && c >= vColOff) {
                int hh = (c - vColOff) >> 6, dd = (c - vColOff) & 63;
#pragma unroll
                for (int e = 0; e < 4; ++e) {
                    int r = rbase + e;
                    if (r >= M) continue;
                    float v = acc[i][j][e] * scale + bv;
                    int bb2 = r / rpb, l = r - bb2 * rpb;
                    vT[(long)(bb2 * 16 + hh) * sVz + (long)dd * vLd + l] = f2bf(v);
                }
                continue;
            }
#pragma unroll
            for (int e = 0; e < 4; ++e) {
                int r = rbase + e;
                if (r >= M) continue;
                float v = acc[i][j][e] * scale + bv;
                long oidx = offC + (long)r * ldc + c;
                if (res) v += res[oidx];
                if (GELU) v = 0.5f * v * (1.0f + erff(v * 0.70710678118654752f));
                if (outFp) outFp[oidx] = v;
                if (outBp) outBp[oidx] = f2bf(v);
            }
        }
    }
}

// -------------------- split-K reduce (bf16 partials) -------------------------
__global__ __launch_bounds__(256)
void k_redux_b(const unsigned short* __restrict__ part, long sPart, int S,
               const float* __restrict__ bias, const float* __restrict__ res,
               float* __restrict__ outF, unsigned short* __restrict__ outB,
               long n8, int ldc8, int gelu)
{
    long i = (long)blockIdx.x * blockDim.x + threadIdx.x;
    long stride = (long)gridDim.x * blockDim.x;
    for (; i < n8; i += stride) {
        long e0 = i * 8;
        float v[8];
        short8 p0 = *(const short8*)(part + e0);
#pragma unroll
        for (int k = 0; k < 8; ++k) v[k] = bf2f((unsigned short)p0[k]);
        for (int s = 1; s < S; ++s) {
            short8 ps = *(const short8*)(part + e0 + (long)s * sPart);
#pragma unroll
            for (int k = 0; k < 8; ++k) v[k] += bf2f((unsigned short)ps[k]);
        }
        if (bias) {
            int c = (int)(i % ldc8) * 8;
            float4 b0 = *(const float4*)(bias + c);
            float4 b1 = *(const float4*)(bias + c + 4);
            v[0] += b0.x; v[1] += b0.y; v[2] += b0.z; v[3] += b0.w;
            v[4] += b1.x; v[5] += b1.y; v[6] += b1.z; v[7] += b1.w;
        }
        if (res) {
            float4 r0 = *(const float4*)(res + e0);
            float4 r1 = *(const float4*)(res + e0 + 4);
            v[0] += r0.x; v[1] += r0.y; v[2] += r0.z; v[3] += r0.w;
            v[4] += r1.x; v[5] += r1.y; v[6] += r1.z; v[7] += r1.w;
        }
        if (gelu) {
#pragma unroll
            for (int k = 0; k < 8; ++k)
                v[k] = 0.5f * v[k] * (1.0f + erff(v[k] * 0.70710678118654752f));
        }
        if (outF) {
            float4 o0 = { v[0], v[1], v[2], v[3] };
            float4 o1 = { v[4], v[5], v[6], v[7] };
            *(float4*)(outF + e0) = o0;
            *(float4*)(outF + e0 + 4) = o1;
        }
        if (outB) {
            short8 o;
#pragma unroll
            for (int k = 0; k < 8; ++k) o[k] = (short)f2bf(v[k]);
            *(short8*)(outB + e0) = o;
        }
    }
}

// ---- fused split-K(bf16) reduce + bias + residual + LayerNorm --------------
__global__ __launch_bounds__(256)
void k_redux_ln_b(const unsigned short* __restrict__ part, long sPart, int S,
                  const float* __restrict__ bias, const float* __restrict__ res,
                  const float* __restrict__ g, const float* __restrict__ bt,
                  float* __restrict__ yf, unsigned short* __restrict__ yb)
{
    int row = blockIdx.x;
    int t = threadIdx.x;
    int lane = t & 63, wid = t >> 6;
    long base = (long)row * 1024 + t * 4;

    ushort4 p0 = *(const ushort4*)(part + base);
    float v0 = bf2f(p0.x), v1 = bf2f(p0.y), v2 = bf2f(p0.z), v3 = bf2f(p0.w);
    for (int s = 1; s < S; ++s) {
        ushort4 ps = *(const ushort4*)(part + base + (long)s * sPart);
        v0 += bf2f(ps.x); v1 += bf2f(ps.y); v2 += bf2f(ps.z); v3 += bf2f(ps.w);
    }
    float4 bv = *(const float4*)(bias + t * 4);
    v0 += bv.x; v1 += bv.y; v2 += bv.z; v3 += bv.w;
    float4 rv = *(const float4*)(res + base);
    v0 += rv.x; v1 += rv.y; v2 += rv.z; v3 += rv.w;

    float s1 = v0 + v1 + v2 + v3;
    float s2 = v0 * v0 + v1 * v1 + v2 * v2 + v3 * v3;
#pragma unroll
    for (int d = 32; d > 0; d >>= 1) { s1 += __shfl_xor(s1, d, 64); s2 += __shfl_xor(s2, d, 64); }
    __shared__ float rs[4], rss[4];
    if (lane == 0) { rs[wid] = s1; rss[wid] = s2; }
    __syncthreads();
    s1 = rs[0] + rs[1] + rs[2] + rs[3];
    s2 = rss[0] + rss[1] + rss[2] + rss[3];
    float mu  = s1 * (1.0f / 1024.0f);
    float var = s2 * (1.0f / 1024.0f) - mu * mu;
    float inv = rsqrtf(var + 1e-5f);

    float4 gv = *(const float4*)(g + t * 4);
    float4 btv = *(const float4*)(bt + t * 4);
    float o0 = (v0 - mu) * inv * gv.x + btv.x;
    float o1 = (v1 - mu) * inv * gv.y + btv.y;
    float o2 = (v2 - mu) * inv * gv.z + btv.z;
    float o3 = (v3 - mu) * inv * gv.w + btv.w;
    float4 of = { o0, o1, o2, o3 };
    ushort4 ob = { f2bf(o0), f2bf(o1), f2bf(o2), f2bf(o3) };
    *(float4*)(yf + base) = of;
    *(ushort4*)(yb + base) = ob;
}

// ---------------------- tiled transpose (bf16) ------------------------------
__global__ __launch_bounds__(256)
void k_tr(const unsigned short* __restrict__ in, unsigned short* __restrict__ out,
          int R, int ldin, int ldout,
          int H, long sIb, long sIh, long sOz)
{
    __shared__ unsigned short tile[32][33];
    int z = blockIdx.z;
    int b = z / H, h = z - b * H;
    const unsigned short* ip = in + (long)b * sIb + (long)h * sIh;
    unsigned short* op = out + (long)z * sOz;
    int t = threadIdx.x;
    int cl = t & 31, rl = t >> 5;
    int c0 = blockIdx.x * 32, r0 = blockIdx.y * 32;
#pragma unroll
    for (int i = 0; i < 4; ++i) {
        int r = r0 + rl + i * 8;
        unsigned short v = 0;
        if (r < R) v = ip[(long)r * ldin + (c0 + cl)];
        tile[rl + i * 8][cl] = v;
    }
    __syncthreads();
#pragma unroll
    for (int i = 0; i < 4; ++i) {
        int orow = c0 + rl + i * 8;
        int ocol = r0 + cl;
        op[(long)orow * ldout + ocol] = tile[cl][rl + i * 8];
    }
}

// --------------------- wave-per-row masked softmax ---------------------------
__global__ __launch_bounds__(256)
void k_softmax_w(const float* __restrict__ sc, long sPart, int S,
                 unsigned short* __restrict__ P,
                 const int* __restrict__ mask, int L, int Lpad,
                 int ld_sc, int ld_p, int rows_per_batch, int nrows)
{
    int gw = (int)((blockIdx.x * 256 + threadIdx.x) >> 6);
    if (gw >= nrows) return;
    int lane = threadIdx.x & 63;
    int b = gw / rows_per_batch;
    const float* p = sc + (long)gw * ld_sc;
    unsigned short* po = P + (long)gw * ld_p;
    const int* mrow = mask + (long)b * L;

    int nch = (Lpad + 255) >> 8;     // 1 or 2
    float v[2][4];
    float mx = -INFINITY;
#pragma unroll
    for (int c = 0; c < 2; ++c) {
        if (c >= nch) { v[c][0]=v[c][1]=v[c][2]=v[c][3] = -INFINITY; continue; }
        int j = c * 256 + lane * 4;
        if (j < L) {
            float4 x = *(const float4*)(p + j);
            for (int s = 1; s < S; ++s) {
                float4 y = *(const float4*)(p + j + (long)s * sPart);
                x.x += y.x; x.y += y.y; x.z += y.z; x.w += y.w;
            }
            int4 m = *(const int4*)(mrow + j);
            v[c][0] = m.x ? x.x : -INFINITY;
            v[c][1] = m.y ? x.y : -INFINITY;
            v[c][2] = m.z ? x.z : -INFINITY;
            v[c][3] = m.w ? x.w : -INFINITY;
        } else {
            v[c][0]=v[c][1]=v[c][2]=v[c][3] = -INFINITY;
        }
        mx = fmaxf(mx, fmaxf(fmaxf(v[c][0], v[c][1]), fmaxf(v[c][2], v[c][3])));
    }
#pragma unroll
    for (int d = 32; d > 0; d >>= 1) mx = fmaxf(mx, __shfl_xor(mx, d, 64));

    float sum = 0.f;
#pragma unroll
    for (int c = 0; c < 2; ++c)
#pragma unroll
        for (int k = 0; k < 4; ++k) {
            float e = (v[c][k] == -INFINITY) ? 0.0f : __expf(v[c][k] - mx);
            v[c][k] = e;
            sum += e;
        }
#pragma unroll
    for (int d = 32; d > 0; d >>= 1) sum += __shfl_xor(sum, d, 64);
    float inv = 1.0f / sum;

#pragma unroll
    for (int c = 0; c < 2; ++c) {
        if (c >= nch) continue;
        int j = c * 256 + lane * 4;
        if (j < Lpad) {
            ushort4 o;
            o.x = f2bf(v[c][0] * inv);
            o.y = f2bf(v[c][1] * inv);
            o.z = f2bf(v[c][2] * inv);
            o.w = f2bf(v[c][3] * inv);
            *(ushort4*)(po + j) = o;
        }
    }
}

// ---------------- combine (bf16 partial aggs) -------------------------------
__global__ void k_combine_b(float* __restrict__ qf, unsigned short* __restrict__ qb,
                            const unsigned short* __restrict__ aggtp,
                            const unsigned short* __restrict__ aggrp,
                            const float* __restrict__ alpha, long n4, long sPart, int S)
{
    float a = *alpha;
    long i = (long)blockIdx.x * blockDim.x + threadIdx.x;
    long stride = (long)gridDim.x * blockDim.x;
    for (; i < n4; i += stride) {
        long e0 = i * 4;
        float st[4] = {0.f, 0.f, 0.f, 0.f}, sr[4] = {0.f, 0.f, 0.f, 0.f};
        for (int s = 0; s < S; ++s) {
            ushort4 pt = *(const ushort4*)(aggtp + e0 + (long)s * sPart);
            ushort4 pr = *(const ushort4*)(aggrp + e0 + (long)s * sPart);
            st[0] += bf2f(pt.x); st[1] += bf2f(pt.y); st[2] += bf2f(pt.z); st[3] += bf2f(pt.w);
            sr[0] += bf2f(pr.x); sr[1] += bf2f(pr.y); sr[2] += bf2f(pr.z); sr[3] += bf2f(pr.w);
        }
        float4 q = *(const float4*)(qf + e0);
        float v0 = q.x + a * sr[0] + (1.0f - a) * st[0];
        float v1 = q.y + a * sr[1] + (1.0f - a) * st[1];
        float v2 = q.z + a * sr[2] + (1.0f - a) * st[2];
        float v3 = q.w + a * sr[3] + (1.0f - a) * st[3];
        float4 of = { v0, v1, v2, v3 };
        ushort4 ob = { f2bf(v0), f2bf(v1), f2bf(v2), f2bf(v3) };
        *(float4*)(qf + e0) = of;
        *(ushort4*)(qb + e0) = ob;
    }
}

// ---------------------------------------------------------------------------
extern "C" void kernel_launch(void* const* d_in, const int* in_sizes, int n_in,
                              void* d_out, int out_size, void* d_ws, size_t ws_size,
                              hipStream_t stream)
{
    const float* queries = (const float*)d_in[0];
    const float* text    = (const float*)d_in[1];
    const float* region  = (const float*)d_in[2];
    const int*   tmask   = (const int*)d_in[3];
    const int*   rmask   = (const int*)d_in[4];
    const float* w_qkv_t = (const float*)d_in[5];
    const float* b_qkv_t = (const float*)d_in[6];
    const float* w_o_t   = (const float*)d_in[7];
    const float* b_o_t   = (const float*)d_in[8];
    const float* w_qkv_r = (const float*)d_in[9];
    const float* b_qkv_r = (const float*)d_in[10];
    const float* w_o_r   = (const float*)d_in[11];
    const float* b_o_r   = (const float*)d_in[12];
    const float* ln_g    = (const float*)d_in[13];
    const float* ln_b    = (const float*)d_in[14];
    const float* w1      = (const float*)d_in[15];
    const float* b1      = (const float*)d_in[16];
    const float* w2      = (const float*)d_in[17];
    const float* b2      = (const float*)d_in[18];
    const float* alpha   = (const float*)d_in[19];

    const int Bn = 16, NQ = 128, LT = 512, LR = 196, D = 1024, H = 16;
    const int LRp = 256;
    const int MQ = Bn * NQ;              // 2048
    const int MT = Bn * LT;              // 8192
    const int MR = Bn * LR;              // 3136

    char* ws = (char*)d_ws;
    size_t off = 0;
    auto alloc = [&](size_t bytes) -> void* {
        void* p = ws + off;
        off = (off + bytes + 255) & ~(size_t)255;
        return p;
    };
    unsigned short* qb     = (unsigned short*)alloc((size_t)MQ * D * 2);
    unsigned short* tb     = (unsigned short*)alloc((size_t)MT * D * 2);
    unsigned short* rb     = (unsigned short*)alloc((size_t)MR * D * 2);
    unsigned short* wqkvtb = (unsigned short*)alloc((size_t)3 * D * D * 2);
    unsigned short* wotb   = (unsigned short*)alloc((size_t)D * D * 2);
    unsigned short* wqkvrb = (unsigned short*)alloc((size_t)3 * D * D * 2);
    unsigned short* worb   = (unsigned short*)alloc((size_t)D * D * 2);
    unsigned short* w1b    = (unsigned short*)alloc((size_t)4 * D * D * 2);
    unsigned short* w2b    = (unsigned short*)alloc((size_t)4 * D * D * 2);
    unsigned short* ktv    = (unsigned short*)alloc((size_t)MT * 2 * D * 2);
    unsigned short* krv    = (unsigned short*)alloc((size_t)MR * 2 * D * 2);
    unsigned short* vtT    = (unsigned short*)alloc((size_t)Bn * H * 64 * LT * 2);
    unsigned short* vrT    = (unsigned short*)alloc((size_t)Bn * H * 64 * LRp * 2);
    unsigned short* qp     = (unsigned short*)alloc((size_t)MQ * D * 2);
    unsigned short* ao     = (unsigned short*)alloc((size_t)MQ * D * 2);
    unsigned short* qlnb   = (unsigned short*)alloc((size_t)MQ * D * 2);
    float* qlf  = (float*)alloc((size_t)MQ * D * 4);
    float* sc   = (float*)alloc((size_t)Bn * H * NQ * LT * 4);   // 67MB arena
    if (off > ws_size) return;

    // phase-reused views
    unsigned short* tbT = ktv;                               // [B][1024][512]
    unsigned short* rbT = ktv + (size_t)Bn * D * LT;         // [B][1024][256p]
    float* sct = sc;
    float* scr = sc;
    unsigned short* Pt = (unsigned short*)sc;
    unsigned short* Pr = (unsigned short*)(sc + 1 * 1048576);
    float* atp   = sc + 2 * 1048576;
    float* arp   = sc + 6 * 1048576;
    unsigned short* aggtp_b = (unsigned short*)((char*)sc + (size_t)32 * 1048576);
    unsigned short* aggrp_b = (unsigned short*)((char*)sc + (size_t)48 * 1048576);
    unsigned short* hb = (unsigned short*)sc;
    unsigned short* part_qb  = (unsigned short*)sc;
    unsigned short* part_f1b = ktv;
    unsigned short* part_f2b = ktv;

    const long PQ = (long)MQ * D;

    // ---- all converts in one balanced launch ----
    {
        CvtPack pk;
        const float* srcs[9] = { queries, text, region, w_qkv_t, w_o_t, w_qkv_r, w_o_r, w1, w2 };
        unsigned short* dsts[9] = { qb, tb, rb, wqkvtb, wotb, wqkvrb, worb, w1b, w2b };
        long ns[9] = { (long)MQ * D, (long)MT * D, (long)MR * D, (long)3 * D * D,
                       (long)D * D, (long)3 * D * D, (long)D * D, (long)4 * D * D,
                       (long)4 * D * D };
        long acc16 = 0;
        pk.start16[0] = 0;
        for (int i = 0; i < 9; ++i) {
            pk.src[i] = srcs[i]; pk.dst[i] = dsts[i];
            acc16 += ns[i] / 16;
            pk.start16[i + 1] = acc16;
        }
        k_cvt_multi<<<2048, 256, 0, stream>>>(pk, acc16);
    }

    auto NT = [&](const unsigned short* A, const unsigned short* Bm, const float* bias,
                  const float* res, float* oF, unsigned short* oB,
                  int M, int N, int K, int lda, int ldb, int ldc,
                  int Hh, long sAb, long sAh, long sBb, long sBh, long sCb, long sCh,
                  int batch, float scale, bool gelu, int S = 1, long sPart = 0,
                  unsigned short* vT = nullptr, int vColOff = 0, long sVz = 0,
                  int vLd = 0, int rpb = 1) {
        dim3 g((N + 127) / 128, (M + 127) / 128, batch * S);
        if (gelu)
            k_gemm_nt<true><<<g, 256, 0, stream>>>(A, Bm, bias, res, oF, oB, M, N, K,
                lda, ldb, ldc, Hh, sAb, sAh, sBb, sBh, sCb, sCh, scale, S, sPart,
                vT, vColOff, sVz, vLd, rpb);
        else
            k_gemm_nt<false><<<g, 256, 0, stream>>>(A, Bm, bias, res, oF, oB, M, N, K,
                lda, ldb, ldc, Hh, sAb, sAh, sBb, sBh, sCb, sCh, scale, S, sPart,
                vT, vColOff, sVz, vLd, rpb);
    };
    auto NT256 = [&](const unsigned short* A, const unsigned short* Bm, const float* bias,
                     float* oF, unsigned short* oB, int M, int N, int Kc,
                     int lda, int ldb, int ldc, int S, long sPart,
                     unsigned short* vT = nullptr, int vColOff = 0, long sVz = 0,
                     int vLd = 0) {
        dim3 g((N + 255) / 256, (M + 255) / 256, S);
        k_gemm_nt256<<<g, 1024, 0, stream>>>(A, Bm, bias, oF, oB, M, N, Kc,
                                             lda, ldb, ldc, sPart, vT, vColOff, sVz, vLd);
    };
    auto REDUXB = [&](const unsigned short* part, long sPart, int S, const float* bias,
                      const float* res, float* oF, unsigned short* oB,
                      long total, int ldc, int gelu) {
        long n8 = total / 8;
        int blocks = (int)((n8 + 255) / 256);
        if (blocks > 2048) blocks = 2048;
        k_redux_b<<<blocks, 256, 0, stream>>>(part, sPart, S, bias, res, oF, oB,
                                              n8, ldc / 8, gelu);
    };
    auto SMAX = [&](const float* scp, long sPart, int S, unsigned short* P,
                    const int* mask, int L, int Lpad, int ld_sc, int ld_p,
                    int rpb, int nrows) {
        int blocks = (nrows + 3) / 4;
        k_softmax_w<<<blocks, 256, 0, stream>>>(scp, sPart, S, P, mask, L, Lpad,
                                                ld_sc, ld_p, rpb, nrows);
    };

    // ---- fused K+V projections (V written directly transposed) ----
    NT256(tb, wqkvtb + (long)D * D, b_qkv_t + D, nullptr, ktv,
          MT, 2 * D, D, D, D, 2 * D, 1, 0,
          vtT, D, (long)64 * LT, LT);
    NT(rb, wqkvrb + (long)D * D, b_qkv_r + D, nullptr, nullptr, krv,
       MR, 2 * D, D, D, D, 2 * D, 1,0,0,0,0,0,0, 1, 1.0f, false, 1, 0,
       vrT, D, (long)64 * LRp, LRp, LR);

    // ================= MHA 1 (text) =================
    NT(qb, wqkvtb, nullptr, nullptr, nullptr, part_qb, MQ, D, 512, D, D, D,
       1,0,0,0,0,0,0, 1, 1.0f, false, 2, PQ);
    REDUXB(part_qb, PQ, 2, b_qkv_t, nullptr, nullptr, qp, PQ, D, 0);
    NT(qp, ktv, nullptr, nullptr, sct, nullptr, NQ, LT, 64, D, 2 * D, LT,
       H, (long)NQ * D, 64, (long)LT * 2 * D, 64, (long)H * NQ * LT, (long)NQ * LT,
       Bn * H, 0.125f, false);
    SMAX(sct, 0, 1, (unsigned short*)sct, tmask, LT, LT, LT, 2 * LT,
         H * NQ, Bn * H * NQ);
    NT((const unsigned short*)sct, vtT, nullptr, nullptr, nullptr, ao, NQ, 64, LT,
       2 * LT, LT, D,
       H, (long)H * NQ * 2 * LT, (long)NQ * 2 * LT, (long)64 * LT * H, (long)64 * LT,
       (long)NQ * D, 64, Bn * H, 1.0f, false);
    NT(ao, wotb, nullptr, nullptr, nullptr, part_qb, MQ, D, 512, D, D, D,
       1,0,0,0,0,0,0, 1, 1.0f, false, 2, PQ);
    k_redux_ln_b<<<MQ, 256, 0, stream>>>(part_qb, PQ, 2, b_o_t, queries,
                                         ln_g, ln_b, qlf, qlnb);

    // ================= MHA 2 (region) =================
    NT(qlnb, wqkvrb, nullptr, nullptr, nullptr, part_qb, MQ, D, 512, D, D, D,
       1,0,0,0,0,0,0, 1, 1.0f, false, 2, PQ);
    REDUXB(part_qb, PQ, 2, b_qkv_r, nullptr, nullptr, qp, PQ, D, 0);
    NT(qp, krv, nullptr, nullptr, scr, nullptr, NQ, LR, 64, D, 2 * D, LRp,
       H, (long)NQ * D, 64, (long)LR * 2 * D, 64, (long)H * NQ * LRp, (long)NQ * LRp,
       Bn * H, 0.125f, false);
    SMAX(scr, 0, 1, (unsigned short*)scr, rmask, LR, LRp, LRp, 2 * LRp,
         H * NQ, Bn * H * NQ);
    NT((const unsigned short*)scr, vrT, nullptr, nullptr, nullptr, ao, NQ, 64, LRp,
       2 * LRp, LRp, D,
       H, (long)H * NQ * 2 * LRp, (long)NQ * 2 * LRp, (long)64 * LRp * H, (long)64 * LRp,
       (long)NQ * D, 64, Bn * H, 1.0f, false);
    NT(ao, worb, nullptr, nullptr, nullptr, part_qb, MQ, D, 512, D, D, D,
       1,0,0,0,0,0,0, 1, 1.0f, false, 2, PQ);
    k_redux_ln_b<<<MQ, 256, 0, stream>>>(part_qb, PQ, 2, b_o_r, qlf,
                                         ln_g, ln_b, qlf, qlnb);

    // ================= manual masked cross-attention =================
    {
        dim3 g1(D / 32, LT / 32, Bn);
        k_tr<<<g1, 256, 0, stream>>>(tb, tbT, LT, D, LT, 1, (long)LT * D, 0, (long)D * LT);
        dim3 g2(D / 32, LRp / 32, Bn);
        k_tr<<<g2, 256, 0, stream>>>(rb, rbT, LR, D, LRp, 1, (long)LR * D, 0, (long)D * LRp);
    }
    NT(qlnb, tb, nullptr, nullptr, atp, nullptr, NQ, LT, 256, D, D, LT,
       1, (long)NQ * D, 0, (long)LT * D, 0, (long)NQ * LT, 0, Bn, 0.03125f, false,
       4, (long)Bn * NQ * LT);
    SMAX(atp, (long)Bn * NQ * LT, 4, Pt, tmask, LT, LT, LT, LT, NQ, Bn * NQ);
    NT(Pt, tbT, nullptr, nullptr, nullptr, aggtp_b, NQ, D, 256, LT, LT, D,
       1, (long)NQ * LT, 0, (long)D * LT, 0, (long)NQ * D, 0, Bn, 1.0f, false,
       2, PQ);
    NT(qlnb, rb, nullptr, nullptr, arp, nullptr, NQ, LR, 256, D, D, LRp,
       1, (long)NQ * D, 0, (long)LR * D, 0, (long)NQ * LRp, 0, Bn, 0.03125f, false,
       4, (long)Bn * NQ * LRp);
    SMAX(arp, (long)Bn * NQ * LRp, 4, Pr, rmask, LR, LRp, LRp, LRp, NQ, Bn * NQ);
    NT(Pr, rbT, nullptr, nullptr, nullptr, aggrp_b, NQ, D, 128, LRp, LRp, D,
       1, (long)NQ * LRp, 0, (long)D * LRp, 0, (long)NQ * D, 0, Bn, 1.0f, false,
       2, PQ);

    k_combine_b<<<2048, 256, 0, stream>>>(qlf, qlnb, aggtp_b, aggrp_b, alpha,
                                          (long)MQ * D / 4, PQ, 2);

    // ================= FFN =================
    NT256(qlnb, w1b, nullptr, nullptr, part_f1b, MQ, 4 * D, 512,
          D, D, 4 * D, 2, (long)MQ * 4 * D);
    REDUXB(part_f1b, (long)MQ * 4 * D, 2, b1, nullptr, nullptr, hb,
           (long)MQ * 4 * D, 4 * D, 1);
    NT256(hb, w2b, nullptr, nullptr, part_f2b, MQ, D, 512,
          4 * D, 4 * D, D, 8, PQ);
    REDUXB(part_f2b, PQ, 8, b2, qlf, (float*)d_out, nullptr, PQ, D, 0);
}

// Round 13
// 514.195 us; speedup vs baseline: 2.1588x; 1.0127x over previous
//
#include <hip/hip_runtime.h>
#include <hip/hip_bf16.h>

// ---------------------------------------------------------------------------
// QueryGuidedFusionNet forward on MI355X.
// Round 13: fix r12's vmcnt bug (stage = 4 VMEM instrs/wave, so steady-state
// wait is vmcnt(4), NOT vmcnt(8) which was a no-op -> race). BK=64 NT256
// otherwise identical to r12; rest identical to r11.
// ---------------------------------------------------------------------------

typedef __attribute__((ext_vector_type(8))) short short8;   // 8 bf16
typedef __attribute__((ext_vector_type(4))) float f32x4;

#define DEV static __device__ __forceinline__

DEV unsigned short f2bf(float f) {
    unsigned u = __float_as_uint(f);
    u += 0x7fffu + ((u >> 16) & 1u);          // RNE
    return (unsigned short)(u >> 16);
}
DEV float bf2f(unsigned short u) {
    return __uint_as_float(((unsigned)u) << 16);
}

// ------------------------- multi-tensor convert (balanced) ------------------
struct CvtPack {
    const float* src[9];
    unsigned short* dst[9];
    long start16[10];       // prefix sums in 16-element units
};

__global__ __launch_bounds__(256)
void k_cvt_multi(CvtPack p, long total16) {
    long i = (long)blockIdx.x * blockDim.x + threadIdx.x;
    long stride = (long)gridDim.x * blockDim.x;
    for (; i < total16; i += stride) {
        int t = 0;
#pragma unroll
        for (int k = 1; k < 9; ++k) t += (i >= p.start16[k]) ? 1 : 0;
        long off = i - p.start16[t];
        const float4* s = (const float4*)p.src[t] + off * 4;
        float4 a = s[0], b = s[1], c = s[2], d = s[3];
        short8 o0, o1;
        o0[0] = (short)f2bf(a.x); o0[1] = (short)f2bf(a.y);
        o0[2] = (short)f2bf(a.z); o0[3] = (short)f2bf(a.w);
        o0[4] = (short)f2bf(b.x); o0[5] = (short)f2bf(b.y);
        o0[6] = (short)f2bf(b.z); o0[7] = (short)f2bf(b.w);
        o1[0] = (short)f2bf(c.x); o1[1] = (short)f2bf(c.y);
        o1[2] = (short)f2bf(c.z); o1[3] = (short)f2bf(c.w);
        o1[4] = (short)f2bf(d.x); o1[5] = (short)f2bf(d.y);
        o1[6] = (short)f2bf(d.z); o1[7] = (short)f2bf(d.w);
        short8* dp = (short8*)p.dst[t] + off * 2;
        dp[0] = o0;
        dp[1] = o1;
    }
}

// --------------------- GEMM NT 256x256 (16 waves, BK=64) --------------------
// 2 LDS buffers x 64KB; per K-step: stage(next, 4 VMEM instrs) -> vmcnt(4)
// (waits current tile's 4 loads) -> barrier -> 32 MFMA -> barrier.
// Rows 128B; XOR swizzle (row&7)<<4 (verified conflict-free r2/r3).
// Optional fused V-transpose (text KV): cols c>=vColOff -> vT ushort4 stores.
__global__ __launch_bounds__(1024)
void k_gemm_nt256(const unsigned short* __restrict__ A, const unsigned short* __restrict__ B,
                  const float* __restrict__ bias,
                  float* __restrict__ outF, unsigned short* __restrict__ outB,
                  int M, int N, int K, int lda, int ldb, int ldc,
                  long sPart,
                  unsigned short* __restrict__ vT, int vColOff, long sVz, int vLd)
{
    __shared__ unsigned short smem[2 * 32768];   // 2 bufs x (A32KB + B32KB)

    unsigned gx = gridDim.x, gy = gridDim.y;
    unsigned nwg = gx * gy * gridDim.z;
    unsigned lin = (blockIdx.z * gy + blockIdx.y) * gx + blockIdx.x;
    unsigned bx = blockIdx.x, by = blockIdx.y, bz = blockIdx.z;
    if ((nwg & 7u) == 0u) {
        unsigned cpx = nwg >> 3;
        unsigned s = (lin & 7u) * cpx + (lin >> 3);
        bx = s % gx; unsigned r2 = s / gx;
        by = r2 % gy; bz = r2 / gy;
    }
    int s_k = (int)bz;
    const unsigned short* Ap = A + (long)s_k * K;
    const unsigned short* Bp = B + (long)s_k * K;
    float* outFp = outF ? outF + (long)s_k * sPart : nullptr;
    unsigned short* outBp = outB ? outB + (long)s_k * sPart : nullptr;

    int t = threadIdx.x;
    int wid = t >> 6, lane = t & 63;
    int lrow = lane & 15, kgrp = lane >> 4;
    int tm = by * 256, tn = bx * 256;
    int wm = (wid >> 2) * 64, wn = (wid & 3) * 64;

    // stage one BK=64 tile pair (A 32KB + B 32KB); 4 VMEM instrs per wave.
    auto stage = [&](int buf, int k0) {
#pragma unroll
        for (int r = 0; r < 2; ++r) {
            int d = r * 16384 + t * 16;                 // byte in 32KB tile
            int row = d >> 7;                           // 128B rows
            int colb = (d & 127) ^ ((row & 7) << 4);    // inverse swizzle
            int gr = tm + row; if (gr > M - 1) gr = M - 1;
            const unsigned short* srcA = Ap + (long)gr * lda + k0 + (colb >> 1);
            unsigned short* dstA = smem + ((buf * 65536 + d) >> 1);
            __builtin_amdgcn_global_load_lds(
                (const __attribute__((address_space(1))) unsigned int*)srcA,
                (__attribute__((address_space(3))) unsigned int*)dstA, 16, 0, 0);
            int gn = tn + row; if (gn > N - 1) gn = N - 1;
            const unsigned short* srcB = Bp + (long)gn * ldb + k0 + (colb >> 1);
            unsigned short* dstB = smem + ((buf * 65536 + 32768 + d) >> 1);
            __builtin_amdgcn_global_load_lds(
                (const __attribute__((address_space(1))) unsigned int*)srcB,
                (__attribute__((address_space(3))) unsigned int*)dstB, 16, 0, 0);
        }
    };

    f32x4 acc[4][4] = {};
    int nt = K >> 6;

    stage(0, 0);

    for (int ti = 0; ti < nt; ++ti) {
        int cur = ti & 1;
        if (ti + 1 < nt) {
            stage(cur ^ 1, (ti + 1) << 6);   // 4 new VMEM instrs in flight
            asm volatile("s_waitcnt vmcnt(4)" ::: "memory");   // current tile done
        } else {
            asm volatile("s_waitcnt vmcnt(0)" ::: "memory");
        }
        __builtin_amdgcn_sched_barrier(0);
        __builtin_amdgcn_s_barrier();
        __builtin_amdgcn_sched_barrier(0);

        const char* Ab = (const char*)smem + cur * 65536;
        const char* Bb = Ab + 32768;
#pragma unroll
        for (int ks = 0; ks < 2; ++ks) {
            short8 a[4], bb[4];
            int kb = ks * 64 + kgrp * 16;
#pragma unroll
            for (int i = 0; i < 4; ++i) {
                int row = wm + i * 16 + lrow;
                a[i] = *(const short8*)(Ab + row * 128 + (kb ^ ((row & 7) << 4)));
            }
#pragma unroll
            for (int j = 0; j < 4; ++j) {
                int row = wn + j * 16 + lrow;
                bb[j] = *(const short8*)(Bb + row * 128 + (kb ^ ((row & 7) << 4)));
            }
#pragma unroll
            for (int i = 0; i < 4; ++i)
#pragma unroll
                for (int j = 0; j < 4; ++j)
                    acc[i][j] = __builtin_amdgcn_mfma_f32_16x16x32_bf16(a[i], bb[j], acc[i][j], 0, 0, 0);
        }
        __builtin_amdgcn_s_barrier();   // protect buf before re-stage next iter
    }

#pragma unroll
    for (int i = 0; i < 4; ++i) {
        int rbase = tm + wm + i * 16 + kgrp * 4;
#pragma unroll
        for (int j = 0; j < 4; ++j) {
            int c = tn + wn + j * 16 + lrow;
            if (c >= N) continue;
            float bv = bias ? bias[c] : 0.0f;
            float v[4];
#pragma unroll
            for (int e = 0; e < 4; ++e) v[e] = acc[i][j][e] + bv;
            if (vT && c >= vColOff) {
                // rowsPerBatch = 512 (text); 4-run never crosses a batch.
                if (rbase + 3 < M) {
                    int hh = (c - vColOff) >> 6, dd = (c - vColOff) & 63;
                    int bb2 = rbase >> 9, l = rbase & 511;
                    ushort4 o = { f2bf(v[0]), f2bf(v[1]), f2bf(v[2]), f2bf(v[3]) };
                    *(ushort4*)(vT + (long)(bb2 * 16 + hh) * sVz + (long)dd * vLd + l) = o;
                }
            } else {
#pragma unroll
                for (int e = 0; e < 4; ++e) {
                    int r = rbase + e;
                    if (r >= M) continue;
                    long oidx = (long)r * ldc + c;
                    if (outFp) outFp[oidx] = v[e];
                    if (outBp) outBp[oidx] = f2bf(v[e]);
                }
            }
        }
    }
}

// ------------------------------ GEMM NT (pipelined 128²) --------------------
// Optional fused V-transpose for region KV (rowsPerBatch=196, scalar stores).
template<bool GELU>
__global__ __launch_bounds__(256)
void k_gemm_nt(const unsigned short* __restrict__ A, const unsigned short* __restrict__ B,
               const float* __restrict__ bias, const float* __restrict__ res,
               float* __restrict__ outF, unsigned short* __restrict__ outB,
               int M, int N, int K, int lda, int ldb, int ldc,
               int H, long sAb, long sAh, long sBb, long sBh, long sCb, long sCh,
               float scale, int S, long sPart,
               unsigned short* __restrict__ vT, int vColOff, long sVz, int vLd, int rpb)
{
    __shared__ unsigned short smem[5 * 8192];

    unsigned gx = gridDim.x, gy = gridDim.y, gz = gridDim.z;
    unsigned nwg = gx * gy * gz;
    unsigned lin = (blockIdx.z * gy + blockIdx.y) * gx + blockIdx.x;
    unsigned bx = blockIdx.x, by = blockIdx.y, bz = blockIdx.z;
    if ((nwg & 7u) == 0u) {
        unsigned cpx = nwg >> 3;
        unsigned s = (lin & 7u) * cpx + (lin >> 3);
        bx = s % gx; unsigned r2 = s / gx;
        by = r2 % gy; bz = r2 / gy;
    }

    int zz = (int)bz;
    int s_k = 0;
    if (S > 1) { s_k = zz % S; zz /= S; }
    int b = zz / H, h = zz - b * H;
    const unsigned short* Ap = A + (long)b * sAb + (long)h * sAh + (long)s_k * K;
    const unsigned short* Bp = B + (long)b * sBb + (long)h * sBh + (long)s_k * K;
    float* outFp = outF;
    if (outFp && S > 1) outFp += (long)s_k * sPart;
    unsigned short* outBp = outB;
    if (outBp && S > 1) outBp += (long)s_k * sPart;
    long offC = (long)b * sCb + (long)h * sCh;

    int t    = threadIdx.x;
    int wid  = t >> 6;
    int lane = t & 63;
    int lrow = lane & 15;
    int kgrp = lane >> 4;

    int tm = by * 128;
    int tn = bx * 128;
    int wm = (wid >> 1) * 64;
    int wn = (wid & 1) * 64;

    auto stage = [&](int buf, int k0) {
#pragma unroll
        for (int r = 0; r < 2; ++r) {
            int d = r * 4096 + t * 16;
            int row = d >> 6;
            int colb = (d & 63) ^ (((row >> 1) & 3) << 4);
            int gr = tm + row; if (gr > M - 1) gr = M - 1;
            const unsigned short* srcA = Ap + (long)gr * lda + k0 + (colb >> 1);
            unsigned short* dstA = smem + ((buf * 16384 + r * 4096 + wid * 1024) >> 1);
            __builtin_amdgcn_global_load_lds(
                (const __attribute__((address_space(1))) unsigned int*)srcA,
                (__attribute__((address_space(3))) unsigned int*)dstA, 16, 0, 0);
            int gn = tn + row; if (gn > N - 1) gn = N - 1;
            const unsigned short* srcB = Bp + (long)gn * ldb + k0 + (colb >> 1);
            unsigned short* dstB = smem + ((buf * 16384 + 8192 + r * 4096 + wid * 1024) >> 1);
            __builtin_amdgcn_global_load_lds(
                (const __attribute__((address_space(1))) unsigned int*)srcB,
                (__attribute__((address_space(3))) unsigned int*)dstB, 16, 0, 0);
        }
    };

    f32x4 acc[4][4] = {};
    int nt = K >> 5;

    for (int p = 0; p < 4 && p < nt; ++p) stage(p, p << 5);

    for (int ti = 0; ti < nt; ++ti) {
        int cur = ti % 5;
        int rem = nt - 1 - ti;
        if (rem >= 3)      asm volatile("s_waitcnt vmcnt(12)" ::: "memory");
        else if (rem == 2) asm volatile("s_waitcnt vmcnt(8)"  ::: "memory");
        else if (rem == 1) asm volatile("s_waitcnt vmcnt(4)"  ::: "memory");
        else               asm volatile("s_waitcnt vmcnt(0)"  ::: "memory");
        __builtin_amdgcn_sched_barrier(0);
        __builtin_amdgcn_s_barrier();
        __builtin_amdgcn_sched_barrier(0);

        if (ti + 4 < nt) stage((ti + 4) % 5, (ti + 4) << 5);

        const char* Ab = (const char*)smem + cur * 16384;
        const char* Bb = Ab + 8192;
        short8 a[4], bb[4];
#pragma unroll
        for (int i = 0; i < 4; ++i) {
            int row = wm + i * 16 + lrow;
            a[i] = *(const short8*)(Ab + row * 64 + ((kgrp * 16) ^ (((row >> 1) & 3) << 4)));
        }
#pragma unroll
        for (int j = 0; j < 4; ++j) {
            int row = wn + j * 16 + lrow;
            bb[j] = *(const short8*)(Bb + row * 64 + ((kgrp * 16) ^ (((row >> 1) & 3) << 4)));
        }
#pragma unroll
        for (int i = 0; i < 4; ++i)
#pragma unroll
            for (int j = 0; j < 4; ++j)
                acc[i][j] = __builtin_amdgcn_mfma_f32_16x16x32_bf16(a[i], bb[j], acc[i][j], 0, 0, 0);
    }

#pragma unroll
    for (int i = 0; i < 4; ++i) {
        int rbase = tm + wm + i * 16 + kgrp * 4;
#pragma unroll
        for (int j = 0; j < 4; ++j) {
            int c = tn + wn + j * 16 + lrow;
            if (c >= N) continue;
            float bv = bias ? bias[c] : 0.0f;
            if (vT && c >= vColOff) {
                int hh = (c - vColOff) >> 6, dd = (c - vColOff) & 63;
#pragma unroll
                for (int e = 0; e < 4; ++e) {
                    int r = rbase + e;
                    if (r >= M) continue;
                    float v = acc[i][j][e] * scale + bv;
                    int bb2 = r / rpb, l = r - bb2 * rpb;
                    vT[(long)(bb2 * 16 + hh) * sVz + (long)dd * vLd + l] = f2bf(v);
                }
                continue;
            }
#pragma unroll
            for (int e = 0; e < 4; ++e) {
                int r = rbase + e;
                if (r >= M) continue;
                float v = acc[i][j][e] * scale + bv;
                long oidx = offC + (long)r * ldc + c;
                if (res) v += res[oidx];
                if (GELU) v = 0.5f * v * (1.0f + erff(v * 0.70710678118654752f));
                if (outFp) outFp[oidx] = v;
                if (outBp) outBp[oidx] = f2bf(v);
            }
        }
    }
}

// -------------------- split-K reduce (bf16 partials) -------------------------
__global__ __launch_bounds__(256)
void k_redux_b(const unsigned short* __restrict__ part, long sPart, int S,
               const float* __restrict__ bias, const float* __restrict__ res,
               float* __restrict__ outF, unsigned short* __restrict__ outB,
               long n8, int ldc8, int gelu)
{
    long i = (long)blockIdx.x * blockDim.x + threadIdx.x;
    long stride = (long)gridDim.x * blockDim.x;
    for (; i < n8; i += stride) {
        long e0 = i * 8;
        float v[8];
        short8 p0 = *(const short8*)(part + e0);
#pragma unroll
        for (int k = 0; k < 8; ++k) v[k] = bf2f((unsigned short)p0[k]);
        for (int s = 1; s < S; ++s) {
            short8 ps = *(const short8*)(part + e0 + (long)s * sPart);
#pragma unroll
            for (int k = 0; k < 8; ++k) v[k] += bf2f((unsigned short)ps[k]);
        }
        if (bias) {
            int c = (int)(i % ldc8) * 8;
            float4 b0 = *(const float4*)(bias + c);
            float4 b1 = *(const float4*)(bias + c + 4);
            v[0] += b0.x; v[1] += b0.y; v[2] += b0.z; v[3] += b0.w;
            v[4] += b1.x; v[5] += b1.y; v[6] += b1.z; v[7] += b1.w;
        }
        if (res) {
            float4 r0 = *(const float4*)(res + e0);
            float4 r1 = *(const float4*)(res + e0 + 4);
            v[0] += r0.x; v[1] += r0.y; v[2] += r0.z; v[3] += r0.w;
            v[4] += r1.x; v[5] += r1.y; v[6] += r1.z; v[7] += r1.w;
        }
        if (gelu) {
#pragma unroll
            for (int k = 0; k < 8; ++k)
                v[k] = 0.5f * v[k] * (1.0f + erff(v[k] * 0.70710678118654752f));
        }
        if (outF) {
            float4 o0 = { v[0], v[1], v[2], v[3] };
            float4 o1 = { v[4], v[5], v[6], v[7] };
            *(float4*)(outF + e0) = o0;
            *(float4*)(outF + e0 + 4) = o1;
        }
        if (outB) {
            short8 o;
#pragma unroll
            for (int k = 0; k < 8; ++k) o[k] = (short)f2bf(v[k]);
            *(short8*)(outB + e0) = o;
        }
    }
}

// ---- fused split-K(bf16) reduce + bias + residual + LayerNorm --------------
__global__ __launch_bounds__(256)
void k_redux_ln_b(const unsigned short* __restrict__ part, long sPart, int S,
                  const float* __restrict__ bias, const float* __restrict__ res,
                  const float* __restrict__ g, const float* __restrict__ bt,
                  float* __restrict__ yf, unsigned short* __restrict__ yb)
{
    int row = blockIdx.x;
    int t = threadIdx.x;
    int lane = t & 63, wid = t >> 6;
    long base = (long)row * 1024 + t * 4;

    ushort4 p0 = *(const ushort4*)(part + base);
    float v0 = bf2f(p0.x), v1 = bf2f(p0.y), v2 = bf2f(p0.z), v3 = bf2f(p0.w);
    for (int s = 1; s < S; ++s) {
        ushort4 ps = *(const ushort4*)(part + base + (long)s * sPart);
        v0 += bf2f(ps.x); v1 += bf2f(ps.y); v2 += bf2f(ps.z); v3 += bf2f(ps.w);
    }
    float4 bv = *(const float4*)(bias + t * 4);
    v0 += bv.x; v1 += bv.y; v2 += bv.z; v3 += bv.w;
    float4 rv = *(const float4*)(res + base);
    v0 += rv.x; v1 += rv.y; v2 += rv.z; v3 += rv.w;

    float s1 = v0 + v1 + v2 + v3;
    float s2 = v0 * v0 + v1 * v1 + v2 * v2 + v3 * v3;
#pragma unroll
    for (int d = 32; d > 0; d >>= 1) { s1 += __shfl_xor(s1, d, 64); s2 += __shfl_xor(s2, d, 64); }
    __shared__ float rs[4], rss[4];
    if (lane == 0) { rs[wid] = s1; rss[wid] = s2; }
    __syncthreads();
    s1 = rs[0] + rs[1] + rs[2] + rs[3];
    s2 = rss[0] + rss[1] + rss[2] + rss[3];
    float mu  = s1 * (1.0f / 1024.0f);
    float var = s2 * (1.0f / 1024.0f) - mu * mu;
    float inv = rsqrtf(var + 1e-5f);

    float4 gv = *(const float4*)(g + t * 4);
    float4 btv = *(const float4*)(bt + t * 4);
    float o0 = (v0 - mu) * inv * gv.x + btv.x;
    float o1 = (v1 - mu) * inv * gv.y + btv.y;
    float o2 = (v2 - mu) * inv * gv.z + btv.z;
    float o3 = (v3 - mu) * inv * gv.w + btv.w;
    float4 of = { o0, o1, o2, o3 };
    ushort4 ob = { f2bf(o0), f2bf(o1), f2bf(o2), f2bf(o3) };
    *(float4*)(yf + base) = of;
    *(ushort4*)(yb + base) = ob;
}

// ---------------------- tiled transpose (bf16) ------------------------------
__global__ __launch_bounds__(256)
void k_tr(const unsigned short* __restrict__ in, unsigned short* __restrict__ out,
          int R, int ldin, int ldout,
          int H, long sIb, long sIh, long sOz)
{
    __shared__ unsigned short tile[32][33];
    int z = blockIdx.z;
    int b = z / H, h = z - b * H;
    const unsigned short* ip = in + (long)b * sIb + (long)h * sIh;
    unsigned short* op = out + (long)z * sOz;
    int t = threadIdx.x;
    int cl = t & 31, rl = t >> 5;
    int c0 = blockIdx.x * 32, r0 = blockIdx.y * 32;
#pragma unroll
    for (int i = 0; i < 4; ++i) {
        int r = r0 + rl + i * 8;
        unsigned short v = 0;
        if (r < R) v = ip[(long)r * ldin + (c0 + cl)];
        tile[rl + i * 8][cl] = v;
    }
    __syncthreads();
#pragma unroll
    for (int i = 0; i < 4; ++i) {
        int orow = c0 + rl + i * 8;
        int ocol = r0 + cl;
        op[(long)orow * ldout + ocol] = tile[cl][rl + i * 8];
    }
}

// --------------------- wave-per-row masked softmax ---------------------------
__global__ __launch_bounds__(256)
void k_softmax_w(const float* __restrict__ sc, long sPart, int S,
                 unsigned short* __restrict__ P,
                 const int* __restrict__ mask, int L, int Lpad,
                 int ld_sc, int ld_p, int rows_per_batch, int nrows)
{
    int gw = (int)((blockIdx.x * 256 + threadIdx.x) >> 6);
    if (gw >= nrows) return;
    int lane = threadIdx.x & 63;
    int b = gw / rows_per_batch;
    const float* p = sc + (long)gw * ld_sc;
    unsigned short* po = P + (long)gw * ld_p;
    const int* mrow = mask + (long)b * L;

    int nch = (Lpad + 255) >> 8;     // 1 or 2
    float v[2][4];
    float mx = -INFINITY;
#pragma unroll
    for (int c = 0; c < 2; ++c) {
        if (c >= nch) { v[c][0]=v[c][1]=v[c][2]=v[c][3] = -INFINITY; continue; }
        int j = c * 256 + lane * 4;
        if (j < L) {
            float4 x = *(const float4*)(p + j);
            for (int s = 1; s < S; ++s) {
                float4 y = *(const float4*)(p + j + (long)s * sPart);
                x.x += y.x; x.y += y.y; x.z += y.z; x.w += y.w;
            }
            int4 m = *(const int4*)(mrow + j);
            v[c][0] = m.x ? x.x : -INFINITY;
            v[c][1] = m.y ? x.y : -INFINITY;
            v[c][2] = m.z ? x.z : -INFINITY;
            v[c][3] = m.w ? x.w : -INFINITY;
        } else {
            v[c][0]=v[c][1]=v[c][2]=v[c][3] = -INFINITY;
        }
        mx = fmaxf(mx, fmaxf(fmaxf(v[c][0], v[c][1]), fmaxf(v[c][2], v[c][3])));
    }
#pragma unroll
    for (int d = 32; d > 0; d >>= 1) mx = fmaxf(mx, __shfl_xor(mx, d, 64));

    float sum = 0.f;
#pragma unroll
    for (int c = 0; c < 2; ++c)
#pragma unroll
        for (int k = 0; k < 4; ++k) {
            float e = (v[c][k] == -INFINITY) ? 0.0f : __expf(v[c][k] - mx);
            v[c][k] = e;
            sum += e;
        }
#pragma unroll
    for (int d = 32; d > 0; d >>= 1) sum += __shfl_xor(sum, d, 64);
    float inv = 1.0f / sum;

#pragma unroll
    for (int c = 0; c < 2; ++c) {
        if (c >= nch) continue;
        int j = c * 256 + lane * 4;
        if (j < Lpad) {
            ushort4 o;
            o.x = f2bf(v[c][0] * inv);
            o.y = f2bf(v[c][1] * inv);
            o.z = f2bf(v[c][2] * inv);
            o.w = f2bf(v[c][3] * inv);
            *(ushort4*)(po + j) = o;
        }
    }
}

// ---------------- combine (bf16 partial aggs) -------------------------------
__global__ void k_combine_b(float* __restrict__ qf, unsigned short* __restrict__ qb,
                            const unsigned short* __restrict__ aggtp,
                            const unsigned short* __restrict__ aggrp,
                            const float* __restrict__ alpha, long n4, long sPart, int S)
{
    float a = *alpha;
    long i = (long)blockIdx.x * blockDim.x + threadIdx.x;
    long stride = (long)gridDim.x * blockDim.x;
    for (; i < n4; i += stride) {
        long e0 = i * 4;
        float st[4] = {0.f, 0.f, 0.f, 0.f}, sr[4] = {0.f, 0.f, 0.f, 0.f};
        for (int s = 0; s < S; ++s) {
            ushort4 pt = *(const ushort4*)(aggtp + e0 + (long)s * sPart);
            ushort4 pr = *(const ushort4*)(aggrp + e0 + (long)s * sPart);
            st[0] += bf2f(pt.x); st[1] += bf2f(pt.y); st[2] += bf2f(pt.z); st[3] += bf2f(pt.w);
            sr[0] += bf2f(pr.x); sr[1] += bf2f(pr.y); sr[2] += bf2f(pr.z); sr[3] += bf2f(pr.w);
        }
        float4 q = *(const float4*)(qf + e0);
        float v0 = q.x + a * sr[0] + (1.0f - a) * st[0];
        float v1 = q.y + a * sr[1] + (1.0f - a) * st[1];
        float v2 = q.z + a * sr[2] + (1.0f - a) * st[2];
        float v3 = q.w + a * sr[3] + (1.0f - a) * st[3];
        float4 of = { v0, v1, v2, v3 };
        ushort4 ob = { f2bf(v0), f2bf(v1), f2bf(v2), f2bf(v3) };
        *(float4*)(qf + e0) = of;
        *(ushort4*)(qb + e0) = ob;
    }
}

// ---------------------------------------------------------------------------
extern "C" void kernel_launch(void* const* d_in, const int* in_sizes, int n_in,
                              void* d_out, int out_size, void* d_ws, size_t ws_size,
                              hipStream_t stream)
{
    const float* queries = (const float*)d_in[0];
    const float* text    = (const float*)d_in[1];
    const float* region  = (const float*)d_in[2];
    const int*   tmask   = (const int*)d_in[3];
    const int*   rmask   = (const int*)d_in[4];
    const float* w_qkv_t = (const float*)d_in[5];
    const float* b_qkv_t = (const float*)d_in[6];
    const float* w_o_t   = (const float*)d_in[7];
    const float* b_o_t   = (const float*)d_in[8];
    const float* w_qkv_r = (const float*)d_in[9];
    const float* b_qkv_r = (const float*)d_in[10];
    const float* w_o_r   = (const float*)d_in[11];
    const float* b_o_r   = (const float*)d_in[12];
    const float* ln_g    = (const float*)d_in[13];
    const float* ln_b    = (const float*)d_in[14];
    const float* w1      = (const float*)d_in[15];
    const float* b1      = (const float*)d_in[16];
    const float* w2      = (const float*)d_in[17];
    const float* b2      = (const float*)d_in[18];
    const float* alpha   = (const float*)d_in[19];

    const int Bn = 16, NQ = 128, LT = 512, LR = 196, D = 1024, H = 16;
    const int LRp = 256;
    const int MQ = Bn * NQ;              // 2048
    const int MT = Bn * LT;              // 8192
    const int MR = Bn * LR;              // 3136

    char* ws = (char*)d_ws;
    size_t off = 0;
    auto alloc = [&](size_t bytes) -> void* {
        void* p = ws + off;
        off = (off + bytes + 255) & ~(size_t)255;
        return p;
    };
    unsigned short* qb     = (unsigned short*)alloc((size_t)MQ * D * 2);
    unsigned short* tb     = (unsigned short*)alloc((size_t)MT * D * 2);
    unsigned short* rb     = (unsigned short*)alloc((size_t)MR * D * 2);
    unsigned short* wqkvtb = (unsigned short*)alloc((size_t)3 * D * D * 2);
    unsigned short* wotb   = (unsigned short*)alloc((size_t)D * D * 2);
    unsigned short* wqkvrb = (unsigned short*)alloc((size_t)3 * D * D * 2);
    unsigned short* worb   = (unsigned short*)alloc((size_t)D * D * 2);
    unsigned short* w1b    = (unsigned short*)alloc((size_t)4 * D * D * 2);
    unsigned short* w2b    = (unsigned short*)alloc((size_t)4 * D * D * 2);
    unsigned short* ktv    = (unsigned short*)alloc((size_t)MT * 2 * D * 2);
    unsigned short* krv    = (unsigned short*)alloc((size_t)MR * 2 * D * 2);
    unsigned short* vtT    = (unsigned short*)alloc((size_t)Bn * H * 64 * LT * 2);
    unsigned short* vrT    = (unsigned short*)alloc((size_t)Bn * H * 64 * LRp * 2);
    unsigned short* qp     = (unsigned short*)alloc((size_t)MQ * D * 2);
    unsigned short* ao     = (unsigned short*)alloc((size_t)MQ * D * 2);
    unsigned short* qlnb   = (unsigned short*)alloc((size_t)MQ * D * 2);
    float* qlf  = (float*)alloc((size_t)MQ * D * 4);
    float* sc   = (float*)alloc((size_t)Bn * H * NQ * LT * 4);   // 67MB arena
    if (off > ws_size) return;

    // phase-reused views
    unsigned short* tbT = ktv;                               // [B][1024][512]
    unsigned short* rbT = ktv + (size_t)Bn * D * LT;         // [B][1024][256p]
    float* sct = sc;
    float* scr = sc;
    unsigned short* Pt = (unsigned short*)sc;
    unsigned short* Pr = (unsigned short*)(sc + 1 * 1048576);
    float* atp   = sc + 2 * 1048576;
    float* arp   = sc + 6 * 1048576;
    unsigned short* aggtp_b = (unsigned short*)((char*)sc + (size_t)32 * 1048576);
    unsigned short* aggrp_b = (unsigned short*)((char*)sc + (size_t)48 * 1048576);
    unsigned short* hb = (unsigned short*)sc;
    unsigned short* part_qb  = (unsigned short*)sc;
    unsigned short* part_f1b = ktv;
    unsigned short* part_f2b = ktv;

    const long PQ = (long)MQ * D;

    // ---- all converts in one balanced launch ----
    {
        CvtPack pk;
        const float* srcs[9] = { queries, text, region, w_qkv_t, w_o_t, w_qkv_r, w_o_r, w1, w2 };
        unsigned short* dsts[9] = { qb, tb, rb, wqkvtb, wotb, wqkvrb, worb, w1b, w2b };
        long ns[9] = { (long)MQ * D, (long)MT * D, (long)MR * D, (long)3 * D * D,
                       (long)D * D, (long)3 * D * D, (long)D * D, (long)4 * D * D,
                       (long)4 * D * D };
        long acc16 = 0;
        pk.start16[0] = 0;
        for (int i = 0; i < 9; ++i) {
            pk.src[i] = srcs[i]; pk.dst[i] = dsts[i];
            acc16 += ns[i] / 16;
            pk.start16[i + 1] = acc16;
        }
        k_cvt_multi<<<2048, 256, 0, stream>>>(pk, acc16);
    }

    auto NT = [&](const unsigned short* A, const unsigned short* Bm, const float* bias,
                  const float* res, float* oF, unsigned short* oB,
                  int M, int N, int K, int lda, int ldb, int ldc,
                  int Hh, long sAb, long sAh, long sBb, long sBh, long sCb, long sCh,
                  int batch, float scale, bool gelu, int S = 1, long sPart = 0,
                  unsigned short* vT = nullptr, int vColOff = 0, long sVz = 0,
                  int vLd = 0, int rpb = 1) {
        dim3 g((N + 127) / 128, (M + 127) / 128, batch * S);
        if (gelu)
            k_gemm_nt<true><<<g, 256, 0, stream>>>(A, Bm, bias, res, oF, oB, M, N, K,
                lda, ldb, ldc, Hh, sAb, sAh, sBb, sBh, sCb, sCh, scale, S, sPart,
                vT, vColOff, sVz, vLd, rpb);
        else
            k_gemm_nt<false><<<g, 256, 0, stream>>>(A, Bm, bias, res, oF, oB, M, N, K,
                lda, ldb, ldc, Hh, sAb, sAh, sBb, sBh, sCb, sCh, scale, S, sPart,
                vT, vColOff, sVz, vLd, rpb);
    };
    auto NT256 = [&](const unsigned short* A, const unsigned short* Bm, const float* bias,
                     float* oF, unsigned short* oB, int M, int N, int Kc,
                     int lda, int ldb, int ldc, int S, long sPart,
                     unsigned short* vT = nullptr, int vColOff = 0, long sVz = 0,
                     int vLd = 0) {
        dim3 g((N + 255) / 256, (M + 255) / 256, S);
        k_gemm_nt256<<<g, 1024, 0, stream>>>(A, Bm, bias, oF, oB, M, N, Kc,
                                             lda, ldb, ldc, sPart, vT, vColOff, sVz, vLd);
    };
    auto REDUXB = [&](const unsigned short* part, long sPart, int S, const float* bias,
                      const float* res, float* oF, unsigned short* oB,
                      long total, int ldc, int gelu) {
        long n8 = total / 8;
        int blocks = (int)((n8 + 255) / 256);
        if (blocks > 2048) blocks = 2048;
        k_redux_b<<<blocks, 256, 0, stream>>>(part, sPart, S, bias, res, oF, oB,
                                              n8, ldc / 8, gelu);
    };
    auto SMAX = [&](const float* scp, long sPart, int S, unsigned short* P,
                    const int* mask, int L, int Lpad, int ld_sc, int ld_p,
                    int rpb, int nrows) {
        int blocks = (nrows + 3) / 4;
        k_softmax_w<<<blocks, 256, 0, stream>>>(scp, sPart, S, P, mask, L, Lpad,
                                                ld_sc, ld_p, rpb, nrows);
    };

    // ---- fused K+V projections (V written directly transposed) ----
    NT256(tb, wqkvtb + (long)D * D, b_qkv_t + D, nullptr, ktv,
          MT, 2 * D, D, D, D, 2 * D, 1, 0,
          vtT, D, (long)64 * LT, LT);
    NT(rb, wqkvrb + (long)D * D, b_qkv_r + D, nullptr, nullptr, krv,
       MR, 2 * D, D, D, D, 2 * D, 1,0,0,0,0,0,0, 1, 1.0f, false, 1, 0,
       vrT, D, (long)64 * LRp, LRp, LR);

    // ================= MHA 1 (text) =================
    NT(qb, wqkvtb, nullptr, nullptr, nullptr, part_qb, MQ, D, 512, D, D, D,
       1,0,0,0,0,0,0, 1, 1.0f, false, 2, PQ);
    REDUXB(part_qb, PQ, 2, b_qkv_t, nullptr, nullptr, qp, PQ, D, 0);
    NT(qp, ktv, nullptr, nullptr, sct, nullptr, NQ, LT, 64, D, 2 * D, LT,
       H, (long)NQ * D, 64, (long)LT * 2 * D, 64, (long)H * NQ * LT, (long)NQ * LT,
       Bn * H, 0.125f, false);
    SMAX(sct, 0, 1, (unsigned short*)sct, tmask, LT, LT, LT, 2 * LT,
         H * NQ, Bn * H * NQ);
    NT((const unsigned short*)sct, vtT, nullptr, nullptr, nullptr, ao, NQ, 64, LT,
       2 * LT, LT, D,
       H, (long)H * NQ * 2 * LT, (long)NQ * 2 * LT, (long)64 * LT * H, (long)64 * LT,
       (long)NQ * D, 64, Bn * H, 1.0f, false);
    NT(ao, wotb, nullptr, nullptr, nullptr, part_qb, MQ, D, 512, D, D, D,
       1,0,0,0,0,0,0, 1, 1.0f, false, 2, PQ);
    k_redux_ln_b<<<MQ, 256, 0, stream>>>(part_qb, PQ, 2, b_o_t, queries,
                                         ln_g, ln_b, qlf, qlnb);

    // ================= MHA 2 (region) =================
    NT(qlnb, wqkvrb, nullptr, nullptr, nullptr, part_qb, MQ, D, 512, D, D, D,
       1,0,0,0,0,0,0, 1, 1.0f, false, 2, PQ);
    REDUXB(part_qb, PQ, 2, b_qkv_r, nullptr, nullptr, qp, PQ, D, 0);
    NT(qp, krv, nullptr, nullptr, scr, nullptr, NQ, LR, 64, D, 2 * D, LRp,
       H, (long)NQ * D, 64, (long)LR * 2 * D, 64, (long)H * NQ * LRp, (long)NQ * LRp,
       Bn * H, 0.125f, false);
    SMAX(scr, 0, 1, (unsigned short*)scr, rmask, LR, LRp, LRp, 2 * LRp,
         H * NQ, Bn * H * NQ);
    NT((const unsigned short*)scr, vrT, nullptr, nullptr, nullptr, ao, NQ, 64, LRp,
       2 * LRp, LRp, D,
       H, (long)H * NQ * 2 * LRp, (long)NQ * 2 * LRp, (long)64 * LRp * H, (long)64 * LRp,
       (long)NQ * D, 64, Bn * H, 1.0f, false);
    NT(ao, worb, nullptr, nullptr, nullptr, part_qb, MQ, D, 512, D, D, D,
       1,0,0,0,0,0,0, 1, 1.0f, false, 2, PQ);
    k_redux_ln_b<<<MQ, 256, 0, stream>>>(part_qb, PQ, 2, b_o_r, qlf,
                                         ln_g, ln_b, qlf, qlnb);

    // ================= manual masked cross-attention =================
    {
        dim3 g1(D / 32, LT / 32, Bn);
        k_tr<<<g1, 256, 0, stream>>>(tb, tbT, LT, D, LT, 1, (long)LT * D, 0, (long)D * LT);
        dim3 g2(D / 32, LRp / 32, Bn);
        k_tr<<<g2, 256, 0, stream>>>(rb, rbT, LR, D, LRp, 1, (long)LR * D, 0, (long)D * LRp);
    }
    NT(qlnb, tb, nullptr, nullptr, atp, nullptr, NQ, LT, 256, D, D, LT,
       1, (long)NQ * D, 0, (long)LT * D, 0, (long)NQ * LT, 0, Bn, 0.03125f, false,
       4, (long)Bn * NQ * LT);
    SMAX(atp, (long)Bn * NQ * LT, 4, Pt, tmask, LT, LT, LT, LT, NQ, Bn * NQ);
    NT(Pt, tbT, nullptr, nullptr, nullptr, aggtp_b, NQ, D, 256, LT, LT, D,
       1, (long)NQ * LT, 0, (long)D * LT, 0, (long)NQ * D, 0, Bn, 1.0f, false,
       2, PQ);
    NT(qlnb, rb, nullptr, nullptr, arp, nullptr, NQ, LR, 256, D, D, LRp,
       1, (long)NQ * D, 0, (long)LR * D, 0, (long)NQ * LRp, 0, Bn, 0.03125f, false,
       4, (long)Bn * NQ * LRp);
    SMAX(arp, (long)Bn * NQ * LRp, 4, Pr, rmask, LR, LRp, LRp, LRp, NQ, Bn * NQ);
    NT(Pr, rbT, nullptr, nullptr, nullptr, aggrp_b, NQ, D, 128, LRp, LRp, D,
       1, (long)NQ * LRp, 0, (long)D * LRp, 0, (long)NQ * D, 0, Bn, 1.0f, false,
       2, PQ);

    k_combine_b<<<2048, 256, 0, stream>>>(qlf, qlnb, aggtp_b, aggrp_b, alpha,
                                          (long)MQ * D / 4, PQ, 2);

    // ================= FFN =================
    NT256(qlnb, w1b, nullptr, nullptr, part_f1b, MQ, 4 * D, 512,
          D, D, 4 * D, 2, (long)MQ * 4 * D);
    REDUXB(part_f1b, (long)MQ * 4 * D, 2, b1, nullptr, nullptr, hb,
           (long)MQ * 4 * D, 4 * D, 1);
    NT256(hb, w2b, nullptr, nullptr, part_f2b, MQ, D, 512,
          4 * D, 4 * D, D, 8, PQ);
    REDUXB(part_f2b, PQ, 8, b2, qlf, (float*)d_out, nullptr, PQ, D, 0);
}

// Round 14
// 489.469 us; speedup vs baseline: 2.2678x; 1.0505x over previous
//
#include <hip/hip_runtime.h>
#include <hip/hip_bf16.h>

// ---------------------------------------------------------------------------
// QueryGuidedFusionNet forward on MI355X.
// Round 14: dedicated 128x64 PV GEMM (half the MFMA/ds_read of the 128-wide
// tile on N=64). Stage = 3 VMEM/wave -> vmcnt(9/6/3/0). Rest identical r13.
// ---------------------------------------------------------------------------

typedef __attribute__((ext_vector_type(8))) short short8;   // 8 bf16
typedef __attribute__((ext_vector_type(4))) float f32x4;

#define DEV static __device__ __forceinline__

DEV unsigned short f2bf(float f) {
    unsigned u = __float_as_uint(f);
    u += 0x7fffu + ((u >> 16) & 1u);          // RNE
    return (unsigned short)(u >> 16);
}
DEV float bf2f(unsigned short u) {
    return __uint_as_float(((unsigned)u) << 16);
}

// ------------------------- multi-tensor convert (balanced) ------------------
struct CvtPack {
    const float* src[9];
    unsigned short* dst[9];
    long start16[10];       // prefix sums in 16-element units
};

__global__ __launch_bounds__(256)
void k_cvt_multi(CvtPack p, long total16) {
    long i = (long)blockIdx.x * blockDim.x + threadIdx.x;
    long stride = (long)gridDim.x * blockDim.x;
    for (; i < total16; i += stride) {
        int t = 0;
#pragma unroll
        for (int k = 1; k < 9; ++k) t += (i >= p.start16[k]) ? 1 : 0;
        long off = i - p.start16[t];
        const float4* s = (const float4*)p.src[t] + off * 4;
        float4 a = s[0], b = s[1], c = s[2], d = s[3];
        short8 o0, o1;
        o0[0] = (short)f2bf(a.x); o0[1] = (short)f2bf(a.y);
        o0[2] = (short)f2bf(a.z); o0[3] = (short)f2bf(a.w);
        o0[4] = (short)f2bf(b.x); o0[5] = (short)f2bf(b.y);
        o0[6] = (short)f2bf(b.z); o0[7] = (short)f2bf(b.w);
        o1[0] = (short)f2bf(c.x); o1[1] = (short)f2bf(c.y);
        o1[2] = (short)f2bf(c.z); o1[3] = (short)f2bf(c.w);
        o1[4] = (short)f2bf(d.x); o1[5] = (short)f2bf(d.y);
        o1[6] = (short)f2bf(d.z); o1[7] = (short)f2bf(d.w);
        short8* dp = (short8*)p.dst[t] + off * 2;
        dp[0] = o0;
        dp[1] = o1;
    }
}

// --------------------- GEMM NT 256x256 (16 waves, BK=64) --------------------
__global__ __launch_bounds__(1024)
void k_gemm_nt256(const unsigned short* __restrict__ A, const unsigned short* __restrict__ B,
                  const float* __restrict__ bias,
                  float* __restrict__ outF, unsigned short* __restrict__ outB,
                  int M, int N, int K, int lda, int ldb, int ldc,
                  long sPart,
                  unsigned short* __restrict__ vT, int vColOff, long sVz, int vLd)
{
    __shared__ unsigned short smem[2 * 32768];   // 2 bufs x (A32KB + B32KB)

    unsigned gx = gridDim.x, gy = gridDim.y;
    unsigned nwg = gx * gy * gridDim.z;
    unsigned lin = (blockIdx.z * gy + blockIdx.y) * gx + blockIdx.x;
    unsigned bx = blockIdx.x, by = blockIdx.y, bz = blockIdx.z;
    if ((nwg & 7u) == 0u) {
        unsigned cpx = nwg >> 3;
        unsigned s = (lin & 7u) * cpx + (lin >> 3);
        bx = s % gx; unsigned r2 = s / gx;
        by = r2 % gy; bz = r2 / gy;
    }
    int s_k = (int)bz;
    const unsigned short* Ap = A + (long)s_k * K;
    const unsigned short* Bp = B + (long)s_k * K;
    float* outFp = outF ? outF + (long)s_k * sPart : nullptr;
    unsigned short* outBp = outB ? outB + (long)s_k * sPart : nullptr;

    int t = threadIdx.x;
    int wid = t >> 6, lane = t & 63;
    int lrow = lane & 15, kgrp = lane >> 4;
    int tm = by * 256, tn = bx * 256;
    int wm = (wid >> 2) * 64, wn = (wid & 3) * 64;

    auto stage = [&](int buf, int k0) {
#pragma unroll
        for (int r = 0; r < 2; ++r) {
            int d = r * 16384 + t * 16;                 // byte in 32KB tile
            int row = d >> 7;                           // 128B rows
            int colb = (d & 127) ^ ((row & 7) << 4);    // inverse swizzle
            int gr = tm + row; if (gr > M - 1) gr = M - 1;
            const unsigned short* srcA = Ap + (long)gr * lda + k0 + (colb >> 1);
            unsigned short* dstA = smem + ((buf * 65536 + d) >> 1);
            __builtin_amdgcn_global_load_lds(
                (const __attribute__((address_space(1))) unsigned int*)srcA,
                (__attribute__((address_space(3))) unsigned int*)dstA, 16, 0, 0);
            int gn = tn + row; if (gn > N - 1) gn = N - 1;
            const unsigned short* srcB = Bp + (long)gn * ldb + k0 + (colb >> 1);
            unsigned short* dstB = smem + ((buf * 65536 + 32768 + d) >> 1);
            __builtin_amdgcn_global_load_lds(
                (const __attribute__((address_space(1))) unsigned int*)srcB,
                (__attribute__((address_space(3))) unsigned int*)dstB, 16, 0, 0);
        }
    };

    f32x4 acc[4][4] = {};
    int nt = K >> 6;

    stage(0, 0);

    for (int ti = 0; ti < nt; ++ti) {
        int cur = ti & 1;
        if (ti + 1 < nt) {
            stage(cur ^ 1, (ti + 1) << 6);   // 4 new VMEM instrs in flight
            asm volatile("s_waitcnt vmcnt(4)" ::: "memory");   // current tile done
        } else {
            asm volatile("s_waitcnt vmcnt(0)" ::: "memory");
        }
        __builtin_amdgcn_sched_barrier(0);
        __builtin_amdgcn_s_barrier();
        __builtin_amdgcn_sched_barrier(0);

        const char* Ab = (const char*)smem + cur * 65536;
        const char* Bb = Ab + 32768;
#pragma unroll
        for (int ks = 0; ks < 2; ++ks) {
            short8 a[4], bb[4];
            int kb = ks * 64 + kgrp * 16;
#pragma unroll
            for (int i = 0; i < 4; ++i) {
                int row = wm + i * 16 + lrow;
                a[i] = *(const short8*)(Ab + row * 128 + (kb ^ ((row & 7) << 4)));
            }
#pragma unroll
            for (int j = 0; j < 4; ++j) {
                int row = wn + j * 16 + lrow;
                bb[j] = *(const short8*)(Bb + row * 128 + (kb ^ ((row & 7) << 4)));
            }
#pragma unroll
            for (int i = 0; i < 4; ++i)
#pragma unroll
                for (int j = 0; j < 4; ++j)
                    acc[i][j] = __builtin_amdgcn_mfma_f32_16x16x32_bf16(a[i], bb[j], acc[i][j], 0, 0, 0);
        }
        __builtin_amdgcn_s_barrier();   // protect buf before re-stage next iter
    }

#pragma unroll
    for (int i = 0; i < 4; ++i) {
        int rbase = tm + wm + i * 16 + kgrp * 4;
#pragma unroll
        for (int j = 0; j < 4; ++j) {
            int c = tn + wn + j * 16 + lrow;
            if (c >= N) continue;
            float bv = bias ? bias[c] : 0.0f;
            float v[4];
#pragma unroll
            for (int e = 0; e < 4; ++e) v[e] = acc[i][j][e] + bv;
            if (vT && c >= vColOff) {
                if (rbase + 3 < M) {
                    int hh = (c - vColOff) >> 6, dd = (c - vColOff) & 63;
                    int bb2 = rbase >> 9, l = rbase & 511;
                    ushort4 o = { f2bf(v[0]), f2bf(v[1]), f2bf(v[2]), f2bf(v[3]) };
                    *(ushort4*)(vT + (long)(bb2 * 16 + hh) * sVz + (long)dd * vLd + l) = o;
                }
            } else {
#pragma unroll
                for (int e = 0; e < 4; ++e) {
                    int r = rbase + e;
                    if (r >= M) continue;
                    long oidx = (long)r * ldc + c;
                    if (outFp) outFp[oidx] = v[e];
                    if (outBp) outBp[oidx] = f2bf(v[e]);
                }
            }
        }
    }
}

// --------------------- GEMM PV 128x64 (4 waves) -----------------------------
// C[z][m][c] = sum_k A[z][m][k]*B[z][c][k], M=128, N=64 exact.
// 4 waves of 32x64 (acc[2][4]); A 8KB + B 4KB per buf, 5 bufs (60KB);
// stage = 3 VMEM/wave -> counted vmcnt(9/6/3/0). Swizzle ((row>>1)&3)<<4.
__global__ __launch_bounds__(256)
void k_gemm_pv(const unsigned short* __restrict__ A, const unsigned short* __restrict__ B,
               unsigned short* __restrict__ outB,
               int K, int lda, int ldb, int ldc,
               int H, long sAb, long sAh, long sBz, long sCb, long sCh)
{
    __shared__ unsigned short smem[5 * 6144];   // 5 x (A 8KB + B 4KB)

    int z = blockIdx.z;
    int b = z / H, h = z - b * H;
    const unsigned short* Ap = A + (long)b * sAb + (long)h * sAh;
    const unsigned short* Bp = B + (long)z * sBz;
    long offC = (long)b * sCb + (long)h * sCh;

    int t = threadIdx.x;
    int wid = t >> 6, lane = t & 63;
    int lrow = lane & 15, kgrp = lane >> 4;
    int wm = wid * 32;

    auto stage = [&](int buf, int k0) {
#pragma unroll
        for (int r = 0; r < 2; ++r) {               // A: 128 rows x 64B
            int d = r * 4096 + t * 16;
            int row = d >> 6;
            int colb = (d & 63) ^ (((row >> 1) & 3) << 4);
            const unsigned short* srcA = Ap + (long)row * lda + k0 + (colb >> 1);
            unsigned short* dstA = smem + ((buf * 12288 + d) >> 1);
            __builtin_amdgcn_global_load_lds(
                (const __attribute__((address_space(1))) unsigned int*)srcA,
                (__attribute__((address_space(3))) unsigned int*)dstA, 16, 0, 0);
        }
        {                                            // B: 64 rows x 64B
            int d = t * 16;
            int row = d >> 6;
            int colb = (d & 63) ^ (((row >> 1) & 3) << 4);
            const unsigned short* srcB = Bp + (long)row * ldb + k0 + (colb >> 1);
            unsigned short* dstB = smem + ((buf * 12288 + 8192 + d) >> 1);
            __builtin_amdgcn_global_load_lds(
                (const __attribute__((address_space(1))) unsigned int*)srcB,
                (__attribute__((address_space(3))) unsigned int*)dstB, 16, 0, 0);
        }
    };

    f32x4 acc[2][4] = {};
    int nt = K >> 5;

    for (int p = 0; p < 4 && p < nt; ++p) stage(p, p << 5);

    for (int ti = 0; ti < nt; ++ti) {
        int cur = ti % 5;
        int rem = nt - 1 - ti;
        if (rem >= 3)      asm volatile("s_waitcnt vmcnt(9)" ::: "memory");
        else if (rem == 2) asm volatile("s_waitcnt vmcnt(6)" ::: "memory");
        else if (rem == 1) asm volatile("s_waitcnt vmcnt(3)" ::: "memory");
        else               asm volatile("s_waitcnt vmcnt(0)" ::: "memory");
        __builtin_amdgcn_sched_barrier(0);
        __builtin_amdgcn_s_barrier();
        __builtin_amdgcn_sched_barrier(0);

        if (ti + 4 < nt) stage((ti + 4) % 5, (ti + 4) << 5);

        const char* Ab = (const char*)smem + cur * 12288;
        const char* Bb = Ab + 8192;
        short8 a[2], bb[4];
#pragma unroll
        for (int i = 0; i < 2; ++i) {
            int row = wm + i * 16 + lrow;
            a[i] = *(const short8*)(Ab + row * 64 + ((kgrp * 16) ^ (((row >> 1) & 3) << 4)));
        }
#pragma unroll
        for (int j = 0; j < 4; ++j) {
            int row = j * 16 + lrow;
            bb[j] = *(const short8*)(Bb + row * 64 + ((kgrp * 16) ^ (((row >> 1) & 3) << 4)));
        }
#pragma unroll
        for (int i = 0; i < 2; ++i)
#pragma unroll
            for (int j = 0; j < 4; ++j)
                acc[i][j] = __builtin_amdgcn_mfma_f32_16x16x32_bf16(a[i], bb[j], acc[i][j], 0, 0, 0);
    }

#pragma unroll
    for (int i = 0; i < 2; ++i) {
        int rbase = wm + i * 16 + kgrp * 4;
#pragma unroll
        for (int j = 0; j < 4; ++j) {
            int c = j * 16 + lrow;
#pragma unroll
            for (int e = 0; e < 4; ++e) {
                int r = rbase + e;
                outB[offC + (long)r * ldc + c] = f2bf(acc[i][j][e]);
            }
        }
    }
}

// ------------------------------ GEMM NT (pipelined 128²) --------------------
template<bool GELU>
__global__ __launch_bounds__(256)
void k_gemm_nt(const unsigned short* __restrict__ A, const unsigned short* __restrict__ B,
               const float* __restrict__ bias, const float* __restrict__ res,
               float* __restrict__ outF, unsigned short* __restrict__ outB,
               int M, int N, int K, int lda, int ldb, int ldc,
               int H, long sAb, long sAh, long sBb, long sBh, long sCb, long sCh,
               float scale, int S, long sPart,
               unsigned short* __restrict__ vT, int vColOff, long sVz, int vLd, int rpb)
{
    __shared__ unsigned short smem[5 * 8192];

    unsigned gx = gridDim.x, gy = gridDim.y, gz = gridDim.z;
    unsigned nwg = gx * gy * gz;
    unsigned lin = (blockIdx.z * gy + blockIdx.y) * gx + blockIdx.x;
    unsigned bx = blockIdx.x, by = blockIdx.y, bz = blockIdx.z;
    if ((nwg & 7u) == 0u) {
        unsigned cpx = nwg >> 3;
        unsigned s = (lin & 7u) * cpx + (lin >> 3);
        bx = s % gx; unsigned r2 = s / gx;
        by = r2 % gy; bz = r2 / gy;
    }

    int zz = (int)bz;
    int s_k = 0;
    if (S > 1) { s_k = zz % S; zz /= S; }
    int b = zz / H, h = zz - b * H;
    const unsigned short* Ap = A + (long)b * sAb + (long)h * sAh + (long)s_k * K;
    const unsigned short* Bp = B + (long)b * sBb + (long)h * sBh + (long)s_k * K;
    float* outFp = outF;
    if (outFp && S > 1) outFp += (long)s_k * sPart;
    unsigned short* outBp = outB;
    if (outBp && S > 1) outBp += (long)s_k * sPart;
    long offC = (long)b * sCb + (long)h * sCh;

    int t    = threadIdx.x;
    int wid  = t >> 6;
    int lane = t & 63;
    int lrow = lane & 15;
    int kgrp = lane >> 4;

    int tm = by * 128;
    int tn = bx * 128;
    int wm = (wid >> 1) * 64;
    int wn = (wid & 1) * 64;

    auto stage = [&](int buf, int k0) {
#pragma unroll
        for (int r = 0; r < 2; ++r) {
            int d = r * 4096 + t * 16;
            int row = d >> 6;
            int colb = (d & 63) ^ (((row >> 1) & 3) << 4);
            int gr = tm + row; if (gr > M - 1) gr = M - 1;
            const unsigned short* srcA = Ap + (long)gr * lda + k0 + (colb >> 1);
            unsigned short* dstA = smem + ((buf * 16384 + r * 4096 + wid * 1024) >> 1);
            __builtin_amdgcn_global_load_lds(
                (const __attribute__((address_space(1))) unsigned int*)srcA,
                (__attribute__((address_space(3))) unsigned int*)dstA, 16, 0, 0);
            int gn = tn + row; if (gn > N - 1) gn = N - 1;
            const unsigned short* srcB = Bp + (long)gn * ldb + k0 + (colb >> 1);
            unsigned short* dstB = smem + ((buf * 16384 + 8192 + r * 4096 + wid * 1024) >> 1);
            __builtin_amdgcn_global_load_lds(
                (const __attribute__((address_space(1))) unsigned int*)srcB,
                (__attribute__((address_space(3))) unsigned int*)dstB, 16, 0, 0);
        }
    };

    f32x4 acc[4][4] = {};
    int nt = K >> 5;

    for (int p = 0; p < 4 && p < nt; ++p) stage(p, p << 5);

    for (int ti = 0; ti < nt; ++ti) {
        int cur = ti % 5;
        int rem = nt - 1 - ti;
        if (rem >= 3)      asm volatile("s_waitcnt vmcnt(12)" ::: "memory");
        else if (rem == 2) asm volatile("s_waitcnt vmcnt(8)"  ::: "memory");
        else if (rem == 1) asm volatile("s_waitcnt vmcnt(4)"  ::: "memory");
        else               asm volatile("s_waitcnt vmcnt(0)"  ::: "memory");
        __builtin_amdgcn_sched_barrier(0);
        __builtin_amdgcn_s_barrier();
        __builtin_amdgcn_sched_barrier(0);

        if (ti + 4 < nt) stage((ti + 4) % 5, (ti + 4) << 5);

        const char* Ab = (const char*)smem + cur * 16384;
        const char* Bb = Ab + 8192;
        short8 a[4], bb[4];
#pragma unroll
        for (int i = 0; i < 4; ++i) {
            int row = wm + i * 16 + lrow;
            a[i] = *(const short8*)(Ab + row * 64 + ((kgrp * 16) ^ (((row >> 1) & 3) << 4)));
        }
#pragma unroll
        for (int j = 0; j < 4; ++j) {
            int row = wn + j * 16 + lrow;
            bb[j] = *(const short8*)(Bb + row * 64 + ((kgrp * 16) ^ (((row >> 1) & 3) << 4)));
        }
#pragma unroll
        for (int i = 0; i < 4; ++i)
#pragma unroll
            for (int j = 0; j < 4; ++j)
                acc[i][j] = __builtin_amdgcn_mfma_f32_16x16x32_bf16(a[i], bb[j], acc[i][j], 0, 0, 0);
    }

#pragma unroll
    for (int i = 0; i < 4; ++i) {
        int rbase = tm + wm + i * 16 + kgrp * 4;
#pragma unroll
        for (int j = 0; j < 4; ++j) {
            int c = tn + wn + j * 16 + lrow;
            if (c >= N) continue;
            float bv = bias ? bias[c] : 0.0f;
            if (vT && c >= vColOff) {
                int hh = (c - vColOff) >> 6, dd = (c - vColOff) & 63;
#pragma unroll
                for (int e = 0; e < 4; ++e) {
                    int r = rbase + e;
                    if (r >= M) continue;
                    float v = acc[i][j][e] * scale + bv;
                    int bb2 = r / rpb, l = r - bb2 * rpb;
                    vT[(long)(bb2 * 16 + hh) * sVz + (long)dd * vLd + l] = f2bf(v);
                }
                continue;
            }
#pragma unroll
            for (int e = 0; e < 4; ++e) {
                int r = rbase + e;
                if (r >= M) continue;
                float v = acc[i][j][e] * scale + bv;
                long oidx = offC + (long)r * ldc + c;
                if (res) v += res[oidx];
                if (GELU) v = 0.5f * v * (1.0f + erff(v * 0.70710678118654752f));
                if (outFp) outFp[oidx] = v;
                if (outBp) outBp[oidx] = f2bf(v);
            }
        }
    }
}

// -------------------- split-K reduce (bf16 partials) -------------------------
__global__ __launch_bounds__(256)
void k_redux_b(const unsigned short* __restrict__ part, long sPart, int S,
               const float* __restrict__ bias, const float* __restrict__ res,
               float* __restrict__ outF, unsigned short* __restrict__ outB,
               long n8, int ldc8, int gelu)
{
    long i = (long)blockIdx.x * blockDim.x + threadIdx.x;
    long stride = (long)gridDim.x * blockDim.x;
    for (; i < n8; i += stride) {
        long e0 = i * 8;
        float v[8];
        short8 p0 = *(const short8*)(part + e0);
#pragma unroll
        for (int k = 0; k < 8; ++k) v[k] = bf2f((unsigned short)p0[k]);
        for (int s = 1; s < S; ++s) {
            short8 ps = *(const short8*)(part + e0 + (long)s * sPart);
#pragma unroll
            for (int k = 0; k < 8; ++k) v[k] += bf2f((unsigned short)ps[k]);
        }
        if (bias) {
            int c = (int)(i % ldc8) * 8;
            float4 b0 = *(const float4*)(bias + c);
            float4 b1 = *(const float4*)(bias + c + 4);
            v[0] += b0.x; v[1] += b0.y; v[2] += b0.z; v[3] += b0.w;
            v[4] += b1.x; v[5] += b1.y; v[6] += b1.z; v[7] += b1.w;
        }
        if (res) {
            float4 r0 = *(const float4*)(res + e0);
            float4 r1 = *(const float4*)(res + e0 + 4);
            v[0] += r0.x; v[1] += r0.y; v[2] += r0.z; v[3] += r0.w;
            v[4] += r1.x; v[5] += r1.y; v[6] += r1.z; v[7] += r1.w;
        }
        if (gelu) {
#pragma unroll
            for (int k = 0; k < 8; ++k)
                v[k] = 0.5f * v[k] * (1.0f + erff(v[k] * 0.70710678118654752f));
        }
        if (outF) {
            float4 o0 = { v[0], v[1], v[2], v[3] };
            float4 o1 = { v[4], v[5], v[6], v[7] };
            *(float4*)(outF + e0) = o0;
            *(float4*)(outF + e0 + 4) = o1;
        }
        if (outB) {
            short8 o;
#pragma unroll
            for (int k = 0; k < 8; ++k) o[k] = (short)f2bf(v[k]);
            *(short8*)(outB + e0) = o;
        }
    }
}

// ---- fused split-K(bf16) reduce + bias + residual + LayerNorm --------------
__global__ __launch_bounds__(256)
void k_redux_ln_b(const unsigned short* __restrict__ part, long sPart, int S,
                  const float* __restrict__ bias, const float* __restrict__ res,
                  const float* __restrict__ g, const float* __restrict__ bt,
                  float* __restrict__ yf, unsigned short* __restrict__ yb)
{
    int row = blockIdx.x;
    int t = threadIdx.x;
    int lane = t & 63, wid = t >> 6;
    long base = (long)row * 1024 + t * 4;

    ushort4 p0 = *(const ushort4*)(part + base);
    float v0 = bf2f(p0.x), v1 = bf2f(p0.y), v2 = bf2f(p0.z), v3 = bf2f(p0.w);
    for (int s = 1; s < S; ++s) {
        ushort4 ps = *(const ushort4*)(part + base + (long)s * sPart);
        v0 += bf2f(ps.x); v1 += bf2f(ps.y); v2 += bf2f(ps.z); v3 += bf2f(ps.w);
    }
    float4 bv = *(const float4*)(bias + t * 4);
    v0 += bv.x; v1 += bv.y; v2 += bv.z; v3 += bv.w;
    float4 rv = *(const float4*)(res + base);
    v0 += rv.x; v1 += rv.y; v2 += rv.z; v3 += rv.w;

    float s1 = v0 + v1 + v2 + v3;
    float s2 = v0 * v0 + v1 * v1 + v2 * v2 + v3 * v3;
#pragma unroll
    for (int d = 32; d > 0; d >>= 1) { s1 += __shfl_xor(s1, d, 64); s2 += __shfl_xor(s2, d, 64); }
    __shared__ float rs[4], rss[4];
    if (lane == 0) { rs[wid] = s1; rss[wid] = s2; }
    __syncthreads();
    s1 = rs[0] + rs[1] + rs[2] + rs[3];
    s2 = rss[0] + rss[1] + rss[2] + rss[3];
    float mu  = s1 * (1.0f / 1024.0f);
    float var = s2 * (1.0f / 1024.0f) - mu * mu;
    float inv = rsqrtf(var + 1e-5f);

    float4 gv = *(const float4*)(g + t * 4);
    float4 btv = *(const float4*)(bt + t * 4);
    float o0 = (v0 - mu) * inv * gv.x + btv.x;
    float o1 = (v1 - mu) * inv * gv.y + btv.y;
    float o2 = (v2 - mu) * inv * gv.z + btv.z;
    float o3 = (v3 - mu) * inv * gv.w + btv.w;
    float4 of = { o0, o1, o2, o3 };
    ushort4 ob = { f2bf(o0), f2bf(o1), f2bf(o2), f2bf(o3) };
    *(float4*)(yf + base) = of;
    *(ushort4*)(yb + base) = ob;
}

// ---------------------- tiled transpose (bf16) ------------------------------
__global__ __launch_bounds__(256)
void k_tr(const unsigned short* __restrict__ in, unsigned short* __restrict__ out,
          int R, int ldin, int ldout,
          int H, long sIb, long sIh, long sOz)
{
    __shared__ unsigned short tile[32][33];
    int z = blockIdx.z;
    int b = z / H, h = z - b * H;
    const unsigned short* ip = in + (long)b * sIb + (long)h * sIh;
    unsigned short* op = out + (long)z * sOz;
    int t = threadIdx.x;
    int cl = t & 31, rl = t >> 5;
    int c0 = blockIdx.x * 32, r0 = blockIdx.y * 32;
#pragma unroll
    for (int i = 0; i < 4; ++i) {
        int r = r0 + rl + i * 8;
        unsigned short v = 0;
        if (r < R) v = ip[(long)r * ldin + (c0 + cl)];
        tile[rl + i * 8][cl] = v;
    }
    __syncthreads();
#pragma unroll
    for (int i = 0; i < 4; ++i) {
        int orow = c0 + rl + i * 8;
        int ocol = r0 + cl;
        op[(long)orow * ldout + ocol] = tile[cl][rl + i * 8];
    }
}

// --------------------- wave-per-row masked softmax ---------------------------
__global__ __launch_bounds__(256)
void k_softmax_w(const float* __restrict__ sc, long sPart, int S,
                 unsigned short* __restrict__ P,
                 const int* __restrict__ mask, int L, int Lpad,
                 int ld_sc, int ld_p, int rows_per_batch, int nrows)
{
    int gw = (int)((blockIdx.x * 256 + threadIdx.x) >> 6);
    if (gw >= nrows) return;
    int lane = threadIdx.x & 63;
    int b = gw / rows_per_batch;
    const float* p = sc + (long)gw * ld_sc;
    unsigned short* po = P + (long)gw * ld_p;
    const int* mrow = mask + (long)b * L;

    int nch = (Lpad + 255) >> 8;     // 1 or 2
    float v[2][4];
    float mx = -INFINITY;
#pragma unroll
    for (int c = 0; c < 2; ++c) {
        if (c >= nch) { v[c][0]=v[c][1]=v[c][2]=v[c][3] = -INFINITY; continue; }
        int j = c * 256 + lane * 4;
        if (j < L) {
            float4 x = *(const float4*)(p + j);
            for (int s = 1; s < S; ++s) {
                float4 y = *(const float4*)(p + j + (long)s * sPart);
                x.x += y.x; x.y += y.y; x.z += y.z; x.w += y.w;
            }
            int4 m = *(const int4*)(mrow + j);
            v[c][0] = m.x ? x.x : -INFINITY;
            v[c][1] = m.y ? x.y : -INFINITY;
            v[c][2] = m.z ? x.z : -INFINITY;
            v[c][3] = m.w ? x.w : -INFINITY;
        } else {
            v[c][0]=v[c][1]=v[c][2]=v[c][3] = -INFINITY;
        }
        mx = fmaxf(mx, fmaxf(fmaxf(v[c][0], v[c][1]), fmaxf(v[c][2], v[c][3])));
    }
#pragma unroll
    for (int d = 32; d > 0; d >>= 1) mx = fmaxf(mx, __shfl_xor(mx, d, 64));

    float sum = 0.f;
#pragma unroll
    for (int c = 0; c < 2; ++c)
#pragma unroll
        for (int k = 0; k < 4; ++k) {
            float e = (v[c][k] == -INFINITY) ? 0.0f : __expf(v[c][k] - mx);
            v[c][k] = e;
            sum += e;
        }
#pragma unroll
    for (int d = 32; d > 0; d >>= 1) sum += __shfl_xor(sum, d, 64);
    float inv = 1.0f / sum;

#pragma unroll
    for (int c = 0; c < 2; ++c) {
        if (c >= nch) continue;
        int j = c * 256 + lane * 4;
        if (j < Lpad) {
            ushort4 o;
            o.x = f2bf(v[c][0] * inv);
            o.y = f2bf(v[c][1] * inv);
            o.z = f2bf(v[c][2] * inv);
            o.w = f2bf(v[c][3] * inv);
            *(ushort4*)(po + j) = o;
        }
    }
}

// ---------------- combine (bf16 partial aggs) -------------------------------
__global__ void k_combine_b(float* __restrict__ qf, unsigned short* __restrict__ qb,
                            const unsigned short* __restrict__ aggtp,
                            const unsigned short* __restrict__ aggrp,
                            const float* __restrict__ alpha, long n4, long sPart, int S)
{
    float a = *alpha;
    long i = (long)blockIdx.x * blockDim.x + threadIdx.x;
    long stride = (long)gridDim.x * blockDim.x;
    for (; i < n4; i += stride) {
        long e0 = i * 4;
        float st[4] = {0.f, 0.f, 0.f, 0.f}, sr[4] = {0.f, 0.f, 0.f, 0.f};
        for (int s = 0; s < S; ++s) {
            ushort4 pt = *(const ushort4*)(aggtp + e0 + (long)s * sPart);
            ushort4 pr = *(const ushort4*)(aggrp + e0 + (long)s * sPart);
            st[0] += bf2f(pt.x); st[1] += bf2f(pt.y); st[2] += bf2f(pt.z); st[3] += bf2f(pt.w);
            sr[0] += bf2f(pr.x); sr[1] += bf2f(pr.y); sr[2] += bf2f(pr.z); sr[3] += bf2f(pr.w);
        }
        float4 q = *(const float4*)(qf + e0);
        float v0 = q.x + a * sr[0] + (1.0f - a) * st[0];
        float v1 = q.y + a * sr[1] + (1.0f - a) * st[1];
        float v2 = q.z + a * sr[2] + (1.0f - a) * st[2];
        float v3 = q.w + a * sr[3] + (1.0f - a) * st[3];
        float4 of = { v0, v1, v2, v3 };
        ushort4 ob = { f2bf(v0), f2bf(v1), f2bf(v2), f2bf(v3) };
        *(float4*)(qf + e0) = of;
        *(ushort4*)(qb + e0) = ob;
    }
}

// ---------------------------------------------------------------------------
extern "C" void kernel_launch(void* const* d_in, const int* in_sizes, int n_in,
                              void* d_out, int out_size, void* d_ws, size_t ws_size,
                              hipStream_t stream)
{
    const float* queries = (const float*)d_in[0];
    const float* text    = (const float*)d_in[1];
    const float* region  = (const float*)d_in[2];
    const int*   tmask   = (const int*)d_in[3];
    const int*   rmask   = (const int*)d_in[4];
    const float* w_qkv_t = (const float*)d_in[5];
    const float* b_qkv_t = (const float*)d_in[6];
    const float* w_o_t   = (const float*)d_in[7];
    const float* b_o_t   = (const float*)d_in[8];
    const float* w_qkv_r = (const float*)d_in[9];
    const float* b_qkv_r = (const float*)d_in[10];
    const float* w_o_r   = (const float*)d_in[11];
    const float* b_o_r   = (const float*)d_in[12];
    const float* ln_g    = (const float*)d_in[13];
    const float* ln_b    = (const float*)d_in[14];
    const float* w1      = (const float*)d_in[15];
    const float* b1      = (const float*)d_in[16];
    const float* w2      = (const float*)d_in[17];
    const float* b2      = (const float*)d_in[18];
    const float* alpha   = (const float*)d_in[19];

    const int Bn = 16, NQ = 128, LT = 512, LR = 196, D = 1024, H = 16;
    const int LRp = 256;
    const int MQ = Bn * NQ;              // 2048
    const int MT = Bn * LT;              // 8192
    const int MR = Bn * LR;              // 3136

    char* ws = (char*)d_ws;
    size_t off = 0;
    auto alloc = [&](size_t bytes) -> void* {
        void* p = ws + off;
        off = (off + bytes + 255) & ~(size_t)255;
        return p;
    };
    unsigned short* qb     = (unsigned short*)alloc((size_t)MQ * D * 2);
    unsigned short* tb     = (unsigned short*)alloc((size_t)MT * D * 2);
    unsigned short* rb     = (unsigned short*)alloc((size_t)MR * D * 2);
    unsigned short* wqkvtb = (unsigned short*)alloc((size_t)3 * D * D * 2);
    unsigned short* wotb   = (unsigned short*)alloc((size_t)D * D * 2);
    unsigned short* wqkvrb = (unsigned short*)alloc((size_t)3 * D * D * 2);
    unsigned short* worb   = (unsigned short*)alloc((size_t)D * D * 2);
    unsigned short* w1b    = (unsigned short*)alloc((size_t)4 * D * D * 2);
    unsigned short* w2b    = (unsigned short*)alloc((size_t)4 * D * D * 2);
    unsigned short* ktv    = (unsigned short*)alloc((size_t)MT * 2 * D * 2);
    unsigned short* krv    = (unsigned short*)alloc((size_t)MR * 2 * D * 2);
    unsigned short* vtT    = (unsigned short*)alloc((size_t)Bn * H * 64 * LT * 2);
    unsigned short* vrT    = (unsigned short*)alloc((size_t)Bn * H * 64 * LRp * 2);
    unsigned short* qp     = (unsigned short*)alloc((size_t)MQ * D * 2);
    unsigned short* ao     = (unsigned short*)alloc((size_t)MQ * D * 2);
    unsigned short* qlnb   = (unsigned short*)alloc((size_t)MQ * D * 2);
    float* qlf  = (float*)alloc((size_t)MQ * D * 4);
    float* sc   = (float*)alloc((size_t)Bn * H * NQ * LT * 4);   // 67MB arena
    if (off > ws_size) return;

    // phase-reused views
    unsigned short* tbT = ktv;                               // [B][1024][512]
    unsigned short* rbT = ktv + (size_t)Bn * D * LT;         // [B][1024][256p]
    float* sct = sc;
    float* scr = sc;
    unsigned short* Pt = (unsigned short*)sc;
    unsigned short* Pr = (unsigned short*)(sc + 1 * 1048576);
    float* atp   = sc + 2 * 1048576;
    float* arp   = sc + 6 * 1048576;
    unsigned short* aggtp_b = (unsigned short*)((char*)sc + (size_t)32 * 1048576);
    unsigned short* aggrp_b = (unsigned short*)((char*)sc + (size_t)48 * 1048576);
    unsigned short* hb = (unsigned short*)sc;
    unsigned short* part_qb  = (unsigned short*)sc;
    unsigned short* part_f1b = ktv;
    unsigned short* part_f2b = ktv;

    const long PQ = (long)MQ * D;

    // ---- all converts in one balanced launch ----
    {
        CvtPack pk;
        const float* srcs[9] = { queries, text, region, w_qkv_t, w_o_t, w_qkv_r, w_o_r, w1, w2 };
        unsigned short* dsts[9] = { qb, tb, rb, wqkvtb, wotb, wqkvrb, worb, w1b, w2b };
        long ns[9] = { (long)MQ * D, (long)MT * D, (long)MR * D, (long)3 * D * D,
                       (long)D * D, (long)3 * D * D, (long)D * D, (long)4 * D * D,
                       (long)4 * D * D };
        long acc16 = 0;
        pk.start16[0] = 0;
        for (int i = 0; i < 9; ++i) {
            pk.src[i] = srcs[i]; pk.dst[i] = dsts[i];
            acc16 += ns[i] / 16;
            pk.start16[i + 1] = acc16;
        }
        k_cvt_multi<<<2048, 256, 0, stream>>>(pk, acc16);
    }

    auto NT = [&](const unsigned short* A, const unsigned short* Bm, const float* bias,
                  const float* res, float* oF, unsigned short* oB,
                  int M, int N, int K, int lda, int ldb, int ldc,
                  int Hh, long sAb, long sAh, long sBb, long sBh, long sCb, long sCh,
                  int batch, float scale, bool gelu, int S = 1, long sPart = 0,
                  unsigned short* vT = nullptr, int vColOff = 0, long sVz = 0,
                  int vLd = 0, int rpb = 1) {
        dim3 g((N + 127) / 128, (M + 127) / 128, batch * S);
        if (gelu)
            k_gemm_nt<true><<<g, 256, 0, stream>>>(A, Bm, bias, res, oF, oB, M, N, K,
                lda, ldb, ldc, Hh, sAb, sAh, sBb, sBh, sCb, sCh, scale, S, sPart,
                vT, vColOff, sVz, vLd, rpb);
        else
            k_gemm_nt<false><<<g, 256, 0, stream>>>(A, Bm, bias, res, oF, oB, M, N, K,
                lda, ldb, ldc, Hh, sAb, sAh, sBb, sBh, sCb, sCh, scale, S, sPart,
                vT, vColOff, sVz, vLd, rpb);
    };
    auto NT256 = [&](const unsigned short* A, const unsigned short* Bm, const float* bias,
                     float* oF, unsigned short* oB, int M, int N, int Kc,
                     int lda, int ldb, int ldc, int S, long sPart,
                     unsigned short* vT = nullptr, int vColOff = 0, long sVz = 0,
                     int vLd = 0) {
        dim3 g((N + 255) / 256, (M + 255) / 256, S);
        k_gemm_nt256<<<g, 1024, 0, stream>>>(A, Bm, bias, oF, oB, M, N, Kc,
                                             lda, ldb, ldc, sPart, vT, vColOff, sVz, vLd);
    };
    auto REDUXB = [&](const unsigned short* part, long sPart, int S, const float* bias,
                      const float* res, float* oF, unsigned short* oB,
                      long total, int ldc, int gelu) {
        long n8 = total / 8;
        int blocks = (int)((n8 + 255) / 256);
        if (blocks > 2048) blocks = 2048;
        k_redux_b<<<blocks, 256, 0, stream>>>(part, sPart, S, bias, res, oF, oB,
                                              n8, ldc / 8, gelu);
    };
    auto SMAX = [&](const float* scp, long sPart, int S, unsigned short* P,
                    const int* mask, int L, int Lpad, int ld_sc, int ld_p,
                    int rpb, int nrows) {
        int blocks = (nrows + 3) / 4;
        k_softmax_w<<<blocks, 256, 0, stream>>>(scp, sPart, S, P, mask, L, Lpad,
                                                ld_sc, ld_p, rpb, nrows);
    };

    // ---- fused K+V projections (V written directly transposed) ----
    NT256(tb, wqkvtb + (long)D * D, b_qkv_t + D, nullptr, ktv,
          MT, 2 * D, D, D, D, 2 * D, 1, 0,
          vtT, D, (long)64 * LT, LT);
    NT(rb, wqkvrb + (long)D * D, b_qkv_r + D, nullptr, nullptr, krv,
       MR, 2 * D, D, D, D, 2 * D, 1,0,0,0,0,0,0, 1, 1.0f, false, 1, 0,
       vrT, D, (long)64 * LRp, LRp, LR);

    // ================= MHA 1 (text) =================
    NT(qb, wqkvtb, nullptr, nullptr, nullptr, part_qb, MQ, D, 512, D, D, D,
       1,0,0,0,0,0,0, 1, 1.0f, false, 2, PQ);
    REDUXB(part_qb, PQ, 2, b_qkv_t, nullptr, nullptr, qp, PQ, D, 0);
    NT(qp, ktv, nullptr, nullptr, sct, nullptr, NQ, LT, 64, D, 2 * D, LT,
       H, (long)NQ * D, 64, (long)LT * 2 * D, 64, (long)H * NQ * LT, (long)NQ * LT,
       Bn * H, 0.125f, false);
    SMAX(sct, 0, 1, (unsigned short*)sct, tmask, LT, LT, LT, 2 * LT,
         H * NQ, Bn * H * NQ);
    k_gemm_pv<<<dim3(1, 1, Bn * H), 256, 0, stream>>>(
        (const unsigned short*)sct, vtT, ao, LT, 2 * LT, LT, D,
        H, (long)H * NQ * 2 * LT, (long)NQ * 2 * LT, (long)64 * LT,
        (long)NQ * D, 64);
    NT(ao, wotb, nullptr, nullptr, nullptr, part_qb, MQ, D, 512, D, D, D,
       1,0,0,0,0,0,0, 1, 1.0f, false, 2, PQ);
    k_redux_ln_b<<<MQ, 256, 0, stream>>>(part_qb, PQ, 2, b_o_t, queries,
                                         ln_g, ln_b, qlf, qlnb);

    // ================= MHA 2 (region) =================
    NT(qlnb, wqkvrb, nullptr, nullptr, nullptr, part_qb, MQ, D, 512, D, D, D,
       1,0,0,0,0,0,0, 1, 1.0f, false, 2, PQ);
    REDUXB(part_qb, PQ, 2, b_qkv_r, nullptr, nullptr, qp, PQ, D, 0);
    NT(qp, krv, nullptr, nullptr, scr, nullptr, NQ, LR, 64, D, 2 * D, LRp,
       H, (long)NQ * D, 64, (long)LR * 2 * D, 64, (long)H * NQ * LRp, (long)NQ * LRp,
       Bn * H, 0.125f, false);
    SMAX(scr, 0, 1, (unsigned short*)scr, rmask, LR, LRp, LRp, 2 * LRp,
         H * NQ, Bn * H * NQ);
    k_gemm_pv<<<dim3(1, 1, Bn * H), 256, 0, stream>>>(
        (const unsigned short*)scr, vrT, ao, LRp, 2 * LRp, LRp, D,
        H, (long)H * NQ * 2 * LRp, (long)NQ * 2 * LRp, (long)64 * LRp,
        (long)NQ * D, 64);
    NT(ao, worb, nullptr, nullptr, nullptr, part_qb, MQ, D, 512, D, D, D,
       1,0,0,0,0,0,0, 1, 1.0f, false, 2, PQ);
    k_redux_ln_b<<<MQ, 256, 0, stream>>>(part_qb, PQ, 2, b_o_r, qlf,
                                         ln_g, ln_b, qlf, qlnb);

    // ================= manual masked cross-attention =================
    {
        dim3 g1(D / 32, LT / 32, Bn);
        k_tr<<<g1, 256, 0, stream>>>(tb, tbT, LT, D, LT, 1, (long)LT * D, 0, (long)D * LT);
        dim3 g2(D / 32, LRp / 32, Bn);
        k_tr<<<g2, 256, 0, stream>>>(rb, rbT, LR, D, LRp, 1, (long)LR * D, 0, (long)D * LRp);
    }
    NT(qlnb, tb, nullptr, nullptr, atp, nullptr, NQ, LT, 256, D, D, LT,
       1, (long)NQ * D, 0, (long)LT * D, 0, (long)NQ * LT, 0, Bn, 0.03125f, false,
       4, (long)Bn * NQ * LT);
    SMAX(atp, (long)Bn * NQ * LT, 4, Pt, tmask, LT, LT, LT, LT, NQ, Bn * NQ);
    NT(Pt, tbT, nullptr, nullptr, nullptr, aggtp_b, NQ, D, 256, LT, LT, D,
       1, (long)NQ * LT, 0, (long)D * LT, 0, (long)NQ * D, 0, Bn, 1.0f, false,
       2, PQ);
    NT(qlnb, rb, nullptr, nullptr, arp, nullptr, NQ, LR, 256, D, D, LRp,
       1, (long)NQ * D, 0, (long)LR * D, 0, (long)NQ * LRp, 0, Bn, 0.03125f, false,
       4, (long)Bn * NQ * LRp);
    SMAX(arp, (long)Bn * NQ * LRp, 4, Pr, rmask, LR, LRp, LRp, LRp, NQ, Bn * NQ);
    NT(Pr, rbT, nullptr, nullptr, nullptr, aggrp_b, NQ, D, 128, LRp, LRp, D,
       1, (long)NQ * LRp, 0, (long)D * LRp, 0, (long)NQ * D, 0, Bn, 1.0f, false,
       2, PQ);

    k_combine_b<<<2048, 256, 0, stream>>>(qlf, qlnb, aggtp_b, aggrp_b, alpha,
                                          (long)MQ * D / 4, PQ, 2);

    // ================= FFN =================
    NT256(qlnb, w1b, nullptr, nullptr, part_f1b, MQ, 4 * D, 512,
          D, D, 4 * D, 2, (long)MQ * 4 * D);
    REDUXB(part_f1b, (long)MQ * 4 * D, 2, b1, nullptr, nullptr, hb,
           (long)MQ * 4 * D, 4 * D, 1);
    NT256(hb, w2b, nullptr, nullptr, part_f2b, MQ, D, 512,
          4 * D, 4 * D, D, 8, PQ);
    REDUXB(part_f2b, PQ, 8, b2, qlf, (float*)d_out, nullptr, PQ, D, 0);
}